// Round 1
// baseline (11472.021 us; speedup 1.0000x reference)
//
#include <hip/hip_runtime.h>
#include <math.h>

#define NL 6
#define NH 12
#define NE 768
#define NHS 64
#define NT 1024
#define NB 2
#define NV 32000
#define NM (NB * NT)   // 2048
#define LN_EPS 1e-5f

// ---------------- embedding: x[b,t,:] = tok_emb[idx[b,t],:] + pos_emb[t,:] ----------------
__global__ void embed_kernel(const int* __restrict__ idx, const float* __restrict__ tok,
                             const float* __restrict__ pos, float* __restrict__ x) {
    int row = blockIdx.x;            // 0..NM-1
    int t = row % NT;
    int id = idx[row];
    const float* te = tok + (long)id * NE;
    const float* pe = pos + (long)t * NE;
    float* xr = x + (long)row * NE;
    for (int e = threadIdx.x; e < NE; e += blockDim.x)
        xr[e] = te[e] + pe[e];
}

// ---------------- layernorm per row ----------------
__global__ void ln_kernel(const float* __restrict__ x, const float* __restrict__ g,
                          const float* __restrict__ b, float* __restrict__ out) {
    __shared__ float red[256];
    int row = blockIdx.x;
    const float* xr = x + (long)row * NE;
    float* outr = out + (long)row * NE;
    int tid = threadIdx.x;

    float s = 0.f;
    for (int e = tid; e < NE; e += 256) s += xr[e];
    red[tid] = s; __syncthreads();
    for (int o = 128; o > 0; o >>= 1) { if (tid < o) red[tid] += red[tid + o]; __syncthreads(); }
    float mu = red[0] / NE;
    __syncthreads();

    float v = 0.f;
    for (int e = tid; e < NE; e += 256) { float d = xr[e] - mu; v += d * d; }
    red[tid] = v; __syncthreads();
    for (int o = 128; o > 0; o >>= 1) { if (tid < o) red[tid] += red[tid + o]; __syncthreads(); }
    float rstd = rsqrtf(red[0] / NE + LN_EPS);

    for (int e = tid; e < NE; e += 256)
        outr[e] = (xr[e] - mu) * rstd * g[e] + b[e];
}

// ---------------- tiled fp32 GEMM: C[M,N] = A[M,K] @ W[K,N] (+bias) (+relu) ----------------
// BM=BN=64, BK=16, 256 threads, 4x4 per thread. All dims divide evenly for our shapes.
template<bool RELU, bool BIAS>
__global__ __launch_bounds__(256) void gemm_kernel(const float* __restrict__ A,
                                                   const float* __restrict__ W,
                                                   const float* __restrict__ bias,
                                                   float* __restrict__ C,
                                                   int N, int K) {
    __shared__ float As[16][65];   // [kk][m], +1 pad to break bank conflicts
    __shared__ float Bs[16][64];   // [kk][n]
    int tid = threadIdx.x;
    int tx = tid & 15, ty = tid >> 4;
    int n0 = blockIdx.x * 64;
    int m0 = blockIdx.y * 64;
    float c[4][4] = {};

    for (int k0 = 0; k0 < K; k0 += 16) {
        #pragma unroll
        for (int i = 0; i < 4; ++i) {
            int e = tid + i * 256;
            int m  = e >> 4, kk  = e & 15;
            As[kk][m] = A[(long)(m0 + m) * K + k0 + kk];
            int kk2 = e >> 6, n   = e & 63;
            Bs[kk2][n] = W[(long)(k0 + kk2) * N + n0 + n];
        }
        __syncthreads();
        #pragma unroll
        for (int kk = 0; kk < 16; ++kk) {
            float a4[4], b4[4];
            #pragma unroll
            for (int i = 0; i < 4; ++i) a4[i] = As[kk][ty * 4 + i];
            #pragma unroll
            for (int j = 0; j < 4; ++j) b4[j] = Bs[kk][tx * 4 + j];
            #pragma unroll
            for (int i = 0; i < 4; ++i)
                #pragma unroll
                for (int j = 0; j < 4; ++j)
                    c[i][j] = fmaf(a4[i], b4[j], c[i][j]);
        }
        __syncthreads();
    }

    #pragma unroll
    for (int i = 0; i < 4; ++i) {
        int m = m0 + ty * 4 + i;
        #pragma unroll
        for (int j = 0; j < 4; ++j) {
            int n = n0 + tx * 4 + j;
            float val = c[i][j];
            if (BIAS) val += bias[n];
            if (RELU) val = fmaxf(val, 0.f);
            C[(long)m * N + n] = val;
        }
    }
}

// ---------------- causal attention, one block per (b,h,q) row ----------------
// q,k,v layout: [B,T,E] with head h at columns h*NHS..h*NHS+63
__global__ __launch_bounds__(256) void attn_kernel(const float* __restrict__ q,
                                                   const float* __restrict__ k,
                                                   const float* __restrict__ v,
                                                   float* __restrict__ out) {
    __shared__ float qs[NHS];
    __shared__ float sc[NT];
    __shared__ float red[256];
    __shared__ float pr[4][NHS];
    int qi = blockIdx.x;            // 0..NT-1
    int bh = blockIdx.y;            // 0..NB*NH-1
    int b = bh / NH, h = bh % NH;
    int tid = threadIdx.x;
    const float scale = 1.0f / sqrtf((float)NE);   // NOTE: reference scales by E^-0.5
    long base = (long)b * NT * NE + (long)h * NHS;

    if (tid < NHS) qs[tid] = q[base + (long)qi * NE + tid];
    __syncthreads();

    int nk = qi + 1;                // causal: keys 0..qi
    float lmax = -INFINITY;
    for (int j = tid; j < nk; j += 256) {
        const float* kr = k + base + (long)j * NE;
        float s = 0.f;
        #pragma unroll
        for (int d = 0; d < NHS; ++d) s = fmaf(qs[d], kr[d], s);
        s *= scale;
        sc[j] = s;
        lmax = fmaxf(lmax, s);
    }
    red[tid] = lmax; __syncthreads();
    for (int o = 128; o > 0; o >>= 1) { if (tid < o) red[tid] = fmaxf(red[tid], red[tid + o]); __syncthreads(); }
    float mx = red[0];
    __syncthreads();

    float lsum = 0.f;
    for (int j = tid; j < nk; j += 256) {
        float e = expf(sc[j] - mx);
        sc[j] = e;
        lsum += e;
    }
    red[tid] = lsum; __syncthreads();
    for (int o = 128; o > 0; o >>= 1) { if (tid < o) red[tid] += red[tid + o]; __syncthreads(); }
    float Z = red[0];
    __syncthreads();

    // out[d] = sum_j sc[j] * v[j,d] / Z, split j over 4 groups of 64 lanes
    int g = tid >> 6;
    int d = tid & 63;
    float acc = 0.f;
    for (int j = g; j < nk; j += 4)
        acc = fmaf(sc[j], v[base + (long)j * NE + d], acc);
    pr[g][d] = acc;
    __syncthreads();
    if (tid < NHS)
        out[base + (long)qi * NE + tid] = (pr[0][tid] + pr[1][tid] + pr[2][tid] + pr[3][tid]) / Z;
}

// ---------------- residual add ----------------
__global__ void add_kernel(float* __restrict__ x, const float* __restrict__ y, int n) {
    int i = blockIdx.x * blockDim.x + threadIdx.x;
    if (i < n) x[i] += y[i];
}

// ---------------- per-row NLL over vocab ----------------
__global__ __launch_bounds__(256) void nll_kernel(const float* __restrict__ logits,
                                                  const int* __restrict__ targets,
                                                  float* __restrict__ nll) {
    __shared__ float red[256];
    int row = blockIdx.x;
    const float* lr = logits + (long)row * NV;
    int tid = threadIdx.x;

    float lmax = -INFINITY;
    for (int i = tid; i < NV; i += 256) lmax = fmaxf(lmax, lr[i]);
    red[tid] = lmax; __syncthreads();
    for (int o = 128; o > 0; o >>= 1) { if (tid < o) red[tid] = fmaxf(red[tid], red[tid + o]); __syncthreads(); }
    float mx = red[0];
    __syncthreads();

    float ls = 0.f;
    for (int i = tid; i < NV; i += 256) ls += expf(lr[i] - mx);
    red[tid] = ls; __syncthreads();
    for (int o = 128; o > 0; o >>= 1) { if (tid < o) red[tid] += red[tid + o]; __syncthreads(); }
    if (tid == 0) {
        float Z = red[0];
        int tgt = targets[row];
        nll[row] = -(lr[tgt] - mx - logf(Z));
    }
}

__global__ void loss_reduce_kernel(const float* __restrict__ nll, float* __restrict__ out) {
    __shared__ float red[256];
    int tid = threadIdx.x;
    float s = 0.f;
    for (int i = tid; i < NM; i += 256) s += nll[i];
    red[tid] = s; __syncthreads();
    for (int o = 128; o > 0; o >>= 1) { if (tid < o) red[tid] += red[tid + o]; __syncthreads(); }
    if (tid == 0) out[0] = red[0] / NM;
}

extern "C" void kernel_launch(void* const* d_in, const int* in_sizes, int n_in,
                              void* d_out, int out_size, void* d_ws, size_t ws_size,
                              hipStream_t stream) {
    const int*   idx     = (const int*)  d_in[0];
    const int*   targets = (const int*)  d_in[1];
    const float* tok     = (const float*)d_in[2];
    const float* pos     = (const float*)d_in[3];
    const float* ln1_g   = (const float*)d_in[4];
    const float* ln1_b   = (const float*)d_in[5];
    const float* wq      = (const float*)d_in[6];
    const float* wk      = (const float*)d_in[7];
    const float* wv      = (const float*)d_in[8];
    const float* wproj   = (const float*)d_in[9];
    const float* bproj   = (const float*)d_in[10];
    const float* ln2_g   = (const float*)d_in[11];
    const float* ln2_b   = (const float*)d_in[12];
    const float* w1      = (const float*)d_in[13];
    const float* b1      = (const float*)d_in[14];
    const float* w2      = (const float*)d_in[15];
    const float* b2      = (const float*)d_in[16];
    const float* lnf_g   = (const float*)d_in[17];
    const float* lnf_b   = (const float*)d_in[18];
    const float* lm_w    = (const float*)d_in[19];
    const float* lm_b    = (const float*)d_in[20];

    float* logits = (float*)d_out;
    float* loss   = logits + (long)NM * NV;

    float* ws  = (float*)d_ws;
    float* x    = ws;  ws += (long)NM * NE;
    float* hbuf = ws;  ws += (long)NM * NE;
    float* qb   = ws;  ws += (long)NM * NE;
    float* kb   = ws;  ws += (long)NM * NE;
    float* vb   = ws;  ws += (long)NM * NE;
    float* att  = ws;  ws += (long)NM * NE;
    float* tmp  = ws;  ws += (long)NM * NE;
    float* hid  = ws;  ws += (long)NM * 4 * NE;
    float* nll  = ws;  ws += NM;

    dim3 blk(256);
    embed_kernel<<<NM, blk, 0, stream>>>(idx, tok, pos, x);

    for (int l = 0; l < NL; ++l) {
        ln_kernel<<<NM, blk, 0, stream>>>(x, ln1_g + l * NE, ln1_b + l * NE, hbuf);
        dim3 gEE(NE / 64, NM / 64);
        gemm_kernel<false, false><<<gEE, blk, 0, stream>>>(hbuf, wq + (long)l * NE * NE, nullptr, qb, NE, NE);
        gemm_kernel<false, false><<<gEE, blk, 0, stream>>>(hbuf, wk + (long)l * NE * NE, nullptr, kb, NE, NE);
        gemm_kernel<false, false><<<gEE, blk, 0, stream>>>(hbuf, wv + (long)l * NE * NE, nullptr, vb, NE, NE);
        attn_kernel<<<dim3(NT, NB * NH), blk, 0, stream>>>(qb, kb, vb, att);
        // proj applied TWICE (faithful to reference)
        gemm_kernel<false, true><<<gEE, blk, 0, stream>>>(att, wproj + (long)l * NE * NE, bproj + l * NE, tmp, NE, NE);
        gemm_kernel<false, true><<<gEE, blk, 0, stream>>>(tmp, wproj + (long)l * NE * NE, bproj + l * NE, att, NE, NE);
        add_kernel<<<(NM * NE + 255) / 256, blk, 0, stream>>>(x, att, NM * NE);

        ln_kernel<<<NM, blk, 0, stream>>>(x, ln2_g + l * NE, ln2_b + l * NE, hbuf);
        gemm_kernel<true, true><<<dim3(4 * NE / 64, NM / 64), blk, 0, stream>>>(
            hbuf, w1 + (long)l * NE * 4 * NE, b1 + l * 4 * NE, hid, 4 * NE, NE);
        gemm_kernel<false, true><<<dim3(NE / 64, NM / 64), blk, 0, stream>>>(
            hid, w2 + (long)l * 4 * NE * NE, b2 + l * NE, tmp, NE, 4 * NE);
        add_kernel<<<(NM * NE + 255) / 256, blk, 0, stream>>>(x, tmp, NM * NE);
    }

    ln_kernel<<<NM, blk, 0, stream>>>(x, lnf_g, lnf_b, hbuf);
    gemm_kernel<false, true><<<dim3(NV / 64, NM / 64), blk, 0, stream>>>(hbuf, lm_w, lm_b, logits, NV, NE);
    nll_kernel<<<NM, blk, 0, stream>>>(logits, targets, nll);
    loss_reduce_kernel<<<1, blk, 0, stream>>>(nll, loss);
}

// Round 2
// 4769.292 us; speedup vs baseline: 2.4054x; 2.4054x over previous
//
#include <hip/hip_runtime.h>
#include <math.h>

#define NL 6
#define NH 12
#define NE 768
#define NHS 64
#define NT 1024
#define NB 2
#define NV 32000
#define NM (NB * NT)   // 2048
#define NQKV (3 * NE)  // 2304
#define NFF (4 * NE)   // 3072
#define LN_EPS 1e-5f

typedef __attribute__((ext_vector_type(8))) short short8;
typedef __attribute__((ext_vector_type(4))) float f32x4;
typedef __attribute__((address_space(1))) const unsigned int as1_cuint;
typedef __attribute__((address_space(3))) unsigned int as3_uint;

__device__ __forceinline__ unsigned short f2bf(float f) {
    unsigned int u = __builtin_bit_cast(unsigned int, f);
    u += 0x7fffu + ((u >> 16) & 1u);   // RNE
    return (unsigned short)(u >> 16);
}
__device__ __forceinline__ float bf2f(unsigned short u) {
    unsigned int v = ((unsigned int)u) << 16;
    return __builtin_bit_cast(float, v);
}
__device__ __forceinline__ void gload_lds16(const void* g, void* l) {
    __builtin_amdgcn_global_load_lds((as1_cuint*)g, (as3_uint*)l, 16, 0, 0);
}

// ---------------- embedding ----------------
__global__ void embed_kernel(const int* __restrict__ idx, const float* __restrict__ tok,
                             const float* __restrict__ pos, float* __restrict__ x) {
    int row = blockIdx.x;
    int t = row % NT;
    int id = idx[row];
    const float* te = tok + (long)id * NE;
    const float* pe = pos + (long)t * NE;
    float* xr = x + (long)row * NE;
    for (int e = threadIdx.x; e < NE; e += blockDim.x)
        xr[e] = te[e] + pe[e];
}

// ---------------- layernorm per row: fp32 in, bf16 out ----------------
__global__ __launch_bounds__(256) void ln_kernel(const float* __restrict__ x, const float* __restrict__ g,
                                                 const float* __restrict__ b, unsigned short* __restrict__ out) {
    __shared__ float red[256];
    int row = blockIdx.x;
    const float* xr = x + (long)row * NE;
    unsigned short* outr = out + (long)row * NE;
    int tid = threadIdx.x;

    float s = 0.f;
    for (int e = tid; e < NE; e += 256) s += xr[e];
    red[tid] = s; __syncthreads();
    for (int o = 128; o > 0; o >>= 1) { if (tid < o) red[tid] += red[tid + o]; __syncthreads(); }
    float mu = red[0] / NE;
    __syncthreads();

    float v = 0.f;
    for (int e = tid; e < NE; e += 256) { float d = xr[e] - mu; v += d * d; }
    red[tid] = v; __syncthreads();
    for (int o = 128; o > 0; o >>= 1) { if (tid < o) red[tid] += red[tid + o]; __syncthreads(); }
    float rstd = rsqrtf(red[0] / NE + LN_EPS);

    for (int e = tid; e < NE; e += 256)
        outr[e] = f2bf((xr[e] - mu) * rstd * g[e] + b[e]);
}

// ---------------- tiled transpose + fp32->bf16 cast: WT[n][k] = W[k][n] ----------------
__global__ __launch_bounds__(256) void transpose_cast_kernel(const float* __restrict__ W,
                                                             unsigned short* __restrict__ WT,
                                                             int K, int N) {
    __shared__ float t[32][33];
    int k0 = blockIdx.y * 32;
    int n0 = blockIdx.x * 32;
    int c = threadIdx.x & 31, r = threadIdx.x >> 5;
    #pragma unroll
    for (int p = 0; p < 4; ++p)
        t[r + p * 8][c] = W[(long)(k0 + r + p * 8) * N + n0 + c];
    __syncthreads();
    #pragma unroll
    for (int p = 0; p < 4; ++p)
        WT[(long)(n0 + r + p * 8) * K + k0 + c] = f2bf(t[c][r + p * 8]);
}

// ---------------- bf16 MFMA GEMM: C[M,N] = A[M,K] @ BT[N,K]^T (+bias)(+relu) ----------------
// 128x128 tile, BK=32, 256 threads = 4 waves (2x2), 4x4 16x16 fragments per wave.
template<typename OutT, bool BIAS, bool RELU>
__global__ __launch_bounds__(256) void gemm_mfma(const unsigned short* __restrict__ A,
                                                 const unsigned short* __restrict__ BT,
                                                 const float* __restrict__ bias,
                                                 OutT* __restrict__ C,
                                                 int N, int K) {
    __shared__ unsigned short As[128 * 32];
    __shared__ unsigned short Bs[128 * 32];
    int tid = threadIdx.x;
    int lane = tid & 63, w = tid >> 6;
    int wr = w >> 1, wc = w & 1;
    int m0 = blockIdx.y * 128, n0 = blockIdx.x * 128;

    f32x4 acc[4][4] = {};

    int srow = lane >> 2;          // 0..15
    int scol = (lane & 3) * 8;     // 0,8,16,24

    for (int k0 = 0; k0 < K; k0 += 32) {
        #pragma unroll
        for (int it = 0; it < 2; ++it) {
            int r = w * 32 + it * 16;   // wave-uniform LDS base; per-lane global src
            gload_lds16(&A [(long)(m0 + r + srow) * K + k0 + scol], &As[r * 32]);
            gload_lds16(&BT[(long)(n0 + r + srow) * K + k0 + scol], &Bs[r * 32]);
        }
        __syncthreads();   // drains vmcnt before reads

        short8 a[4], b[4];
        #pragma unroll
        for (int f = 0; f < 4; ++f) {
            a[f] = *(const short8*)&As[(wr * 64 + f * 16 + (lane & 15)) * 32 + (lane >> 4) * 8];
            b[f] = *(const short8*)&Bs[(wc * 64 + f * 16 + (lane & 15)) * 32 + (lane >> 4) * 8];
        }
        #pragma unroll
        for (int fm = 0; fm < 4; ++fm)
            #pragma unroll
            for (int fn = 0; fn < 4; ++fn)
                acc[fm][fn] = __builtin_amdgcn_mfma_f32_16x16x32_bf16(a[fm], b[fn], acc[fm][fn], 0, 0, 0);
        __syncthreads();   // protect LDS before next stage
    }

    float bs[4];
    #pragma unroll
    for (int fn = 0; fn < 4; ++fn)
        bs[fn] = BIAS ? bias[n0 + wc * 64 + fn * 16 + (lane & 15)] : 0.f;

    #pragma unroll
    for (int fm = 0; fm < 4; ++fm) {
        #pragma unroll
        for (int j = 0; j < 4; ++j) {
            long row = m0 + wr * 64 + fm * 16 + (lane >> 4) * 4 + j;
            #pragma unroll
            for (int fn = 0; fn < 4; ++fn) {
                int col = n0 + wc * 64 + fn * 16 + (lane & 15);
                float v = acc[fm][fn][j] + bs[fn];
                if (RELU) v = fmaxf(v, 0.f);
                if constexpr (sizeof(OutT) == 2) C[row * N + col] = (OutT)f2bf(v);
                else                             C[row * N + col] = v;
            }
        }
    }
}

// ---------------- causal attention, one block per (b,h,q) row; bf16 in/out, fp32 math ----------------
// qkv layout: [B*T][2304], q at col h*64, k at 768+h*64, v at 1536+h*64
__global__ __launch_bounds__(256) void attn_kernel(const unsigned short* __restrict__ qkv,
                                                   unsigned short* __restrict__ out) {
    __shared__ float qs[NHS];
    __shared__ float sc[NT];
    __shared__ float red[256];
    __shared__ float pr[4][NHS];
    int qi = blockIdx.x;
    int bh = blockIdx.y;
    int b = bh / NH, h = bh % NH;
    int tid = threadIdx.x;
    const float scale = 0.03608439182435161f;   // 768^-0.5 (reference uses E, not HS)
    long rowbase = (long)b * NT;

    const unsigned short* qr = qkv + (rowbase + qi) * NQKV + h * NHS;
    if (tid < NHS) qs[tid] = bf2f(qr[tid]);
    __syncthreads();

    int nk = qi + 1;
    float lmax = -INFINITY;
    for (int j = tid; j < nk; j += 256) {
        const unsigned short* kr = qkv + (rowbase + j) * NQKV + NE + h * NHS;
        float s = 0.f;
        #pragma unroll
        for (int d = 0; d < NHS; ++d) s = fmaf(qs[d], bf2f(kr[d]), s);
        s *= scale;
        sc[j] = s;
        lmax = fmaxf(lmax, s);
    }
    red[tid] = lmax; __syncthreads();
    for (int o = 128; o > 0; o >>= 1) { if (tid < o) red[tid] = fmaxf(red[tid], red[tid + o]); __syncthreads(); }
    float mx = red[0];
    __syncthreads();

    float lsum = 0.f;
    for (int j = tid; j < nk; j += 256) {
        float e = expf(sc[j] - mx);
        sc[j] = e;
        lsum += e;
    }
    red[tid] = lsum; __syncthreads();
    for (int o = 128; o > 0; o >>= 1) { if (tid < o) red[tid] += red[tid + o]; __syncthreads(); }
    float Z = red[0];
    __syncthreads();

    int g = tid >> 6;
    int d = tid & 63;
    float acc = 0.f;
    for (int j = g; j < nk; j += 4)
        acc = fmaf(sc[j], bf2f(qkv[(rowbase + j) * NQKV + 2 * NE + h * NHS + d]), acc);
    pr[g][d] = acc;
    __syncthreads();
    if (tid < NHS)
        out[(rowbase + qi) * (long)NE + h * NHS + tid] =
            f2bf((pr[0][tid] + pr[1][tid] + pr[2][tid] + pr[3][tid]) / Z);
}

// ---------------- residual add (fp32) ----------------
__global__ void add_kernel(float* __restrict__ x, const float* __restrict__ y, int n) {
    int i = blockIdx.x * blockDim.x + threadIdx.x;
    if (i < n) x[i] += y[i];
}

// ---------------- per-row NLL over vocab ----------------
__global__ __launch_bounds__(256) void nll_kernel(const float* __restrict__ logits,
                                                  const int* __restrict__ targets,
                                                  float* __restrict__ nll) {
    __shared__ float red[256];
    int row = blockIdx.x;
    const float* lr = logits + (long)row * NV;
    int tid = threadIdx.x;

    float lmax = -INFINITY;
    for (int i = tid; i < NV; i += 256) lmax = fmaxf(lmax, lr[i]);
    red[tid] = lmax; __syncthreads();
    for (int o = 128; o > 0; o >>= 1) { if (tid < o) red[tid] = fmaxf(red[tid], red[tid + o]); __syncthreads(); }
    float mx = red[0];
    __syncthreads();

    float ls = 0.f;
    for (int i = tid; i < NV; i += 256) ls += expf(lr[i] - mx);
    red[tid] = ls; __syncthreads();
    for (int o = 128; o > 0; o >>= 1) { if (tid < o) red[tid] += red[tid + o]; __syncthreads(); }
    if (tid == 0) {
        float Z = red[0];
        int tgt = targets[row];
        nll[row] = -(lr[tgt] - mx - logf(Z));
    }
}

__global__ void loss_reduce_kernel(const float* __restrict__ nll, float* __restrict__ out) {
    __shared__ float red[256];
    int tid = threadIdx.x;
    float s = 0.f;
    for (int i = tid; i < NM; i += 256) s += nll[i];
    red[tid] = s; __syncthreads();
    for (int o = 128; o > 0; o >>= 1) { if (tid < o) red[tid] += red[tid + o]; __syncthreads(); }
    if (tid == 0) out[0] = red[0] / NM;
}

extern "C" void kernel_launch(void* const* d_in, const int* in_sizes, int n_in,
                              void* d_out, int out_size, void* d_ws, size_t ws_size,
                              hipStream_t stream) {
    const int*   idx     = (const int*)  d_in[0];
    const int*   targets = (const int*)  d_in[1];
    const float* tok     = (const float*)d_in[2];
    const float* pos     = (const float*)d_in[3];
    const float* ln1_g   = (const float*)d_in[4];
    const float* ln1_b   = (const float*)d_in[5];
    const float* wq      = (const float*)d_in[6];
    const float* wk      = (const float*)d_in[7];
    const float* wv      = (const float*)d_in[8];
    const float* wproj   = (const float*)d_in[9];
    const float* bproj   = (const float*)d_in[10];
    const float* ln2_g   = (const float*)d_in[11];
    const float* ln2_b   = (const float*)d_in[12];
    const float* w1      = (const float*)d_in[13];
    const float* b1      = (const float*)d_in[14];
    const float* w2      = (const float*)d_in[15];
    const float* b2      = (const float*)d_in[16];
    const float* lnf_g   = (const float*)d_in[17];
    const float* lnf_b   = (const float*)d_in[18];
    const float* lm_w    = (const float*)d_in[19];
    const float* lm_b    = (const float*)d_in[20];

    float* logits = (float*)d_out;
    float* loss   = logits + (long)NM * NV;

    char* p = (char*)d_ws;
    float*          x      = (float*)p;          p += (long)NM * NE * 4;
    unsigned short* hbuf   = (unsigned short*)p; p += (long)NM * NE * 2;
    unsigned short* qkv    = (unsigned short*)p; p += (long)NM * NQKV * 2;
    unsigned short* att    = (unsigned short*)p; p += (long)NM * NE * 2;
    unsigned short* tmp    = (unsigned short*)p; p += (long)NM * NE * 2;
    float*          tmp32  = (float*)p;          p += (long)NM * NE * 4;
    unsigned short* hid    = (unsigned short*)p; p += (long)NM * NFF * 2;
    float*          nll    = (float*)p;          p += (long)NM * 4;
    unsigned short* wqkvT  = (unsigned short*)p; p += (long)NQKV * NE * 2;
    unsigned short* wprojT = (unsigned short*)p; p += (long)NE * NE * 2;
    unsigned short* w1T    = (unsigned short*)p; p += (long)NFF * NE * 2;
    unsigned short* w2T    = (unsigned short*)p; p += (long)NE * NFF * 2;
    unsigned short* lmT    = (unsigned short*)p; p += (long)NV * NE * 2;

    dim3 blk(256);
    embed_kernel<<<NM, blk, 0, stream>>>(idx, tok, pos, x);

    dim3 gT_EE(NE / 32, NE / 32);
    for (int l = 0; l < NL; ++l) {
        long wofs = (long)l * NE * NE;
        // weight transposes (fp32 [K][N] -> bf16 [N][K]); q|k|v fused into [2304][768]
        transpose_cast_kernel<<<gT_EE, blk, 0, stream>>>(wq + wofs, wqkvT,                 NE, NE);
        transpose_cast_kernel<<<gT_EE, blk, 0, stream>>>(wk + wofs, wqkvT + (long)NE * NE, NE, NE);
        transpose_cast_kernel<<<gT_EE, blk, 0, stream>>>(wv + wofs, wqkvT + (long)2 * NE * NE, NE, NE);
        transpose_cast_kernel<<<gT_EE, blk, 0, stream>>>(wproj + wofs, wprojT, NE, NE);
        transpose_cast_kernel<<<dim3(NFF / 32, NE / 32), blk, 0, stream>>>(w1 + (long)l * NE * NFF, w1T, NE, NFF);
        transpose_cast_kernel<<<dim3(NE / 32, NFF / 32), blk, 0, stream>>>(w2 + (long)l * NFF * NE, w2T, NFF, NE);

        ln_kernel<<<NM, blk, 0, stream>>>(x, ln1_g + l * NE, ln1_b + l * NE, hbuf);
        gemm_mfma<unsigned short, false, false><<<dim3(NQKV / 128, NM / 128), blk, 0, stream>>>(
            hbuf, wqkvT, nullptr, qkv, NQKV, NE);
        attn_kernel<<<dim3(NT, NB * NH), blk, 0, stream>>>(qkv, att);
        // proj applied TWICE (faithful to reference)
        gemm_mfma<unsigned short, true, false><<<dim3(NE / 128, NM / 128), blk, 0, stream>>>(
            att, wprojT, bproj + l * NE, tmp, NE, NE);
        gemm_mfma<float, true, false><<<dim3(NE / 128, NM / 128), blk, 0, stream>>>(
            tmp, wprojT, bproj + l * NE, tmp32, NE, NE);
        add_kernel<<<(NM * NE + 255) / 256, blk, 0, stream>>>(x, tmp32, NM * NE);

        ln_kernel<<<NM, blk, 0, stream>>>(x, ln2_g + l * NE, ln2_b + l * NE, hbuf);
        gemm_mfma<unsigned short, true, true><<<dim3(NFF / 128, NM / 128), blk, 0, stream>>>(
            hbuf, w1T, b1 + (long)l * NFF, hid, NFF, NE);
        gemm_mfma<float, true, false><<<dim3(NE / 128, NM / 128), blk, 0, stream>>>(
            hid, w2T, b2 + l * NE, tmp32, NE, NFF);
        add_kernel<<<(NM * NE + 255) / 256, blk, 0, stream>>>(x, tmp32, NM * NE);
    }

    ln_kernel<<<NM, blk, 0, stream>>>(x, lnf_g, lnf_b, hbuf);
    transpose_cast_kernel<<<dim3(NV / 32, NE / 32), blk, 0, stream>>>(lm_w, lmT, NE, NV);
    gemm_mfma<float, true, false><<<dim3(NV / 128, NM / 128), blk, 0, stream>>>(
        hbuf, lmT, lm_b, logits, NV, NE);
    nll_kernel<<<NM, blk, 0, stream>>>(logits, targets, nll);
    loss_reduce_kernel<<<1, blk, 0, stream>>>(nll, loss);
}

// Round 3
// 1807.251 us; speedup vs baseline: 6.3478x; 2.6390x over previous
//
#include <hip/hip_runtime.h>
#include <math.h>

#define NL 6
#define NH 12
#define NE 768
#define NHS 64
#define NT 1024
#define NB 2
#define NV 32000
#define NM (NB * NT)   // 2048
#define NQKV (3 * NE)  // 2304
#define NFF (4 * NE)   // 3072
#define LN_EPS 1e-5f

typedef __attribute__((ext_vector_type(8))) short short8;
typedef __attribute__((ext_vector_type(4))) float f32x4;
typedef __attribute__((address_space(1))) const unsigned int as1_cuint;
typedef __attribute__((address_space(3))) unsigned int as3_uint;

__device__ __forceinline__ unsigned short f2bf(float f) {
    unsigned int u = __builtin_bit_cast(unsigned int, f);
    u += 0x7fffu + ((u >> 16) & 1u);   // RNE
    return (unsigned short)(u >> 16);
}
__device__ __forceinline__ float bf2f(unsigned short u) {
    unsigned int v = ((unsigned int)u) << 16;
    return __builtin_bit_cast(float, v);
}
__device__ __forceinline__ void gload_lds16(const void* g, void* l) {
    __builtin_amdgcn_global_load_lds((as1_cuint*)g, (as3_uint*)l, 16, 0, 0);
}

// ---------------- embedding ----------------
__global__ void embed_kernel(const int* __restrict__ idx, const float* __restrict__ tok,
                             const float* __restrict__ pos, float* __restrict__ x) {
    int row = blockIdx.x;
    int t = row % NT;
    int id = idx[row];
    const float* te = tok + (long)id * NE;
    const float* pe = pos + (long)t * NE;
    float* xr = x + (long)row * NE;
    for (int e = threadIdx.x; e < NE; e += blockDim.x)
        xr[e] = te[e] + pe[e];
}

// ---------------- layernorm per row: fp32 in, bf16 out ----------------
__global__ __launch_bounds__(256) void ln_kernel(const float* __restrict__ x, const float* __restrict__ g,
                                                 const float* __restrict__ b, unsigned short* __restrict__ out) {
    __shared__ float red[256];
    int row = blockIdx.x;
    const float* xr = x + (long)row * NE;
    unsigned short* outr = out + (long)row * NE;
    int tid = threadIdx.x;

    float s = 0.f;
    for (int e = tid; e < NE; e += 256) s += xr[e];
    red[tid] = s; __syncthreads();
    for (int o = 128; o > 0; o >>= 1) { if (tid < o) red[tid] += red[tid + o]; __syncthreads(); }
    float mu = red[0] / NE;
    __syncthreads();

    float v = 0.f;
    for (int e = tid; e < NE; e += 256) { float d = xr[e] - mu; v += d * d; }
    red[tid] = v; __syncthreads();
    for (int o = 128; o > 0; o >>= 1) { if (tid < o) red[tid] += red[tid + o]; __syncthreads(); }
    float rstd = rsqrtf(red[0] / NE + LN_EPS);

    for (int e = tid; e < NE; e += 256)
        outr[e] = f2bf((xr[e] - mu) * rstd * g[e] + b[e]);
}

// ---------------- tiled transpose + fp32->bf16 cast: WT[n][k] = W[k][n] ----------------
__global__ __launch_bounds__(256) void transpose_cast_kernel(const float* __restrict__ W,
                                                             unsigned short* __restrict__ WT,
                                                             int K, int N) {
    __shared__ float t[32][33];
    int k0 = blockIdx.y * 32;
    int n0 = blockIdx.x * 32;
    int c = threadIdx.x & 31, r = threadIdx.x >> 5;
    #pragma unroll
    for (int p = 0; p < 4; ++p)
        t[r + p * 8][c] = W[(long)(k0 + r + p * 8) * N + n0 + c];
    __syncthreads();
    #pragma unroll
    for (int p = 0; p < 4; ++p)
        WT[(long)(n0 + r + p * 8) * K + k0 + c] = f2bf(t[c][r + p * 8]);
}

// ---------------- bf16 MFMA GEMM: C[M,N] = A[M,K] @ BT[N,K]^T (+bias)(+relu) ----------------
template<typename OutT, bool BIAS, bool RELU>
__global__ __launch_bounds__(256) void gemm_mfma(const unsigned short* __restrict__ A,
                                                 const unsigned short* __restrict__ BT,
                                                 const float* __restrict__ bias,
                                                 OutT* __restrict__ C,
                                                 int N, int K) {
    __shared__ unsigned short As[128 * 32];
    __shared__ unsigned short Bs[128 * 32];
    int tid = threadIdx.x;
    int lane = tid & 63, w = tid >> 6;
    int wr = w >> 1, wc = w & 1;
    int m0 = blockIdx.y * 128, n0 = blockIdx.x * 128;

    f32x4 acc[4][4] = {};

    int srow = lane >> 2;
    int scol = (lane & 3) * 8;

    for (int k0 = 0; k0 < K; k0 += 32) {
        #pragma unroll
        for (int it = 0; it < 2; ++it) {
            int r = w * 32 + it * 16;
            gload_lds16(&A [(long)(m0 + r + srow) * K + k0 + scol], &As[r * 32]);
            gload_lds16(&BT[(long)(n0 + r + srow) * K + k0 + scol], &Bs[r * 32]);
        }
        __syncthreads();

        short8 a[4], b[4];
        #pragma unroll
        for (int f = 0; f < 4; ++f) {
            a[f] = *(const short8*)&As[(wr * 64 + f * 16 + (lane & 15)) * 32 + (lane >> 4) * 8];
            b[f] = *(const short8*)&Bs[(wc * 64 + f * 16 + (lane & 15)) * 32 + (lane >> 4) * 8];
        }
        #pragma unroll
        for (int fm = 0; fm < 4; ++fm)
            #pragma unroll
            for (int fn = 0; fn < 4; ++fn)
                acc[fm][fn] = __builtin_amdgcn_mfma_f32_16x16x32_bf16(a[fm], b[fn], acc[fm][fn], 0, 0, 0);
        __syncthreads();
    }

    float bs[4];
    #pragma unroll
    for (int fn = 0; fn < 4; ++fn)
        bs[fn] = BIAS ? bias[n0 + wc * 64 + fn * 16 + (lane & 15)] : 0.f;

    #pragma unroll
    for (int fm = 0; fm < 4; ++fm) {
        #pragma unroll
        for (int j = 0; j < 4; ++j) {
            long row = m0 + wr * 64 + fm * 16 + (lane >> 4) * 4 + j;
            #pragma unroll
            for (int fn = 0; fn < 4; ++fn) {
                int col = n0 + wc * 64 + fn * 16 + (lane & 15);
                float v = acc[fm][fn][j] + bs[fn];
                if (RELU) v = fmaxf(v, 0.f);
                if constexpr (sizeof(OutT) == 2) C[row * N + col] = (OutT)f2bf(v);
                else                             C[row * N + col] = v;
            }
        }
    }
}

// ---------------- flash attention, MFMA, one block per (q-tile of 64, b*h) ----------------
// qkv layout: [B*T][2304]: q at h*64, k at 768+h*64, v at 1536+h*64
// 4 waves; wave w owns q-rows qt*64+w*16 .. +15. KV tiles of 64 keys.
__global__ __launch_bounds__(256) void fattn_kernel(const unsigned short* __restrict__ qkv,
                                                    unsigned short* __restrict__ out) {
    __shared__ unsigned short Ks[64 * 64];       // [key][d], XOR-swizzled 16B blocks
    __shared__ unsigned short Vt[64 * 64];       // [d][key], XOR-swizzled
    __shared__ unsigned short Ps[4 * 16 * 64];   // per-wave [q][key], XOR-swizzled
    int qt = gridDim.x - 1 - blockIdx.x;         // heavy q-tiles first
    int bh = blockIdx.y;
    int b = bh / NH, h = bh % NH;
    int tid = threadIdx.x, lane = tid & 63, w = tid >> 6;
    int l4 = lane >> 4, l15 = lane & 15;
    long rowb = (long)b * NT;
    const float scale = 0.03608439182435161f;    // 768^-0.5 (reference scales by E)

    // Q fragments (A-operand): row = l15, d = kk*32 + l4*8
    const unsigned short* qptr = qkv + (rowb + qt * 64 + w * 16 + l15) * NQKV + h * NHS;
    short8 qa0 = *(const short8*)(qptr + l4 * 8);
    short8 qa1 = *(const short8*)(qptr + 32 + l4 * 8);

    f32x4 o[4] = {};        // d-chunk fn: O[q=l4*4+j][d=fn*16+l15]
    float m[4], lsum[4];
    #pragma unroll
    for (int j = 0; j < 4; ++j) { m[j] = -INFINITY; lsum[j] = 0.f; }

    for (int t = 0; t <= qt; ++t) {
        int kbase = t * 64;
        // ---- stage K row-major and V transposed, both swizzled ----
        #pragma unroll
        for (int i = 0; i < 2; ++i) {
            int idx = tid + i * 256;
            int r = idx >> 3, cc = idx & 7;
            const unsigned short* kv = qkv + (rowb + kbase + r) * NQKV + h * NHS;
            short8 k8 = *(const short8*)(kv + NE + cc * 8);
            *(short8*)&Ks[r * 64 + ((cc * 8) ^ ((r & 7) << 3))] = k8;
            short8 v8 = *(const short8*)(kv + 2 * NE + cc * 8);
            #pragma unroll
            for (int j = 0; j < 8; ++j) {
                int d = cc * 8 + j;
                Vt[d * 64 + (r ^ ((d & 7) << 3))] = (unsigned short)v8[j];
            }
        }
        __syncthreads();

        // ---- S = Q K^T ----
        f32x4 s[4];
        #pragma unroll
        for (int fn = 0; fn < 4; ++fn) {
            int key = fn * 16 + l15;
            short8 kb0 = *(const short8*)&Ks[key * 64 + ((l4 * 8) ^ ((key & 7) << 3))];
            short8 kb1 = *(const short8*)&Ks[key * 64 + ((32 + l4 * 8) ^ ((key & 7) << 3))];
            f32x4 z = {};
            z = __builtin_amdgcn_mfma_f32_16x16x32_bf16(qa0, kb0, z, 0, 0, 0);
            s[fn] = __builtin_amdgcn_mfma_f32_16x16x32_bf16(qa1, kb1, z, 0, 0, 0);
        }

        // ---- scale + causal mask (only diagonal tile needs masking) ----
        if (t == qt) {
            #pragma unroll
            for (int fn = 0; fn < 4; ++fn) {
                int key = kbase + fn * 16 + l15;
                #pragma unroll
                for (int j = 0; j < 4; ++j) {
                    int q = qt * 64 + w * 16 + l4 * 4 + j;
                    s[fn][j] = (key <= q) ? s[fn][j] * scale : -1e30f;
                }
            }
        } else {
            #pragma unroll
            for (int fn = 0; fn < 4; ++fn)
                #pragma unroll
                for (int j = 0; j < 4; ++j)
                    s[fn][j] *= scale;
        }

        // ---- online softmax ----
        #pragma unroll
        for (int j = 0; j < 4; ++j) {
            float mj = fmaxf(fmaxf(s[0][j], s[1][j]), fmaxf(s[2][j], s[3][j]));
            #pragma unroll
            for (int off = 1; off < 16; off <<= 1) mj = fmaxf(mj, __shfl_xor(mj, off));
            float mnew = fmaxf(m[j], mj);
            float alpha = __expf(m[j] - mnew);
            m[j] = mnew;
            float psum = 0.f;
            #pragma unroll
            for (int fn = 0; fn < 4; ++fn) {
                float p = __expf(s[fn][j] - mnew);
                psum += p;
                int r = l4 * 4 + j, c = fn * 16 + l15;
                Ps[w * 1024 + r * 64 + (c ^ ((r & 7) << 3))] = f2bf(p);
            }
            #pragma unroll
            for (int off = 1; off < 16; off <<= 1) psum += __shfl_xor(psum, off);
            lsum[j] = lsum[j] * alpha + psum;
            #pragma unroll
            for (int fn = 0; fn < 4; ++fn) o[fn][j] *= alpha;
        }

        // ---- O += P V ----
        short8 pa0 = *(const short8*)&Ps[w * 1024 + l15 * 64 + ((l4 * 8) ^ ((l15 & 7) << 3))];
        short8 pa1 = *(const short8*)&Ps[w * 1024 + l15 * 64 + ((32 + l4 * 8) ^ ((l15 & 7) << 3))];
        #pragma unroll
        for (int fn = 0; fn < 4; ++fn) {
            int d = fn * 16 + l15;
            short8 vb0 = *(const short8*)&Vt[d * 64 + ((l4 * 8) ^ ((d & 7) << 3))];
            short8 vb1 = *(const short8*)&Vt[d * 64 + ((32 + l4 * 8) ^ ((d & 7) << 3))];
            o[fn] = __builtin_amdgcn_mfma_f32_16x16x32_bf16(pa0, vb0, o[fn], 0, 0, 0);
            o[fn] = __builtin_amdgcn_mfma_f32_16x16x32_bf16(pa1, vb1, o[fn], 0, 0, 0);
        }
        __syncthreads();   // protect Ks/Vt before next stage
    }

    // ---- write O / lsum ----
    #pragma unroll
    for (int j = 0; j < 4; ++j) {
        long row = rowb + qt * 64 + w * 16 + l4 * 4 + j;
        float inv = 1.0f / lsum[j];
        #pragma unroll
        for (int fn = 0; fn < 4; ++fn)
            out[row * NE + h * NHS + fn * 16 + l15] = f2bf(o[fn][j] * inv);
    }
}

// ---------------- residual add (fp32) ----------------
__global__ void add_kernel(float* __restrict__ x, const float* __restrict__ y, int n) {
    int i = blockIdx.x * blockDim.x + threadIdx.x;
    if (i < n) x[i] += y[i];
}

// ---------------- per-row NLL over vocab ----------------
__global__ __launch_bounds__(256) void nll_kernel(const float* __restrict__ logits,
                                                  const int* __restrict__ targets,
                                                  float* __restrict__ nll) {
    __shared__ float red[256];
    int row = blockIdx.x;
    const float* lr = logits + (long)row * NV;
    int tid = threadIdx.x;

    float lmax = -INFINITY;
    for (int i = tid; i < NV; i += 256) lmax = fmaxf(lmax, lr[i]);
    red[tid] = lmax; __syncthreads();
    for (int o = 128; o > 0; o >>= 1) { if (tid < o) red[tid] = fmaxf(red[tid], red[tid + o]); __syncthreads(); }
    float mx = red[0];
    __syncthreads();

    float ls = 0.f;
    for (int i = tid; i < NV; i += 256) ls += expf(lr[i] - mx);
    red[tid] = ls; __syncthreads();
    for (int o = 128; o > 0; o >>= 1) { if (tid < o) red[tid] += red[tid + o]; __syncthreads(); }
    if (tid == 0) {
        float Z = red[0];
        int tgt = targets[row];
        nll[row] = -(lr[tgt] - mx - logf(Z));
    }
}

__global__ void loss_reduce_kernel(const float* __restrict__ nll, float* __restrict__ out) {
    __shared__ float red[256];
    int tid = threadIdx.x;
    float s = 0.f;
    for (int i = tid; i < NM; i += 256) s += nll[i];
    red[tid] = s; __syncthreads();
    for (int o = 128; o > 0; o >>= 1) { if (tid < o) red[tid] += red[tid + o]; __syncthreads(); }
    if (tid == 0) out[0] = red[0] / NM;
}

extern "C" void kernel_launch(void* const* d_in, const int* in_sizes, int n_in,
                              void* d_out, int out_size, void* d_ws, size_t ws_size,
                              hipStream_t stream) {
    const int*   idx     = (const int*)  d_in[0];
    const int*   targets = (const int*)  d_in[1];
    const float* tok     = (const float*)d_in[2];
    const float* pos     = (const float*)d_in[3];
    const float* ln1_g   = (const float*)d_in[4];
    const float* ln1_b   = (const float*)d_in[5];
    const float* wq      = (const float*)d_in[6];
    const float* wk      = (const float*)d_in[7];
    const float* wv      = (const float*)d_in[8];
    const float* wproj   = (const float*)d_in[9];
    const float* bproj   = (const float*)d_in[10];
    const float* ln2_g   = (const float*)d_in[11];
    const float* ln2_b   = (const float*)d_in[12];
    const float* w1      = (const float*)d_in[13];
    const float* b1      = (const float*)d_in[14];
    const float* w2      = (const float*)d_in[15];
    const float* b2      = (const float*)d_in[16];
    const float* lnf_g   = (const float*)d_in[17];
    const float* lnf_b   = (const float*)d_in[18];
    const float* lm_w    = (const float*)d_in[19];
    const float* lm_b    = (const float*)d_in[20];

    float* logits = (float*)d_out;
    float* loss   = logits + (long)NM * NV;

    char* p = (char*)d_ws;
    float*          x      = (float*)p;          p += (long)NM * NE * 4;
    unsigned short* hbuf   = (unsigned short*)p; p += (long)NM * NE * 2;
    unsigned short* qkv    = (unsigned short*)p; p += (long)NM * NQKV * 2;
    unsigned short* att    = (unsigned short*)p; p += (long)NM * NE * 2;
    unsigned short* tmp    = (unsigned short*)p; p += (long)NM * NE * 2;
    float*          tmp32  = (float*)p;          p += (long)NM * NE * 4;
    unsigned short* hid    = (unsigned short*)p; p += (long)NM * NFF * 2;
    float*          nll    = (float*)p;          p += (long)NM * 4;
    unsigned short* wqkvT  = (unsigned short*)p; p += (long)NQKV * NE * 2;
    unsigned short* wprojT = (unsigned short*)p; p += (long)NE * NE * 2;
    unsigned short* w1T    = (unsigned short*)p; p += (long)NFF * NE * 2;
    unsigned short* w2T    = (unsigned short*)p; p += (long)NE * NFF * 2;
    unsigned short* lmT    = (unsigned short*)p; p += (long)NV * NE * 2;

    dim3 blk(256);
    embed_kernel<<<NM, blk, 0, stream>>>(idx, tok, pos, x);

    dim3 gT_EE(NE / 32, NE / 32);
    for (int l = 0; l < NL; ++l) {
        long wofs = (long)l * NE * NE;
        transpose_cast_kernel<<<gT_EE, blk, 0, stream>>>(wq + wofs, wqkvT,                 NE, NE);
        transpose_cast_kernel<<<gT_EE, blk, 0, stream>>>(wk + wofs, wqkvT + (long)NE * NE, NE, NE);
        transpose_cast_kernel<<<gT_EE, blk, 0, stream>>>(wv + wofs, wqkvT + (long)2 * NE * NE, NE, NE);
        transpose_cast_kernel<<<gT_EE, blk, 0, stream>>>(wproj + wofs, wprojT, NE, NE);
        transpose_cast_kernel<<<dim3(NFF / 32, NE / 32), blk, 0, stream>>>(w1 + (long)l * NE * NFF, w1T, NE, NFF);
        transpose_cast_kernel<<<dim3(NE / 32, NFF / 32), blk, 0, stream>>>(w2 + (long)l * NFF * NE, w2T, NFF, NE);

        ln_kernel<<<NM, blk, 0, stream>>>(x, ln1_g + l * NE, ln1_b + l * NE, hbuf);
        gemm_mfma<unsigned short, false, false><<<dim3(NQKV / 128, NM / 128), blk, 0, stream>>>(
            hbuf, wqkvT, nullptr, qkv, NQKV, NE);
        fattn_kernel<<<dim3(NT / 64, NB * NH), blk, 0, stream>>>(qkv, att);
        // proj applied TWICE (faithful to reference)
        gemm_mfma<unsigned short, true, false><<<dim3(NE / 128, NM / 128), blk, 0, stream>>>(
            att, wprojT, bproj + l * NE, tmp, NE, NE);
        gemm_mfma<float, true, false><<<dim3(NE / 128, NM / 128), blk, 0, stream>>>(
            tmp, wprojT, bproj + l * NE, tmp32, NE, NE);
        add_kernel<<<(NM * NE + 255) / 256, blk, 0, stream>>>(x, tmp32, NM * NE);

        ln_kernel<<<NM, blk, 0, stream>>>(x, ln2_g + l * NE, ln2_b + l * NE, hbuf);
        gemm_mfma<unsigned short, true, true><<<dim3(NFF / 128, NM / 128), blk, 0, stream>>>(
            hbuf, w1T, b1 + (long)l * NFF, hid, NFF, NE);
        gemm_mfma<float, true, false><<<dim3(NE / 128, NM / 128), blk, 0, stream>>>(
            hid, w2T, b2 + l * NE, tmp32, NE, NFF);
        add_kernel<<<(NM * NE + 255) / 256, blk, 0, stream>>>(x, tmp32, NM * NE);
    }

    ln_kernel<<<NM, blk, 0, stream>>>(x, lnf_g, lnf_b, hbuf);
    transpose_cast_kernel<<<dim3(NV / 32, NE / 32), blk, 0, stream>>>(lm_w, lmT, NE, NV);
    gemm_mfma<float, true, false><<<dim3(NV / 128, NM / 128), blk, 0, stream>>>(
        hbuf, lmT, lm_b, logits, NV, NE);
    nll_kernel<<<NM, blk, 0, stream>>>(logits, targets, nll);
    loss_reduce_kernel<<<1, blk, 0, stream>>>(nll, loss);
}

// Round 4
// 1787.291 us; speedup vs baseline: 6.4187x; 1.0112x over previous
//
#include <hip/hip_runtime.h>
#include <math.h>

#define NL 6
#define NH 12
#define NE 768
#define NHS 64
#define NT 1024
#define NB 2
#define NV 32000
#define NM (NB * NT)   // 2048
#define NQKV (3 * NE)  // 2304
#define NFF (4 * NE)   // 3072
#define LN_EPS 1e-5f

typedef __attribute__((ext_vector_type(8))) short short8;
typedef __attribute__((ext_vector_type(4))) float f32x4;
typedef __attribute__((ext_vector_type(4))) unsigned short ushort4v;
typedef __attribute__((address_space(1))) const unsigned int as1_cuint;
typedef __attribute__((address_space(3))) unsigned int as3_uint;

__device__ __forceinline__ unsigned short f2bf(float f) {
    unsigned int u = __builtin_bit_cast(unsigned int, f);
    u += 0x7fffu + ((u >> 16) & 1u);   // RNE
    return (unsigned short)(u >> 16);
}
__device__ __forceinline__ float bf2f(unsigned short u) {
    unsigned int v = ((unsigned int)u) << 16;
    return __builtin_bit_cast(float, v);
}
__device__ __forceinline__ void gload_lds16(const void* g, void* l) {
    __builtin_amdgcn_global_load_lds((as1_cuint*)g, (as3_uint*)l, 16, 0, 0);
}

// ---------------- embedding ----------------
__global__ void embed_kernel(const int* __restrict__ idx, const float* __restrict__ tok,
                             const float* __restrict__ pos, float* __restrict__ x) {
    int row = blockIdx.x;
    int t = row % NT;
    int id = idx[row];
    const float* te = tok + (long)id * NE;
    const float* pe = pos + (long)t * NE;
    float* xr = x + (long)row * NE;
    for (int e = threadIdx.x; e < NE; e += blockDim.x)
        xr[e] = te[e] + pe[e];
}

// ---------------- layernorm per row: fp32 in, bf16 out ----------------
__global__ __launch_bounds__(256) void ln_kernel(const float* __restrict__ x, const float* __restrict__ g,
                                                 const float* __restrict__ b, unsigned short* __restrict__ out) {
    __shared__ float red[256];
    int row = blockIdx.x;
    const float* xr = x + (long)row * NE;
    unsigned short* outr = out + (long)row * NE;
    int tid = threadIdx.x;

    float s = 0.f;
    for (int e = tid; e < NE; e += 256) s += xr[e];
    red[tid] = s; __syncthreads();
    for (int o = 128; o > 0; o >>= 1) { if (tid < o) red[tid] += red[tid + o]; __syncthreads(); }
    float mu = red[0] / NE;
    __syncthreads();

    float v = 0.f;
    for (int e = tid; e < NE; e += 256) { float d = xr[e] - mu; v += d * d; }
    red[tid] = v; __syncthreads();
    for (int o = 128; o > 0; o >>= 1) { if (tid < o) red[tid] += red[tid + o]; __syncthreads(); }
    float rstd = rsqrtf(red[0] / NE + LN_EPS);

    for (int e = tid; e < NE; e += 256)
        outr[e] = f2bf((xr[e] - mu) * rstd * g[e] + b[e]);
}

// ---------------- tiled transpose + fp32->bf16 cast: WT[n][k] = W[k][n] ----------------
__global__ __launch_bounds__(256) void transpose_cast_kernel(const float* __restrict__ W,
                                                             unsigned short* __restrict__ WT,
                                                             int K, int N) {
    __shared__ float t[32][33];
    int k0 = blockIdx.y * 32;
    int n0 = blockIdx.x * 32;
    int c = threadIdx.x & 31, r = threadIdx.x >> 5;
    #pragma unroll
    for (int p = 0; p < 4; ++p)
        t[r + p * 8][c] = W[(long)(k0 + r + p * 8) * N + n0 + c];
    __syncthreads();
    #pragma unroll
    for (int p = 0; p < 4; ++p)
        WT[(long)(n0 + r + p * 8) * K + k0 + c] = f2bf(t[c][r + p * 8]);
}

// ---------------- plain fp32 -> bf16 cast ----------------
__global__ __launch_bounds__(256) void cast_kernel(const float* __restrict__ W,
                                                   unsigned short* __restrict__ O, int n) {
    int i = (blockIdx.x * 256 + threadIdx.x) * 4;
    if (i < n) {
        float4 v = *(const float4*)(W + i);
        ushort4v o;
        o[0] = f2bf(v.x); o[1] = f2bf(v.y); o[2] = f2bf(v.z); o[3] = f2bf(v.w);
        *(ushort4v*)(O + i) = o;
    }
}

// ---------------- beff[n] = sum_j bproj[j]*Wp[j][n] + bproj[n]  (uses wprojT rows) ----------------
__global__ __launch_bounds__(256) void beff_kernel(const float* __restrict__ bproj,
                                                   const unsigned short* __restrict__ wprojT,
                                                   float* __restrict__ beff) {
    __shared__ float red[256];
    int n = blockIdx.x, tid = threadIdx.x;
    float acc = 0.f;
    for (int j = tid; j < NE; j += 256) acc += bproj[j] * bf2f(wprojT[(long)n * NE + j]);
    red[tid] = acc; __syncthreads();
    for (int o = 128; o > 0; o >>= 1) { if (tid < o) red[tid] += red[tid + o]; __syncthreads(); }
    if (tid == 0) beff[n] = red[0] + bproj[n];
}

// ---------------- bf16 MFMA GEMM: C[M,N] = A[M,K] @ BT[N,K]^T (+bias)(+relu)(+resadd)(+lse) ----------------
// 128x128 tile, BK=32, 256 threads = 4 waves (2x2). 1-D grid, XCD-chunked + m-fastest remap.
template<typename OutT, bool BIAS, bool RELU, bool RESADD, bool LSE>
__global__ __launch_bounds__(256) void gemm_mfma(const unsigned short* __restrict__ A,
                                                 const unsigned short* __restrict__ BT,
                                                 const float* __restrict__ bias,
                                                 OutT* __restrict__ C,
                                                 float* __restrict__ pm, float* __restrict__ ps,
                                                 int gridM, int N, int K) {
    __shared__ unsigned short As[128 * 32];
    __shared__ unsigned short Bs[128 * 32];
    int tid = threadIdx.x;
    int lane = tid & 63, w = tid >> 6;
    int wr = w >> 1, wc = w & 1;
    int l4 = lane >> 4, l15 = lane & 15;

    // bijective XCD-chunked remap, then m-fastest decode
    int nwg = gridDim.x, orig = blockIdx.x;
    int q = nwg >> 3, r8 = nwg & 7;
    int xcd = orig & 7, ii = orig >> 3;
    int wg = (xcd < r8) ? (xcd * (q + 1) + ii) : (r8 * (q + 1) + (xcd - r8) * q + ii);
    int bm = wg % gridM, bn = wg / gridM;
    int m0 = bm * 128, n0 = bn * 128;

    f32x4 acc[4][4] = {};

    int srow = lane >> 2;
    int scol = (lane & 3) * 8;

    for (int k0 = 0; k0 < K; k0 += 32) {
        #pragma unroll
        for (int it = 0; it < 2; ++it) {
            int rr = w * 32 + it * 16;
            gload_lds16(&A [(long)(m0 + rr + srow) * K + k0 + scol], &As[rr * 32]);
            gload_lds16(&BT[(long)(n0 + rr + srow) * K + k0 + scol], &Bs[rr * 32]);
        }
        __syncthreads();

        short8 a[4], b[4];
        #pragma unroll
        for (int f = 0; f < 4; ++f) {
            a[f] = *(const short8*)&As[(wr * 64 + f * 16 + l15) * 32 + l4 * 8];
            b[f] = *(const short8*)&Bs[(wc * 64 + f * 16 + l15) * 32 + l4 * 8];
        }
        #pragma unroll
        for (int fm = 0; fm < 4; ++fm)
            #pragma unroll
            for (int fn = 0; fn < 4; ++fn)
                acc[fm][fn] = __builtin_amdgcn_mfma_f32_16x16x32_bf16(a[fm], b[fn], acc[fm][fn], 0, 0, 0);
        __syncthreads();
    }

    float bs[4];
    #pragma unroll
    for (int fn = 0; fn < 4; ++fn)
        bs[fn] = BIAS ? bias[n0 + wc * 64 + fn * 16 + l15] : 0.f;

    #pragma unroll
    for (int fm = 0; fm < 4; ++fm) {
        #pragma unroll
        for (int j = 0; j < 4; ++j) {
            long row = m0 + wr * 64 + fm * 16 + l4 * 4 + j;
            float v4[4];
            #pragma unroll
            for (int fn = 0; fn < 4; ++fn) {
                int col = n0 + wc * 64 + fn * 16 + l15;
                float v = acc[fm][fn][j] + bs[fn];
                if (RELU) v = fmaxf(v, 0.f);
                v4[fn] = v;
                if constexpr (RESADD)               C[row * N + col] += v;
                else if constexpr (sizeof(OutT)==2) C[row * N + col] = (OutT)f2bf(v);
                else                                C[row * N + col] = v;
            }
            if constexpr (LSE) {
                float mx = fmaxf(fmaxf(v4[0], v4[1]), fmaxf(v4[2], v4[3]));
                #pragma unroll
                for (int off = 1; off < 16; off <<= 1) mx = fmaxf(mx, __shfl_xor(mx, off));
                float sm = 0.f;
                #pragma unroll
                for (int fn = 0; fn < 4; ++fn) sm += __expf(v4[fn] - mx);
                #pragma unroll
                for (int off = 1; off < 16; off <<= 1) sm += __shfl_xor(sm, off);
                if (l15 == 0) {
                    int pidx = bn * 2 + wc;
                    pm[row * 512 + pidx] = mx;
                    ps[row * 512 + pidx] = sm;
                }
            }
        }
    }
}

// ---------------- flash attention, MFMA, one block per (q-tile of 64, b*h) ----------------
__global__ __launch_bounds__(256) void fattn_kernel(const unsigned short* __restrict__ qkv,
                                                    unsigned short* __restrict__ out) {
    __shared__ unsigned short Ks[64 * 64];       // [key][d], XOR-swizzled 16B granules
    __shared__ unsigned short Vt[64 * 64];       // [d][key], XOR-swizzled
    __shared__ unsigned short Ps[4 * 16 * 64];   // per-wave [q][key], XOR-swizzled
    int qt = gridDim.x - 1 - blockIdx.x;         // heavy q-tiles first
    int bh = blockIdx.y;
    int b = bh / NH, h = bh % NH;
    int tid = threadIdx.x, lane = tid & 63, w = tid >> 6;
    int l4 = lane >> 4, l15 = lane & 15;
    long rowb = (long)b * NT;
    const float scale = 0.03608439182435161f;    // 768^-0.5 (reference scales by E)

    const unsigned short* qptr = qkv + (rowb + qt * 64 + w * 16 + l15) * NQKV + h * NHS;
    short8 qa0 = *(const short8*)(qptr + l4 * 8);
    short8 qa1 = *(const short8*)(qptr + 32 + l4 * 8);

    f32x4 o[4] = {};
    float m[4], lsum[4];
    #pragma unroll
    for (int j = 0; j < 4; ++j) { m[j] = -INFINITY; lsum[j] = 0.f; }

    for (int t = 0; t <= qt; ++t) {
        int kbase = t * 64;
        // ---- stage K rows (vector) ----
        #pragma unroll
        for (int i = 0; i < 2; ++i) {
            int idx = tid + i * 256;
            int r = idx >> 3, cc = idx & 7;
            const unsigned short* kv = qkv + (rowb + kbase + r) * NQKV + NE + h * NHS;
            short8 k8 = *(const short8*)(kv + cc * 8);
            *(short8*)&Ks[r * 64 + ((cc * 8) ^ ((r & 7) << 3))] = k8;
        }
        // ---- stage V transposed: coalesced global gather + vector LDS write ----
        #pragma unroll
        for (int i = 0; i < 2; ++i) {
            int d = tid & 63, kc = (tid >> 6) + i * 4;
            const unsigned short* vp = qkv + (rowb + kbase + kc * 8) * NQKV + 2 * NE + h * NHS + d;
            short8 v8;
            #pragma unroll
            for (int j = 0; j < 8; ++j) v8[j] = (short)vp[(long)j * NQKV];
            *(short8*)&Vt[d * 64 + ((kc * 8) ^ ((d & 7) << 3))] = v8;
        }
        __syncthreads();

        // ---- S = Q K^T ----
        f32x4 s[4];
        #pragma unroll
        for (int fn = 0; fn < 4; ++fn) {
            int key = fn * 16 + l15;
            short8 kb0 = *(const short8*)&Ks[key * 64 + ((l4 * 8) ^ ((key & 7) << 3))];
            short8 kb1 = *(const short8*)&Ks[key * 64 + ((32 + l4 * 8) ^ ((key & 7) << 3))];
            f32x4 z = {};
            z = __builtin_amdgcn_mfma_f32_16x16x32_bf16(qa0, kb0, z, 0, 0, 0);
            s[fn] = __builtin_amdgcn_mfma_f32_16x16x32_bf16(qa1, kb1, z, 0, 0, 0);
        }

        // ---- scale + causal mask (diagonal tile only) ----
        if (t == qt) {
            #pragma unroll
            for (int fn = 0; fn < 4; ++fn) {
                int key = kbase + fn * 16 + l15;
                #pragma unroll
                for (int j = 0; j < 4; ++j) {
                    int qrow = qt * 64 + w * 16 + l4 * 4 + j;
                    s[fn][j] = (key <= qrow) ? s[fn][j] * scale : -1e30f;
                }
            }
        } else {
            #pragma unroll
            for (int fn = 0; fn < 4; ++fn)
                #pragma unroll
                for (int j = 0; j < 4; ++j)
                    s[fn][j] *= scale;
        }

        // ---- online softmax ----
        #pragma unroll
        for (int j = 0; j < 4; ++j) {
            float mj = fmaxf(fmaxf(s[0][j], s[1][j]), fmaxf(s[2][j], s[3][j]));
            #pragma unroll
            for (int off = 1; off < 16; off <<= 1) mj = fmaxf(mj, __shfl_xor(mj, off));
            float mnew = fmaxf(m[j], mj);
            float alpha = __expf(m[j] - mnew);
            m[j] = mnew;
            float psum = 0.f;
            #pragma unroll
            for (int fn = 0; fn < 4; ++fn) {
                float p = __expf(s[fn][j] - mnew);
                psum += p;
                int rr = l4 * 4 + j, c = fn * 16 + l15;
                Ps[w * 1024 + rr * 64 + (c ^ ((rr & 7) << 3))] = f2bf(p);
            }
            #pragma unroll
            for (int off = 1; off < 16; off <<= 1) psum += __shfl_xor(psum, off);
            lsum[j] = lsum[j] * alpha + psum;
            #pragma unroll
            for (int fn = 0; fn < 4; ++fn) o[fn][j] *= alpha;
        }

        // ---- O += P V ----
        short8 pa0 = *(const short8*)&Ps[w * 1024 + l15 * 64 + ((l4 * 8) ^ ((l15 & 7) << 3))];
        short8 pa1 = *(const short8*)&Ps[w * 1024 + l15 * 64 + ((32 + l4 * 8) ^ ((l15 & 7) << 3))];
        #pragma unroll
        for (int fn = 0; fn < 4; ++fn) {
            int d = fn * 16 + l15;
            short8 vb0 = *(const short8*)&Vt[d * 64 + ((l4 * 8) ^ ((d & 7) << 3))];
            short8 vb1 = *(const short8*)&Vt[d * 64 + ((32 + l4 * 8) ^ ((d & 7) << 3))];
            o[fn] = __builtin_amdgcn_mfma_f32_16x16x32_bf16(pa0, vb0, o[fn], 0, 0, 0);
            o[fn] = __builtin_amdgcn_mfma_f32_16x16x32_bf16(pa1, vb1, o[fn], 0, 0, 0);
        }
        __syncthreads();
    }

    #pragma unroll
    for (int j = 0; j < 4; ++j) {
        long row = rowb + qt * 64 + w * 16 + l4 * 4 + j;
        float inv = 1.0f / lsum[j];
        #pragma unroll
        for (int fn = 0; fn < 4; ++fn)
            out[row * NE + h * NHS + fn * 16 + l15] = f2bf(o[fn][j] * inv);
    }
}

// ---------------- NLL from LM-head partials ----------------
__global__ __launch_bounds__(256) void nll_combine_kernel(const float* __restrict__ logits,
                                                          const float* __restrict__ pm,
                                                          const float* __restrict__ ps,
                                                          const int* __restrict__ targets,
                                                          float* __restrict__ nll) {
    __shared__ float rm[256], rs[256];
    int row = blockIdx.x, tid = threadIdx.x;
    float m = -1e30f, s = 0.f;
    for (int i = tid; i < 500; i += 256) {
        float m2 = pm[(long)row * 512 + i], s2 = ps[(long)row * 512 + i];
        float mm = fmaxf(m, m2);
        s = s * __expf(m - mm) + s2 * __expf(m2 - mm);
        m = mm;
    }
    rm[tid] = m; rs[tid] = s; __syncthreads();
    for (int o = 128; o > 0; o >>= 1) {
        if (tid < o) {
            float m2 = rm[tid + o], s2 = rs[tid + o];
            float mm = fmaxf(rm[tid], m2);
            rs[tid] = rs[tid] * __expf(rm[tid] - mm) + s2 * __expf(m2 - mm);
            rm[tid] = mm;
        }
        __syncthreads();
    }
    if (tid == 0) {
        int tgt = targets[row];
        nll[row] = -(logits[(long)row * NV + tgt] - rm[0] - logf(rs[0]));
    }
}

__global__ void loss_reduce_kernel(const float* __restrict__ nll, float* __restrict__ out) {
    __shared__ float red[256];
    int tid = threadIdx.x;
    float s = 0.f;
    for (int i = tid; i < NM; i += 256) s += nll[i];
    red[tid] = s; __syncthreads();
    for (int o = 128; o > 0; o >>= 1) { if (tid < o) red[tid] += red[tid + o]; __syncthreads(); }
    if (tid == 0) out[0] = red[0] / NM;
}

extern "C" void kernel_launch(void* const* d_in, const int* in_sizes, int n_in,
                              void* d_out, int out_size, void* d_ws, size_t ws_size,
                              hipStream_t stream) {
    const int*   idx     = (const int*)  d_in[0];
    const int*   targets = (const int*)  d_in[1];
    const float* tok     = (const float*)d_in[2];
    const float* pos     = (const float*)d_in[3];
    const float* ln1_g   = (const float*)d_in[4];
    const float* ln1_b   = (const float*)d_in[5];
    const float* wq      = (const float*)d_in[6];
    const float* wk      = (const float*)d_in[7];
    const float* wv      = (const float*)d_in[8];
    const float* wproj   = (const float*)d_in[9];
    const float* bproj   = (const float*)d_in[10];
    const float* ln2_g   = (const float*)d_in[11];
    const float* ln2_b   = (const float*)d_in[12];
    const float* w1      = (const float*)d_in[13];
    const float* b1      = (const float*)d_in[14];
    const float* w2      = (const float*)d_in[15];
    const float* b2      = (const float*)d_in[16];
    const float* lnf_g   = (const float*)d_in[17];
    const float* lnf_b   = (const float*)d_in[18];
    const float* lm_w    = (const float*)d_in[19];
    const float* lm_b    = (const float*)d_in[20];

    float* logits = (float*)d_out;
    float* loss   = logits + (long)NM * NV;

    char* p = (char*)d_ws;
    float*          x      = (float*)p;          p += (long)NM * NE * 4;
    unsigned short* hbuf   = (unsigned short*)p; p += (long)NM * NE * 2;
    unsigned short* qkv    = (unsigned short*)p; p += (long)NM * NQKV * 2;
    unsigned short* att    = (unsigned short*)p; p += (long)NM * NE * 2;
    unsigned short* hid    = (unsigned short*)p; p += (long)NM * NFF * 2;
    float*          nll    = (float*)p;          p += (long)NM * 4;
    float*          pmb    = (float*)p;          p += (long)NM * 512 * 4;
    float*          psb    = (float*)p;          p += (long)NM * 512 * 4;
    unsigned short* wqkvT  = (unsigned short*)p; p += (long)NQKV * NE * 2;
    unsigned short* wprojT = (unsigned short*)p; p += (long)NE * NE * 2;
    unsigned short* wprojC = (unsigned short*)p; p += (long)NE * NE * 2;
    unsigned short* weffT  = (unsigned short*)p; p += (long)NE * NE * 2;
    float*          beff   = (float*)p;          p += (long)NE * 4;
    unsigned short* w1T    = (unsigned short*)p; p += (long)NFF * NE * 2;
    unsigned short* w2T    = (unsigned short*)p; p += (long)NE * NFF * 2;
    unsigned short* lmT    = (unsigned short*)p; p += (long)NV * NE * 2;

    dim3 blk(256);
    embed_kernel<<<NM, blk, 0, stream>>>(idx, tok, pos, x);

    dim3 gT_EE(NE / 32, NE / 32);
    for (int l = 0; l < NL; ++l) {
        long wofs = (long)l * NE * NE;
        transpose_cast_kernel<<<gT_EE, blk, 0, stream>>>(wq + wofs, wqkvT,                     NE, NE);
        transpose_cast_kernel<<<gT_EE, blk, 0, stream>>>(wk + wofs, wqkvT + (long)NE * NE,     NE, NE);
        transpose_cast_kernel<<<gT_EE, blk, 0, stream>>>(wv + wofs, wqkvT + (long)2 * NE * NE, NE, NE);
        transpose_cast_kernel<<<gT_EE, blk, 0, stream>>>(wproj + wofs, wprojT, NE, NE);
        cast_kernel<<<(NE * NE) / 1024, blk, 0, stream>>>(wproj + wofs, wprojC, NE * NE);
        // WeffT[n][k] = (Wp @ Wp)[k][n]:  A = wprojT, BT = wprojC
        gemm_mfma<unsigned short, false, false, false, false><<<dim3(36), blk, 0, stream>>>(
            wprojT, wprojC, nullptr, weffT, nullptr, nullptr, 6, NE, NE);
        beff_kernel<<<NE, blk, 0, stream>>>(bproj + l * NE, wprojT, beff);
        transpose_cast_kernel<<<dim3(NFF / 32, NE / 32), blk, 0, stream>>>(w1 + (long)l * NE * NFF, w1T, NE, NFF);
        transpose_cast_kernel<<<dim3(NE / 32, NFF / 32), blk, 0, stream>>>(w2 + (long)l * NFF * NE, w2T, NFF, NE);

        ln_kernel<<<NM, blk, 0, stream>>>(x, ln1_g + l * NE, ln1_b + l * NE, hbuf);
        gemm_mfma<unsigned short, false, false, false, false><<<dim3((NM/128)*(NQKV/128)), blk, 0, stream>>>(
            hbuf, wqkvT, nullptr, qkv, nullptr, nullptr, NM / 128, NQKV, NE);
        fattn_kernel<<<dim3(NT / 64, NB * NH), blk, 0, stream>>>(qkv, att);
        // fused double-proj + residual: x += att @ Weff + beff
        gemm_mfma<float, true, false, true, false><<<dim3((NM/128)*(NE/128)), blk, 0, stream>>>(
            att, weffT, beff, x, nullptr, nullptr, NM / 128, NE, NE);

        ln_kernel<<<NM, blk, 0, stream>>>(x, ln2_g + l * NE, ln2_b + l * NE, hbuf);
        gemm_mfma<unsigned short, true, true, false, false><<<dim3((NM/128)*(NFF/128)), blk, 0, stream>>>(
            hbuf, w1T, b1 + (long)l * NFF, hid, nullptr, nullptr, NM / 128, NFF, NE);
        gemm_mfma<float, true, false, true, false><<<dim3((NM/128)*(NE/128)), blk, 0, stream>>>(
            hid, w2T, b2 + l * NE, x, nullptr, nullptr, NM / 128, NE, NFF);
    }

    ln_kernel<<<NM, blk, 0, stream>>>(x, lnf_g, lnf_b, hbuf);
    transpose_cast_kernel<<<dim3(NV / 32, NE / 32), blk, 0, stream>>>(lm_w, lmT, NE, NV);
    gemm_mfma<float, true, false, false, true><<<dim3((NM/128)*(NV/128)), blk, 0, stream>>>(
        hbuf, lmT, lm_b, logits, pmb, psb, NM / 128, NV, NE);
    nll_combine_kernel<<<NM, blk, 0, stream>>>(logits, pmb, psb, targets, nll);
    loss_reduce_kernel<<<1, blk, 0, stream>>>(nll, loss);
}

// Round 5
// 1310.155 us; speedup vs baseline: 8.7562x; 1.3642x over previous
//
#include <hip/hip_runtime.h>
#include <math.h>

#define NL 6
#define NH 12
#define NE 768
#define NHS 64
#define NT 1024
#define NB 2
#define NV 32000
#define NM (NB * NT)   // 2048
#define NQKV (3 * NE)  // 2304
#define NFF (4 * NE)   // 3072
#define LN_EPS 1e-5f

typedef __attribute__((ext_vector_type(8))) short short8;
typedef __attribute__((ext_vector_type(4))) float f32x4;
typedef __attribute__((ext_vector_type(4))) unsigned short ushort4v;
typedef __attribute__((address_space(1))) const unsigned int as1_cuint;
typedef __attribute__((address_space(3))) unsigned int as3_uint;

__device__ __forceinline__ unsigned short f2bf(float f) {
    unsigned int u = __builtin_bit_cast(unsigned int, f);
    u += 0x7fffu + ((u >> 16) & 1u);   // RNE
    return (unsigned short)(u >> 16);
}
__device__ __forceinline__ float bf2f(unsigned short u) {
    unsigned int v = ((unsigned int)u) << 16;
    return __builtin_bit_cast(float, v);
}
__device__ __forceinline__ void gload_lds16(const void* g, void* l) {
    __builtin_amdgcn_global_load_lds((as1_cuint*)g, (as3_uint*)l, 16, 0, 0);
}

// ---------------- embedding ----------------
__global__ void embed_kernel(const int* __restrict__ idx, const float* __restrict__ tok,
                             const float* __restrict__ pos, float* __restrict__ x) {
    int row = blockIdx.x;
    int t = row % NT;
    int id = idx[row];
    const float* te = tok + (long)id * NE;
    const float* pe = pos + (long)t * NE;
    float* xr = x + (long)row * NE;
    for (int e = threadIdx.x; e < NE; e += blockDim.x)
        xr[e] = te[e] + pe[e];
}

// ---------------- layernorm per row: fp32 in, bf16 out ----------------
__global__ __launch_bounds__(256) void ln_kernel(const float* __restrict__ x, const float* __restrict__ g,
                                                 const float* __restrict__ b, unsigned short* __restrict__ out) {
    __shared__ float red[256];
    int row = blockIdx.x;
    const float* xr = x + (long)row * NE;
    unsigned short* outr = out + (long)row * NE;
    int tid = threadIdx.x;

    float s = 0.f;
    for (int e = tid; e < NE; e += 256) s += xr[e];
    red[tid] = s; __syncthreads();
    for (int o = 128; o > 0; o >>= 1) { if (tid < o) red[tid] += red[tid + o]; __syncthreads(); }
    float mu = red[0] / NE;
    __syncthreads();

    float v = 0.f;
    for (int e = tid; e < NE; e += 256) { float d = xr[e] - mu; v += d * d; }
    red[tid] = v; __syncthreads();
    for (int o = 128; o > 0; o >>= 1) { if (tid < o) red[tid] += red[tid + o]; __syncthreads(); }
    float rstd = rsqrtf(red[0] / NE + LN_EPS);

    for (int e = tid; e < NE; e += 256)
        outr[e] = f2bf((xr[e] - mu) * rstd * g[e] + b[e]);
}

// ---------------- tiled transpose + fp32->bf16 cast: WT[n][k] = W[k][n] ----------------
__global__ __launch_bounds__(256) void transpose_cast_kernel(const float* __restrict__ W,
                                                             unsigned short* __restrict__ WT,
                                                             int K, int N) {
    __shared__ float t[32][33];
    int k0 = blockIdx.y * 32;
    int n0 = blockIdx.x * 32;
    int c = threadIdx.x & 31, r = threadIdx.x >> 5;
    #pragma unroll
    for (int p = 0; p < 4; ++p)
        t[r + p * 8][c] = W[(long)(k0 + r + p * 8) * N + n0 + c];
    __syncthreads();
    #pragma unroll
    for (int p = 0; p < 4; ++p)
        WT[(long)(n0 + r + p * 8) * K + k0 + c] = f2bf(t[c][r + p * 8]);
}

// ---------------- batched transpose of the four 768x768 weights ----------------
__global__ __launch_bounds__(256) void transpose4_kernel(const float* __restrict__ wq,
                                                         const float* __restrict__ wk,
                                                         const float* __restrict__ wv,
                                                         const float* __restrict__ wp,
                                                         unsigned short* __restrict__ wqkvT,
                                                         unsigned short* __restrict__ wprojT) {
    __shared__ float t[32][33];
    int z = blockIdx.z;
    const float* W = (z == 0) ? wq : (z == 1) ? wk : (z == 2) ? wv : wp;
    unsigned short* WT = (z < 3) ? (wqkvT + (long)z * NE * NE) : wprojT;
    int k0 = blockIdx.y * 32;
    int n0 = blockIdx.x * 32;
    int c = threadIdx.x & 31, r = threadIdx.x >> 5;
    #pragma unroll
    for (int p = 0; p < 4; ++p)
        t[r + p * 8][c] = W[(long)(k0 + r + p * 8) * NE + n0 + c];
    __syncthreads();
    #pragma unroll
    for (int p = 0; p < 4; ++p)
        WT[(long)(n0 + r + p * 8) * NE + k0 + c] = f2bf(t[c][r + p * 8]);
}

// ---------------- plain fp32 -> bf16 cast ----------------
__global__ __launch_bounds__(256) void cast_kernel(const float* __restrict__ W,
                                                   unsigned short* __restrict__ O, int n) {
    int i = (blockIdx.x * 256 + threadIdx.x) * 4;
    if (i < n) {
        float4 v = *(const float4*)(W + i);
        ushort4v o;
        o[0] = f2bf(v.x); o[1] = f2bf(v.y); o[2] = f2bf(v.z); o[3] = f2bf(v.w);
        *(ushort4v*)(O + i) = o;
    }
}

// ---------------- beff[n] = sum_j bproj[j]*Wp[j][n] + bproj[n] ----------------
__global__ __launch_bounds__(256) void beff_kernel(const float* __restrict__ bproj,
                                                   const unsigned short* __restrict__ wprojT,
                                                   float* __restrict__ beff) {
    __shared__ float red[256];
    int n = blockIdx.x, tid = threadIdx.x;
    float acc = 0.f;
    for (int j = tid; j < NE; j += 256) acc += bproj[j] * bf2f(wprojT[(long)n * NE + j]);
    red[tid] = acc; __syncthreads();
    for (int o = 128; o > 0; o >>= 1) { if (tid < o) red[tid] += red[tid + o]; __syncthreads(); }
    if (tid == 0) beff[n] = red[0] + bproj[n];
}

// ---------------- combine split-K partials (+bias)(+residual-add or bf16-out) ----------------
template<int S, bool RESADD, bool BIAS>
__global__ __launch_bounds__(256) void combine_kernel(const float* __restrict__ parts,
                                                      const float* __restrict__ bias,
                                                      float* __restrict__ x,
                                                      unsigned short* __restrict__ bout,
                                                      int N, long total) {
    long i = ((long)blockIdx.x * 256 + threadIdx.x) * 4;
    if (i >= total) return;
    float4 a = *(const float4*)(parts + i);
    #pragma unroll
    for (int s = 1; s < S; ++s) {
        float4 b = *(const float4*)(parts + (long)s * total + i);
        a.x += b.x; a.y += b.y; a.z += b.z; a.w += b.w;
    }
    if (BIAS) {
        int n = (int)(i % N);
        a.x += bias[n]; a.y += bias[n + 1]; a.z += bias[n + 2]; a.w += bias[n + 3];
    }
    if (RESADD) {
        float4 xv = *(const float4*)(x + i);
        a.x += xv.x; a.y += xv.y; a.z += xv.z; a.w += xv.w;
        *(float4*)(x + i) = a;
    } else {
        ushort4v o;
        o[0] = f2bf(a.x); o[1] = f2bf(a.y); o[2] = f2bf(a.z); o[3] = f2bf(a.w);
        *(ushort4v*)(bout + i) = o;
    }
}

// ---------------- bf16 MFMA GEMM, 2-phase double-buffered, optional split-K ----------------
// 128x128 tile, BK=32, 256 threads = 4 waves (2x2). grid.x = gridM*gridN (XCD-swizzled,
// m-fastest); grid.y = SPLITK slice. SPLITK>1: OutT=float, writes partials at slice offset.
template<typename OutT, bool BIAS, bool RELU, bool RESADD, bool LSE, int SPLITK>
__global__ __launch_bounds__(256) void gemm_mfma(const unsigned short* __restrict__ A,
                                                 const unsigned short* __restrict__ BT,
                                                 const float* __restrict__ bias,
                                                 OutT* __restrict__ C,
                                                 float* __restrict__ pm, float* __restrict__ ps,
                                                 int gridM, int N, int K) {
    __shared__ unsigned short As[2][128 * 32];
    __shared__ unsigned short Bs[2][128 * 32];
    int tid = threadIdx.x;
    int lane = tid & 63, w = tid >> 6;
    int wr = w >> 1, wc = w & 1;
    int l4 = lane >> 4, l15 = lane & 15;

    // bijective XCD-chunked remap, then m-fastest decode
    int nwg = gridDim.x, orig = blockIdx.x;
    int q = nwg >> 3, r8 = nwg & 7;
    int xcd = orig & 7, ii = orig >> 3;
    int wg = (xcd < r8) ? (xcd * (q + 1) + ii) : (r8 * (q + 1) + (xcd - r8) * q + ii);
    int bm = wg % gridM, bn = wg / gridM;
    int m0 = bm * 128, n0 = bn * 128;

    int kb = K / SPLITK;                       // K range for this slice
    int koff = (SPLITK > 1) ? blockIdx.y * kb : 0;

    f32x4 acc[4][4] = {};

    int srow = lane >> 2;
    int scol = (lane & 3) * 8;

    // prologue: stage k-step 0 into buffer 0
    #pragma unroll
    for (int it = 0; it < 2; ++it) {
        int rr = w * 32 + it * 16;
        gload_lds16(&A [(long)(m0 + rr + srow) * K + koff + scol], &As[0][rr * 32]);
        gload_lds16(&BT[(long)(n0 + rr + srow) * K + koff + scol], &Bs[0][rr * 32]);
    }

    int cur = 0;
    for (int k0 = 0; k0 < kb; k0 += 32) {
        __syncthreads();   // drains vmcnt: buf[cur] staged; prev compute's LDS reads done
        if (k0 + 32 < kb) {
            #pragma unroll
            for (int it = 0; it < 2; ++it) {
                int rr = w * 32 + it * 16;
                gload_lds16(&A [(long)(m0 + rr + srow) * K + koff + k0 + 32 + scol], &As[cur ^ 1][rr * 32]);
                gload_lds16(&BT[(long)(n0 + rr + srow) * K + koff + k0 + 32 + scol], &Bs[cur ^ 1][rr * 32]);
            }
        }

        short8 a[4], b[4];
        #pragma unroll
        for (int f = 0; f < 4; ++f) {
            a[f] = *(const short8*)&As[cur][(wr * 64 + f * 16 + l15) * 32 + l4 * 8];
            b[f] = *(const short8*)&Bs[cur][(wc * 64 + f * 16 + l15) * 32 + l4 * 8];
        }
        __builtin_amdgcn_s_setprio(1);
        #pragma unroll
        for (int fm = 0; fm < 4; ++fm)
            #pragma unroll
            for (int fn = 0; fn < 4; ++fn)
                acc[fm][fn] = __builtin_amdgcn_mfma_f32_16x16x32_bf16(a[fm], b[fn], acc[fm][fn], 0, 0, 0);
        __builtin_amdgcn_s_setprio(0);
        cur ^= 1;
    }

    if constexpr (SPLITK > 1) {
        float* Cp = (float*)C + (long)blockIdx.y * gridM * 128 * N;
        #pragma unroll
        for (int fm = 0; fm < 4; ++fm)
            #pragma unroll
            for (int j = 0; j < 4; ++j) {
                long row = m0 + wr * 64 + fm * 16 + l4 * 4 + j;
                #pragma unroll
                for (int fn = 0; fn < 4; ++fn)
                    Cp[row * N + n0 + wc * 64 + fn * 16 + l15] = acc[fm][fn][j];
            }
    } else {
        float bs[4];
        #pragma unroll
        for (int fn = 0; fn < 4; ++fn)
            bs[fn] = BIAS ? bias[n0 + wc * 64 + fn * 16 + l15] : 0.f;

        #pragma unroll
        for (int fm = 0; fm < 4; ++fm) {
            #pragma unroll
            for (int j = 0; j < 4; ++j) {
                long row = m0 + wr * 64 + fm * 16 + l4 * 4 + j;
                float v4[4];
                #pragma unroll
                for (int fn = 0; fn < 4; ++fn) {
                    int col = n0 + wc * 64 + fn * 16 + l15;
                    float v = acc[fm][fn][j] + bs[fn];
                    if (RELU) v = fmaxf(v, 0.f);
                    v4[fn] = v;
                    if constexpr (RESADD)               C[row * N + col] += v;
                    else if constexpr (sizeof(OutT)==2) C[row * N + col] = (OutT)f2bf(v);
                    else                                C[row * N + col] = v;
                }
                if constexpr (LSE) {
                    float mx = fmaxf(fmaxf(v4[0], v4[1]), fmaxf(v4[2], v4[3]));
                    #pragma unroll
                    for (int off = 1; off < 16; off <<= 1) mx = fmaxf(mx, __shfl_xor(mx, off));
                    float sm = 0.f;
                    #pragma unroll
                    for (int fn = 0; fn < 4; ++fn) sm += __expf(v4[fn] - mx);
                    #pragma unroll
                    for (int off = 1; off < 16; off <<= 1) sm += __shfl_xor(sm, off);
                    if (l15 == 0) {
                        int pidx = bn * 2 + wc;
                        pm[row * 512 + pidx] = mx;
                        ps[row * 512 + pidx] = sm;
                    }
                }
            }
        }
    }
}

// ---------------- flash attention, MFMA, one block per (q-tile of 64, b*h) ----------------
__global__ __launch_bounds__(256) void fattn_kernel(const unsigned short* __restrict__ qkv,
                                                    unsigned short* __restrict__ out) {
    __shared__ unsigned short Ks[64 * 64];       // [key][d], XOR-swizzled 16B granules
    __shared__ unsigned short Vt[64 * 64];       // [d][key], XOR-swizzled
    __shared__ unsigned short Ps[4 * 16 * 64];   // per-wave [q][key], XOR-swizzled
    int qt = gridDim.x - 1 - blockIdx.x;         // heavy q-tiles first
    int bh = blockIdx.y;
    int b = bh / NH, h = bh % NH;
    int tid = threadIdx.x, lane = tid & 63, w = tid >> 6;
    int l4 = lane >> 4, l15 = lane & 15;
    long rowb = (long)b * NT;
    const float scale = 0.03608439182435161f;    // 768^-0.5 (reference scales by E)

    const unsigned short* qptr = qkv + (rowb + qt * 64 + w * 16 + l15) * NQKV + h * NHS;
    short8 qa0 = *(const short8*)(qptr + l4 * 8);
    short8 qa1 = *(const short8*)(qptr + 32 + l4 * 8);

    f32x4 o[4] = {};
    float m[4], lsum[4];
    #pragma unroll
    for (int j = 0; j < 4; ++j) { m[j] = -INFINITY; lsum[j] = 0.f; }

    for (int t = 0; t <= qt; ++t) {
        int kbase = t * 64;
        #pragma unroll
        for (int i = 0; i < 2; ++i) {
            int idx = tid + i * 256;
            int r = idx >> 3, cc = idx & 7;
            const unsigned short* kv = qkv + (rowb + kbase + r) * NQKV + NE + h * NHS;
            short8 k8 = *(const short8*)(kv + cc * 8);
            *(short8*)&Ks[r * 64 + ((cc * 8) ^ ((r & 7) << 3))] = k8;
        }
        #pragma unroll
        for (int i = 0; i < 2; ++i) {
            int d = tid & 63, kc = (tid >> 6) + i * 4;
            const unsigned short* vp = qkv + (rowb + kbase + kc * 8) * NQKV + 2 * NE + h * NHS + d;
            short8 v8;
            #pragma unroll
            for (int j = 0; j < 8; ++j) v8[j] = (short)vp[(long)j * NQKV];
            *(short8*)&Vt[d * 64 + ((kc * 8) ^ ((d & 7) << 3))] = v8;
        }
        __syncthreads();

        f32x4 s[4];
        __builtin_amdgcn_s_setprio(1);
        #pragma unroll
        for (int fn = 0; fn < 4; ++fn) {
            int key = fn * 16 + l15;
            short8 kb0 = *(const short8*)&Ks[key * 64 + ((l4 * 8) ^ ((key & 7) << 3))];
            short8 kb1 = *(const short8*)&Ks[key * 64 + ((32 + l4 * 8) ^ ((key & 7) << 3))];
            f32x4 z = {};
            z = __builtin_amdgcn_mfma_f32_16x16x32_bf16(qa0, kb0, z, 0, 0, 0);
            s[fn] = __builtin_amdgcn_mfma_f32_16x16x32_bf16(qa1, kb1, z, 0, 0, 0);
        }
        __builtin_amdgcn_s_setprio(0);

        if (t == qt) {
            #pragma unroll
            for (int fn = 0; fn < 4; ++fn) {
                int key = kbase + fn * 16 + l15;
                #pragma unroll
                for (int j = 0; j < 4; ++j) {
                    int qrow = qt * 64 + w * 16 + l4 * 4 + j;
                    s[fn][j] = (key <= qrow) ? s[fn][j] * scale : -1e30f;
                }
            }
        } else {
            #pragma unroll
            for (int fn = 0; fn < 4; ++fn)
                #pragma unroll
                for (int j = 0; j < 4; ++j)
                    s[fn][j] *= scale;
        }

        #pragma unroll
        for (int j = 0; j < 4; ++j) {
            float mj = fmaxf(fmaxf(s[0][j], s[1][j]), fmaxf(s[2][j], s[3][j]));
            #pragma unroll
            for (int off = 1; off < 16; off <<= 1) mj = fmaxf(mj, __shfl_xor(mj, off));
            float mnew = fmaxf(m[j], mj);
            float alpha = __expf(m[j] - mnew);
            m[j] = mnew;
            float psum = 0.f;
            #pragma unroll
            for (int fn = 0; fn < 4; ++fn) {
                float p = __expf(s[fn][j] - mnew);
                psum += p;
                int rr = l4 * 4 + j, c = fn * 16 + l15;
                Ps[w * 1024 + rr * 64 + (c ^ ((rr & 7) << 3))] = f2bf(p);
            }
            #pragma unroll
            for (int off = 1; off < 16; off <<= 1) psum += __shfl_xor(psum, off);
            lsum[j] = lsum[j] * alpha + psum;
            #pragma unroll
            for (int fn = 0; fn < 4; ++fn) o[fn][j] *= alpha;
        }

        short8 pa0 = *(const short8*)&Ps[w * 1024 + l15 * 64 + ((l4 * 8) ^ ((l15 & 7) << 3))];
        short8 pa1 = *(const short8*)&Ps[w * 1024 + l15 * 64 + ((32 + l4 * 8) ^ ((l15 & 7) << 3))];
        __builtin_amdgcn_s_setprio(1);
        #pragma unroll
        for (int fn = 0; fn < 4; ++fn) {
            int d = fn * 16 + l15;
            short8 vb0 = *(const short8*)&Vt[d * 64 + ((l4 * 8) ^ ((d & 7) << 3))];
            short8 vb1 = *(const short8*)&Vt[d * 64 + ((32 + l4 * 8) ^ ((d & 7) << 3))];
            o[fn] = __builtin_amdgcn_mfma_f32_16x16x32_bf16(pa0, vb0, o[fn], 0, 0, 0);
            o[fn] = __builtin_amdgcn_mfma_f32_16x16x32_bf16(pa1, vb1, o[fn], 0, 0, 0);
        }
        __builtin_amdgcn_s_setprio(0);
        __syncthreads();
    }

    #pragma unroll
    for (int j = 0; j < 4; ++j) {
        long row = rowb + qt * 64 + w * 16 + l4 * 4 + j;
        float inv = 1.0f / lsum[j];
        #pragma unroll
        for (int fn = 0; fn < 4; ++fn)
            out[row * NE + h * NHS + fn * 16 + l15] = f2bf(o[fn][j] * inv);
    }
}

// ---------------- NLL from LM-head partials ----------------
__global__ __launch_bounds__(256) void nll_combine_kernel(const float* __restrict__ logits,
                                                          const float* __restrict__ pm,
                                                          const float* __restrict__ ps,
                                                          const int* __restrict__ targets,
                                                          float* __restrict__ nll) {
    __shared__ float rm[256], rs[256];
    int row = blockIdx.x, tid = threadIdx.x;
    float m = -1e30f, s = 0.f;
    for (int i = tid; i < 500; i += 256) {
        float m2 = pm[(long)row * 512 + i], s2 = ps[(long)row * 512 + i];
        float mm = fmaxf(m, m2);
        s = s * __expf(m - mm) + s2 * __expf(m2 - mm);
        m = mm;
    }
    rm[tid] = m; rs[tid] = s; __syncthreads();
    for (int o = 128; o > 0; o >>= 1) {
        if (tid < o) {
            float m2 = rm[tid + o], s2 = rs[tid + o];
            float mm = fmaxf(rm[tid], m2);
            rs[tid] = rs[tid] * __expf(rm[tid] - mm) + s2 * __expf(m2 - mm);
            rm[tid] = mm;
        }
        __syncthreads();
    }
    if (tid == 0) {
        int tgt = targets[row];
        nll[row] = -(logits[(long)row * NV + tgt] - rm[0] - logf(rs[0]));
    }
}

__global__ void loss_reduce_kernel(const float* __restrict__ nll, float* __restrict__ out) {
    __shared__ float red[256];
    int tid = threadIdx.x;
    float s = 0.f;
    for (int i = tid; i < NM; i += 256) s += nll[i];
    red[tid] = s; __syncthreads();
    for (int o = 128; o > 0; o >>= 1) { if (tid < o) red[tid] += red[tid + o]; __syncthreads(); }
    if (tid == 0) out[0] = red[0] / NM;
}

extern "C" void kernel_launch(void* const* d_in, const int* in_sizes, int n_in,
                              void* d_out, int out_size, void* d_ws, size_t ws_size,
                              hipStream_t stream) {
    const int*   idx     = (const int*)  d_in[0];
    const int*   targets = (const int*)  d_in[1];
    const float* tok     = (const float*)d_in[2];
    const float* pos     = (const float*)d_in[3];
    const float* ln1_g   = (const float*)d_in[4];
    const float* ln1_b   = (const float*)d_in[5];
    const float* wq      = (const float*)d_in[6];
    const float* wk      = (const float*)d_in[7];
    const float* wv      = (const float*)d_in[8];
    const float* wproj   = (const float*)d_in[9];
    const float* bproj   = (const float*)d_in[10];
    const float* ln2_g   = (const float*)d_in[11];
    const float* ln2_b   = (const float*)d_in[12];
    const float* w1      = (const float*)d_in[13];
    const float* b1      = (const float*)d_in[14];
    const float* w2      = (const float*)d_in[15];
    const float* b2      = (const float*)d_in[16];
    const float* lnf_g   = (const float*)d_in[17];
    const float* lnf_b   = (const float*)d_in[18];
    const float* lm_w    = (const float*)d_in[19];
    const float* lm_b    = (const float*)d_in[20];

    float* logits = (float*)d_out;
    float* loss   = logits + (long)NM * NV;

    char* p = (char*)d_ws;
    float*          x      = (float*)p;          p += (long)NM * NE * 4;
    unsigned short* hbuf   = (unsigned short*)p; p += (long)NM * NE * 2;
    unsigned short* qkv    = (unsigned short*)p; p += (long)NM * NQKV * 2;
    unsigned short* att    = (unsigned short*)p; p += (long)NM * NE * 2;
    unsigned short* hid    = (unsigned short*)p; p += (long)NM * NFF * 2;
    float*          nll    = (float*)p;          p += (long)NM * 4;
    float*          pmb    = (float*)p;          p += (long)NM * 512 * 4;
    float*          psb    = (float*)p;          p += (long)NM * 512 * 4;
    float*          parts  = (float*)p;          p += (long)4 * NM * NQKV * 4;  // split-K arena (covers all uses)
    unsigned short* wqkvT  = (unsigned short*)p; p += (long)NQKV * NE * 2;
    unsigned short* wprojT = (unsigned short*)p; p += (long)NE * NE * 2;
    unsigned short* wprojC = (unsigned short*)p; p += (long)NE * NE * 2;
    unsigned short* weffT  = (unsigned short*)p; p += (long)NE * NE * 2;
    float*          beff   = (float*)p;          p += (long)NE * 4;
    unsigned short* w1T    = (unsigned short*)p; p += (long)NFF * NE * 2;
    unsigned short* w2T    = (unsigned short*)p; p += (long)NE * NFF * 2;
    unsigned short* lmT    = (unsigned short*)p; p += (long)NV * NE * 2;

    dim3 blk(256);
    embed_kernel<<<NM, blk, 0, stream>>>(idx, tok, pos, x);

    for (int l = 0; l < NL; ++l) {
        long wofs = (long)l * NE * NE;
        transpose4_kernel<<<dim3(NE / 32, NE / 32, 4), blk, 0, stream>>>(
            wq + wofs, wk + wofs, wv + wofs, wproj + wofs, wqkvT, wprojT);
        cast_kernel<<<(NE * NE) / 1024, blk, 0, stream>>>(wproj + wofs, wprojC, NE * NE);
        // Weff = Wp @ Wp via split-K=4 partials, combine to bf16 weffT
        gemm_mfma<float, false, false, false, false, 4><<<dim3(36, 4), blk, 0, stream>>>(
            wprojT, wprojC, nullptr, parts, nullptr, nullptr, 6, NE, NE);
        combine_kernel<4, false, false><<<(NE * NE) / 1024, blk, 0, stream>>>(
            parts, nullptr, nullptr, weffT, NE, (long)NE * NE);
        beff_kernel<<<NE, blk, 0, stream>>>(bproj + l * NE, wprojT, beff);
        transpose_cast_kernel<<<dim3(NFF / 32, NE / 32), blk, 0, stream>>>(w1 + (long)l * NE * NFF, w1T, NE, NFF);
        transpose_cast_kernel<<<dim3(NE / 32, NFF / 32), blk, 0, stream>>>(w2 + (long)l * NFF * NE, w2T, NFF, NE);

        ln_kernel<<<NM, blk, 0, stream>>>(x, ln1_g + l * NE, ln1_b + l * NE, hbuf);
        // QKV: split-K=2, combine to bf16
        gemm_mfma<float, false, false, false, false, 2><<<dim3((NM/128)*(NQKV/128), 2), blk, 0, stream>>>(
            hbuf, wqkvT, nullptr, parts, nullptr, nullptr, NM / 128, NQKV, NE);
        combine_kernel<2, false, false><<<(NM * NQKV) / 1024, blk, 0, stream>>>(
            parts, nullptr, nullptr, qkv, NQKV, (long)NM * NQKV);
        fattn_kernel<<<dim3(NT / 64, NB * NH), blk, 0, stream>>>(qkv, att);
        // fused double-proj: split-K=2, combine adds beff + residual into x
        gemm_mfma<float, false, false, false, false, 2><<<dim3((NM/128)*(NE/128), 2), blk, 0, stream>>>(
            att, weffT, nullptr, parts, nullptr, nullptr, NM / 128, NE, NE);
        combine_kernel<2, true, true><<<(NM * NE) / 1024, blk, 0, stream>>>(
            parts, beff, x, nullptr, NE, (long)NM * NE);

        ln_kernel<<<NM, blk, 0, stream>>>(x, ln2_g + l * NE, ln2_b + l * NE, hbuf);
        gemm_mfma<unsigned short, true, true, false, false, 1><<<dim3((NM/128)*(NFF/128)), blk, 0, stream>>>(
            hbuf, w1T, b1 + (long)l * NFF, hid, nullptr, nullptr, NM / 128, NFF, NE);
        // FF2: split-K=4, combine adds b2 + residual into x
        gemm_mfma<float, false, false, false, false, 4><<<dim3((NM/128)*(NE/128), 4), blk, 0, stream>>>(
            hid, w2T, nullptr, parts, nullptr, nullptr, NM / 128, NE, NFF);
        combine_kernel<4, true, true><<<(NM * NE) / 1024, blk, 0, stream>>>(
            parts, b2 + l * NE, x, nullptr, NE, (long)NM * NE);
    }

    ln_kernel<<<NM, blk, 0, stream>>>(x, lnf_g, lnf_b, hbuf);
    transpose_cast_kernel<<<dim3(NV / 32, NE / 32), blk, 0, stream>>>(lm_w, lmT, NE, NV);
    gemm_mfma<float, true, false, false, true, 1><<<dim3((NM/128)*(NV/128)), blk, 0, stream>>>(
        hbuf, lmT, lm_b, logits, pmb, psb, NM / 128, NV, NE);
    nll_combine_kernel<<<NM, blk, 0, stream>>>(logits, pmb, psb, targets, nll);
    loss_reduce_kernel<<<1, blk, 0, stream>>>(nll, loss);
}

// Round 6
// 1287.952 us; speedup vs baseline: 8.9072x; 1.0172x over previous
//
#include <hip/hip_runtime.h>
#include <math.h>

#define NL 6
#define NH 12
#define NE 768
#define NHS 64
#define NT 1024
#define NB 2
#define NV 32000
#define NM (NB * NT)   // 2048
#define NQKV (3 * NE)  // 2304
#define NFF (4 * NE)   // 3072
#define LN_EPS 1e-5f

typedef __attribute__((ext_vector_type(8))) short short8;
typedef __attribute__((ext_vector_type(4))) float f32x4;
typedef __attribute__((ext_vector_type(4))) unsigned short ushort4v;
typedef __attribute__((address_space(1))) const unsigned int as1_cuint;
typedef __attribute__((address_space(3))) unsigned int as3_uint;

__device__ __forceinline__ unsigned short f2bf(float f) {
    unsigned int u = __builtin_bit_cast(unsigned int, f);
    u += 0x7fffu + ((u >> 16) & 1u);   // RNE
    return (unsigned short)(u >> 16);
}
__device__ __forceinline__ float bf2f(unsigned short u) {
    unsigned int v = ((unsigned int)u) << 16;
    return __builtin_bit_cast(float, v);
}
__device__ __forceinline__ void gload_lds16(const void* g, void* l) {
    __builtin_amdgcn_global_load_lds((as1_cuint*)g, (as3_uint*)l, 16, 0, 0);
}

// ---------------- embedding ----------------
__global__ void embed_kernel(const int* __restrict__ idx, const float* __restrict__ tok,
                             const float* __restrict__ pos, float* __restrict__ x) {
    int row = blockIdx.x;
    int t = row % NT;
    int id = idx[row];
    const float* te = tok + (long)id * NE;
    const float* pe = pos + (long)t * NE;
    float* xr = x + (long)row * NE;
    for (int e = threadIdx.x; e < NE; e += blockDim.x)
        xr[e] = te[e] + pe[e];
}

// ---------------- layernorm per row: fp32 in, bf16 out ----------------
__global__ __launch_bounds__(256) void ln_kernel(const float* __restrict__ x, const float* __restrict__ g,
                                                 const float* __restrict__ b, unsigned short* __restrict__ out) {
    __shared__ float red[256];
    int row = blockIdx.x;
    const float* xr = x + (long)row * NE;
    unsigned short* outr = out + (long)row * NE;
    int tid = threadIdx.x;

    float s = 0.f;
    for (int e = tid; e < NE; e += 256) s += xr[e];
    red[tid] = s; __syncthreads();
    for (int o = 128; o > 0; o >>= 1) { if (tid < o) red[tid] += red[tid + o]; __syncthreads(); }
    float mu = red[0] / NE;
    __syncthreads();

    float v = 0.f;
    for (int e = tid; e < NE; e += 256) { float d = xr[e] - mu; v += d * d; }
    red[tid] = v; __syncthreads();
    for (int o = 128; o > 0; o >>= 1) { if (tid < o) red[tid] += red[tid + o]; __syncthreads(); }
    float rstd = rsqrtf(red[0] / NE + LN_EPS);

    for (int e = tid; e < NE; e += 256)
        outr[e] = f2bf((xr[e] - mu) * rstd * g[e] + b[e]);
}

// ---------------- tiled transpose + fp32->bf16 cast: WT[n][k] = W[k][n] ----------------
__global__ __launch_bounds__(256) void transpose_cast_kernel(const float* __restrict__ W,
                                                             unsigned short* __restrict__ WT,
                                                             int K, int N) {
    __shared__ float t[32][33];
    int k0 = blockIdx.y * 32;
    int n0 = blockIdx.x * 32;
    int c = threadIdx.x & 31, r = threadIdx.x >> 5;
    #pragma unroll
    for (int p = 0; p < 4; ++p)
        t[r + p * 8][c] = W[(long)(k0 + r + p * 8) * N + n0 + c];
    __syncthreads();
    #pragma unroll
    for (int p = 0; p < 4; ++p)
        WT[(long)(n0 + r + p * 8) * K + k0 + c] = f2bf(t[c][r + p * 8]);
}

// ---------------- batched transpose of the four 768x768 weights ----------------
__global__ __launch_bounds__(256) void transpose4_kernel(const float* __restrict__ wq,
                                                         const float* __restrict__ wk,
                                                         const float* __restrict__ wv,
                                                         const float* __restrict__ wp,
                                                         unsigned short* __restrict__ wqkvT,
                                                         unsigned short* __restrict__ wprojT) {
    __shared__ float t[32][33];
    int z = blockIdx.z;
    const float* W = (z == 0) ? wq : (z == 1) ? wk : (z == 2) ? wv : wp;
    unsigned short* WT = (z < 3) ? (wqkvT + (long)z * NE * NE) : wprojT;
    int k0 = blockIdx.y * 32;
    int n0 = blockIdx.x * 32;
    int c = threadIdx.x & 31, r = threadIdx.x >> 5;
    #pragma unroll
    for (int p = 0; p < 4; ++p)
        t[r + p * 8][c] = W[(long)(k0 + r + p * 8) * NE + n0 + c];
    __syncthreads();
    #pragma unroll
    for (int p = 0; p < 4; ++p)
        WT[(long)(n0 + r + p * 8) * NE + k0 + c] = f2bf(t[c][r + p * 8]);
}

// ---------------- plain fp32 -> bf16 cast ----------------
__global__ __launch_bounds__(256) void cast_kernel(const float* __restrict__ W,
                                                   unsigned short* __restrict__ O, int n) {
    int i = (blockIdx.x * 256 + threadIdx.x) * 4;
    if (i < n) {
        float4 v = *(const float4*)(W + i);
        ushort4v o;
        o[0] = f2bf(v.x); o[1] = f2bf(v.y); o[2] = f2bf(v.z); o[3] = f2bf(v.w);
        *(ushort4v*)(O + i) = o;
    }
}

// ---------------- beff[n] = sum_j bproj[j]*Wp[j][n] + bproj[n] ----------------
__global__ __launch_bounds__(256) void beff_kernel(const float* __restrict__ bproj,
                                                   const unsigned short* __restrict__ wprojT,
                                                   float* __restrict__ beff) {
    __shared__ float red[256];
    int n = blockIdx.x, tid = threadIdx.x;
    float acc = 0.f;
    for (int j = tid; j < NE; j += 256) acc += bproj[j] * bf2f(wprojT[(long)n * NE + j]);
    red[tid] = acc; __syncthreads();
    for (int o = 128; o > 0; o >>= 1) { if (tid < o) red[tid] += red[tid + o]; __syncthreads(); }
    if (tid == 0) beff[n] = red[0] + bproj[n];
}

// ---------------- combine split-K partials (+bias)(+residual-add or bf16-out) ----------------
template<int S, bool RESADD, bool BIAS>
__global__ __launch_bounds__(256) void combine_kernel(const float* __restrict__ parts,
                                                      const float* __restrict__ bias,
                                                      float* __restrict__ x,
                                                      unsigned short* __restrict__ bout,
                                                      int N, long total) {
    long i = ((long)blockIdx.x * 256 + threadIdx.x) * 4;
    if (i >= total) return;
    float4 a = *(const float4*)(parts + i);
    #pragma unroll
    for (int s = 1; s < S; ++s) {
        float4 b = *(const float4*)(parts + (long)s * total + i);
        a.x += b.x; a.y += b.y; a.z += b.z; a.w += b.w;
    }
    if (BIAS) {
        int n = (int)(i % N);
        a.x += bias[n]; a.y += bias[n + 1]; a.z += bias[n + 2]; a.w += bias[n + 3];
    }
    if (RESADD) {
        float4 xv = *(const float4*)(x + i);
        a.x += xv.x; a.y += xv.y; a.z += xv.z; a.w += xv.w;
        *(float4*)(x + i) = a;
    } else {
        ushort4v o;
        o[0] = f2bf(a.x); o[1] = f2bf(a.y); o[2] = f2bf(a.z); o[3] = f2bf(a.w);
        *(ushort4v*)(bout + i) = o;
    }
}

// ---------------- 128x128 bf16 MFMA GEMM, 2-phase dbuf, optional split-K ----------------
template<typename OutT, bool BIAS, bool RELU, bool RESADD, int SPLITK>
__global__ __launch_bounds__(256) void gemm_mfma(const unsigned short* __restrict__ A,
                                                 const unsigned short* __restrict__ BT,
                                                 const float* __restrict__ bias,
                                                 OutT* __restrict__ C,
                                                 int gridM, int N, int K) {
    __shared__ unsigned short As[2][128 * 32];
    __shared__ unsigned short Bs[2][128 * 32];
    int tid = threadIdx.x;
    int lane = tid & 63, w = tid >> 6;
    int wr = w >> 1, wc = w & 1;
    int l4 = lane >> 4, l15 = lane & 15;

    int nwg = gridDim.x, orig = blockIdx.x;
    int q = nwg >> 3, r8 = nwg & 7;
    int xcd = orig & 7, ii = orig >> 3;
    int wg = (xcd < r8) ? (xcd * (q + 1) + ii) : (r8 * (q + 1) + (xcd - r8) * q + ii);
    int bm = wg % gridM, bn = wg / gridM;
    int m0 = bm * 128, n0 = bn * 128;

    int kb = K / SPLITK;
    int koff = (SPLITK > 1) ? blockIdx.y * kb : 0;

    f32x4 acc[4][4] = {};

    int srow = lane >> 2;
    int scol = (lane & 3) * 8;

    #pragma unroll
    for (int it = 0; it < 2; ++it) {
        int rr = w * 32 + it * 16;
        gload_lds16(&A [(long)(m0 + rr + srow) * K + koff + scol], &As[0][rr * 32]);
        gload_lds16(&BT[(long)(n0 + rr + srow) * K + koff + scol], &Bs[0][rr * 32]);
    }

    int cur = 0;
    for (int k0 = 0; k0 < kb; k0 += 32) {
        __syncthreads();
        if (k0 + 32 < kb) {
            #pragma unroll
            for (int it = 0; it < 2; ++it) {
                int rr = w * 32 + it * 16;
                gload_lds16(&A [(long)(m0 + rr + srow) * K + koff + k0 + 32 + scol], &As[cur ^ 1][rr * 32]);
                gload_lds16(&BT[(long)(n0 + rr + srow) * K + koff + k0 + 32 + scol], &Bs[cur ^ 1][rr * 32]);
            }
        }

        short8 a[4], b[4];
        #pragma unroll
        for (int f = 0; f < 4; ++f) {
            a[f] = *(const short8*)&As[cur][(wr * 64 + f * 16 + l15) * 32 + l4 * 8];
            b[f] = *(const short8*)&Bs[cur][(wc * 64 + f * 16 + l15) * 32 + l4 * 8];
        }
        __builtin_amdgcn_s_setprio(1);
        #pragma unroll
        for (int fm = 0; fm < 4; ++fm)
            #pragma unroll
            for (int fn = 0; fn < 4; ++fn)
                acc[fm][fn] = __builtin_amdgcn_mfma_f32_16x16x32_bf16(a[fm], b[fn], acc[fm][fn], 0, 0, 0);
        __builtin_amdgcn_s_setprio(0);
        cur ^= 1;
    }

    if constexpr (SPLITK > 1) {
        float* Cp = (float*)C + (long)blockIdx.y * gridM * 128 * N;
        #pragma unroll
        for (int fm = 0; fm < 4; ++fm)
            #pragma unroll
            for (int j = 0; j < 4; ++j) {
                long row = m0 + wr * 64 + fm * 16 + l4 * 4 + j;
                #pragma unroll
                for (int fn = 0; fn < 4; ++fn)
                    Cp[row * N + n0 + wc * 64 + fn * 16 + l15] = acc[fm][fn][j];
            }
    } else {
        float bs[4];
        #pragma unroll
        for (int fn = 0; fn < 4; ++fn)
            bs[fn] = BIAS ? bias[n0 + wc * 64 + fn * 16 + l15] : 0.f;

        #pragma unroll
        for (int fm = 0; fm < 4; ++fm) {
            #pragma unroll
            for (int j = 0; j < 4; ++j) {
                long row = m0 + wr * 64 + fm * 16 + l4 * 4 + j;
                #pragma unroll
                for (int fn = 0; fn < 4; ++fn) {
                    int col = n0 + wc * 64 + fn * 16 + l15;
                    float v = acc[fm][fn][j] + bs[fn];
                    if (RELU) v = fmaxf(v, 0.f);
                    if constexpr (RESADD)               C[row * N + col] += v;
                    else if constexpr (sizeof(OutT)==2) C[row * N + col] = (OutT)f2bf(v);
                    else                                C[row * N + col] = v;
                }
            }
        }
    }
}

// ---------------- 256x256 bf16 MFMA GEMM, 4-slot LDS, depth-2 counted-vmcnt pipeline ----------------
// 512 threads = 8 waves (2 M-rows x 4 N-cols), per-wave 128x64 output, BK=32.
// LDS st-swizzle: logical 16B slot q at row r stored at slot q^((r>>1)&3); reads use
// lane-only form q = l4 ^ ((l15>>1)&3); staging pre-swizzles the GLOBAL source (rule #21).
// Epilogue: +bias, fp32 store, per-row LSE partials (max,sumexp over 64-col slice).
__global__ __launch_bounds__(512, 2) void gemm256_lse(const unsigned short* __restrict__ A,
                                                      const unsigned short* __restrict__ BT,
                                                      const float* __restrict__ bias,
                                                      float* __restrict__ C,
                                                      float* __restrict__ pm, float* __restrict__ ps,
                                                      int gridM, int N, int K) {
    __shared__ unsigned short Al[4][256 * 32];
    __shared__ unsigned short Bl[4][256 * 32];
    int tid = threadIdx.x;
    int lane = tid & 63, w = tid >> 6;
    int wr = w >> 2, wn = w & 3;
    int l4 = lane >> 4, l15 = lane & 15;

    int nwg = gridDim.x, orig = blockIdx.x;
    int q = nwg >> 3, r8 = nwg & 7;
    int xcd = orig & 7, ii = orig >> 3;
    int wg = (xcd < r8) ? (xcd * (q + 1) + ii) : (r8 * (q + 1) + (xcd - r8) * q + ii);
    int bm = wg % gridM, bn = wg / gridM;
    int m0 = bm * 256, n0 = bn * 256;

    int nkt = K >> 5;

    // staging geometry: 8 waves x 2 iters x (16 rows x 64B) = 256x64B per operand
    int srow = lane >> 2;                          // 0..15 within the 16-row group
    int sslot = (lane & 3) ^ ((lane >> 3) & 3);    // inverse-swizzled source slot

    auto STAGE = [&](int slot, int kt) {
        #pragma unroll
        for (int it = 0; it < 2; ++it) {
            int r0 = (w * 2 + it) * 16;
            gload_lds16(&A [(long)(m0 + r0 + srow) * K + kt * 32 + sslot * 8], &Al[slot][r0 * 32]);
            gload_lds16(&BT[(long)(n0 + r0 + srow) * K + kt * 32 + sslot * 8], &Bl[slot][r0 * 32]);
        }
    };

    f32x4 acc[8][4] = {};
    int rsw = (l4 ^ ((l15 >> 1) & 3)) * 8;         // swizzled read slot (elements)

    STAGE(0, 0);
    STAGE(1, 1);

    for (int t = 0; t < nkt; ++t) {
        if (t + 2 < nkt) STAGE((t + 2) & 3, t + 2);
        int ahead = nkt - 1 - t;
        if (ahead >= 2)      asm volatile("s_waitcnt vmcnt(8)" ::: "memory");
        else if (ahead == 1) asm volatile("s_waitcnt vmcnt(4)" ::: "memory");
        else                 asm volatile("s_waitcnt vmcnt(0)" ::: "memory");
        asm volatile("s_barrier" ::: "memory");

        int s = t & 3;
        short8 af[8], bf[4];
        #pragma unroll
        for (int f = 0; f < 8; ++f)
            af[f] = *(const short8*)&Al[s][(wr * 128 + f * 16 + l15) * 32 + rsw];
        #pragma unroll
        for (int f = 0; f < 4; ++f)
            bf[f] = *(const short8*)&Bl[s][(wn * 64 + f * 16 + l15) * 32 + rsw];

        __builtin_amdgcn_s_setprio(1);
        #pragma unroll
        for (int fm = 0; fm < 8; ++fm)
            #pragma unroll
            for (int fn = 0; fn < 4; ++fn)
                acc[fm][fn] = __builtin_amdgcn_mfma_f32_16x16x32_bf16(af[fm], bf[fn], acc[fm][fn], 0, 0, 0);
        __builtin_amdgcn_s_setprio(0);
        asm volatile("s_barrier" ::: "memory");     // reads of slot s done before its next overwrite
    }

    float bs[4];
    #pragma unroll
    for (int fn = 0; fn < 4; ++fn)
        bs[fn] = bias[n0 + wn * 64 + fn * 16 + l15];

    #pragma unroll
    for (int fm = 0; fm < 8; ++fm) {
        #pragma unroll
        for (int j = 0; j < 4; ++j) {
            long row = m0 + wr * 128 + fm * 16 + l4 * 4 + j;
            float v4[4];
            #pragma unroll
            for (int fn = 0; fn < 4; ++fn) {
                int col = n0 + wn * 64 + fn * 16 + l15;
                float v = acc[fm][fn][j] + bs[fn];
                C[row * N + col] = v;
                v4[fn] = v;
            }
            float mx = fmaxf(fmaxf(v4[0], v4[1]), fmaxf(v4[2], v4[3]));
            #pragma unroll
            for (int off = 1; off < 16; off <<= 1) mx = fmaxf(mx, __shfl_xor(mx, off));
            float sm = 0.f;
            #pragma unroll
            for (int fn = 0; fn < 4; ++fn) sm += __expf(v4[fn] - mx);
            #pragma unroll
            for (int off = 1; off < 16; off <<= 1) sm += __shfl_xor(sm, off);
            if (l15 == 0) {
                int pidx = bn * 4 + wn;
                pm[row * 512 + pidx] = mx;
                ps[row * 512 + pidx] = sm;
            }
        }
    }
}

// ---------------- V transpose: vt[bh][d][t] = V[b][t][h][d] ----------------
__global__ __launch_bounds__(256) void vtrans_kernel(const unsigned short* __restrict__ qkv,
                                                     unsigned short* __restrict__ vt) {
    __shared__ unsigned short t[64][72];
    int t0 = blockIdx.x * 64;
    int bh = blockIdx.y;
    int b = bh / NH, h = bh % NH;
    int tid = threadIdx.x;
    #pragma unroll
    for (int i = 0; i < 2; ++i) {
        int r = (tid >> 3) + i * 32, c8 = (tid & 7) * 8;
        short8 v = *(const short8*)(qkv + ((long)b * NT + t0 + r) * NQKV + 2 * NE + h * NHS + c8);
        *(short8*)&t[r][c8] = v;
    }
    __syncthreads();
    #pragma unroll
    for (int i = 0; i < 2; ++i) {
        int d = (tid >> 3) + i * 32, s = (tid & 7) * 8;
        short8 o;
        #pragma unroll
        for (int j = 0; j < 8; ++j) o[j] = (short)t[s + j][d];
        *(short8*)(vt + ((long)bh * NHS + d) * NT + t0 + s) = o;
    }
}

// ---------------- flash attention: dbuf K/V LDS, 1 barrier/tile, prefetch overlap ----------------
__global__ __launch_bounds__(256) void fattn_kernel(const unsigned short* __restrict__ qkv,
                                                    const unsigned short* __restrict__ vt,
                                                    unsigned short* __restrict__ out) {
    __shared__ unsigned short Ks[2][64 * 64];    // [key][d], XOR-swizzled 16B granules
    __shared__ unsigned short Vl[2][64 * 64];    // [d][key], XOR-swizzled
    __shared__ unsigned short Ps[4 * 16 * 64];   // per-wave [q][key], XOR-swizzled
    int qt = gridDim.x - 1 - blockIdx.x;         // heavy q-tiles first
    int bh = blockIdx.y;
    int b = bh / NH, h = bh % NH;
    int tid = threadIdx.x, lane = tid & 63, w = tid >> 6;
    int l4 = lane >> 4, l15 = lane & 15;
    long rowb = (long)b * NT;
    const float scale = 0.03608439182435161f;    // 768^-0.5 (reference scales by E)
    const unsigned short* vtp = vt + (long)bh * NHS * NT;

    const unsigned short* qptr = qkv + (rowb + qt * 64 + w * 16 + l15) * NQKV + h * NHS;
    short8 qa0 = *(const short8*)(qptr + l4 * 8);
    short8 qa1 = *(const short8*)(qptr + 32 + l4 * 8);

    f32x4 o[4] = {};
    float m[4], lsum[4];
    #pragma unroll
    for (int j = 0; j < 4; ++j) { m[j] = -INFINITY; lsum[j] = 0.f; }

    int kr_r = tid >> 3, kr_c = (tid & 7) * 8;          // K staging coords (2 iters: +32 rows)
    int vr_d = tid >> 3, vr_s = tid & 7;                // V staging coords (2 iters: +32 d)

    short8 kr[2], vr[2];
    auto LOADT = [&](int t) {
        int kbase = t * 64;
        #pragma unroll
        for (int i = 0; i < 2; ++i) {
            kr[i] = *(const short8*)(qkv + (rowb + kbase + kr_r + i * 32) * NQKV + NE + h * NHS + kr_c);
            vr[i] = *(const short8*)(vtp + (long)(vr_d + i * 32) * NT + kbase + vr_s * 8);
        }
    };

    LOADT(0);
    for (int t = 0; t <= qt; ++t) {
        int cur = t & 1;
        #pragma unroll
        for (int i = 0; i < 2; ++i) {
            int r = kr_r + i * 32;
            *(short8*)&Ks[cur][r * 64 + (kr_c ^ ((r & 7) << 3))] = kr[i];
            int d = vr_d + i * 32;
            *(short8*)&Vl[cur][d * 64 + ((vr_s * 8) ^ ((d & 7) << 3))] = vr[i];
        }
        asm volatile("s_waitcnt lgkmcnt(0)" ::: "memory");
        if (t < qt) LOADT(t + 1);                       // overlap HBM with compute
        asm volatile("s_barrier" ::: "memory");

        f32x4 s[4];
        __builtin_amdgcn_s_setprio(1);
        #pragma unroll
        for (int fn = 0; fn < 4; ++fn) {
            int key = fn * 16 + l15;
            short8 kb0 = *(const short8*)&Ks[cur][key * 64 + ((l4 * 8) ^ ((key & 7) << 3))];
            short8 kb1 = *(const short8*)&Ks[cur][key * 64 + ((32 + l4 * 8) ^ ((key & 7) << 3))];
            f32x4 z = {};
            z = __builtin_amdgcn_mfma_f32_16x16x32_bf16(qa0, kb0, z, 0, 0, 0);
            s[fn] = __builtin_amdgcn_mfma_f32_16x16x32_bf16(qa1, kb1, z, 0, 0, 0);
        }
        __builtin_amdgcn_s_setprio(0);

        if (t == qt) {
            #pragma unroll
            for (int fn = 0; fn < 4; ++fn) {
                int key = t * 64 + fn * 16 + l15;
                #pragma unroll
                for (int j = 0; j < 4; ++j) {
                    int qrow = qt * 64 + w * 16 + l4 * 4 + j;
                    s[fn][j] = (key <= qrow) ? s[fn][j] * scale : -1e30f;
                }
            }
        } else {
            #pragma unroll
            for (int fn = 0; fn < 4; ++fn)
                #pragma unroll
                for (int j = 0; j < 4; ++j)
                    s[fn][j] *= scale;
        }

        #pragma unroll
        for (int j = 0; j < 4; ++j) {
            float mj = fmaxf(fmaxf(s[0][j], s[1][j]), fmaxf(s[2][j], s[3][j]));
            #pragma unroll
            for (int off = 1; off < 16; off <<= 1) mj = fmaxf(mj, __shfl_xor(mj, off));
            float mnew = fmaxf(m[j], mj);
            float alpha = __expf(m[j] - mnew);
            m[j] = mnew;
            float psum = 0.f;
            #pragma unroll
            for (int fn = 0; fn < 4; ++fn) {
                float p = __expf(s[fn][j] - mnew);
                psum += p;
                int rr = l4 * 4 + j, c = fn * 16 + l15;
                Ps[w * 1024 + rr * 64 + (c ^ ((rr & 7) << 3))] = f2bf(p);
            }
            #pragma unroll
            for (int off = 1; off < 16; off <<= 1) psum += __shfl_xor(psum, off);
            lsum[j] = lsum[j] * alpha + psum;
            #pragma unroll
            for (int fn = 0; fn < 4; ++fn) o[fn][j] *= alpha;
        }

        short8 pa0 = *(const short8*)&Ps[w * 1024 + l15 * 64 + ((l4 * 8) ^ ((l15 & 7) << 3))];
        short8 pa1 = *(const short8*)&Ps[w * 1024 + l15 * 64 + ((32 + l4 * 8) ^ ((l15 & 7) << 3))];
        __builtin_amdgcn_s_setprio(1);
        #pragma unroll
        for (int fn = 0; fn < 4; ++fn) {
            int d = fn * 16 + l15;
            short8 vb0 = *(const short8*)&Vl[cur][d * 64 + ((l4 * 8) ^ ((d & 7) << 3))];
            short8 vb1 = *(const short8*)&Vl[cur][d * 64 + ((32 + l4 * 8) ^ ((d & 7) << 3))];
            o[fn] = __builtin_amdgcn_mfma_f32_16x16x32_bf16(pa0, vb0, o[fn], 0, 0, 0);
            o[fn] = __builtin_amdgcn_mfma_f32_16x16x32_bf16(pa1, vb1, o[fn], 0, 0, 0);
        }
        __builtin_amdgcn_s_setprio(0);
    }

    #pragma unroll
    for (int j = 0; j < 4; ++j) {
        long row = rowb + qt * 64 + w * 16 + l4 * 4 + j;
        float inv = 1.0f / lsum[j];
        #pragma unroll
        for (int fn = 0; fn < 4; ++fn)
            out[row * NE + h * NHS + fn * 16 + l15] = f2bf(o[fn][j] * inv);
    }
}

// ---------------- NLL from LM-head partials ----------------
__global__ __launch_bounds__(256) void nll_combine_kernel(const float* __restrict__ logits,
                                                          const float* __restrict__ pm,
                                                          const float* __restrict__ ps,
                                                          const int* __restrict__ targets,
                                                          float* __restrict__ nll) {
    __shared__ float rm[256], rs[256];
    int row = blockIdx.x, tid = threadIdx.x;
    float m = -1e30f, s = 0.f;
    for (int i = tid; i < 500; i += 256) {
        float m2 = pm[(long)row * 512 + i], s2 = ps[(long)row * 512 + i];
        float mm = fmaxf(m, m2);
        s = s * __expf(m - mm) + s2 * __expf(m2 - mm);
        m = mm;
    }
    rm[tid] = m; rs[tid] = s; __syncthreads();
    for (int o = 128; o > 0; o >>= 1) {
        if (tid < o) {
            float m2 = rm[tid + o], s2 = rs[tid + o];
            float mm = fmaxf(rm[tid], m2);
            rs[tid] = rs[tid] * __expf(rm[tid] - mm) + s2 * __expf(m2 - mm);
            rm[tid] = mm;
        }
        __syncthreads();
    }
    if (tid == 0) {
        int tgt = targets[row];
        nll[row] = -(logits[(long)row * NV + tgt] - rm[0] - logf(rs[0]));
    }
}

__global__ void loss_reduce_kernel(const float* __restrict__ nll, float* __restrict__ out) {
    __shared__ float red[256];
    int tid = threadIdx.x;
    float s = 0.f;
    for (int i = tid; i < NM; i += 256) s += nll[i];
    red[tid] = s; __syncthreads();
    for (int o = 128; o > 0; o >>= 1) { if (tid < o) red[tid] += red[tid + o]; __syncthreads(); }
    if (tid == 0) out[0] = red[0] / NM;
}

extern "C" void kernel_launch(void* const* d_in, const int* in_sizes, int n_in,
                              void* d_out, int out_size, void* d_ws, size_t ws_size,
                              hipStream_t stream) {
    const int*   idx     = (const int*)  d_in[0];
    const int*   targets = (const int*)  d_in[1];
    const float* tok     = (const float*)d_in[2];
    const float* pos     = (const float*)d_in[3];
    const float* ln1_g   = (const float*)d_in[4];
    const float* ln1_b   = (const float*)d_in[5];
    const float* wq      = (const float*)d_in[6];
    const float* wk      = (const float*)d_in[7];
    const float* wv      = (const float*)d_in[8];
    const float* wproj   = (const float*)d_in[9];
    const float* bproj   = (const float*)d_in[10];
    const float* ln2_g   = (const float*)d_in[11];
    const float* ln2_b   = (const float*)d_in[12];
    const float* w1      = (const float*)d_in[13];
    const float* b1      = (const float*)d_in[14];
    const float* w2      = (const float*)d_in[15];
    const float* b2      = (const float*)d_in[16];
    const float* lnf_g   = (const float*)d_in[17];
    const float* lnf_b   = (const float*)d_in[18];
    const float* lm_w    = (const float*)d_in[19];
    const float* lm_b    = (const float*)d_in[20];

    float* logits = (float*)d_out;
    float* loss   = logits + (long)NM * NV;

    char* p = (char*)d_ws;
    float*          x      = (float*)p;          p += (long)NM * NE * 4;
    unsigned short* hbuf   = (unsigned short*)p; p += (long)NM * NE * 2;
    unsigned short* qkv    = (unsigned short*)p; p += (long)NM * NQKV * 2;
    unsigned short* att    = (unsigned short*)p; p += (long)NM * NE * 2;
    unsigned short* hid    = (unsigned short*)p; p += (long)NM * NFF * 2;
    unsigned short* vt     = (unsigned short*)p; p += (long)NB * NH * NHS * NT * 2;
    float*          nll    = (float*)p;          p += (long)NM * 4;
    float*          pmb    = (float*)p;          p += (long)NM * 512 * 4;
    float*          psb    = (float*)p;          p += (long)NM * 512 * 4;
    float*          parts  = (float*)p;          p += (long)4 * NM * NQKV * 4;  // split-K arena
    unsigned short* wqkvT  = (unsigned short*)p; p += (long)NQKV * NE * 2;
    unsigned short* wprojT = (unsigned short*)p; p += (long)NE * NE * 2;
    unsigned short* wprojC = (unsigned short*)p; p += (long)NE * NE * 2;
    unsigned short* weffT  = (unsigned short*)p; p += (long)NE * NE * 2;
    float*          beff   = (float*)p;          p += (long)NE * 4;
    unsigned short* w1T    = (unsigned short*)p; p += (long)NFF * NE * 2;
    unsigned short* w2T    = (unsigned short*)p; p += (long)NE * NFF * 2;
    unsigned short* lmT    = (unsigned short*)p; p += (long)NV * NE * 2;

    dim3 blk(256);
    embed_kernel<<<NM, blk, 0, stream>>>(idx, tok, pos, x);

    for (int l = 0; l < NL; ++l) {
        long wofs = (long)l * NE * NE;
        transpose4_kernel<<<dim3(NE / 32, NE / 32, 4), blk, 0, stream>>>(
            wq + wofs, wk + wofs, wv + wofs, wproj + wofs, wqkvT, wprojT);
        cast_kernel<<<(NE * NE) / 1024, blk, 0, stream>>>(wproj + wofs, wprojC, NE * NE);
        gemm_mfma<float, false, false, false, 4><<<dim3(36, 4), blk, 0, stream>>>(
            wprojT, wprojC, nullptr, parts, 6, NE, NE);
        combine_kernel<4, false, false><<<(NE * NE) / 1024, blk, 0, stream>>>(
            parts, nullptr, nullptr, weffT, NE, (long)NE * NE);
        beff_kernel<<<NE, blk, 0, stream>>>(bproj + l * NE, wprojT, beff);
        transpose_cast_kernel<<<dim3(NFF / 32, NE / 32), blk, 0, stream>>>(w1 + (long)l * NE * NFF, w1T, NE, NFF);
        transpose_cast_kernel<<<dim3(NE / 32, NFF / 32), blk, 0, stream>>>(w2 + (long)l * NFF * NE, w2T, NFF, NE);

        ln_kernel<<<NM, blk, 0, stream>>>(x, ln1_g + l * NE, ln1_b + l * NE, hbuf);
        gemm_mfma<float, false, false, false, 2><<<dim3((NM/128)*(NQKV/128), 2), blk, 0, stream>>>(
            hbuf, wqkvT, nullptr, parts, NM / 128, NQKV, NE);
        combine_kernel<2, false, false><<<(NM * NQKV) / 1024, blk, 0, stream>>>(
            parts, nullptr, nullptr, qkv, NQKV, (long)NM * NQKV);
        vtrans_kernel<<<dim3(NT / 64, NB * NH), blk, 0, stream>>>(qkv, vt);
        fattn_kernel<<<dim3(NT / 64, NB * NH), blk, 0, stream>>>(qkv, vt, att);
        gemm_mfma<float, false, false, false, 2><<<dim3((NM/128)*(NE/128), 2), blk, 0, stream>>>(
            att, weffT, nullptr, parts, NM / 128, NE, NE);
        combine_kernel<2, true, true><<<(NM * NE) / 1024, blk, 0, stream>>>(
            parts, beff, x, nullptr, NE, (long)NM * NE);

        ln_kernel<<<NM, blk, 0, stream>>>(x, ln2_g + l * NE, ln2_b + l * NE, hbuf);
        gemm_mfma<unsigned short, true, true, false, 1><<<dim3((NM/128)*(NFF/128)), blk, 0, stream>>>(
            hbuf, w1T, b1 + (long)l * NFF, hid, NM / 128, NFF, NE);
        gemm_mfma<float, false, false, false, 4><<<dim3((NM/128)*(NE/128), 4), blk, 0, stream>>>(
            hid, w2T, nullptr, parts, NM / 128, NE, NFF);
        combine_kernel<4, true, true><<<(NM * NE) / 1024, blk, 0, stream>>>(
            parts, b2 + l * NE, x, nullptr, NE, (long)NM * NE);
    }

    ln_kernel<<<NM, blk, 0, stream>>>(x, lnf_g, lnf_b, hbuf);
    transpose_cast_kernel<<<dim3(NV / 32, NE / 32), blk, 0, stream>>>(lm_w, lmT, NE, NV);
    gemm256_lse<<<dim3((NM/256)*(NV/256)), dim3(512), 0, stream>>>(
        hbuf, lmT, lm_b, logits, pmb, psb, NM / 256, NV, NE);
    nll_combine_kernel<<<NM, blk, 0, stream>>>(logits, pmb, psb, targets, nll);
    loss_reduce_kernel<<<1, blk, 0, stream>>>(nll, loss);
}

// Round 7
// 1186.325 us; speedup vs baseline: 9.6702x; 1.0857x over previous
//
#include <hip/hip_runtime.h>
#include <math.h>

#define NL 6
#define NH 12
#define NE 768
#define NHS 64
#define NT 1024
#define NB 2
#define NV 32000
#define NM (NB * NT)   // 2048
#define NQKV (3 * NE)  // 2304
#define NFF (4 * NE)   // 3072
#define LN_EPS 1e-5f

typedef __attribute__((ext_vector_type(8))) short short8;
typedef __attribute__((ext_vector_type(4))) float f32x4;
typedef __attribute__((ext_vector_type(4))) unsigned short ushort4v;
typedef __attribute__((address_space(1))) const unsigned int as1_cuint;
typedef __attribute__((address_space(3))) unsigned int as3_uint;

__device__ __forceinline__ unsigned short f2bf(float f) {
    unsigned int u = __builtin_bit_cast(unsigned int, f);
    u += 0x7fffu + ((u >> 16) & 1u);   // RNE
    return (unsigned short)(u >> 16);
}
__device__ __forceinline__ float bf2f(unsigned short u) {
    unsigned int v = ((unsigned int)u) << 16;
    return __builtin_bit_cast(float, v);
}
__device__ __forceinline__ void gload_lds16(const void* g, void* l) {
    __builtin_amdgcn_global_load_lds((as1_cuint*)g, (as3_uint*)l, 16, 0, 0);
}

// ---------------- embedding + LN1(layer0) fused: one block per row ----------------
__global__ __launch_bounds__(256) void embed_ln_kernel(const int* __restrict__ idx,
                                                       const float* __restrict__ tok,
                                                       const float* __restrict__ pos,
                                                       const float* __restrict__ g,
                                                       const float* __restrict__ b,
                                                       float* __restrict__ x,
                                                       unsigned short* __restrict__ hbuf) {
    __shared__ float red[256];
    int row = blockIdx.x, tid = threadIdx.x;
    int t = row % NT;
    int id = idx[row];
    float v[3]; float s = 0.f;
    #pragma unroll
    for (int k = 0; k < 3; ++k) {
        int c = tid + k * 256;
        v[k] = tok[(long)id * NE + c] + pos[(long)t * NE + c];
        x[(long)row * NE + c] = v[k];
        s += v[k];
    }
    red[tid] = s; __syncthreads();
    for (int o = 128; o > 0; o >>= 1) { if (tid < o) red[tid] += red[tid + o]; __syncthreads(); }
    float mu = red[0] / NE;
    __syncthreads();
    float vr = 0.f;
    #pragma unroll
    for (int k = 0; k < 3; ++k) { float d = v[k] - mu; vr += d * d; }
    red[tid] = vr; __syncthreads();
    for (int o = 128; o > 0; o >>= 1) { if (tid < o) red[tid] += red[tid + o]; __syncthreads(); }
    float rstd = rsqrtf(red[0] / NE + LN_EPS);
    #pragma unroll
    for (int k = 0; k < 3; ++k) {
        int c = tid + k * 256;
        hbuf[(long)row * NE + c] = f2bf((v[k] - mu) * rstd * g[c] + b[c]);
    }
}

// ---------------- fused split-K combine + residual + LayerNorm ----------------
// parts: S slices of [NM][NE] fp32. val = sum(parts) + bias + x; x = val; hbuf = LN(val).
template<int S>
__global__ __launch_bounds__(256) void combine_ln_kernel(const float* __restrict__ parts,
                                                         const float* __restrict__ bias,
                                                         float* __restrict__ x,
                                                         const float* __restrict__ g,
                                                         const float* __restrict__ b,
                                                         unsigned short* __restrict__ hbuf) {
    __shared__ float red[256];
    int row = blockIdx.x, tid = threadIdx.x;
    float v[3]; float s = 0.f;
    #pragma unroll
    for (int k = 0; k < 3; ++k) {
        int c = tid + k * 256;
        long i = (long)row * NE + c;
        float a = parts[i];
        #pragma unroll
        for (int si = 1; si < S; ++si) a += parts[(long)si * NM * NE + i];
        a += bias[c] + x[i];
        x[i] = a;
        v[k] = a; s += a;
    }
    red[tid] = s; __syncthreads();
    for (int o = 128; o > 0; o >>= 1) { if (tid < o) red[tid] += red[tid + o]; __syncthreads(); }
    float mu = red[0] / NE;
    __syncthreads();
    float vr = 0.f;
    #pragma unroll
    for (int k = 0; k < 3; ++k) { float d = v[k] - mu; vr += d * d; }
    red[tid] = vr; __syncthreads();
    for (int o = 128; o > 0; o >>= 1) { if (tid < o) red[tid] += red[tid + o]; __syncthreads(); }
    float rstd = rsqrtf(red[0] / NE + LN_EPS);
    #pragma unroll
    for (int k = 0; k < 3; ++k) {
        int c = tid + k * 256;
        hbuf[(long)row * NE + c] = f2bf((v[k] - mu) * rstd * g[c] + b[c]);
    }
}

// ---------------- batched transpose of the four 768x768 weights, all layers ----------------
__global__ __launch_bounds__(256) void transpose4b_kernel(const float* __restrict__ wq,
                                                          const float* __restrict__ wk,
                                                          const float* __restrict__ wv,
                                                          const float* __restrict__ wp,
                                                          unsigned short* __restrict__ wqkvT,
                                                          unsigned short* __restrict__ wprojT) {
    __shared__ float t[32][33];
    int z = blockIdx.z, l = z >> 2, which = z & 3;
    const float* W = ((which == 0) ? wq : (which == 1) ? wk : (which == 2) ? wv : wp) + (long)l * NE * NE;
    unsigned short* WT = (which < 3) ? (wqkvT + (long)l * NQKV * NE + (long)which * NE * NE)
                                     : (wprojT + (long)l * NE * NE);
    int k0 = blockIdx.y * 32, n0 = blockIdx.x * 32;
    int c = threadIdx.x & 31, r = threadIdx.x >> 5;
    #pragma unroll
    for (int p = 0; p < 4; ++p)
        t[r + p * 8][c] = W[(long)(k0 + r + p * 8) * NE + n0 + c];
    __syncthreads();
    #pragma unroll
    for (int p = 0; p < 4; ++p)
        WT[(long)(n0 + r + p * 8) * NE + k0 + c] = f2bf(t[c][r + p * 8]);
}

// ---------------- batched tiled transpose + cast: per-layer stride K*N ----------------
__global__ __launch_bounds__(256) void transpose_cast_b_kernel(const float* __restrict__ W0,
                                                               unsigned short* __restrict__ WT0,
                                                               int K, int N) {
    __shared__ float t[32][33];
    long lofs = (long)blockIdx.z * K * N;
    const float* W = W0 + lofs;
    unsigned short* WT = WT0 + lofs;
    int k0 = blockIdx.y * 32, n0 = blockIdx.x * 32;
    int c = threadIdx.x & 31, r = threadIdx.x >> 5;
    #pragma unroll
    for (int p = 0; p < 4; ++p)
        t[r + p * 8][c] = W[(long)(k0 + r + p * 8) * N + n0 + c];
    __syncthreads();
    #pragma unroll
    for (int p = 0; p < 4; ++p)
        WT[(long)(n0 + r + p * 8) * K + k0 + c] = f2bf(t[c][r + p * 8]);
}

// ---------------- plain fp32 -> bf16 cast ----------------
__global__ __launch_bounds__(256) void cast_kernel(const float* __restrict__ W,
                                                   unsigned short* __restrict__ O, long n) {
    long i = ((long)blockIdx.x * 256 + threadIdx.x) * 4;
    if (i < n) {
        float4 v = *(const float4*)(W + i);
        ushort4v o;
        o[0] = f2bf(v.x); o[1] = f2bf(v.y); o[2] = f2bf(v.z); o[3] = f2bf(v.w);
        *(ushort4v*)(O + i) = o;
    }
}

// ---------------- batched beff: beff[l][n] = sum_j bproj[l][j]*Wp_l[j][n] + bproj[l][n] ----------------
__global__ __launch_bounds__(256) void beff_b_kernel(const float* __restrict__ bproj,
                                                     const unsigned short* __restrict__ wprojT,
                                                     float* __restrict__ beff) {
    __shared__ float red[256];
    int n = blockIdx.x, l = blockIdx.y, tid = threadIdx.x;
    const unsigned short* wp = wprojT + (long)l * NE * NE + (long)n * NE;
    const float* bp = bproj + (long)l * NE;
    float acc = 0.f;
    for (int j = tid; j < NE; j += 256) acc += bp[j] * bf2f(wp[j]);
    red[tid] = acc; __syncthreads();
    for (int o = 128; o > 0; o >>= 1) { if (tid < o) red[tid] += red[tid + o]; __syncthreads(); }
    if (tid == 0) beff[(long)l * NE + n] = red[0] + bp[n];
}

// ---------------- combine split-K partials to bf16 (QKV path) ----------------
template<int S>
__global__ __launch_bounds__(256) void combine_kernel(const float* __restrict__ parts,
                                                      unsigned short* __restrict__ bout,
                                                      long total) {
    long i = ((long)blockIdx.x * 256 + threadIdx.x) * 4;
    if (i >= total) return;
    float4 a = *(const float4*)(parts + i);
    #pragma unroll
    for (int s = 1; s < S; ++s) {
        float4 b = *(const float4*)(parts + (long)s * total + i);
        a.x += b.x; a.y += b.y; a.z += b.z; a.w += b.w;
    }
    ushort4v o;
    o[0] = f2bf(a.x); o[1] = f2bf(a.y); o[2] = f2bf(a.z); o[3] = f2bf(a.w);
    *(ushort4v*)(bout + i) = o;
}

// ---------------- 128x128 bf16 MFMA GEMM, 2-phase dbuf, optional split-K ----------------
template<typename OutT, bool BIAS, bool RELU, int SPLITK>
__global__ __launch_bounds__(256) void gemm_mfma(const unsigned short* __restrict__ A,
                                                 const unsigned short* __restrict__ BT,
                                                 const float* __restrict__ bias,
                                                 OutT* __restrict__ C,
                                                 int gridM, int N, int K) {
    __shared__ unsigned short As[2][128 * 32];
    __shared__ unsigned short Bs[2][128 * 32];
    int tid = threadIdx.x;
    int lane = tid & 63, w = tid >> 6;
    int wr = w >> 1, wc = w & 1;
    int l4 = lane >> 4, l15 = lane & 15;

    int nwg = gridDim.x, orig = blockIdx.x;
    int q = nwg >> 3, r8 = nwg & 7;
    int xcd = orig & 7, ii = orig >> 3;
    int wg = (xcd < r8) ? (xcd * (q + 1) + ii) : (r8 * (q + 1) + (xcd - r8) * q + ii);
    int bm = wg % gridM, bn = wg / gridM;
    int m0 = bm * 128, n0 = bn * 128;

    int kb = K / SPLITK;
    int koff = (SPLITK > 1) ? blockIdx.y * kb : 0;

    f32x4 acc[4][4] = {};

    int srow = lane >> 2;
    int scol = (lane & 3) * 8;

    #pragma unroll
    for (int it = 0; it < 2; ++it) {
        int rr = w * 32 + it * 16;
        gload_lds16(&A [(long)(m0 + rr + srow) * K + koff + scol], &As[0][rr * 32]);
        gload_lds16(&BT[(long)(n0 + rr + srow) * K + koff + scol], &Bs[0][rr * 32]);
    }

    int cur = 0;
    for (int k0 = 0; k0 < kb; k0 += 32) {
        __syncthreads();
        if (k0 + 32 < kb) {
            #pragma unroll
            for (int it = 0; it < 2; ++it) {
                int rr = w * 32 + it * 16;
                gload_lds16(&A [(long)(m0 + rr + srow) * K + koff + k0 + 32 + scol], &As[cur ^ 1][rr * 32]);
                gload_lds16(&BT[(long)(n0 + rr + srow) * K + koff + k0 + 32 + scol], &Bs[cur ^ 1][rr * 32]);
            }
        }

        short8 a[4], b[4];
        #pragma unroll
        for (int f = 0; f < 4; ++f) {
            a[f] = *(const short8*)&As[cur][(wr * 64 + f * 16 + l15) * 32 + l4 * 8];
            b[f] = *(const short8*)&Bs[cur][(wc * 64 + f * 16 + l15) * 32 + l4 * 8];
        }
        __builtin_amdgcn_s_setprio(1);
        #pragma unroll
        for (int fm = 0; fm < 4; ++fm)
            #pragma unroll
            for (int fn = 0; fn < 4; ++fn)
                acc[fm][fn] = __builtin_amdgcn_mfma_f32_16x16x32_bf16(a[fm], b[fn], acc[fm][fn], 0, 0, 0);
        __builtin_amdgcn_s_setprio(0);
        cur ^= 1;
    }

    if constexpr (SPLITK > 1) {
        float* Cp = (float*)C + (long)blockIdx.y * gridM * 128 * N;
        #pragma unroll
        for (int fm = 0; fm < 4; ++fm)
            #pragma unroll
            for (int j = 0; j < 4; ++j) {
                long row = m0 + wr * 64 + fm * 16 + l4 * 4 + j;
                #pragma unroll
                for (int fn = 0; fn < 4; ++fn)
                    Cp[row * N + n0 + wc * 64 + fn * 16 + l15] = acc[fm][fn][j];
            }
    } else {
        float bs[4];
        #pragma unroll
        for (int fn = 0; fn < 4; ++fn)
            bs[fn] = BIAS ? bias[n0 + wc * 64 + fn * 16 + l15] : 0.f;

        #pragma unroll
        for (int fm = 0; fm < 4; ++fm) {
            #pragma unroll
            for (int j = 0; j < 4; ++j) {
                long row = m0 + wr * 64 + fm * 16 + l4 * 4 + j;
                #pragma unroll
                for (int fn = 0; fn < 4; ++fn) {
                    int col = n0 + wc * 64 + fn * 16 + l15;
                    float v = acc[fm][fn][j] + bs[fn];
                    if (RELU) v = fmaxf(v, 0.f);
                    if constexpr (sizeof(OutT) == 2) C[row * N + col] = (OutT)f2bf(v);
                    else                             C[row * N + col] = v;
                }
            }
        }
    }
}

// ---------------- batched square bf16 GEMM (weff = Wp@Wp per layer), z = layer ----------------
__global__ __launch_bounds__(256) void gemm_weff_kernel(const unsigned short* __restrict__ A0,
                                                        const unsigned short* __restrict__ B0,
                                                        unsigned short* __restrict__ C0,
                                                        int gridM, int N, int K) {
    __shared__ unsigned short As[2][128 * 32];
    __shared__ unsigned short Bs[2][128 * 32];
    long zofs = (long)blockIdx.z * N * K;
    const unsigned short* A = A0 + zofs;
    const unsigned short* BT = B0 + zofs;
    unsigned short* C = C0 + zofs;
    int tid = threadIdx.x;
    int lane = tid & 63, w = tid >> 6;
    int wr = w >> 1, wc = w & 1;
    int l4 = lane >> 4, l15 = lane & 15;
    int bm = blockIdx.x % gridM, bn = blockIdx.x / gridM;
    int m0 = bm * 128, n0 = bn * 128;

    f32x4 acc[4][4] = {};
    int srow = lane >> 2;
    int scol = (lane & 3) * 8;

    #pragma unroll
    for (int it = 0; it < 2; ++it) {
        int rr = w * 32 + it * 16;
        gload_lds16(&A [(long)(m0 + rr + srow) * K + scol], &As[0][rr * 32]);
        gload_lds16(&BT[(long)(n0 + rr + srow) * K + scol], &Bs[0][rr * 32]);
    }
    int cur = 0;
    for (int k0 = 0; k0 < K; k0 += 32) {
        __syncthreads();
        if (k0 + 32 < K) {
            #pragma unroll
            for (int it = 0; it < 2; ++it) {
                int rr = w * 32 + it * 16;
                gload_lds16(&A [(long)(m0 + rr + srow) * K + k0 + 32 + scol], &As[cur ^ 1][rr * 32]);
                gload_lds16(&BT[(long)(n0 + rr + srow) * K + k0 + 32 + scol], &Bs[cur ^ 1][rr * 32]);
            }
        }
        short8 a[4], b[4];
        #pragma unroll
        for (int f = 0; f < 4; ++f) {
            a[f] = *(const short8*)&As[cur][(wr * 64 + f * 16 + l15) * 32 + l4 * 8];
            b[f] = *(const short8*)&Bs[cur][(wc * 64 + f * 16 + l15) * 32 + l4 * 8];
        }
        #pragma unroll
        for (int fm = 0; fm < 4; ++fm)
            #pragma unroll
            for (int fn = 0; fn < 4; ++fn)
                acc[fm][fn] = __builtin_amdgcn_mfma_f32_16x16x32_bf16(a[fm], b[fn], acc[fm][fn], 0, 0, 0);
        cur ^= 1;
    }
    #pragma unroll
    for (int fm = 0; fm < 4; ++fm)
        #pragma unroll
        for (int j = 0; j < 4; ++j) {
            long row = m0 + wr * 64 + fm * 16 + l4 * 4 + j;
            #pragma unroll
            for (int fn = 0; fn < 4; ++fn)
                C[row * N + n0 + wc * 64 + fn * 16 + l15] = f2bf(acc[fm][fn][j]);
        }
}

// ---------------- 256x256 bf16 MFMA GEMM, 4-slot LDS, depth-2 counted-vmcnt, 1 barrier/K-step ----------------
__global__ __launch_bounds__(512, 2) void gemm256_lse(const unsigned short* __restrict__ A,
                                                      const unsigned short* __restrict__ BT,
                                                      const float* __restrict__ bias,
                                                      float* __restrict__ C,
                                                      float* __restrict__ pm, float* __restrict__ ps,
                                                      int gridM, int N, int K) {
    __shared__ unsigned short Al[4][256 * 32];
    __shared__ unsigned short Bl[4][256 * 32];
    int tid = threadIdx.x;
    int lane = tid & 63, w = tid >> 6;
    int wr = w >> 2, wn = w & 3;
    int l4 = lane >> 4, l15 = lane & 15;

    int nwg = gridDim.x, orig = blockIdx.x;
    int q = nwg >> 3, r8 = nwg & 7;
    int xcd = orig & 7, ii = orig >> 3;
    int wg = (xcd < r8) ? (xcd * (q + 1) + ii) : (r8 * (q + 1) + (xcd - r8) * q + ii);
    int bm = wg % gridM, bn = wg / gridM;
    int m0 = bm * 256, n0 = bn * 256;

    int nkt = K >> 5;

    int srow = lane >> 2;
    int sslot = (lane & 3) ^ ((lane >> 3) & 3);    // inverse-swizzled source slot

    auto STAGE = [&](int slot, int kt) {
        #pragma unroll
        for (int it = 0; it < 2; ++it) {
            int r0 = (w * 2 + it) * 16;
            gload_lds16(&A [(long)(m0 + r0 + srow) * K + kt * 32 + sslot * 8], &Al[slot][r0 * 32]);
            gload_lds16(&BT[(long)(n0 + r0 + srow) * K + kt * 32 + sslot * 8], &Bl[slot][r0 * 32]);
        }
    };

    f32x4 acc[8][4] = {};
    int rsw = (l4 ^ ((l15 >> 1) & 3)) * 8;         // swizzled read slot

    STAGE(0, 0);
    STAGE(1, 1);

    for (int t = 0; t < nkt; ++t) {
        if (t + 2 < nkt) STAGE((t + 2) & 3, t + 2);
        int ahead = nkt - 1 - t;
        if (ahead >= 2)      asm volatile("s_waitcnt vmcnt(8)" ::: "memory");
        else if (ahead == 1) asm volatile("s_waitcnt vmcnt(4)" ::: "memory");
        else                 asm volatile("s_waitcnt vmcnt(0)" ::: "memory");
        asm volatile("s_barrier" ::: "memory");    // single barrier per K-step (4-slot ring)

        int s = t & 3;
        short8 af[8], bf[4];
        #pragma unroll
        for (int f = 0; f < 8; ++f)
            af[f] = *(const short8*)&Al[s][(wr * 128 + f * 16 + l15) * 32 + rsw];
        #pragma unroll
        for (int f = 0; f < 4; ++f)
            bf[f] = *(const short8*)&Bl[s][(wn * 64 + f * 16 + l15) * 32 + rsw];

        __builtin_amdgcn_s_setprio(1);
        #pragma unroll
        for (int fm = 0; fm < 8; ++fm)
            #pragma unroll
            for (int fn = 0; fn < 4; ++fn)
                acc[fm][fn] = __builtin_amdgcn_mfma_f32_16x16x32_bf16(af[fm], bf[fn], acc[fm][fn], 0, 0, 0);
        __builtin_amdgcn_s_setprio(0);
    }

    float bs[4];
    #pragma unroll
    for (int fn = 0; fn < 4; ++fn)
        bs[fn] = bias[n0 + wn * 64 + fn * 16 + l15];

    #pragma unroll
    for (int fm = 0; fm < 8; ++fm) {
        #pragma unroll
        for (int j = 0; j < 4; ++j) {
            long row = m0 + wr * 128 + fm * 16 + l4 * 4 + j;
            float v4[4];
            #pragma unroll
            for (int fn = 0; fn < 4; ++fn) {
                int col = n0 + wn * 64 + fn * 16 + l15;
                float v = acc[fm][fn][j] + bs[fn];
                C[row * N + col] = v;
                v4[fn] = v;
            }
            float mx = fmaxf(fmaxf(v4[0], v4[1]), fmaxf(v4[2], v4[3]));
            #pragma unroll
            for (int off = 1; off < 16; off <<= 1) mx = fmaxf(mx, __shfl_xor(mx, off));
            float sm = 0.f;
            #pragma unroll
            for (int fn = 0; fn < 4; ++fn) sm += __expf(v4[fn] - mx);
            #pragma unroll
            for (int off = 1; off < 16; off <<= 1) sm += __shfl_xor(sm, off);
            if (l15 == 0) {
                int pidx = bn * 4 + wn;
                pm[row * 512 + pidx] = mx;
                ps[row * 512 + pidx] = sm;
            }
        }
    }
}

// ---------------- V transpose: vt[bh][d][t] = V[b][t][h][d] ----------------
__global__ __launch_bounds__(256) void vtrans_kernel(const unsigned short* __restrict__ qkv,
                                                     unsigned short* __restrict__ vt) {
    __shared__ unsigned short t[64][72];
    int t0 = blockIdx.x * 64;
    int bh = blockIdx.y;
    int b = bh / NH, h = bh % NH;
    int tid = threadIdx.x;
    #pragma unroll
    for (int i = 0; i < 2; ++i) {
        int r = (tid >> 3) + i * 32, c8 = (tid & 7) * 8;
        short8 v = *(const short8*)(qkv + ((long)b * NT + t0 + r) * NQKV + 2 * NE + h * NHS + c8);
        *(short8*)&t[r][c8] = v;
    }
    __syncthreads();
    #pragma unroll
    for (int i = 0; i < 2; ++i) {
        int d = (tid >> 3) + i * 32, s = (tid & 7) * 8;
        short8 o;
        #pragma unroll
        for (int j = 0; j < 8; ++j) o[j] = (short)t[s + j][d];
        *(short8*)(vt + ((long)bh * NHS + d) * NT + t0 + s) = o;
    }
}

// ---------------- flash attention: dbuf K/V LDS, 1 barrier/tile, prefetch overlap ----------------
__global__ __launch_bounds__(256) void fattn_kernel(const unsigned short* __restrict__ qkv,
                                                    const unsigned short* __restrict__ vt,
                                                    unsigned short* __restrict__ out) {
    __shared__ unsigned short Ks[2][64 * 64];
    __shared__ unsigned short Vl[2][64 * 64];
    __shared__ unsigned short Ps[4 * 16 * 64];
    int qt = gridDim.x - 1 - blockIdx.x;
    int bh = blockIdx.y;
    int b = bh / NH, h = bh % NH;
    int tid = threadIdx.x, lane = tid & 63, w = tid >> 6;
    int l4 = lane >> 4, l15 = lane & 15;
    long rowb = (long)b * NT;
    const float scale = 0.03608439182435161f;    // 768^-0.5 (reference scales by E)
    const unsigned short* vtp = vt + (long)bh * NHS * NT;

    const unsigned short* qptr = qkv + (rowb + qt * 64 + w * 16 + l15) * NQKV + h * NHS;
    short8 qa0 = *(const short8*)(qptr + l4 * 8);
    short8 qa1 = *(const short8*)(qptr + 32 + l4 * 8);

    f32x4 o[4] = {};
    float m[4], lsum[4];
    #pragma unroll
    for (int j = 0; j < 4; ++j) { m[j] = -INFINITY; lsum[j] = 0.f; }

    int kr_r = tid >> 3, kr_c = (tid & 7) * 8;
    int vr_d = tid >> 3, vr_s = tid & 7;

    short8 kr[2], vr[2];
    auto LOADT = [&](int t) {
        int kbase = t * 64;
        #pragma unroll
        for (int i = 0; i < 2; ++i) {
            kr[i] = *(const short8*)(qkv + (rowb + kbase + kr_r + i * 32) * NQKV + NE + h * NHS + kr_c);
            vr[i] = *(const short8*)(vtp + (long)(vr_d + i * 32) * NT + kbase + vr_s * 8);
        }
    };

    LOADT(0);
    for (int t = 0; t <= qt; ++t) {
        int cur = t & 1;
        #pragma unroll
        for (int i = 0; i < 2; ++i) {
            int r = kr_r + i * 32;
            *(short8*)&Ks[cur][r * 64 + (kr_c ^ ((r & 7) << 3))] = kr[i];
            int d = vr_d + i * 32;
            *(short8*)&Vl[cur][d * 64 + ((vr_s * 8) ^ ((d & 7) << 3))] = vr[i];
        }
        asm volatile("s_waitcnt lgkmcnt(0)" ::: "memory");
        if (t < qt) LOADT(t + 1);
        asm volatile("s_barrier" ::: "memory");

        f32x4 s[4];
        __builtin_amdgcn_s_setprio(1);
        #pragma unroll
        for (int fn = 0; fn < 4; ++fn) {
            int key = fn * 16 + l15;
            short8 kb0 = *(const short8*)&Ks[cur][key * 64 + ((l4 * 8) ^ ((key & 7) << 3))];
            short8 kb1 = *(const short8*)&Ks[cur][key * 64 + ((32 + l4 * 8) ^ ((key & 7) << 3))];
            f32x4 z = {};
            z = __builtin_amdgcn_mfma_f32_16x16x32_bf16(qa0, kb0, z, 0, 0, 0);
            s[fn] = __builtin_amdgcn_mfma_f32_16x16x32_bf16(qa1, kb1, z, 0, 0, 0);
        }
        __builtin_amdgcn_s_setprio(0);

        if (t == qt) {
            #pragma unroll
            for (int fn = 0; fn < 4; ++fn) {
                int key = t * 64 + fn * 16 + l15;
                #pragma unroll
                for (int j = 0; j < 4; ++j) {
                    int qrow = qt * 64 + w * 16 + l4 * 4 + j;
                    s[fn][j] = (key <= qrow) ? s[fn][j] * scale : -1e30f;
                }
            }
        } else {
            #pragma unroll
            for (int fn = 0; fn < 4; ++fn)
                #pragma unroll
                for (int j = 0; j < 4; ++j)
                    s[fn][j] *= scale;
        }

        #pragma unroll
        for (int j = 0; j < 4; ++j) {
            float mj = fmaxf(fmaxf(s[0][j], s[1][j]), fmaxf(s[2][j], s[3][j]));
            #pragma unroll
            for (int off = 1; off < 16; off <<= 1) mj = fmaxf(mj, __shfl_xor(mj, off));
            float mnew = fmaxf(m[j], mj);
            float alpha = __expf(m[j] - mnew);
            m[j] = mnew;
            float psum = 0.f;
            #pragma unroll
            for (int fn = 0; fn < 4; ++fn) {
                float p = __expf(s[fn][j] - mnew);
                psum += p;
                int rr = l4 * 4 + j, c = fn * 16 + l15;
                Ps[w * 1024 + rr * 64 + (c ^ ((rr & 7) << 3))] = f2bf(p);
            }
            #pragma unroll
            for (int off = 1; off < 16; off <<= 1) psum += __shfl_xor(psum, off);
            lsum[j] = lsum[j] * alpha + psum;
            #pragma unroll
            for (int fn = 0; fn < 4; ++fn) o[fn][j] *= alpha;
        }

        short8 pa0 = *(const short8*)&Ps[w * 1024 + l15 * 64 + ((l4 * 8) ^ ((l15 & 7) << 3))];
        short8 pa1 = *(const short8*)&Ps[w * 1024 + l15 * 64 + ((32 + l4 * 8) ^ ((l15 & 7) << 3))];
        __builtin_amdgcn_s_setprio(1);
        #pragma unroll
        for (int fn = 0; fn < 4; ++fn) {
            int d = fn * 16 + l15;
            short8 vb0 = *(const short8*)&Vl[cur][d * 64 + ((l4 * 8) ^ ((d & 7) << 3))];
            short8 vb1 = *(const short8*)&Vl[cur][d * 64 + ((32 + l4 * 8) ^ ((d & 7) << 3))];
            o[fn] = __builtin_amdgcn_mfma_f32_16x16x32_bf16(pa0, vb0, o[fn], 0, 0, 0);
            o[fn] = __builtin_amdgcn_mfma_f32_16x16x32_bf16(pa1, vb1, o[fn], 0, 0, 0);
        }
        __builtin_amdgcn_s_setprio(0);
    }

    #pragma unroll
    for (int j = 0; j < 4; ++j) {
        long row = rowb + qt * 64 + w * 16 + l4 * 4 + j;
        float inv = 1.0f / lsum[j];
        #pragma unroll
        for (int fn = 0; fn < 4; ++fn)
            out[row * NE + h * NHS + fn * 16 + l15] = f2bf(o[fn][j] * inv);
    }
}

// ---------------- NLL from LM-head partials ----------------
__global__ __launch_bounds__(256) void nll_combine_kernel(const float* __restrict__ logits,
                                                          const float* __restrict__ pm,
                                                          const float* __restrict__ ps,
                                                          const int* __restrict__ targets,
                                                          float* __restrict__ nll) {
    __shared__ float rm[256], rs[256];
    int row = blockIdx.x, tid = threadIdx.x;
    float m = -1e30f, s = 0.f;
    for (int i = tid; i < 500; i += 256) {
        float m2 = pm[(long)row * 512 + i], s2 = ps[(long)row * 512 + i];
        float mm = fmaxf(m, m2);
        s = s * __expf(m - mm) + s2 * __expf(m2 - mm);
        m = mm;
    }
    rm[tid] = m; rs[tid] = s; __syncthreads();
    for (int o = 128; o > 0; o >>= 1) {
        if (tid < o) {
            float m2 = rm[tid + o], s2 = rs[tid + o];
            float mm = fmaxf(rm[tid], m2);
            rs[tid] = rs[tid] * __expf(rm[tid] - mm) + s2 * __expf(m2 - mm);
            rm[tid] = mm;
        }
        __syncthreads();
    }
    if (tid == 0) {
        int tgt = targets[row];
        nll[row] = -(logits[(long)row * NV + tgt] - rm[0] - logf(rs[0]));
    }
}

__global__ void loss_reduce_kernel(const float* __restrict__ nll, float* __restrict__ out) {
    __shared__ float red[256];
    int tid = threadIdx.x;
    float s = 0.f;
    for (int i = tid; i < NM; i += 256) s += nll[i];
    red[tid] = s; __syncthreads();
    for (int o = 128; o > 0; o >>= 1) { if (tid < o) red[tid] += red[tid + o]; __syncthreads(); }
    if (tid == 0) out[0] = red[0] / NM;
}

extern "C" void kernel_launch(void* const* d_in, const int* in_sizes, int n_in,
                              void* d_out, int out_size, void* d_ws, size_t ws_size,
                              hipStream_t stream) {
    const int*   idx     = (const int*)  d_in[0];
    const int*   targets = (const int*)  d_in[1];
    const float* tok     = (const float*)d_in[2];
    const float* pos     = (const float*)d_in[3];
    const float* ln1_g   = (const float*)d_in[4];
    const float* ln1_b   = (const float*)d_in[5];
    const float* wq      = (const float*)d_in[6];
    const float* wk      = (const float*)d_in[7];
    const float* wv      = (const float*)d_in[8];
    const float* wproj   = (const float*)d_in[9];
    const float* bproj   = (const float*)d_in[10];
    const float* ln2_g   = (const float*)d_in[11];
    const float* ln2_b   = (const float*)d_in[12];
    const float* w1      = (const float*)d_in[13];
    const float* b1      = (const float*)d_in[14];
    const float* w2      = (const float*)d_in[15];
    const float* b2      = (const float*)d_in[16];
    const float* lnf_g   = (const float*)d_in[17];
    const float* lnf_b   = (const float*)d_in[18];
    const float* lm_w    = (const float*)d_in[19];
    const float* lm_b    = (const float*)d_in[20];

    float* logits = (float*)d_out;
    float* loss   = logits + (long)NM * NV;

    char* p = (char*)d_ws;
    float*          x      = (float*)p;          p += (long)NM * NE * 4;
    unsigned short* hbuf   = (unsigned short*)p; p += (long)NM * NE * 2;
    unsigned short* qkv    = (unsigned short*)p; p += (long)NM * NQKV * 2;
    unsigned short* att    = (unsigned short*)p; p += (long)NM * NE * 2;
    unsigned short* hid    = (unsigned short*)p; p += (long)NM * NFF * 2;
    unsigned short* vt     = (unsigned short*)p; p += (long)NB * NH * NHS * NT * 2;
    float*          nll    = (float*)p;          p += (long)NM * 4;
    float*          pmb    = (float*)p;          p += (long)NM * 512 * 4;
    float*          psb    = (float*)p;          p += (long)NM * 512 * 4;
    float*          parts  = (float*)p;          p += (long)2 * NM * NQKV * 4;   // split-K arena (max user: QKV S=2)
    unsigned short* wqkvT6 = (unsigned short*)p; p += (long)NL * NQKV * NE * 2;
    unsigned short* wprojT6= (unsigned short*)p; p += (long)NL * NE * NE * 2;
    unsigned short* wprojC6= (unsigned short*)p; p += (long)NL * NE * NE * 2;
    unsigned short* weffT6 = (unsigned short*)p; p += (long)NL * NE * NE * 2;
    float*          beff6  = (float*)p;          p += (long)NL * NE * 4;
    unsigned short* w1T6   = (unsigned short*)p; p += (long)NL * NFF * NE * 2;
    unsigned short* w2T6   = (unsigned short*)p; p += (long)NL * NE * NFF * 2;
    unsigned short* lmT    = (unsigned short*)p; p += (long)NV * NE * 2;

    dim3 blk(256);

    // ---- batched weight prep (7 launches, all layers) ----
    transpose4b_kernel<<<dim3(NE / 32, NE / 32, 4 * NL), blk, 0, stream>>>(
        wq, wk, wv, wproj, wqkvT6, wprojT6);
    cast_kernel<<<(NL * NE * NE) / 1024, blk, 0, stream>>>(wproj, wprojC6, (long)NL * NE * NE);
    transpose_cast_b_kernel<<<dim3(NFF / 32, NE / 32, NL), blk, 0, stream>>>(w1, w1T6, NE, NFF);
    transpose_cast_b_kernel<<<dim3(NE / 32, NFF / 32, NL), blk, 0, stream>>>(w2, w2T6, NFF, NE);
    gemm_weff_kernel<<<dim3(36, 1, NL), blk, 0, stream>>>(wprojT6, wprojC6, weffT6, 6, NE, NE);
    beff_b_kernel<<<dim3(NE, NL), blk, 0, stream>>>(bproj, wprojT6, beff6);
    transpose_cast_b_kernel<<<dim3(NV / 32, NE / 32, 1), blk, 0, stream>>>(lm_w, lmT, NE, NV);

    // ---- embedding + LN1(0) ----
    embed_ln_kernel<<<NM, blk, 0, stream>>>(idx, tok, pos, ln1_g, ln1_b, x, hbuf);

    for (int l = 0; l < NL; ++l) {
        // QKV (split-K=2) -> combine to bf16
        gemm_mfma<float, false, false, 2><<<dim3((NM/128)*(NQKV/128), 2), blk, 0, stream>>>(
            hbuf, wqkvT6 + (long)l * NQKV * NE, nullptr, parts, NM / 128, NQKV, NE);
        combine_kernel<2><<<(NM * NQKV) / 1024, blk, 0, stream>>>(parts, qkv, (long)NM * NQKV);
        vtrans_kernel<<<dim3(NT / 64, NB * NH), blk, 0, stream>>>(qkv, vt);
        fattn_kernel<<<dim3(NT / 64, NB * NH), blk, 0, stream>>>(qkv, vt, att);
        // fused double-proj (split-K=2) -> combine+residual+LN2
        gemm_mfma<float, false, false, 2><<<dim3((NM/128)*(NE/128), 2), blk, 0, stream>>>(
            att, weffT6 + (long)l * NE * NE, nullptr, parts, NM / 128, NE, NE);
        combine_ln_kernel<2><<<NM, blk, 0, stream>>>(
            parts, beff6 + (long)l * NE, x, ln2_g + (long)l * NE, ln2_b + (long)l * NE, hbuf);
        // FF1 (bias+relu, bf16 out)
        gemm_mfma<unsigned short, true, true, 1><<<dim3((NM/128)*(NFF/128)), blk, 0, stream>>>(
            hbuf, w1T6 + (long)l * NFF * NE, b1 + (long)l * NFF, hid, NM / 128, NFF, NE);
        // FF2 (split-K=4) -> combine+residual+LN(next or final)
        gemm_mfma<float, false, false, 4><<<dim3((NM/128)*(NE/128), 4), blk, 0, stream>>>(
            hid, w2T6 + (long)l * NE * NFF, nullptr, parts, NM / 128, NE, NFF);
        const float* ng = (l < NL - 1) ? (ln1_g + (long)(l + 1) * NE) : lnf_g;
        const float* nb = (l < NL - 1) ? (ln1_b + (long)(l + 1) * NE) : lnf_b;
        combine_ln_kernel<4><<<NM, blk, 0, stream>>>(parts, b2 + (long)l * NE, x, ng, nb, hbuf);
    }

    // ---- LM head + fused LSE ----
    gemm256_lse<<<dim3((NM/256)*(NV/256)), dim3(512), 0, stream>>>(
        hbuf, lmT, lm_b, logits, pmb, psb, NM / 256, NV, NE);
    nll_combine_kernel<<<NM, blk, 0, stream>>>(logits, pmb, psb, targets, nll);
    loss_reduce_kernel<<<1, blk, 0, stream>>>(nll, loss);
}

// Round 8
// 1180.387 us; speedup vs baseline: 9.7189x; 1.0050x over previous
//
#include <hip/hip_runtime.h>
#include <math.h>

#define NL 6
#define NH 12
#define NE 768
#define NHS 64
#define NT 1024
#define NB 2
#define NV 32000
#define NM (NB * NT)   // 2048
#define NQKV (3 * NE)  // 2304
#define NFF (4 * NE)   // 3072
#define LN_EPS 1e-5f

typedef __attribute__((ext_vector_type(8))) short short8;
typedef __attribute__((ext_vector_type(4))) float f32x4;
typedef __attribute__((ext_vector_type(4))) unsigned short ushort4v;
typedef __attribute__((address_space(1))) const unsigned int as1_cuint;
typedef __attribute__((address_space(3))) unsigned int as3_uint;

__device__ __forceinline__ unsigned short f2bf(float f) {
    unsigned int u = __builtin_bit_cast(unsigned int, f);
    u += 0x7fffu + ((u >> 16) & 1u);   // RNE
    return (unsigned short)(u >> 16);
}
__device__ __forceinline__ float bf2f(unsigned short u) {
    unsigned int v = ((unsigned int)u) << 16;
    return __builtin_bit_cast(float, v);
}
__device__ __forceinline__ void gload_lds16(const void* g, void* l) {
    __builtin_amdgcn_global_load_lds((as1_cuint*)g, (as3_uint*)l, 16, 0, 0);
}

// ---------------- embedding + LN1(layer0) fused: one block per row ----------------
__global__ __launch_bounds__(256) void embed_ln_kernel(const int* __restrict__ idx,
                                                       const float* __restrict__ tok,
                                                       const float* __restrict__ pos,
                                                       const float* __restrict__ g,
                                                       const float* __restrict__ b,
                                                       float* __restrict__ x,
                                                       unsigned short* __restrict__ hbuf) {
    __shared__ float red[256];
    int row = blockIdx.x, tid = threadIdx.x;
    int t = row % NT;
    int id = idx[row];
    float v[3]; float s = 0.f;
    #pragma unroll
    for (int k = 0; k < 3; ++k) {
        int c = tid + k * 256;
        v[k] = tok[(long)id * NE + c] + pos[(long)t * NE + c];
        x[(long)row * NE + c] = v[k];
        s += v[k];
    }
    red[tid] = s; __syncthreads();
    for (int o = 128; o > 0; o >>= 1) { if (tid < o) red[tid] += red[tid + o]; __syncthreads(); }
    float mu = red[0] / NE;
    __syncthreads();
    float vr = 0.f;
    #pragma unroll
    for (int k = 0; k < 3; ++k) { float d = v[k] - mu; vr += d * d; }
    red[tid] = vr; __syncthreads();
    for (int o = 128; o > 0; o >>= 1) { if (tid < o) red[tid] += red[tid + o]; __syncthreads(); }
    float rstd = rsqrtf(red[0] / NE + LN_EPS);
    #pragma unroll
    for (int k = 0; k < 3; ++k) {
        int c = tid + k * 256;
        hbuf[(long)row * NE + c] = f2bf((v[k] - mu) * rstd * g[c] + b[c]);
    }
}

// ---------------- fused split-K combine + residual + LayerNorm ----------------
template<int S>
__global__ __launch_bounds__(256) void combine_ln_kernel(const float* __restrict__ parts,
                                                         const float* __restrict__ bias,
                                                         float* __restrict__ x,
                                                         const float* __restrict__ g,
                                                         const float* __restrict__ b,
                                                         unsigned short* __restrict__ hbuf) {
    __shared__ float red[256];
    int row = blockIdx.x, tid = threadIdx.x;
    float v[3]; float s = 0.f;
    #pragma unroll
    for (int k = 0; k < 3; ++k) {
        int c = tid + k * 256;
        long i = (long)row * NE + c;
        float a = parts[i];
        #pragma unroll
        for (int si = 1; si < S; ++si) a += parts[(long)si * NM * NE + i];
        a += bias[c] + x[i];
        x[i] = a;
        v[k] = a; s += a;
    }
    red[tid] = s; __syncthreads();
    for (int o = 128; o > 0; o >>= 1) { if (tid < o) red[tid] += red[tid + o]; __syncthreads(); }
    float mu = red[0] / NE;
    __syncthreads();
    float vr = 0.f;
    #pragma unroll
    for (int k = 0; k < 3; ++k) { float d = v[k] - mu; vr += d * d; }
    red[tid] = vr; __syncthreads();
    for (int o = 128; o > 0; o >>= 1) { if (tid < o) red[tid] += red[tid + o]; __syncthreads(); }
    float rstd = rsqrtf(red[0] / NE + LN_EPS);
    #pragma unroll
    for (int k = 0; k < 3; ++k) {
        int c = tid + k * 256;
        hbuf[(long)row * NE + c] = f2bf((v[k] - mu) * rstd * g[c] + b[c]);
    }
}

// ---------------- batched transpose of the four 768x768 weights, all layers ----------------
__global__ __launch_bounds__(256) void transpose4b_kernel(const float* __restrict__ wq,
                                                          const float* __restrict__ wk,
                                                          const float* __restrict__ wv,
                                                          const float* __restrict__ wp,
                                                          unsigned short* __restrict__ wqkvT,
                                                          unsigned short* __restrict__ wprojT) {
    __shared__ float t[32][33];
    int z = blockIdx.z, l = z >> 2, which = z & 3;
    const float* W = ((which == 0) ? wq : (which == 1) ? wk : (which == 2) ? wv : wp) + (long)l * NE * NE;
    unsigned short* WT = (which < 3) ? (wqkvT + (long)l * NQKV * NE + (long)which * NE * NE)
                                     : (wprojT + (long)l * NE * NE);
    int k0 = blockIdx.y * 32, n0 = blockIdx.x * 32;
    int c = threadIdx.x & 31, r = threadIdx.x >> 5;
    #pragma unroll
    for (int p = 0; p < 4; ++p)
        t[r + p * 8][c] = W[(long)(k0 + r + p * 8) * NE + n0 + c];
    __syncthreads();
    #pragma unroll
    for (int p = 0; p < 4; ++p)
        WT[(long)(n0 + r + p * 8) * NE + k0 + c] = f2bf(t[c][r + p * 8]);
}

// ---------------- batched tiled transpose + cast: per-layer stride K*N ----------------
__global__ __launch_bounds__(256) void transpose_cast_b_kernel(const float* __restrict__ W0,
                                                               unsigned short* __restrict__ WT0,
                                                               int K, int N) {
    __shared__ float t[32][33];
    long lofs = (long)blockIdx.z * K * N;
    const float* W = W0 + lofs;
    unsigned short* WT = WT0 + lofs;
    int k0 = blockIdx.y * 32, n0 = blockIdx.x * 32;
    int c = threadIdx.x & 31, r = threadIdx.x >> 5;
    #pragma unroll
    for (int p = 0; p < 4; ++p)
        t[r + p * 8][c] = W[(long)(k0 + r + p * 8) * N + n0 + c];
    __syncthreads();
    #pragma unroll
    for (int p = 0; p < 4; ++p)
        WT[(long)(n0 + r + p * 8) * K + k0 + c] = f2bf(t[c][r + p * 8]);
}

// ---------------- plain fp32 -> bf16 cast ----------------
__global__ __launch_bounds__(256) void cast_kernel(const float* __restrict__ W,
                                                   unsigned short* __restrict__ O, long n) {
    long i = ((long)blockIdx.x * 256 + threadIdx.x) * 4;
    if (i < n) {
        float4 v = *(const float4*)(W + i);
        ushort4v o;
        o[0] = f2bf(v.x); o[1] = f2bf(v.y); o[2] = f2bf(v.z); o[3] = f2bf(v.w);
        *(ushort4v*)(O + i) = o;
    }
}

// ---------------- batched beff ----------------
__global__ __launch_bounds__(256) void beff_b_kernel(const float* __restrict__ bproj,
                                                     const unsigned short* __restrict__ wprojT,
                                                     float* __restrict__ beff) {
    __shared__ float red[256];
    int n = blockIdx.x, l = blockIdx.y, tid = threadIdx.x;
    const unsigned short* wp = wprojT + (long)l * NE * NE + (long)n * NE;
    const float* bp = bproj + (long)l * NE;
    float acc = 0.f;
    for (int j = tid; j < NE; j += 256) acc += bp[j] * bf2f(wp[j]);
    red[tid] = acc; __syncthreads();
    for (int o = 128; o > 0; o >>= 1) { if (tid < o) red[tid] += red[tid + o]; __syncthreads(); }
    if (tid == 0) beff[(long)l * NE + n] = red[0] + bp[n];
}

// ---------------- combine split-K partials to bf16 (QKV path) ----------------
template<int S>
__global__ __launch_bounds__(256) void combine_kernel(const float* __restrict__ parts,
                                                      unsigned short* __restrict__ bout,
                                                      long total) {
    long i = ((long)blockIdx.x * 256 + threadIdx.x) * 4;
    if (i >= total) return;
    float4 a = *(const float4*)(parts + i);
    #pragma unroll
    for (int s = 1; s < S; ++s) {
        float4 b = *(const float4*)(parts + (long)s * total + i);
        a.x += b.x; a.y += b.y; a.z += b.z; a.w += b.w;
    }
    ushort4v o;
    o[0] = f2bf(a.x); o[1] = f2bf(a.y); o[2] = f2bf(a.z); o[3] = f2bf(a.w);
    *(ushort4v*)(bout + i) = o;
}

// ---------------- 128x128 bf16 MFMA GEMM, 2-phase dbuf, T2 swizzle, optional split-K ----------------
template<typename OutT, bool BIAS, bool RELU, int SPLITK>
__global__ __launch_bounds__(256) void gemm_mfma(const unsigned short* __restrict__ A,
                                                 const unsigned short* __restrict__ BT,
                                                 const float* __restrict__ bias,
                                                 OutT* __restrict__ C,
                                                 int gridM, int N, int K) {
    __shared__ unsigned short As[2][128 * 32];
    __shared__ unsigned short Bs[2][128 * 32];
    int tid = threadIdx.x;
    int lane = tid & 63, w = tid >> 6;
    int wr = w >> 1, wc = w & 1;
    int l4 = lane >> 4, l15 = lane & 15;

    int nwg = gridDim.x, orig = blockIdx.x;
    int q = nwg >> 3, r8 = nwg & 7;
    int xcd = orig & 7, ii = orig >> 3;
    int wg = (xcd < r8) ? (xcd * (q + 1) + ii) : (r8 * (q + 1) + (xcd - r8) * q + ii);
    int bm = wg % gridM, bn = wg / gridM;
    int m0 = bm * 128, n0 = bn * 128;

    int kb = K / SPLITK;
    int koff = (SPLITK > 1) ? blockIdx.y * kb : 0;

    f32x4 acc[4][4] = {};

    int srow = lane >> 2;
    int scol = ((lane & 3) ^ ((lane >> 3) & 3)) * 8;   // inverse-swizzled source slot
    int rsw  = (l4 ^ ((l15 >> 1) & 3)) * 8;            // swizzled read slot

    #pragma unroll
    for (int it = 0; it < 2; ++it) {
        int rr = w * 32 + it * 16;
        gload_lds16(&A [(long)(m0 + rr + srow) * K + koff + scol], &As[0][rr * 32]);
        gload_lds16(&BT[(long)(n0 + rr + srow) * K + koff + scol], &Bs[0][rr * 32]);
    }

    int cur = 0;
    for (int k0 = 0; k0 < kb; k0 += 32) {
        __syncthreads();
        if (k0 + 32 < kb) {
            #pragma unroll
            for (int it = 0; it < 2; ++it) {
                int rr = w * 32 + it * 16;
                gload_lds16(&A [(long)(m0 + rr + srow) * K + koff + k0 + 32 + scol], &As[cur ^ 1][rr * 32]);
                gload_lds16(&BT[(long)(n0 + rr + srow) * K + koff + k0 + 32 + scol], &Bs[cur ^ 1][rr * 32]);
            }
        }

        short8 a[4], b[4];
        #pragma unroll
        for (int f = 0; f < 4; ++f) {
            a[f] = *(const short8*)&As[cur][(wr * 64 + f * 16 + l15) * 32 + rsw];
            b[f] = *(const short8*)&Bs[cur][(wc * 64 + f * 16 + l15) * 32 + rsw];
        }
        __builtin_amdgcn_s_setprio(1);
        #pragma unroll
        for (int fm = 0; fm < 4; ++fm)
            #pragma unroll
            for (int fn = 0; fn < 4; ++fn)
                acc[fm][fn] = __builtin_amdgcn_mfma_f32_16x16x32_bf16(a[fm], b[fn], acc[fm][fn], 0, 0, 0);
        __builtin_amdgcn_s_setprio(0);
        cur ^= 1;
    }

    if constexpr (SPLITK > 1) {
        float* Cp = (float*)C + (long)blockIdx.y * gridM * 128 * N;
        #pragma unroll
        for (int fm = 0; fm < 4; ++fm)
            #pragma unroll
            for (int j = 0; j < 4; ++j) {
                long row = m0 + wr * 64 + fm * 16 + l4 * 4 + j;
                #pragma unroll
                for (int fn = 0; fn < 4; ++fn)
                    Cp[row * N + n0 + wc * 64 + fn * 16 + l15] = acc[fm][fn][j];
            }
    } else {
        float bs[4];
        #pragma unroll
        for (int fn = 0; fn < 4; ++fn)
            bs[fn] = BIAS ? bias[n0 + wc * 64 + fn * 16 + l15] : 0.f;

        #pragma unroll
        for (int fm = 0; fm < 4; ++fm) {
            #pragma unroll
            for (int j = 0; j < 4; ++j) {
                long row = m0 + wr * 64 + fm * 16 + l4 * 4 + j;
                #pragma unroll
                for (int fn = 0; fn < 4; ++fn) {
                    int col = n0 + wc * 64 + fn * 16 + l15;
                    float v = acc[fm][fn][j] + bs[fn];
                    if (RELU) v = fmaxf(v, 0.f);
                    if constexpr (sizeof(OutT) == 2) C[row * N + col] = (OutT)f2bf(v);
                    else                             C[row * N + col] = v;
                }
            }
        }
    }
}

// ---------------- batched square bf16 GEMM (weff = Wp@Wp per layer), T2 swizzle ----------------
__global__ __launch_bounds__(256) void gemm_weff_kernel(const unsigned short* __restrict__ A0,
                                                        const unsigned short* __restrict__ B0,
                                                        unsigned short* __restrict__ C0,
                                                        int gridM, int N, int K) {
    __shared__ unsigned short As[2][128 * 32];
    __shared__ unsigned short Bs[2][128 * 32];
    long zofs = (long)blockIdx.z * N * K;
    const unsigned short* A = A0 + zofs;
    const unsigned short* BT = B0 + zofs;
    unsigned short* C = C0 + zofs;
    int tid = threadIdx.x;
    int lane = tid & 63, w = tid >> 6;
    int wr = w >> 1, wc = w & 1;
    int l4 = lane >> 4, l15 = lane & 15;
    int bm = blockIdx.x % gridM, bn = blockIdx.x / gridM;
    int m0 = bm * 128, n0 = bn * 128;

    f32x4 acc[4][4] = {};
    int srow = lane >> 2;
    int scol = ((lane & 3) ^ ((lane >> 3) & 3)) * 8;
    int rsw  = (l4 ^ ((l15 >> 1) & 3)) * 8;

    #pragma unroll
    for (int it = 0; it < 2; ++it) {
        int rr = w * 32 + it * 16;
        gload_lds16(&A [(long)(m0 + rr + srow) * K + scol], &As[0][rr * 32]);
        gload_lds16(&BT[(long)(n0 + rr + srow) * K + scol], &Bs[0][rr * 32]);
    }
    int cur = 0;
    for (int k0 = 0; k0 < K; k0 += 32) {
        __syncthreads();
        if (k0 + 32 < K) {
            #pragma unroll
            for (int it = 0; it < 2; ++it) {
                int rr = w * 32 + it * 16;
                gload_lds16(&A [(long)(m0 + rr + srow) * K + k0 + 32 + scol], &As[cur ^ 1][rr * 32]);
                gload_lds16(&BT[(long)(n0 + rr + srow) * K + k0 + 32 + scol], &Bs[cur ^ 1][rr * 32]);
            }
        }
        short8 a[4], b[4];
        #pragma unroll
        for (int f = 0; f < 4; ++f) {
            a[f] = *(const short8*)&As[cur][(wr * 64 + f * 16 + l15) * 32 + rsw];
            b[f] = *(const short8*)&Bs[cur][(wc * 64 + f * 16 + l15) * 32 + rsw];
        }
        #pragma unroll
        for (int fm = 0; fm < 4; ++fm)
            #pragma unroll
            for (int fn = 0; fn < 4; ++fn)
                acc[fm][fn] = __builtin_amdgcn_mfma_f32_16x16x32_bf16(a[fm], b[fn], acc[fm][fn], 0, 0, 0);
        cur ^= 1;
    }
    #pragma unroll
    for (int fm = 0; fm < 4; ++fm)
        #pragma unroll
        for (int j = 0; j < 4; ++j) {
            long row = m0 + wr * 64 + fm * 16 + l4 * 4 + j;
            #pragma unroll
            for (int fn = 0; fn < 4; ++fn)
                C[row * N + n0 + wc * 64 + fn * 16 + l15] = f2bf(acc[fm][fn][j]);
        }
}

// ---------------- LM head: 256x128 tile, 8 waves x (64x64), 2-slot LDS, counted vmcnt ----------------
// Regs: acc 64 VGPR -> target <=128/wave => 4 waves/SIMD (2 blocks/CU). LDS 48KB.
__global__ __launch_bounds__(512, 4) void gemm256x128_lse(const unsigned short* __restrict__ A,
                                                          const unsigned short* __restrict__ BT,
                                                          const float* __restrict__ bias,
                                                          float* __restrict__ C,
                                                          float* __restrict__ pm, float* __restrict__ ps,
                                                          int gridM, int N, int K) {
    __shared__ unsigned short Al[2][256 * 32];   // 32 KB
    __shared__ unsigned short Bl[2][128 * 32];   // 16 KB
    int tid = threadIdx.x;
    int lane = tid & 63, w = tid >> 6;
    int wm = w >> 1, wn = w & 1;
    int l4 = lane >> 4, l15 = lane & 15;

    int nwg = gridDim.x, orig = blockIdx.x;
    int q = nwg >> 3, r8 = nwg & 7;
    int xcd = orig & 7, ii = orig >> 3;
    int wg = (xcd < r8) ? (xcd * (q + 1) + ii) : (r8 * (q + 1) + (xcd - r8) * q + ii);
    int bm = wg % gridM, bn = wg / gridM;
    int m0 = bm * 256, n0 = bn * 128;

    int nkt = K >> 5;
    int srow = lane >> 2;
    int sslot = ((lane & 3) ^ ((lane >> 3) & 3)) * 8;

    auto STAGE = [&](int slot, int kt) {       // 3 gload_lds per wave
        #pragma unroll
        for (int p = 0; p < 2; ++p) {
            int r0 = p * 128 + w * 16;
            gload_lds16(&A[(long)(m0 + r0 + srow) * K + kt * 32 + sslot], &Al[slot][r0 * 32]);
        }
        int r0 = w * 16;
        gload_lds16(&BT[(long)(n0 + r0 + srow) * K + kt * 32 + sslot], &Bl[slot][r0 * 32]);
    };

    f32x4 acc[4][4] = {};
    int rsw = (l4 ^ ((l15 >> 1) & 3)) * 8;

    STAGE(0, 0);
    for (int t = 0; t < nkt; ++t) {
        if (t + 1 < nkt) {
            STAGE((t + 1) & 1, t + 1);
            asm volatile("s_waitcnt vmcnt(3)" ::: "memory");   // slot t's 3 loads done
        } else {
            asm volatile("s_waitcnt vmcnt(0)" ::: "memory");
        }
        asm volatile("s_barrier" ::: "memory");                // slot t staged for all waves

        int s = t & 1;
        short8 af[4], bf[4];
        #pragma unroll
        for (int f = 0; f < 4; ++f) {
            af[f] = *(const short8*)&Al[s][(wm * 64 + f * 16 + l15) * 32 + rsw];
            bf[f] = *(const short8*)&Bl[s][(wn * 64 + f * 16 + l15) * 32 + rsw];
        }
        asm volatile("s_waitcnt lgkmcnt(0)" ::: "memory");
        asm volatile("s_barrier" ::: "memory");                // all reads of slot s done

        __builtin_amdgcn_s_setprio(1);
        #pragma unroll
        for (int fm = 0; fm < 4; ++fm)
            #pragma unroll
            for (int fn = 0; fn < 4; ++fn)
                acc[fm][fn] = __builtin_amdgcn_mfma_f32_16x16x32_bf16(af[fm], bf[fn], acc[fm][fn], 0, 0, 0);
        __builtin_amdgcn_s_setprio(0);
    }

    float bs[4];
    #pragma unroll
    for (int fn = 0; fn < 4; ++fn)
        bs[fn] = bias[n0 + wn * 64 + fn * 16 + l15];

    #pragma unroll
    for (int fm = 0; fm < 4; ++fm) {
        #pragma unroll
        for (int j = 0; j < 4; ++j) {
            long row = m0 + wm * 64 + fm * 16 + l4 * 4 + j;
            float v4[4];
            #pragma unroll
            for (int fn = 0; fn < 4; ++fn) {
                int col = n0 + wn * 64 + fn * 16 + l15;
                float v = acc[fm][fn][j] + bs[fn];
                C[row * N + col] = v;
                v4[fn] = v;
            }
            float mx = fmaxf(fmaxf(v4[0], v4[1]), fmaxf(v4[2], v4[3]));
            #pragma unroll
            for (int off = 1; off < 16; off <<= 1) mx = fmaxf(mx, __shfl_xor(mx, off));
            float sm = 0.f;
            #pragma unroll
            for (int fn = 0; fn < 4; ++fn) sm += __expf(v4[fn] - mx);
            #pragma unroll
            for (int off = 1; off < 16; off <<= 1) sm += __shfl_xor(sm, off);
            if (l15 == 0) {
                int pidx = bn * 2 + wn;
                pm[row * 512 + pidx] = mx;
                ps[row * 512 + pidx] = sm;
            }
        }
    }
}

// ---------------- V transpose: vt[bh][d][t] = V[b][t][h][d] ----------------
__global__ __launch_bounds__(256) void vtrans_kernel(const unsigned short* __restrict__ qkv,
                                                     unsigned short* __restrict__ vt) {
    __shared__ unsigned short t[64][72];
    int t0 = blockIdx.x * 64;
    int bh = blockIdx.y;
    int b = bh / NH, h = bh % NH;
    int tid = threadIdx.x;
    #pragma unroll
    for (int i = 0; i < 2; ++i) {
        int r = (tid >> 3) + i * 32, c8 = (tid & 7) * 8;
        short8 v = *(const short8*)(qkv + ((long)b * NT + t0 + r) * NQKV + 2 * NE + h * NHS + c8);
        *(short8*)&t[r][c8] = v;
    }
    __syncthreads();
    #pragma unroll
    for (int i = 0; i < 2; ++i) {
        int d = (tid >> 3) + i * 32, s = (tid & 7) * 8;
        short8 o;
        #pragma unroll
        for (int j = 0; j < 8; ++j) o[j] = (short)t[s + j][d];
        *(short8*)(vt + ((long)bh * NHS + d) * NT + t0 + s) = o;
    }
}

// ---------------- flash attention: dbuf K/V LDS, 1 barrier/tile, prefetch overlap ----------------
__global__ __launch_bounds__(256) void fattn_kernel(const unsigned short* __restrict__ qkv,
                                                    const unsigned short* __restrict__ vt,
                                                    unsigned short* __restrict__ out) {
    __shared__ unsigned short Ks[2][64 * 64];
    __shared__ unsigned short Vl[2][64 * 64];
    __shared__ unsigned short Ps[4 * 16 * 64];
    int qt = gridDim.x - 1 - blockIdx.x;
    int bh = blockIdx.y;
    int b = bh / NH, h = bh % NH;
    int tid = threadIdx.x, lane = tid & 63, w = tid >> 6;
    int l4 = lane >> 4, l15 = lane & 15;
    long rowb = (long)b * NT;
    const float scale = 0.03608439182435161f;    // 768^-0.5 (reference scales by E)
    const unsigned short* vtp = vt + (long)bh * NHS * NT;

    const unsigned short* qptr = qkv + (rowb + qt * 64 + w * 16 + l15) * NQKV + h * NHS;
    short8 qa0 = *(const short8*)(qptr + l4 * 8);
    short8 qa1 = *(const short8*)(qptr + 32 + l4 * 8);

    f32x4 o[4] = {};
    float m[4], lsum[4];
    #pragma unroll
    for (int j = 0; j < 4; ++j) { m[j] = -INFINITY; lsum[j] = 0.f; }

    int kr_r = tid >> 3, kr_c = (tid & 7) * 8;
    int vr_d = tid >> 3, vr_s = tid & 7;

    short8 kr[2], vr[2];
    auto LOADT = [&](int t) {
        int kbase = t * 64;
        #pragma unroll
        for (int i = 0; i < 2; ++i) {
            kr[i] = *(const short8*)(qkv + (rowb + kbase + kr_r + i * 32) * NQKV + NE + h * NHS + kr_c);
            vr[i] = *(const short8*)(vtp + (long)(vr_d + i * 32) * NT + kbase + vr_s * 8);
        }
    };

    LOADT(0);
    for (int t = 0; t <= qt; ++t) {
        int cur = t & 1;
        #pragma unroll
        for (int i = 0; i < 2; ++i) {
            int r = kr_r + i * 32;
            *(short8*)&Ks[cur][r * 64 + (kr_c ^ ((r & 7) << 3))] = kr[i];
            int d = vr_d + i * 32;
            *(short8*)&Vl[cur][d * 64 + ((vr_s * 8) ^ ((d & 7) << 3))] = vr[i];
        }
        asm volatile("s_waitcnt lgkmcnt(0)" ::: "memory");
        if (t < qt) LOADT(t + 1);
        asm volatile("s_barrier" ::: "memory");

        f32x4 s[4];
        __builtin_amdgcn_s_setprio(1);
        #pragma unroll
        for (int fn = 0; fn < 4; ++fn) {
            int key = fn * 16 + l15;
            short8 kb0 = *(const short8*)&Ks[cur][key * 64 + ((l4 * 8) ^ ((key & 7) << 3))];
            short8 kb1 = *(const short8*)&Ks[cur][key * 64 + ((32 + l4 * 8) ^ ((key & 7) << 3))];
            f32x4 z = {};
            z = __builtin_amdgcn_mfma_f32_16x16x32_bf16(qa0, kb0, z, 0, 0, 0);
            s[fn] = __builtin_amdgcn_mfma_f32_16x16x32_bf16(qa1, kb1, z, 0, 0, 0);
        }
        __builtin_amdgcn_s_setprio(0);

        if (t == qt) {
            #pragma unroll
            for (int fn = 0; fn < 4; ++fn) {
                int key = t * 64 + fn * 16 + l15;
                #pragma unroll
                for (int j = 0; j < 4; ++j) {
                    int qrow = qt * 64 + w * 16 + l4 * 4 + j;
                    s[fn][j] = (key <= qrow) ? s[fn][j] * scale : -1e30f;
                }
            }
        } else {
            #pragma unroll
            for (int fn = 0; fn < 4; ++fn)
                #pragma unroll
                for (int j = 0; j < 4; ++j)
                    s[fn][j] *= scale;
        }

        #pragma unroll
        for (int j = 0; j < 4; ++j) {
            float mj = fmaxf(fmaxf(s[0][j], s[1][j]), fmaxf(s[2][j], s[3][j]));
            #pragma unroll
            for (int off = 1; off < 16; off <<= 1) mj = fmaxf(mj, __shfl_xor(mj, off));
            float mnew = fmaxf(m[j], mj);
            float alpha = __expf(m[j] - mnew);
            m[j] = mnew;
            float psum = 0.f;
            #pragma unroll
            for (int fn = 0; fn < 4; ++fn) {
                float p = __expf(s[fn][j] - mnew);
                psum += p;
                int rr = l4 * 4 + j, c = fn * 16 + l15;
                Ps[w * 1024 + rr * 64 + (c ^ ((rr & 7) << 3))] = f2bf(p);
            }
            #pragma unroll
            for (int off = 1; off < 16; off <<= 1) psum += __shfl_xor(psum, off);
            lsum[j] = lsum[j] * alpha + psum;
            #pragma unroll
            for (int fn = 0; fn < 4; ++fn) o[fn][j] *= alpha;
        }

        short8 pa0 = *(const short8*)&Ps[w * 1024 + l15 * 64 + ((l4 * 8) ^ ((l15 & 7) << 3))];
        short8 pa1 = *(const short8*)&Ps[w * 1024 + l15 * 64 + ((32 + l4 * 8) ^ ((l15 & 7) << 3))];
        __builtin_amdgcn_s_setprio(1);
        #pragma unroll
        for (int fn = 0; fn < 4; ++fn) {
            int d = fn * 16 + l15;
            short8 vb0 = *(const short8*)&Vl[cur][d * 64 + ((l4 * 8) ^ ((d & 7) << 3))];
            short8 vb1 = *(const short8*)&Vl[cur][d * 64 + ((32 + l4 * 8) ^ ((d & 7) << 3))];
            o[fn] = __builtin_amdgcn_mfma_f32_16x16x32_bf16(pa0, vb0, o[fn], 0, 0, 0);
            o[fn] = __builtin_amdgcn_mfma_f32_16x16x32_bf16(pa1, vb1, o[fn], 0, 0, 0);
        }
        __builtin_amdgcn_s_setprio(0);
    }

    #pragma unroll
    for (int j = 0; j < 4; ++j) {
        long row = rowb + qt * 64 + w * 16 + l4 * 4 + j;
        float inv = 1.0f / lsum[j];
        #pragma unroll
        for (int fn = 0; fn < 4; ++fn)
            out[row * NE + h * NHS + fn * 16 + l15] = f2bf(o[fn][j] * inv);
    }
}

// ---------------- NLL from LM-head partials ----------------
__global__ __launch_bounds__(256) void nll_combine_kernel(const float* __restrict__ logits,
                                                          const float* __restrict__ pm,
                                                          const float* __restrict__ ps,
                                                          const int* __restrict__ targets,
                                                          float* __restrict__ nll) {
    __shared__ float rm[256], rs[256];
    int row = blockIdx.x, tid = threadIdx.x;
    float m = -1e30f, s = 0.f;
    for (int i = tid; i < 500; i += 256) {
        float m2 = pm[(long)row * 512 + i], s2 = ps[(long)row * 512 + i];
        float mm = fmaxf(m, m2);
        s = s * __expf(m - mm) + s2 * __expf(m2 - mm);
        m = mm;
    }
    rm[tid] = m; rs[tid] = s; __syncthreads();
    for (int o = 128; o > 0; o >>= 1) {
        if (tid < o) {
            float m2 = rm[tid + o], s2 = rs[tid + o];
            float mm = fmaxf(rm[tid], m2);
            rs[tid] = rs[tid] * __expf(rm[tid] - mm) + s2 * __expf(m2 - mm);
            rm[tid] = mm;
        }
        __syncthreads();
    }
    if (tid == 0) {
        int tgt = targets[row];
        nll[row] = -(logits[(long)row * NV + tgt] - rm[0] - logf(rs[0]));
    }
}

__global__ void loss_reduce_kernel(const float* __restrict__ nll, float* __restrict__ out) {
    __shared__ float red[256];
    int tid = threadIdx.x;
    float s = 0.f;
    for (int i = tid; i < NM; i += 256) s += nll[i];
    red[tid] = s; __syncthreads();
    for (int o = 128; o > 0; o >>= 1) { if (tid < o) red[tid] += red[tid + o]; __syncthreads(); }
    if (tid == 0) out[0] = red[0] / NM;
}

extern "C" void kernel_launch(void* const* d_in, const int* in_sizes, int n_in,
                              void* d_out, int out_size, void* d_ws, size_t ws_size,
                              hipStream_t stream) {
    const int*   idx     = (const int*)  d_in[0];
    const int*   targets = (const int*)  d_in[1];
    const float* tok     = (const float*)d_in[2];
    const float* pos     = (const float*)d_in[3];
    const float* ln1_g   = (const float*)d_in[4];
    const float* ln1_b   = (const float*)d_in[5];
    const float* wq      = (const float*)d_in[6];
    const float* wk      = (const float*)d_in[7];
    const float* wv      = (const float*)d_in[8];
    const float* wproj   = (const float*)d_in[9];
    const float* bproj   = (const float*)d_in[10];
    const float* ln2_g   = (const float*)d_in[11];
    const float* ln2_b   = (const float*)d_in[12];
    const float* w1      = (const float*)d_in[13];
    const float* b1      = (const float*)d_in[14];
    const float* w2      = (const float*)d_in[15];
    const float* b2      = (const float*)d_in[16];
    const float* lnf_g   = (const float*)d_in[17];
    const float* lnf_b   = (const float*)d_in[18];
    const float* lm_w    = (const float*)d_in[19];
    const float* lm_b    = (const float*)d_in[20];

    float* logits = (float*)d_out;
    float* loss   = logits + (long)NM * NV;

    char* p = (char*)d_ws;
    float*          x      = (float*)p;          p += (long)NM * NE * 4;
    unsigned short* hbuf   = (unsigned short*)p; p += (long)NM * NE * 2;
    unsigned short* qkv    = (unsigned short*)p; p += (long)NM * NQKV * 2;
    unsigned short* att    = (unsigned short*)p; p += (long)NM * NE * 2;
    unsigned short* hid    = (unsigned short*)p; p += (long)NM * NFF * 2;
    unsigned short* vt     = (unsigned short*)p; p += (long)NB * NH * NHS * NT * 2;
    float*          nll    = (float*)p;          p += (long)NM * 4;
    float*          pmb    = (float*)p;          p += (long)NM * 512 * 4;
    float*          psb    = (float*)p;          p += (long)NM * 512 * 4;
    float*          parts  = (float*)p;          p += (long)2 * NM * NQKV * 4;
    unsigned short* wqkvT6 = (unsigned short*)p; p += (long)NL * NQKV * NE * 2;
    unsigned short* wprojT6= (unsigned short*)p; p += (long)NL * NE * NE * 2;
    unsigned short* wprojC6= (unsigned short*)p; p += (long)NL * NE * NE * 2;
    unsigned short* weffT6 = (unsigned short*)p; p += (long)NL * NE * NE * 2;
    float*          beff6  = (float*)p;          p += (long)NL * NE * 4;
    unsigned short* w1T6   = (unsigned short*)p; p += (long)NL * NFF * NE * 2;
    unsigned short* w2T6   = (unsigned short*)p; p += (long)NL * NE * NFF * 2;
    unsigned short* lmT    = (unsigned short*)p; p += (long)NV * NE * 2;

    dim3 blk(256);

    // ---- batched weight prep ----
    transpose4b_kernel<<<dim3(NE / 32, NE / 32, 4 * NL), blk, 0, stream>>>(
        wq, wk, wv, wproj, wqkvT6, wprojT6);
    cast_kernel<<<(NL * NE * NE) / 1024, blk, 0, stream>>>(wproj, wprojC6, (long)NL * NE * NE);
    transpose_cast_b_kernel<<<dim3(NFF / 32, NE / 32, NL), blk, 0, stream>>>(w1, w1T6, NE, NFF);
    transpose_cast_b_kernel<<<dim3(NE / 32, NFF / 32, NL), blk, 0, stream>>>(w2, w2T6, NFF, NE);
    gemm_weff_kernel<<<dim3(36, 1, NL), blk, 0, stream>>>(wprojT6, wprojC6, weffT6, 6, NE, NE);
    beff_b_kernel<<<dim3(NE, NL), blk, 0, stream>>>(bproj, wprojT6, beff6);
    transpose_cast_b_kernel<<<dim3(NV / 32, NE / 32, 1), blk, 0, stream>>>(lm_w, lmT, NE, NV);

    // ---- embedding + LN1(0) ----
    embed_ln_kernel<<<NM, blk, 0, stream>>>(idx, tok, pos, ln1_g, ln1_b, x, hbuf);

    for (int l = 0; l < NL; ++l) {
        gemm_mfma<float, false, false, 2><<<dim3((NM/128)*(NQKV/128), 2), blk, 0, stream>>>(
            hbuf, wqkvT6 + (long)l * NQKV * NE, nullptr, parts, NM / 128, NQKV, NE);
        combine_kernel<2><<<(NM * NQKV) / 1024, blk, 0, stream>>>(parts, qkv, (long)NM * NQKV);
        vtrans_kernel<<<dim3(NT / 64, NB * NH), blk, 0, stream>>>(qkv, vt);
        fattn_kernel<<<dim3(NT / 64, NB * NH), blk, 0, stream>>>(qkv, vt, att);
        gemm_mfma<float, false, false, 2><<<dim3((NM/128)*(NE/128), 2), blk, 0, stream>>>(
            att, weffT6 + (long)l * NE * NE, nullptr, parts, NM / 128, NE, NE);
        combine_ln_kernel<2><<<NM, blk, 0, stream>>>(
            parts, beff6 + (long)l * NE, x, ln2_g + (long)l * NE, ln2_b + (long)l * NE, hbuf);
        gemm_mfma<unsigned short, true, true, 1><<<dim3((NM/128)*(NFF/128)), blk, 0, stream>>>(
            hbuf, w1T6 + (long)l * NFF * NE, b1 + (long)l * NFF, hid, NM / 128, NFF, NE);
        gemm_mfma<float, false, false, 4><<<dim3((NM/128)*(NE/128), 4), blk, 0, stream>>>(
            hid, w2T6 + (long)l * NE * NFF, nullptr, parts, NM / 128, NE, NFF);
        const float* ng = (l < NL - 1) ? (ln1_g + (long)(l + 1) * NE) : lnf_g;
        const float* nb = (l < NL - 1) ? (ln1_b + (long)(l + 1) * NE) : lnf_b;
        combine_ln_kernel<4><<<NM, blk, 0, stream>>>(parts, b2 + (long)l * NE, x, ng, nb, hbuf);
    }

    // ---- LM head + fused LSE ----
    gemm256x128_lse<<<dim3((NM/256)*(NV/128)), dim3(512), 0, stream>>>(
        hbuf, lmT, lm_b, logits, pmb, psb, NM / 256, NV, NE);
    nll_combine_kernel<<<NM, blk, 0, stream>>>(logits, pmb, psb, targets, nll);
    loss_reduce_kernel<<<1, blk, 0, stream>>>(nll, loss);
}

// Round 9
// 1140.024 us; speedup vs baseline: 10.0630x; 1.0354x over previous
//
#include <hip/hip_runtime.h>
#include <math.h>

#define NL 6
#define NH 12
#define NE 768
#define NHS 64
#define NT 1024
#define NB 2
#define NV 32000
#define NM (NB * NT)   // 2048
#define NQKV (3 * NE)  // 2304
#define NFF (4 * NE)   // 3072
#define LN_EPS 1e-5f

typedef __attribute__((ext_vector_type(8))) short short8;
typedef __attribute__((ext_vector_type(4))) float f32x4;
typedef __attribute__((ext_vector_type(4))) unsigned short ushort4v;
typedef __attribute__((address_space(1))) const unsigned int as1_cuint;
typedef __attribute__((address_space(3))) unsigned int as3_uint;

__device__ __forceinline__ unsigned short f2bf(float f) {
    unsigned int u = __builtin_bit_cast(unsigned int, f);
    u += 0x7fffu + ((u >> 16) & 1u);   // RNE
    return (unsigned short)(u >> 16);
}
__device__ __forceinline__ float bf2f(unsigned short u) {
    unsigned int v = ((unsigned int)u) << 16;
    return __builtin_bit_cast(float, v);
}
__device__ __forceinline__ void gload_lds16(const void* g, void* l) {
    __builtin_amdgcn_global_load_lds((as1_cuint*)g, (as3_uint*)l, 16, 0, 0);
}

// ---------------- embedding + LN1(layer0) fused: one block per row ----------------
__global__ __launch_bounds__(256) void embed_ln_kernel(const int* __restrict__ idx,
                                                       const float* __restrict__ tok,
                                                       const float* __restrict__ pos,
                                                       const float* __restrict__ g,
                                                       const float* __restrict__ b,
                                                       float* __restrict__ x,
                                                       unsigned short* __restrict__ hbuf) {
    __shared__ float red[256];
    int row = blockIdx.x, tid = threadIdx.x;
    int t = row % NT;
    int id = idx[row];
    float v[3]; float s = 0.f;
    #pragma unroll
    for (int k = 0; k < 3; ++k) {
        int c = tid + k * 256;
        v[k] = tok[(long)id * NE + c] + pos[(long)t * NE + c];
        x[(long)row * NE + c] = v[k];
        s += v[k];
    }
    red[tid] = s; __syncthreads();
    for (int o = 128; o > 0; o >>= 1) { if (tid < o) red[tid] += red[tid + o]; __syncthreads(); }
    float mu = red[0] / NE;
    __syncthreads();
    float vr = 0.f;
    #pragma unroll
    for (int k = 0; k < 3; ++k) { float d = v[k] - mu; vr += d * d; }
    red[tid] = vr; __syncthreads();
    for (int o = 128; o > 0; o >>= 1) { if (tid < o) red[tid] += red[tid + o]; __syncthreads(); }
    float rstd = rsqrtf(red[0] / NE + LN_EPS);
    #pragma unroll
    for (int k = 0; k < 3; ++k) {
        int c = tid + k * 256;
        hbuf[(long)row * NE + c] = f2bf((v[k] - mu) * rstd * g[c] + b[c]);
    }
}

// ---------------- fused split-K combine + residual + LayerNorm ----------------
template<int S>
__global__ __launch_bounds__(256) void combine_ln_kernel(const float* __restrict__ parts,
                                                         const float* __restrict__ bias,
                                                         float* __restrict__ x,
                                                         const float* __restrict__ g,
                                                         const float* __restrict__ b,
                                                         unsigned short* __restrict__ hbuf) {
    __shared__ float red[256];
    int row = blockIdx.x, tid = threadIdx.x;
    float v[3]; float s = 0.f;
    #pragma unroll
    for (int k = 0; k < 3; ++k) {
        int c = tid + k * 256;
        long i = (long)row * NE + c;
        float a = parts[i];
        #pragma unroll
        for (int si = 1; si < S; ++si) a += parts[(long)si * NM * NE + i];
        a += bias[c] + x[i];
        x[i] = a;
        v[k] = a; s += a;
    }
    red[tid] = s; __syncthreads();
    for (int o = 128; o > 0; o >>= 1) { if (tid < o) red[tid] += red[tid + o]; __syncthreads(); }
    float mu = red[0] / NE;
    __syncthreads();
    float vr = 0.f;
    #pragma unroll
    for (int k = 0; k < 3; ++k) { float d = v[k] - mu; vr += d * d; }
    red[tid] = vr; __syncthreads();
    for (int o = 128; o > 0; o >>= 1) { if (tid < o) red[tid] += red[tid + o]; __syncthreads(); }
    float rstd = rsqrtf(red[0] / NE + LN_EPS);
    #pragma unroll
    for (int k = 0; k < 3; ++k) {
        int c = tid + k * 256;
        hbuf[(long)row * NE + c] = f2bf((v[k] - mu) * rstd * g[c] + b[c]);
    }
}

// ---------------- batched transpose of the four 768x768 weights, all layers ----------------
__global__ __launch_bounds__(256) void transpose4b_kernel(const float* __restrict__ wq,
                                                          const float* __restrict__ wk,
                                                          const float* __restrict__ wv,
                                                          const float* __restrict__ wp,
                                                          unsigned short* __restrict__ wqkvT,
                                                          unsigned short* __restrict__ wprojT) {
    __shared__ float t[32][33];
    int z = blockIdx.z, l = z >> 2, which = z & 3;
    const float* W = ((which == 0) ? wq : (which == 1) ? wk : (which == 2) ? wv : wp) + (long)l * NE * NE;
    unsigned short* WT = (which < 3) ? (wqkvT + (long)l * NQKV * NE + (long)which * NE * NE)
                                     : (wprojT + (long)l * NE * NE);
    int k0 = blockIdx.y * 32, n0 = blockIdx.x * 32;
    int c = threadIdx.x & 31, r = threadIdx.x >> 5;
    #pragma unroll
    for (int p = 0; p < 4; ++p)
        t[r + p * 8][c] = W[(long)(k0 + r + p * 8) * NE + n0 + c];
    __syncthreads();
    #pragma unroll
    for (int p = 0; p < 4; ++p)
        WT[(long)(n0 + r + p * 8) * NE + k0 + c] = f2bf(t[c][r + p * 8]);
}

// ---------------- batched tiled transpose + cast: per-layer stride K*N ----------------
__global__ __launch_bounds__(256) void transpose_cast_b_kernel(const float* __restrict__ W0,
                                                               unsigned short* __restrict__ WT0,
                                                               int K, int N) {
    __shared__ float t[32][33];
    long lofs = (long)blockIdx.z * K * N;
    const float* W = W0 + lofs;
    unsigned short* WT = WT0 + lofs;
    int k0 = blockIdx.y * 32, n0 = blockIdx.x * 32;
    int c = threadIdx.x & 31, r = threadIdx.x >> 5;
    #pragma unroll
    for (int p = 0; p < 4; ++p)
        t[r + p * 8][c] = W[(long)(k0 + r + p * 8) * N + n0 + c];
    __syncthreads();
    #pragma unroll
    for (int p = 0; p < 4; ++p)
        WT[(long)(n0 + r + p * 8) * K + k0 + c] = f2bf(t[c][r + p * 8]);
}

// ---------------- plain fp32 -> bf16 cast ----------------
__global__ __launch_bounds__(256) void cast_kernel(const float* __restrict__ W,
                                                   unsigned short* __restrict__ O, long n) {
    long i = ((long)blockIdx.x * 256 + threadIdx.x) * 4;
    if (i < n) {
        float4 v = *(const float4*)(W + i);
        ushort4v o;
        o[0] = f2bf(v.x); o[1] = f2bf(v.y); o[2] = f2bf(v.z); o[3] = f2bf(v.w);
        *(ushort4v*)(O + i) = o;
    }
}

// ---------------- batched beff ----------------
__global__ __launch_bounds__(256) void beff_b_kernel(const float* __restrict__ bproj,
                                                     const unsigned short* __restrict__ wprojT,
                                                     float* __restrict__ beff) {
    __shared__ float red[256];
    int n = blockIdx.x, l = blockIdx.y, tid = threadIdx.x;
    const unsigned short* wp = wprojT + (long)l * NE * NE + (long)n * NE;
    const float* bp = bproj + (long)l * NE;
    float acc = 0.f;
    for (int j = tid; j < NE; j += 256) acc += bp[j] * bf2f(wp[j]);
    red[tid] = acc; __syncthreads();
    for (int o = 128; o > 0; o >>= 1) { if (tid < o) red[tid] += red[tid + o]; __syncthreads(); }
    if (tid == 0) beff[(long)l * NE + n] = red[0] + bp[n];
}

// ---------------- combine split-K partials to bf16 (QKV path) ----------------
template<int S>
__global__ __launch_bounds__(256) void combine_kernel(const float* __restrict__ parts,
                                                      unsigned short* __restrict__ bout,
                                                      long total) {
    long i = ((long)blockIdx.x * 256 + threadIdx.x) * 4;
    if (i >= total) return;
    float4 a = *(const float4*)(parts + i);
    #pragma unroll
    for (int s = 1; s < S; ++s) {
        float4 b = *(const float4*)(parts + (long)s * total + i);
        a.x += b.x; a.y += b.y; a.z += b.z; a.w += b.w;
    }
    ushort4v o;
    o[0] = f2bf(a.x); o[1] = f2bf(a.y); o[2] = f2bf(a.z); o[3] = f2bf(a.w);
    *(ushort4v*)(bout + i) = o;
}

// ---------------- 128x128 bf16 MFMA GEMM: 3-slot ring, depth-2 counted vmcnt ----------------
template<typename OutT, bool BIAS, bool RELU, int SPLITK>
__global__ __launch_bounds__(256) void gemm_mfma(const unsigned short* __restrict__ A,
                                                 const unsigned short* __restrict__ BT,
                                                 const float* __restrict__ bias,
                                                 OutT* __restrict__ C,
                                                 int gridM, int N, int K) {
    __shared__ unsigned short As[3][128 * 32];
    __shared__ unsigned short Bs[3][128 * 32];
    int tid = threadIdx.x;
    int lane = tid & 63, w = tid >> 6;
    int wr = w >> 1, wc = w & 1;
    int l4 = lane >> 4, l15 = lane & 15;

    int nwg = gridDim.x, orig = blockIdx.x;
    int q = nwg >> 3, r8 = nwg & 7;
    int xcd = orig & 7, ii = orig >> 3;
    int wg = (xcd < r8) ? (xcd * (q + 1) + ii) : (r8 * (q + 1) + (xcd - r8) * q + ii);
    int bm = wg % gridM, bn = wg / gridM;
    int m0 = bm * 128, n0 = bn * 128;

    int kb = K / SPLITK;
    int koff = (SPLITK > 1) ? blockIdx.y * kb : 0;
    int nkt = kb >> 5;

    f32x4 acc[4][4] = {};

    int srow = lane >> 2;
    int scol = ((lane & 3) ^ ((lane >> 3) & 3)) * 8;   // inverse-swizzled source slot
    int rsw  = (l4 ^ ((l15 >> 1) & 3)) * 8;            // swizzled read slot

    auto STAGE = [&](int slot, int kt) {   // 4 gload_lds per wave
        #pragma unroll
        for (int it = 0; it < 2; ++it) {
            int rr = w * 32 + it * 16;
            gload_lds16(&A [(long)(m0 + rr + srow) * K + koff + kt * 32 + scol], &As[slot][rr * 32]);
            gload_lds16(&BT[(long)(n0 + rr + srow) * K + koff + kt * 32 + scol], &Bs[slot][rr * 32]);
        }
    };

    STAGE(0, 0);
    if (nkt > 1) STAGE(1, 1);

    int s = 0;
    for (int t = 0; t < nkt; ++t) {
        if (t + 2 < nkt) STAGE((t + 2) % 3, t + 2);
        int ahead = nkt - 1 - t;
        if (ahead >= 2)      asm volatile("s_waitcnt vmcnt(8)" ::: "memory");
        else if (ahead == 1) asm volatile("s_waitcnt vmcnt(4)" ::: "memory");
        else                 asm volatile("s_waitcnt vmcnt(0)" ::: "memory");
        asm volatile("s_barrier" ::: "memory");        // slot s fully staged for all waves

        short8 a[4], b[4];
        #pragma unroll
        for (int f = 0; f < 4; ++f) {
            a[f] = *(const short8*)&As[s][(wr * 64 + f * 16 + l15) * 32 + rsw];
            b[f] = *(const short8*)&Bs[s][(wc * 64 + f * 16 + l15) * 32 + rsw];
        }
        asm volatile("s_waitcnt lgkmcnt(0)" ::: "memory");
        asm volatile("s_barrier" ::: "memory");        // all reads of slot s done -> restageable

        __builtin_amdgcn_s_setprio(1);
        #pragma unroll
        for (int fm = 0; fm < 4; ++fm)
            #pragma unroll
            for (int fn = 0; fn < 4; ++fn)
                acc[fm][fn] = __builtin_amdgcn_mfma_f32_16x16x32_bf16(a[fm], b[fn], acc[fm][fn], 0, 0, 0);
        __builtin_amdgcn_s_setprio(0);
        s = (s + 1) % 3;
    }

    if constexpr (SPLITK > 1) {
        float* Cp = (float*)C + (long)blockIdx.y * gridM * 128 * N;
        #pragma unroll
        for (int fm = 0; fm < 4; ++fm)
            #pragma unroll
            for (int j = 0; j < 4; ++j) {
                long row = m0 + wr * 64 + fm * 16 + l4 * 4 + j;
                #pragma unroll
                for (int fn = 0; fn < 4; ++fn)
                    Cp[row * N + n0 + wc * 64 + fn * 16 + l15] = acc[fm][fn][j];
            }
    } else {
        float bs[4];
        #pragma unroll
        for (int fn = 0; fn < 4; ++fn)
            bs[fn] = BIAS ? bias[n0 + wc * 64 + fn * 16 + l15] : 0.f;

        #pragma unroll
        for (int fm = 0; fm < 4; ++fm) {
            #pragma unroll
            for (int j = 0; j < 4; ++j) {
                long row = m0 + wr * 64 + fm * 16 + l4 * 4 + j;
                #pragma unroll
                for (int fn = 0; fn < 4; ++fn) {
                    int col = n0 + wc * 64 + fn * 16 + l15;
                    float v = acc[fm][fn][j] + bs[fn];
                    if (RELU) v = fmaxf(v, 0.f);
                    if constexpr (sizeof(OutT) == 2) C[row * N + col] = (OutT)f2bf(v);
                    else                             C[row * N + col] = v;
                }
            }
        }
    }
}

// ---------------- batched square bf16 GEMM (weff = Wp@Wp per layer), T2 swizzle ----------------
__global__ __launch_bounds__(256) void gemm_weff_kernel(const unsigned short* __restrict__ A0,
                                                        const unsigned short* __restrict__ B0,
                                                        unsigned short* __restrict__ C0,
                                                        int gridM, int N, int K) {
    __shared__ unsigned short As[2][128 * 32];
    __shared__ unsigned short Bs[2][128 * 32];
    long zofs = (long)blockIdx.z * N * K;
    const unsigned short* A = A0 + zofs;
    const unsigned short* BT = B0 + zofs;
    unsigned short* C = C0 + zofs;
    int tid = threadIdx.x;
    int lane = tid & 63, w = tid >> 6;
    int wr = w >> 1, wc = w & 1;
    int l4 = lane >> 4, l15 = lane & 15;
    int bm = blockIdx.x % gridM, bn = blockIdx.x / gridM;
    int m0 = bm * 128, n0 = bn * 128;

    f32x4 acc[4][4] = {};
    int srow = lane >> 2;
    int scol = ((lane & 3) ^ ((lane >> 3) & 3)) * 8;
    int rsw  = (l4 ^ ((l15 >> 1) & 3)) * 8;

    #pragma unroll
    for (int it = 0; it < 2; ++it) {
        int rr = w * 32 + it * 16;
        gload_lds16(&A [(long)(m0 + rr + srow) * K + scol], &As[0][rr * 32]);
        gload_lds16(&BT[(long)(n0 + rr + srow) * K + scol], &Bs[0][rr * 32]);
    }
    int cur = 0;
    for (int k0 = 0; k0 < K; k0 += 32) {
        __syncthreads();
        if (k0 + 32 < K) {
            #pragma unroll
            for (int it = 0; it < 2; ++it) {
                int rr = w * 32 + it * 16;
                gload_lds16(&A [(long)(m0 + rr + srow) * K + k0 + 32 + scol], &As[cur ^ 1][rr * 32]);
                gload_lds16(&BT[(long)(n0 + rr + srow) * K + k0 + 32 + scol], &Bs[cur ^ 1][rr * 32]);
            }
        }
        short8 a[4], b[4];
        #pragma unroll
        for (int f = 0; f < 4; ++f) {
            a[f] = *(const short8*)&As[cur][(wr * 64 + f * 16 + l15) * 32 + rsw];
            b[f] = *(const short8*)&Bs[cur][(wc * 64 + f * 16 + l15) * 32 + rsw];
        }
        #pragma unroll
        for (int fm = 0; fm < 4; ++fm)
            #pragma unroll
            for (int fn = 0; fn < 4; ++fn)
                acc[fm][fn] = __builtin_amdgcn_mfma_f32_16x16x32_bf16(a[fm], b[fn], acc[fm][fn], 0, 0, 0);
        cur ^= 1;
    }
    #pragma unroll
    for (int fm = 0; fm < 4; ++fm)
        #pragma unroll
        for (int j = 0; j < 4; ++j) {
            long row = m0 + wr * 64 + fm * 16 + l4 * 4 + j;
            #pragma unroll
            for (int fn = 0; fn < 4; ++fn)
                C[row * N + n0 + wc * 64 + fn * 16 + l15] = f2bf(acc[fm][fn][j]);
        }
}

// ---------------- LM head: 256x128 tile, 8 waves, 3-slot ring, depth-2 vmcnt, nt stores ----------------
__global__ __launch_bounds__(512, 4) void gemm256x128_lse(const unsigned short* __restrict__ A,
                                                          const unsigned short* __restrict__ BT,
                                                          const float* __restrict__ bias,
                                                          float* __restrict__ C,
                                                          float* __restrict__ pm, float* __restrict__ ps,
                                                          int gridM, int N, int K) {
    __shared__ unsigned short Al[3][256 * 32];   // 48 KB
    __shared__ unsigned short Bl[3][128 * 32];   // 24 KB
    int tid = threadIdx.x;
    int lane = tid & 63, w = tid >> 6;
    int wm = w >> 1, wn = w & 1;
    int l4 = lane >> 4, l15 = lane & 15;

    int nwg = gridDim.x, orig = blockIdx.x;
    int q = nwg >> 3, r8 = nwg & 7;
    int xcd = orig & 7, ii = orig >> 3;
    int wg = (xcd < r8) ? (xcd * (q + 1) + ii) : (r8 * (q + 1) + (xcd - r8) * q + ii);
    int bm = wg % gridM, bn = wg / gridM;
    int m0 = bm * 256, n0 = bn * 128;

    int nkt = K >> 5;
    int srow = lane >> 2;
    int sslot = ((lane & 3) ^ ((lane >> 3) & 3)) * 8;

    auto STAGE = [&](int slot, int kt) {       // 3 gload_lds per wave
        #pragma unroll
        for (int p = 0; p < 2; ++p) {
            int r0 = p * 128 + w * 16;
            gload_lds16(&A[(long)(m0 + r0 + srow) * K + kt * 32 + sslot], &Al[slot][r0 * 32]);
        }
        int r0 = w * 16;
        gload_lds16(&BT[(long)(n0 + r0 + srow) * K + kt * 32 + sslot], &Bl[slot][r0 * 32]);
    };

    f32x4 acc[4][4] = {};
    int rsw = (l4 ^ ((l15 >> 1) & 3)) * 8;

    STAGE(0, 0);
    STAGE(1, 1);
    int s = 0;
    for (int t = 0; t < nkt; ++t) {
        if (t + 2 < nkt) STAGE((t + 2) % 3, t + 2);
        int ahead = nkt - 1 - t;
        if (ahead >= 2)      asm volatile("s_waitcnt vmcnt(6)" ::: "memory");
        else if (ahead == 1) asm volatile("s_waitcnt vmcnt(3)" ::: "memory");
        else                 asm volatile("s_waitcnt vmcnt(0)" ::: "memory");
        asm volatile("s_barrier" ::: "memory");                // slot s staged for all waves

        short8 af[4], bf[4];
        #pragma unroll
        for (int f = 0; f < 4; ++f) {
            af[f] = *(const short8*)&Al[s][(wm * 64 + f * 16 + l15) * 32 + rsw];
            bf[f] = *(const short8*)&Bl[s][(wn * 64 + f * 16 + l15) * 32 + rsw];
        }
        asm volatile("s_waitcnt lgkmcnt(0)" ::: "memory");
        asm volatile("s_barrier" ::: "memory");                // all reads of slot s done

        __builtin_amdgcn_s_setprio(1);
        #pragma unroll
        for (int fm = 0; fm < 4; ++fm)
            #pragma unroll
            for (int fn = 0; fn < 4; ++fn)
                acc[fm][fn] = __builtin_amdgcn_mfma_f32_16x16x32_bf16(af[fm], bf[fn], acc[fm][fn], 0, 0, 0);
        __builtin_amdgcn_s_setprio(0);
        s = (s + 1) % 3;
    }

    float bs[4];
    #pragma unroll
    for (int fn = 0; fn < 4; ++fn)
        bs[fn] = bias[n0 + wn * 64 + fn * 16 + l15];

    #pragma unroll
    for (int fm = 0; fm < 4; ++fm) {
        #pragma unroll
        for (int j = 0; j < 4; ++j) {
            long row = m0 + wm * 64 + fm * 16 + l4 * 4 + j;
            float v4[4];
            #pragma unroll
            for (int fn = 0; fn < 4; ++fn) {
                int col = n0 + wn * 64 + fn * 16 + l15;
                float v = acc[fm][fn][j] + bs[fn];
                __builtin_nontemporal_store(v, &C[row * N + col]);   // logits: write-once stream
                v4[fn] = v;
            }
            float mx = fmaxf(fmaxf(v4[0], v4[1]), fmaxf(v4[2], v4[3]));
            #pragma unroll
            for (int off = 1; off < 16; off <<= 1) mx = fmaxf(mx, __shfl_xor(mx, off));
            float sm = 0.f;
            #pragma unroll
            for (int fn = 0; fn < 4; ++fn) sm += __expf(v4[fn] - mx);
            #pragma unroll
            for (int off = 1; off < 16; off <<= 1) sm += __shfl_xor(sm, off);
            if (l15 == 0) {
                int pidx = bn * 2 + wn;
                pm[row * 512 + pidx] = mx;
                ps[row * 512 + pidx] = sm;
            }
        }
    }
}

// ---------------- V transpose: vt[bh][d][t] = V[b][t][h][d] ----------------
__global__ __launch_bounds__(256) void vtrans_kernel(const unsigned short* __restrict__ qkv,
                                                     unsigned short* __restrict__ vt) {
    __shared__ unsigned short t[64][72];
    int t0 = blockIdx.x * 64;
    int bh = blockIdx.y;
    int b = bh / NH, h = bh % NH;
    int tid = threadIdx.x;
    #pragma unroll
    for (int i = 0; i < 2; ++i) {
        int r = (tid >> 3) + i * 32, c8 = (tid & 7) * 8;
        short8 v = *(const short8*)(qkv + ((long)b * NT + t0 + r) * NQKV + 2 * NE + h * NHS + c8);
        *(short8*)&t[r][c8] = v;
    }
    __syncthreads();
    #pragma unroll
    for (int i = 0; i < 2; ++i) {
        int d = (tid >> 3) + i * 32, s = (tid & 7) * 8;
        short8 o;
        #pragma unroll
        for (int j = 0; j < 8; ++j) o[j] = (short)t[s + j][d];
        *(short8*)(vt + ((long)bh * NHS + d) * NT + t0 + s) = o;
    }
}

// ---------------- flash attention: dbuf K/V LDS, 1 barrier/tile, prefetch overlap ----------------
__global__ __launch_bounds__(256) void fattn_kernel(const unsigned short* __restrict__ qkv,
                                                    const unsigned short* __restrict__ vt,
                                                    unsigned short* __restrict__ out) {
    __shared__ unsigned short Ks[2][64 * 64];
    __shared__ unsigned short Vl[2][64 * 64];
    __shared__ unsigned short Ps[4 * 16 * 64];
    int qt = gridDim.x - 1 - blockIdx.x;
    int bh = blockIdx.y;
    int b = bh / NH, h = bh % NH;
    int tid = threadIdx.x, lane = tid & 63, w = tid >> 6;
    int l4 = lane >> 4, l15 = lane & 15;
    long rowb = (long)b * NT;
    const float scale = 0.03608439182435161f;    // 768^-0.5 (reference scales by E)
    const unsigned short* vtp = vt + (long)bh * NHS * NT;

    const unsigned short* qptr = qkv + (rowb + qt * 64 + w * 16 + l15) * NQKV + h * NHS;
    short8 qa0 = *(const short8*)(qptr + l4 * 8);
    short8 qa1 = *(const short8*)(qptr + 32 + l4 * 8);

    f32x4 o[4] = {};
    float m[4], lsum[4];
    #pragma unroll
    for (int j = 0; j < 4; ++j) { m[j] = -INFINITY; lsum[j] = 0.f; }

    int kr_r = tid >> 3, kr_c = (tid & 7) * 8;
    int vr_d = tid >> 3, vr_s = tid & 7;

    short8 kr[2], vr[2];
    auto LOADT = [&](int t) {
        int kbase = t * 64;
        #pragma unroll
        for (int i = 0; i < 2; ++i) {
            kr[i] = *(const short8*)(qkv + (rowb + kbase + kr_r + i * 32) * NQKV + NE + h * NHS + kr_c);
            vr[i] = *(const short8*)(vtp + (long)(vr_d + i * 32) * NT + kbase + vr_s * 8);
        }
    };

    LOADT(0);
    for (int t = 0; t <= qt; ++t) {
        int cur = t & 1;
        #pragma unroll
        for (int i = 0; i < 2; ++i) {
            int r = kr_r + i * 32;
            *(short8*)&Ks[cur][r * 64 + (kr_c ^ ((r & 7) << 3))] = kr[i];
            int d = vr_d + i * 32;
            *(short8*)&Vl[cur][d * 64 + ((vr_s * 8) ^ ((d & 7) << 3))] = vr[i];
        }
        asm volatile("s_waitcnt lgkmcnt(0)" ::: "memory");
        if (t < qt) LOADT(t + 1);
        asm volatile("s_barrier" ::: "memory");

        f32x4 s[4];
        __builtin_amdgcn_s_setprio(1);
        #pragma unroll
        for (int fn = 0; fn < 4; ++fn) {
            int key = fn * 16 + l15;
            short8 kb0 = *(const short8*)&Ks[cur][key * 64 + ((l4 * 8) ^ ((key & 7) << 3))];
            short8 kb1 = *(const short8*)&Ks[cur][key * 64 + ((32 + l4 * 8) ^ ((key & 7) << 3))];
            f32x4 z = {};
            z = __builtin_amdgcn_mfma_f32_16x16x32_bf16(qa0, kb0, z, 0, 0, 0);
            s[fn] = __builtin_amdgcn_mfma_f32_16x16x32_bf16(qa1, kb1, z, 0, 0, 0);
        }
        __builtin_amdgcn_s_setprio(0);

        if (t == qt) {
            #pragma unroll
            for (int fn = 0; fn < 4; ++fn) {
                int key = t * 64 + fn * 16 + l15;
                #pragma unroll
                for (int j = 0; j < 4; ++j) {
                    int qrow = qt * 64 + w * 16 + l4 * 4 + j;
                    s[fn][j] = (key <= qrow) ? s[fn][j] * scale : -1e30f;
                }
            }
        } else {
            #pragma unroll
            for (int fn = 0; fn < 4; ++fn)
                #pragma unroll
                for (int j = 0; j < 4; ++j)
                    s[fn][j] *= scale;
        }

        #pragma unroll
        for (int j = 0; j < 4; ++j) {
            float mj = fmaxf(fmaxf(s[0][j], s[1][j]), fmaxf(s[2][j], s[3][j]));
            #pragma unroll
            for (int off = 1; off < 16; off <<= 1) mj = fmaxf(mj, __shfl_xor(mj, off));
            float mnew = fmaxf(m[j], mj);
            float alpha = __expf(m[j] - mnew);
            m[j] = mnew;
            float psum = 0.f;
            #pragma unroll
            for (int fn = 0; fn < 4; ++fn) {
                float p = __expf(s[fn][j] - mnew);
                psum += p;
                int rr = l4 * 4 + j, c = fn * 16 + l15;
                Ps[w * 1024 + rr * 64 + (c ^ ((rr & 7) << 3))] = f2bf(p);
            }
            #pragma unroll
            for (int off = 1; off < 16; off <<= 1) psum += __shfl_xor(psum, off);
            lsum[j] = lsum[j] * alpha + psum;
            #pragma unroll
            for (int fn = 0; fn < 4; ++fn) o[fn][j] *= alpha;
        }

        short8 pa0 = *(const short8*)&Ps[w * 1024 + l15 * 64 + ((l4 * 8) ^ ((l15 & 7) << 3))];
        short8 pa1 = *(const short8*)&Ps[w * 1024 + l15 * 64 + ((32 + l4 * 8) ^ ((l15 & 7) << 3))];
        __builtin_amdgcn_s_setprio(1);
        #pragma unroll
        for (int fn = 0; fn < 4; ++fn) {
            int d = fn * 16 + l15;
            short8 vb0 = *(const short8*)&Vl[cur][d * 64 + ((l4 * 8) ^ ((d & 7) << 3))];
            short8 vb1 = *(const short8*)&Vl[cur][d * 64 + ((32 + l4 * 8) ^ ((d & 7) << 3))];
            o[fn] = __builtin_amdgcn_mfma_f32_16x16x32_bf16(pa0, vb0, o[fn], 0, 0, 0);
            o[fn] = __builtin_amdgcn_mfma_f32_16x16x32_bf16(pa1, vb1, o[fn], 0, 0, 0);
        }
        __builtin_amdgcn_s_setprio(0);
    }

    #pragma unroll
    for (int j = 0; j < 4; ++j) {
        long row = rowb + qt * 64 + w * 16 + l4 * 4 + j;
        float inv = 1.0f / lsum[j];
        #pragma unroll
        for (int fn = 0; fn < 4; ++fn)
            out[row * NE + h * NHS + fn * 16 + l15] = f2bf(o[fn][j] * inv);
    }
}

// ---------------- NLL from LM-head partials ----------------
__global__ __launch_bounds__(256) void nll_combine_kernel(const float* __restrict__ logits,
                                                          const float* __restrict__ pm,
                                                          const float* __restrict__ ps,
                                                          const int* __restrict__ targets,
                                                          float* __restrict__ nll) {
    __shared__ float rm[256], rs[256];
    int row = blockIdx.x, tid = threadIdx.x;
    float m = -1e30f, s = 0.f;
    for (int i = tid; i < 500; i += 256) {
        float m2 = pm[(long)row * 512 + i], s2 = ps[(long)row * 512 + i];
        float mm = fmaxf(m, m2);
        s = s * __expf(m - mm) + s2 * __expf(m2 - mm);
        m = mm;
    }
    rm[tid] = m; rs[tid] = s; __syncthreads();
    for (int o = 128; o > 0; o >>= 1) {
        if (tid < o) {
            float m2 = rm[tid + o], s2 = rs[tid + o];
            float mm = fmaxf(rm[tid], m2);
            rs[tid] = rs[tid] * __expf(rm[tid] - mm) + s2 * __expf(m2 - mm);
            rm[tid] = mm;
        }
        __syncthreads();
    }
    if (tid == 0) {
        int tgt = targets[row];
        nll[row] = -(logits[(long)row * NV + tgt] - rm[0] - logf(rs[0]));
    }
}

__global__ void loss_reduce_kernel(const float* __restrict__ nll, float* __restrict__ out) {
    __shared__ float red[256];
    int tid = threadIdx.x;
    float s = 0.f;
    for (int i = tid; i < NM; i += 256) s += nll[i];
    red[tid] = s; __syncthreads();
    for (int o = 128; o > 0; o >>= 1) { if (tid < o) red[tid] += red[tid + o]; __syncthreads(); }
    if (tid == 0) out[0] = red[0] / NM;
}

extern "C" void kernel_launch(void* const* d_in, const int* in_sizes, int n_in,
                              void* d_out, int out_size, void* d_ws, size_t ws_size,
                              hipStream_t stream) {
    const int*   idx     = (const int*)  d_in[0];
    const int*   targets = (const int*)  d_in[1];
    const float* tok     = (const float*)d_in[2];
    const float* pos     = (const float*)d_in[3];
    const float* ln1_g   = (const float*)d_in[4];
    const float* ln1_b   = (const float*)d_in[5];
    const float* wq      = (const float*)d_in[6];
    const float* wk      = (const float*)d_in[7];
    const float* wv      = (const float*)d_in[8];
    const float* wproj   = (const float*)d_in[9];
    const float* bproj   = (const float*)d_in[10];
    const float* ln2_g   = (const float*)d_in[11];
    const float* ln2_b   = (const float*)d_in[12];
    const float* w1      = (const float*)d_in[13];
    const float* b1      = (const float*)d_in[14];
    const float* w2      = (const float*)d_in[15];
    const float* b2      = (const float*)d_in[16];
    const float* lnf_g   = (const float*)d_in[17];
    const float* lnf_b   = (const float*)d_in[18];
    const float* lm_w    = (const float*)d_in[19];
    const float* lm_b    = (const float*)d_in[20];

    float* logits = (float*)d_out;
    float* loss   = logits + (long)NM * NV;

    char* p = (char*)d_ws;
    float*          x      = (float*)p;          p += (long)NM * NE * 4;
    unsigned short* hbuf   = (unsigned short*)p; p += (long)NM * NE * 2;
    unsigned short* qkv    = (unsigned short*)p; p += (long)NM * NQKV * 2;
    unsigned short* att    = (unsigned short*)p; p += (long)NM * NE * 2;
    unsigned short* hid    = (unsigned short*)p; p += (long)NM * NFF * 2;
    unsigned short* vt     = (unsigned short*)p; p += (long)NB * NH * NHS * NT * 2;
    float*          nll    = (float*)p;          p += (long)NM * 4;
    float*          pmb    = (float*)p;          p += (long)NM * 512 * 4;
    float*          psb    = (float*)p;          p += (long)NM * 512 * 4;
    float*          parts  = (float*)p;          p += (long)2 * NM * NQKV * 4;
    unsigned short* wqkvT6 = (unsigned short*)p; p += (long)NL * NQKV * NE * 2;
    unsigned short* wprojT6= (unsigned short*)p; p += (long)NL * NE * NE * 2;
    unsigned short* wprojC6= (unsigned short*)p; p += (long)NL * NE * NE * 2;
    unsigned short* weffT6 = (unsigned short*)p; p += (long)NL * NE * NE * 2;
    float*          beff6  = (float*)p;          p += (long)NL * NE * 4;
    unsigned short* w1T6   = (unsigned short*)p; p += (long)NL * NFF * NE * 2;
    unsigned short* w2T6   = (unsigned short*)p; p += (long)NL * NE * NFF * 2;
    unsigned short* lmT    = (unsigned short*)p; p += (long)NV * NE * 2;

    dim3 blk(256);

    // ---- batched weight prep ----
    transpose4b_kernel<<<dim3(NE / 32, NE / 32, 4 * NL), blk, 0, stream>>>(
        wq, wk, wv, wproj, wqkvT6, wprojT6);
    cast_kernel<<<(NL * NE * NE) / 1024, blk, 0, stream>>>(wproj, wprojC6, (long)NL * NE * NE);
    transpose_cast_b_kernel<<<dim3(NFF / 32, NE / 32, NL), blk, 0, stream>>>(w1, w1T6, NE, NFF);
    transpose_cast_b_kernel<<<dim3(NE / 32, NFF / 32, NL), blk, 0, stream>>>(w2, w2T6, NFF, NE);
    gemm_weff_kernel<<<dim3(36, 1, NL), blk, 0, stream>>>(wprojT6, wprojC6, weffT6, 6, NE, NE);
    beff_b_kernel<<<dim3(NE, NL), blk, 0, stream>>>(bproj, wprojT6, beff6);
    transpose_cast_b_kernel<<<dim3(NV / 32, NE / 32, 1), blk, 0, stream>>>(lm_w, lmT, NE, NV);

    // ---- embedding + LN1(0) ----
    embed_ln_kernel<<<NM, blk, 0, stream>>>(idx, tok, pos, ln1_g, ln1_b, x, hbuf);

    for (int l = 0; l < NL; ++l) {
        gemm_mfma<float, false, false, 2><<<dim3((NM/128)*(NQKV/128), 2), blk, 0, stream>>>(
            hbuf, wqkvT6 + (long)l * NQKV * NE, nullptr, parts, NM / 128, NQKV, NE);
        combine_kernel<2><<<(NM * NQKV) / 1024, blk, 0, stream>>>(parts, qkv, (long)NM * NQKV);
        vtrans_kernel<<<dim3(NT / 64, NB * NH), blk, 0, stream>>>(qkv, vt);
        fattn_kernel<<<dim3(NT / 64, NB * NH), blk, 0, stream>>>(qkv, vt, att);
        gemm_mfma<float, false, false, 2><<<dim3((NM/128)*(NE/128), 2), blk, 0, stream>>>(
            att, weffT6 + (long)l * NE * NE, nullptr, parts, NM / 128, NE, NE);
        combine_ln_kernel<2><<<NM, blk, 0, stream>>>(
            parts, beff6 + (long)l * NE, x, ln2_g + (long)l * NE, ln2_b + (long)l * NE, hbuf);
        gemm_mfma<unsigned short, true, true, 1><<<dim3((NM/128)*(NFF/128)), blk, 0, stream>>>(
            hbuf, w1T6 + (long)l * NFF * NE, b1 + (long)l * NFF, hid, NM / 128, NFF, NE);
        gemm_mfma<float, false, false, 4><<<dim3((NM/128)*(NE/128), 4), blk, 0, stream>>>(
            hid, w2T6 + (long)l * NE * NFF, nullptr, parts, NM / 128, NE, NFF);
        const float* ng = (l < NL - 1) ? (ln1_g + (long)(l + 1) * NE) : lnf_g;
        const float* nb = (l < NL - 1) ? (ln1_b + (long)(l + 1) * NE) : lnf_b;
        combine_ln_kernel<4><<<NM, blk, 0, stream>>>(parts, b2 + (long)l * NE, x, ng, nb, hbuf);
    }

    // ---- LM head + fused LSE ----
    gemm256x128_lse<<<dim3((NM/256)*(NV/128)), dim3(512), 0, stream>>>(
        hbuf, lmT, lm_b, logits, pmb, psb, NM / 256, NV, NE);
    nll_combine_kernel<<<NM, blk, 0, stream>>>(logits, pmb, psb, targets, nll);
    loss_reduce_kernel<<<1, blk, 0, stream>>>(nll, loss);
}

// Round 10
// 1087.162 us; speedup vs baseline: 10.5523x; 1.0486x over previous
//
#include <hip/hip_runtime.h>
#include <math.h>

#define NL 6
#define NH 12
#define NE 768
#define NHS 64
#define NT 1024
#define NB 2
#define NV 32000
#define NM (NB * NT)   // 2048
#define NQKV (3 * NE)  // 2304
#define NFF (4 * NE)   // 3072
#define LN_EPS 1e-5f

typedef __attribute__((ext_vector_type(8))) short short8;
typedef __attribute__((ext_vector_type(4))) float f32x4;
typedef __attribute__((ext_vector_type(4))) unsigned short ushort4v;
typedef __attribute__((address_space(1))) const unsigned int as1_cuint;
typedef __attribute__((address_space(3))) unsigned int as3_uint;

__device__ __forceinline__ unsigned short f2bf(float f) {
    unsigned int u = __builtin_bit_cast(unsigned int, f);
    u += 0x7fffu + ((u >> 16) & 1u);   // RNE
    return (unsigned short)(u >> 16);
}
__device__ __forceinline__ float bf2f(unsigned short u) {
    unsigned int v = ((unsigned int)u) << 16;
    return __builtin_bit_cast(float, v);
}
__device__ __forceinline__ void gload_lds16(const void* g, void* l) {
    __builtin_amdgcn_global_load_lds((as1_cuint*)g, (as3_uint*)l, 16, 0, 0);
}

// ---------------- embedding + LN1(layer0) fused: one block per row ----------------
__global__ __launch_bounds__(256) void embed_ln_kernel(const int* __restrict__ idx,
                                                       const float* __restrict__ tok,
                                                       const float* __restrict__ pos,
                                                       const float* __restrict__ g,
                                                       const float* __restrict__ b,
                                                       float* __restrict__ x,
                                                       unsigned short* __restrict__ hbuf) {
    __shared__ float red[256];
    int row = blockIdx.x, tid = threadIdx.x;
    int t = row % NT;
    int id = idx[row];
    float v[3]; float s = 0.f;
    #pragma unroll
    for (int k = 0; k < 3; ++k) {
        int c = tid + k * 256;
        v[k] = tok[(long)id * NE + c] + pos[(long)t * NE + c];
        x[(long)row * NE + c] = v[k];
        s += v[k];
    }
    red[tid] = s; __syncthreads();
    for (int o = 128; o > 0; o >>= 1) { if (tid < o) red[tid] += red[tid + o]; __syncthreads(); }
    float mu = red[0] / NE;
    __syncthreads();
    float vr = 0.f;
    #pragma unroll
    for (int k = 0; k < 3; ++k) { float d = v[k] - mu; vr += d * d; }
    red[tid] = vr; __syncthreads();
    for (int o = 128; o > 0; o >>= 1) { if (tid < o) red[tid] += red[tid + o]; __syncthreads(); }
    float rstd = rsqrtf(red[0] / NE + LN_EPS);
    #pragma unroll
    for (int k = 0; k < 3; ++k) {
        int c = tid + k * 256;
        hbuf[(long)row * NE + c] = f2bf((v[k] - mu) * rstd * g[c] + b[c]);
    }
}

// ---------------- fused split-K combine + residual + LayerNorm ----------------
template<int S>
__global__ __launch_bounds__(256) void combine_ln_kernel(const float* __restrict__ parts,
                                                         const float* __restrict__ bias,
                                                         float* __restrict__ x,
                                                         const float* __restrict__ g,
                                                         const float* __restrict__ b,
                                                         unsigned short* __restrict__ hbuf) {
    __shared__ float red[256];
    int row = blockIdx.x, tid = threadIdx.x;
    float v[3]; float s = 0.f;
    #pragma unroll
    for (int k = 0; k < 3; ++k) {
        int c = tid + k * 256;
        long i = (long)row * NE + c;
        float a = parts[i];
        #pragma unroll
        for (int si = 1; si < S; ++si) a += parts[(long)si * NM * NE + i];
        a += bias[c] + x[i];
        x[i] = a;
        v[k] = a; s += a;
    }
    red[tid] = s; __syncthreads();
    for (int o = 128; o > 0; o >>= 1) { if (tid < o) red[tid] += red[tid + o]; __syncthreads(); }
    float mu = red[0] / NE;
    __syncthreads();
    float vr = 0.f;
    #pragma unroll
    for (int k = 0; k < 3; ++k) { float d = v[k] - mu; vr += d * d; }
    red[tid] = vr; __syncthreads();
    for (int o = 128; o > 0; o >>= 1) { if (tid < o) red[tid] += red[tid + o]; __syncthreads(); }
    float rstd = rsqrtf(red[0] / NE + LN_EPS);
    #pragma unroll
    for (int k = 0; k < 3; ++k) {
        int c = tid + k * 256;
        hbuf[(long)row * NE + c] = f2bf((v[k] - mu) * rstd * g[c] + b[c]);
    }
}

// ---------------- batched transpose of the four 768x768 weights, all layers ----------------
__global__ __launch_bounds__(256) void transpose4b_kernel(const float* __restrict__ wq,
                                                          const float* __restrict__ wk,
                                                          const float* __restrict__ wv,
                                                          const float* __restrict__ wp,
                                                          unsigned short* __restrict__ wqkvT,
                                                          unsigned short* __restrict__ wprojT) {
    __shared__ float t[32][33];
    int z = blockIdx.z, l = z >> 2, which = z & 3;
    const float* W = ((which == 0) ? wq : (which == 1) ? wk : (which == 2) ? wv : wp) + (long)l * NE * NE;
    unsigned short* WT = (which < 3) ? (wqkvT + (long)l * NQKV * NE + (long)which * NE * NE)
                                     : (wprojT + (long)l * NE * NE);
    int k0 = blockIdx.y * 32, n0 = blockIdx.x * 32;
    int c = threadIdx.x & 31, r = threadIdx.x >> 5;
    #pragma unroll
    for (int p = 0; p < 4; ++p)
        t[r + p * 8][c] = W[(long)(k0 + r + p * 8) * NE + n0 + c];
    __syncthreads();
    #pragma unroll
    for (int p = 0; p < 4; ++p)
        WT[(long)(n0 + r + p * 8) * NE + k0 + c] = f2bf(t[c][r + p * 8]);
}

// ---------------- batched tiled transpose + cast: per-layer stride K*N ----------------
__global__ __launch_bounds__(256) void transpose_cast_b_kernel(const float* __restrict__ W0,
                                                               unsigned short* __restrict__ WT0,
                                                               int K, int N) {
    __shared__ float t[32][33];
    long lofs = (long)blockIdx.z * K * N;
    const float* W = W0 + lofs;
    unsigned short* WT = WT0 + lofs;
    int k0 = blockIdx.y * 32, n0 = blockIdx.x * 32;
    int c = threadIdx.x & 31, r = threadIdx.x >> 5;
    #pragma unroll
    for (int p = 0; p < 4; ++p)
        t[r + p * 8][c] = W[(long)(k0 + r + p * 8) * N + n0 + c];
    __syncthreads();
    #pragma unroll
    for (int p = 0; p < 4; ++p)
        WT[(long)(n0 + r + p * 8) * K + k0 + c] = f2bf(t[c][r + p * 8]);
}

// ---------------- plain fp32 -> bf16 cast ----------------
__global__ __launch_bounds__(256) void cast_kernel(const float* __restrict__ W,
                                                   unsigned short* __restrict__ O, long n) {
    long i = ((long)blockIdx.x * 256 + threadIdx.x) * 4;
    if (i < n) {
        float4 v = *(const float4*)(W + i);
        ushort4v o;
        o[0] = f2bf(v.x); o[1] = f2bf(v.y); o[2] = f2bf(v.z); o[3] = f2bf(v.w);
        *(ushort4v*)(O + i) = o;
    }
}

// ---------------- batched beff ----------------
__global__ __launch_bounds__(256) void beff_b_kernel(const float* __restrict__ bproj,
                                                     const unsigned short* __restrict__ wprojT,
                                                     float* __restrict__ beff) {
    __shared__ float red[256];
    int n = blockIdx.x, l = blockIdx.y, tid = threadIdx.x;
    const unsigned short* wp = wprojT + (long)l * NE * NE + (long)n * NE;
    const float* bp = bproj + (long)l * NE;
    float acc = 0.f;
    for (int j = tid; j < NE; j += 256) acc += bp[j] * bf2f(wp[j]);
    red[tid] = acc; __syncthreads();
    for (int o = 128; o > 0; o >>= 1) { if (tid < o) red[tid] += red[tid + o]; __syncthreads(); }
    if (tid == 0) beff[(long)l * NE + n] = red[0] + bp[n];
}

// ---------------- 128x128 bf16 MFMA GEMM: 3-slot ring, depth-2 counted vmcnt ----------------
template<typename OutT, bool BIAS, bool RELU, int SPLITK>
__global__ __launch_bounds__(256) void gemm_mfma(const unsigned short* __restrict__ A,
                                                 const unsigned short* __restrict__ BT,
                                                 const float* __restrict__ bias,
                                                 OutT* __restrict__ C,
                                                 int gridM, int N, int K) {
    __shared__ unsigned short As[3][128 * 32];
    __shared__ unsigned short Bs[3][128 * 32];
    int tid = threadIdx.x;
    int lane = tid & 63, w = tid >> 6;
    int wr = w >> 1, wc = w & 1;
    int l4 = lane >> 4, l15 = lane & 15;

    int nwg = gridDim.x, orig = blockIdx.x;
    int q = nwg >> 3, r8 = nwg & 7;
    int xcd = orig & 7, ii = orig >> 3;
    int wg = (xcd < r8) ? (xcd * (q + 1) + ii) : (r8 * (q + 1) + (xcd - r8) * q + ii);
    int bm = wg % gridM, bn = wg / gridM;
    int m0 = bm * 128, n0 = bn * 128;

    int kb = K / SPLITK;
    int koff = (SPLITK > 1) ? blockIdx.y * kb : 0;
    int nkt = kb >> 5;

    f32x4 acc[4][4] = {};

    int srow = lane >> 2;
    int scol = ((lane & 3) ^ ((lane >> 3) & 3)) * 8;   // inverse-swizzled source slot
    int rsw  = (l4 ^ ((l15 >> 1) & 3)) * 8;            // swizzled read slot

    auto STAGE = [&](int slot, int kt) {   // 4 gload_lds per wave
        #pragma unroll
        for (int it = 0; it < 2; ++it) {
            int rr = w * 32 + it * 16;
            gload_lds16(&A [(long)(m0 + rr + srow) * K + koff + kt * 32 + scol], &As[slot][rr * 32]);
            gload_lds16(&BT[(long)(n0 + rr + srow) * K + koff + kt * 32 + scol], &Bs[slot][rr * 32]);
        }
    };

    STAGE(0, 0);
    if (nkt > 1) STAGE(1, 1);

    int s = 0;
    for (int t = 0; t < nkt; ++t) {
        if (t + 2 < nkt) STAGE((t + 2) % 3, t + 2);
        int ahead = nkt - 1 - t;
        if (ahead >= 2)      asm volatile("s_waitcnt vmcnt(8)" ::: "memory");
        else if (ahead == 1) asm volatile("s_waitcnt vmcnt(4)" ::: "memory");
        else                 asm volatile("s_waitcnt vmcnt(0)" ::: "memory");
        asm volatile("s_barrier" ::: "memory");        // slot s fully staged for all waves

        short8 a[4], b[4];
        #pragma unroll
        for (int f = 0; f < 4; ++f) {
            a[f] = *(const short8*)&As[s][(wr * 64 + f * 16 + l15) * 32 + rsw];
            b[f] = *(const short8*)&Bs[s][(wc * 64 + f * 16 + l15) * 32 + rsw];
        }
        asm volatile("s_waitcnt lgkmcnt(0)" ::: "memory");
        asm volatile("s_barrier" ::: "memory");        // all reads of slot s done -> restageable

        __builtin_amdgcn_s_setprio(1);
        #pragma unroll
        for (int fm = 0; fm < 4; ++fm)
            #pragma unroll
            for (int fn = 0; fn < 4; ++fn)
                acc[fm][fn] = __builtin_amdgcn_mfma_f32_16x16x32_bf16(a[fm], b[fn], acc[fm][fn], 0, 0, 0);
        __builtin_amdgcn_s_setprio(0);
        s = (s + 1) % 3;
    }

    if constexpr (SPLITK > 1) {
        float* Cp = (float*)C + (long)blockIdx.y * gridM * 128 * N;
        #pragma unroll
        for (int fm = 0; fm < 4; ++fm)
            #pragma unroll
            for (int j = 0; j < 4; ++j) {
                long row = m0 + wr * 64 + fm * 16 + l4 * 4 + j;
                #pragma unroll
                for (int fn = 0; fn < 4; ++fn)
                    Cp[row * N + n0 + wc * 64 + fn * 16 + l15] = acc[fm][fn][j];
            }
    } else {
        float bs[4];
        #pragma unroll
        for (int fn = 0; fn < 4; ++fn)
            bs[fn] = BIAS ? bias[n0 + wc * 64 + fn * 16 + l15] : 0.f;

        #pragma unroll
        for (int fm = 0; fm < 4; ++fm) {
            #pragma unroll
            for (int j = 0; j < 4; ++j) {
                long row = m0 + wr * 64 + fm * 16 + l4 * 4 + j;
                #pragma unroll
                for (int fn = 0; fn < 4; ++fn) {
                    int col = n0 + wc * 64 + fn * 16 + l15;
                    float v = acc[fm][fn][j] + bs[fn];
                    if (RELU) v = fmaxf(v, 0.f);
                    if constexpr (sizeof(OutT) == 2) C[row * N + col] = (OutT)f2bf(v);
                    else                             C[row * N + col] = v;
                }
            }
        }
    }
}

// ---------------- batched square bf16 GEMM (weff = Wp@Wp per layer), T2 swizzle ----------------
__global__ __launch_bounds__(256) void gemm_weff_kernel(const unsigned short* __restrict__ A0,
                                                        const unsigned short* __restrict__ B0,
                                                        unsigned short* __restrict__ C0,
                                                        int gridM, int N, int K) {
    __shared__ unsigned short As[2][128 * 32];
    __shared__ unsigned short Bs[2][128 * 32];
    long zofs = (long)blockIdx.z * N * K;
    const unsigned short* A = A0 + zofs;
    const unsigned short* BT = B0 + zofs;
    unsigned short* C = C0 + zofs;
    int tid = threadIdx.x;
    int lane = tid & 63, w = tid >> 6;
    int wr = w >> 1, wc = w & 1;
    int l4 = lane >> 4, l15 = lane & 15;
    int bm = blockIdx.x % gridM, bn = blockIdx.x / gridM;
    int m0 = bm * 128, n0 = bn * 128;

    f32x4 acc[4][4] = {};
    int srow = lane >> 2;
    int scol = ((lane & 3) ^ ((lane >> 3) & 3)) * 8;
    int rsw  = (l4 ^ ((l15 >> 1) & 3)) * 8;

    #pragma unroll
    for (int it = 0; it < 2; ++it) {
        int rr = w * 32 + it * 16;
        gload_lds16(&A [(long)(m0 + rr + srow) * K + scol], &As[0][rr * 32]);
        gload_lds16(&BT[(long)(n0 + rr + srow) * K + scol], &Bs[0][rr * 32]);
    }
    int cur = 0;
    for (int k0 = 0; k0 < K; k0 += 32) {
        __syncthreads();
        if (k0 + 32 < K) {
            #pragma unroll
            for (int it = 0; it < 2; ++it) {
                int rr = w * 32 + it * 16;
                gload_lds16(&A [(long)(m0 + rr + srow) * K + k0 + 32 + scol], &As[cur ^ 1][rr * 32]);
                gload_lds16(&BT[(long)(n0 + rr + srow) * K + k0 + 32 + scol], &Bs[cur ^ 1][rr * 32]);
            }
        }
        short8 a[4], b[4];
        #pragma unroll
        for (int f = 0; f < 4; ++f) {
            a[f] = *(const short8*)&As[cur][(wr * 64 + f * 16 + l15) * 32 + rsw];
            b[f] = *(const short8*)&Bs[cur][(wc * 64 + f * 16 + l15) * 32 + rsw];
        }
        #pragma unroll
        for (int fm = 0; fm < 4; ++fm)
            #pragma unroll
            for (int fn = 0; fn < 4; ++fn)
                acc[fm][fn] = __builtin_amdgcn_mfma_f32_16x16x32_bf16(a[fm], b[fn], acc[fm][fn], 0, 0, 0);
        cur ^= 1;
    }
    #pragma unroll
    for (int fm = 0; fm < 4; ++fm)
        #pragma unroll
        for (int j = 0; j < 4; ++j) {
            long row = m0 + wr * 64 + fm * 16 + l4 * 4 + j;
            #pragma unroll
            for (int fn = 0; fn < 4; ++fn)
                C[row * N + n0 + wc * 64 + fn * 16 + l15] = f2bf(acc[fm][fn][j]);
        }
}

// ---------------- LM head: 256x128 tile, 8 waves, 3-slot ring, depth-2 vmcnt, nt stores ----------------
__global__ __launch_bounds__(512, 4) void gemm256x128_lse(const unsigned short* __restrict__ A,
                                                          const unsigned short* __restrict__ BT,
                                                          const float* __restrict__ bias,
                                                          float* __restrict__ C,
                                                          float* __restrict__ pm, float* __restrict__ ps,
                                                          int gridM, int N, int K) {
    __shared__ unsigned short Al[3][256 * 32];   // 48 KB
    __shared__ unsigned short Bl[3][128 * 32];   // 24 KB
    int tid = threadIdx.x;
    int lane = tid & 63, w = tid >> 6;
    int wm = w >> 1, wn = w & 1;
    int l4 = lane >> 4, l15 = lane & 15;

    int nwg = gridDim.x, orig = blockIdx.x;
    int q = nwg >> 3, r8 = nwg & 7;
    int xcd = orig & 7, ii = orig >> 3;
    int wg = (xcd < r8) ? (xcd * (q + 1) + ii) : (r8 * (q + 1) + (xcd - r8) * q + ii);
    int bm = wg % gridM, bn = wg / gridM;
    int m0 = bm * 256, n0 = bn * 128;

    int nkt = K >> 5;
    int srow = lane >> 2;
    int sslot = ((lane & 3) ^ ((lane >> 3) & 3)) * 8;

    auto STAGE = [&](int slot, int kt) {       // 3 gload_lds per wave
        #pragma unroll
        for (int p = 0; p < 2; ++p) {
            int r0 = p * 128 + w * 16;
            gload_lds16(&A[(long)(m0 + r0 + srow) * K + kt * 32 + sslot], &Al[slot][r0 * 32]);
        }
        int r0 = w * 16;
        gload_lds16(&BT[(long)(n0 + r0 + srow) * K + kt * 32 + sslot], &Bl[slot][r0 * 32]);
    };

    f32x4 acc[4][4] = {};
    int rsw = (l4 ^ ((l15 >> 1) & 3)) * 8;

    STAGE(0, 0);
    STAGE(1, 1);
    int s = 0;
    for (int t = 0; t < nkt; ++t) {
        if (t + 2 < nkt) STAGE((t + 2) % 3, t + 2);
        int ahead = nkt - 1 - t;
        if (ahead >= 2)      asm volatile("s_waitcnt vmcnt(6)" ::: "memory");
        else if (ahead == 1) asm volatile("s_waitcnt vmcnt(3)" ::: "memory");
        else                 asm volatile("s_waitcnt vmcnt(0)" ::: "memory");
        asm volatile("s_barrier" ::: "memory");                // slot s staged for all waves

        short8 af[4], bf[4];
        #pragma unroll
        for (int f = 0; f < 4; ++f) {
            af[f] = *(const short8*)&Al[s][(wm * 64 + f * 16 + l15) * 32 + rsw];
            bf[f] = *(const short8*)&Bl[s][(wn * 64 + f * 16 + l15) * 32 + rsw];
        }
        asm volatile("s_waitcnt lgkmcnt(0)" ::: "memory");
        asm volatile("s_barrier" ::: "memory");                // all reads of slot s done

        __builtin_amdgcn_s_setprio(1);
        #pragma unroll
        for (int fm = 0; fm < 4; ++fm)
            #pragma unroll
            for (int fn = 0; fn < 4; ++fn)
                acc[fm][fn] = __builtin_amdgcn_mfma_f32_16x16x32_bf16(af[fm], bf[fn], acc[fm][fn], 0, 0, 0);
        __builtin_amdgcn_s_setprio(0);
        s = (s + 1) % 3;
    }

    float bs[4];
    #pragma unroll
    for (int fn = 0; fn < 4; ++fn)
        bs[fn] = bias[n0 + wn * 64 + fn * 16 + l15];

    #pragma unroll
    for (int fm = 0; fm < 4; ++fm) {
        #pragma unroll
        for (int j = 0; j < 4; ++j) {
            long row = m0 + wm * 64 + fm * 16 + l4 * 4 + j;
            float v4[4];
            #pragma unroll
            for (int fn = 0; fn < 4; ++fn) {
                int col = n0 + wn * 64 + fn * 16 + l15;
                float v = acc[fm][fn][j] + bs[fn];
                __builtin_nontemporal_store(v, &C[row * N + col]);   // logits: write-once stream
                v4[fn] = v;
            }
            float mx = fmaxf(fmaxf(v4[0], v4[1]), fmaxf(v4[2], v4[3]));
            #pragma unroll
            for (int off = 1; off < 16; off <<= 1) mx = fmaxf(mx, __shfl_xor(mx, off));
            float sm = 0.f;
            #pragma unroll
            for (int fn = 0; fn < 4; ++fn) sm += __expf(v4[fn] - mx);
            #pragma unroll
            for (int off = 1; off < 16; off <<= 1) sm += __shfl_xor(sm, off);
            if (l15 == 0) {
                int pidx = bn * 2 + wn;
                pm[row * 512 + pidx] = mx;
                ps[row * 512 + pidx] = sm;
            }
        }
    }
}

// ---------------- V transpose: vt[bh][d][t] = V[b][t][h][d] ----------------
__global__ __launch_bounds__(256) void vtrans_kernel(const unsigned short* __restrict__ qkv,
                                                     unsigned short* __restrict__ vt) {
    __shared__ unsigned short t[64][72];
    int t0 = blockIdx.x * 64;
    int bh = blockIdx.y;
    int b = bh / NH, h = bh % NH;
    int tid = threadIdx.x;
    #pragma unroll
    for (int i = 0; i < 2; ++i) {
        int r = (tid >> 3) + i * 32, c8 = (tid & 7) * 8;
        short8 v = *(const short8*)(qkv + ((long)b * NT + t0 + r) * NQKV + 2 * NE + h * NHS + c8);
        *(short8*)&t[r][c8] = v;
    }
    __syncthreads();
    #pragma unroll
    for (int i = 0; i < 2; ++i) {
        int d = (tid >> 3) + i * 32, s = (tid & 7) * 8;
        short8 o;
        #pragma unroll
        for (int j = 0; j < 8; ++j) o[j] = (short)t[s + j][d];
        *(short8*)(vt + ((long)bh * NHS + d) * NT + t0 + s) = o;
    }
}

// ---------------- flash attention, QBLK=128: 8 waves, dbuf K/V LDS, 1 barrier/tile ----------------
__global__ __launch_bounds__(512) void fattn_kernel(const unsigned short* __restrict__ qkv,
                                                    const unsigned short* __restrict__ vt,
                                                    unsigned short* __restrict__ out) {
    __shared__ unsigned short Ks[2][64 * 64];     // 16 KB
    __shared__ unsigned short Vl[2][64 * 64];     // 16 KB
    __shared__ unsigned short Ps[8 * 16 * 64];    // 16 KB
    int qt = gridDim.x - 1 - blockIdx.x;          // heavy q-tiles first
    int bh = blockIdx.y;
    int b = bh / NH, h = bh % NH;
    int tid = threadIdx.x, lane = tid & 63, w = tid >> 6;   // w = 0..7
    int l4 = lane >> 4, l15 = lane & 15;
    long rowb = (long)b * NT;
    const float scale = 0.03608439182435161f;     // 768^-0.5 (reference scales by E)
    const unsigned short* vtp = vt + (long)bh * NHS * NT;

    const unsigned short* qptr = qkv + (rowb + qt * 128 + w * 16 + l15) * NQKV + h * NHS;
    short8 qa0 = *(const short8*)(qptr + l4 * 8);
    short8 qa1 = *(const short8*)(qptr + 32 + l4 * 8);

    f32x4 o[4] = {};
    float m[4], lsum[4];
    #pragma unroll
    for (int j = 0; j < 4; ++j) { m[j] = -INFINITY; lsum[j] = 0.f; }

    // staging: 512 threads cover one 64x64 K tile and one 64x64 V^T tile in one shot
    int kr_r = tid >> 3, kr_c = (tid & 7) * 8;    // K: row 0..63, col-chunk
    int vr_d = tid >> 3, vr_s = tid & 7;          // V^T: d 0..63, t-chunk

    short8 kr, vr;
    auto LOADT = [&](int t) {
        int kbase = t * 64;
        kr = *(const short8*)(qkv + (rowb + kbase + kr_r) * NQKV + NE + h * NHS + kr_c);
        vr = *(const short8*)(vtp + (long)vr_d * NT + kbase + vr_s * 8);
    };

    int ntiles = 2 * qt + 2;
    LOADT(0);
    for (int t = 0; t < ntiles; ++t) {
        int cur = t & 1;
        *(short8*)&Ks[cur][kr_r * 64 + (kr_c ^ ((kr_r & 7) << 3))] = kr;
        *(short8*)&Vl[cur][vr_d * 64 + ((vr_s * 8) ^ ((vr_d & 7) << 3))] = vr;
        asm volatile("s_waitcnt lgkmcnt(0)" ::: "memory");
        if (t + 1 < ntiles) LOADT(t + 1);         // overlap HBM with compute
        asm volatile("s_barrier" ::: "memory");

        f32x4 s[4];
        __builtin_amdgcn_s_setprio(1);
        #pragma unroll
        for (int fn = 0; fn < 4; ++fn) {
            int key = fn * 16 + l15;
            short8 kb0 = *(const short8*)&Ks[cur][key * 64 + ((l4 * 8) ^ ((key & 7) << 3))];
            short8 kb1 = *(const short8*)&Ks[cur][key * 64 + ((32 + l4 * 8) ^ ((key & 7) << 3))];
            f32x4 z = {};
            z = __builtin_amdgcn_mfma_f32_16x16x32_bf16(qa0, kb0, z, 0, 0, 0);
            s[fn] = __builtin_amdgcn_mfma_f32_16x16x32_bf16(qa1, kb1, z, 0, 0, 0);
        }
        __builtin_amdgcn_s_setprio(0);

        if (t >= 2 * qt) {                        // only last two tiles touch the diagonal
            #pragma unroll
            for (int fn = 0; fn < 4; ++fn) {
                int key = t * 64 + fn * 16 + l15;
                #pragma unroll
                for (int j = 0; j < 4; ++j) {
                    int qrow = qt * 128 + w * 16 + l4 * 4 + j;
                    s[fn][j] = (key <= qrow) ? s[fn][j] * scale : -1e30f;
                }
            }
        } else {
            #pragma unroll
            for (int fn = 0; fn < 4; ++fn)
                #pragma unroll
                for (int j = 0; j < 4; ++j)
                    s[fn][j] *= scale;
        }

        #pragma unroll
        for (int j = 0; j < 4; ++j) {
            float mj = fmaxf(fmaxf(s[0][j], s[1][j]), fmaxf(s[2][j], s[3][j]));
            #pragma unroll
            for (int off = 1; off < 16; off <<= 1) mj = fmaxf(mj, __shfl_xor(mj, off));
            float mnew = fmaxf(m[j], mj);
            float alpha = __expf(m[j] - mnew);
            m[j] = mnew;
            float psum = 0.f;
            #pragma unroll
            for (int fn = 0; fn < 4; ++fn) {
                float p = __expf(s[fn][j] - mnew);
                psum += p;
                int rr = l4 * 4 + j, c = fn * 16 + l15;
                Ps[w * 1024 + rr * 64 + (c ^ ((rr & 7) << 3))] = f2bf(p);
            }
            #pragma unroll
            for (int off = 1; off < 16; off <<= 1) psum += __shfl_xor(psum, off);
            lsum[j] = lsum[j] * alpha + psum;
            #pragma unroll
            for (int fn = 0; fn < 4; ++fn) o[fn][j] *= alpha;
        }

        short8 pa0 = *(const short8*)&Ps[w * 1024 + l15 * 64 + ((l4 * 8) ^ ((l15 & 7) << 3))];
        short8 pa1 = *(const short8*)&Ps[w * 1024 + l15 * 64 + ((32 + l4 * 8) ^ ((l15 & 7) << 3))];
        __builtin_amdgcn_s_setprio(1);
        #pragma unroll
        for (int fn = 0; fn < 4; ++fn) {
            int d = fn * 16 + l15;
            short8 vb0 = *(const short8*)&Vl[cur][d * 64 + ((l4 * 8) ^ ((d & 7) << 3))];
            short8 vb1 = *(const short8*)&Vl[cur][d * 64 + ((32 + l4 * 8) ^ ((d & 7) << 3))];
            o[fn] = __builtin_amdgcn_mfma_f32_16x16x32_bf16(pa0, vb0, o[fn], 0, 0, 0);
            o[fn] = __builtin_amdgcn_mfma_f32_16x16x32_bf16(pa1, vb1, o[fn], 0, 0, 0);
        }
        __builtin_amdgcn_s_setprio(0);
    }

    #pragma unroll
    for (int j = 0; j < 4; ++j) {
        long row = rowb + qt * 128 + w * 16 + l4 * 4 + j;
        float inv = 1.0f / lsum[j];
        #pragma unroll
        for (int fn = 0; fn < 4; ++fn)
            out[row * NE + h * NHS + fn * 16 + l15] = f2bf(o[fn][j] * inv);
    }
}

// ---------------- NLL from LM-head partials ----------------
__global__ __launch_bounds__(256) void nll_combine_kernel(const float* __restrict__ logits,
                                                          const float* __restrict__ pm,
                                                          const float* __restrict__ ps,
                                                          const int* __restrict__ targets,
                                                          float* __restrict__ nll) {
    __shared__ float rm[256], rs[256];
    int row = blockIdx.x, tid = threadIdx.x;
    float m = -1e30f, s = 0.f;
    for (int i = tid; i < 500; i += 256) {
        float m2 = pm[(long)row * 512 + i], s2 = ps[(long)row * 512 + i];
        float mm = fmaxf(m, m2);
        s = s * __expf(m - mm) + s2 * __expf(m2 - mm);
        m = mm;
    }
    rm[tid] = m; rs[tid] = s; __syncthreads();
    for (int o = 128; o > 0; o >>= 1) {
        if (tid < o) {
            float m2 = rm[tid + o], s2 = rs[tid + o];
            float mm = fmaxf(rm[tid], m2);
            rs[tid] = rs[tid] * __expf(rm[tid] - mm) + s2 * __expf(m2 - mm);
            rm[tid] = mm;
        }
        __syncthreads();
    }
    if (tid == 0) {
        int tgt = targets[row];
        nll[row] = -(logits[(long)row * NV + tgt] - rm[0] - logf(rs[0]));
    }
}

__global__ void loss_reduce_kernel(const float* __restrict__ nll, float* __restrict__ out) {
    __shared__ float red[256];
    int tid = threadIdx.x;
    float s = 0.f;
    for (int i = tid; i < NM; i += 256) s += nll[i];
    red[tid] = s; __syncthreads();
    for (int o = 128; o > 0; o >>= 1) { if (tid < o) red[tid] += red[tid + o]; __syncthreads(); }
    if (tid == 0) out[0] = red[0] / NM;
}

extern "C" void kernel_launch(void* const* d_in, const int* in_sizes, int n_in,
                              void* d_out, int out_size, void* d_ws, size_t ws_size,
                              hipStream_t stream) {
    const int*   idx     = (const int*)  d_in[0];
    const int*   targets = (const int*)  d_in[1];
    const float* tok     = (const float*)d_in[2];
    const float* pos     = (const float*)d_in[3];
    const float* ln1_g   = (const float*)d_in[4];
    const float* ln1_b   = (const float*)d_in[5];
    const float* wq      = (const float*)d_in[6];
    const float* wk      = (const float*)d_in[7];
    const float* wv      = (const float*)d_in[8];
    const float* wproj   = (const float*)d_in[9];
    const float* bproj   = (const float*)d_in[10];
    const float* ln2_g   = (const float*)d_in[11];
    const float* ln2_b   = (const float*)d_in[12];
    const float* w1      = (const float*)d_in[13];
    const float* b1      = (const float*)d_in[14];
    const float* w2      = (const float*)d_in[15];
    const float* b2      = (const float*)d_in[16];
    const float* lnf_g   = (const float*)d_in[17];
    const float* lnf_b   = (const float*)d_in[18];
    const float* lm_w    = (const float*)d_in[19];
    const float* lm_b    = (const float*)d_in[20];

    float* logits = (float*)d_out;
    float* loss   = logits + (long)NM * NV;

    char* p = (char*)d_ws;
    float*          x      = (float*)p;          p += (long)NM * NE * 4;
    unsigned short* hbuf   = (unsigned short*)p; p += (long)NM * NE * 2;
    unsigned short* qkv    = (unsigned short*)p; p += (long)NM * NQKV * 2;
    unsigned short* att    = (unsigned short*)p; p += (long)NM * NE * 2;
    unsigned short* hid    = (unsigned short*)p; p += (long)NM * NFF * 2;
    unsigned short* vt     = (unsigned short*)p; p += (long)NB * NH * NHS * NT * 2;
    float*          nll    = (float*)p;          p += (long)NM * 4;
    float*          pmb    = (float*)p;          p += (long)NM * 512 * 4;
    float*          psb    = (float*)p;          p += (long)NM * 512 * 4;
    float*          parts  = (float*)p;          p += (long)2 * NM * NQKV * 4;   // covers proj S=2 / FF2 S=4
    unsigned short* wqkvT6 = (unsigned short*)p; p += (long)NL * NQKV * NE * 2;
    unsigned short* wprojT6= (unsigned short*)p; p += (long)NL * NE * NE * 2;
    unsigned short* wprojC6= (unsigned short*)p; p += (long)NL * NE * NE * 2;
    unsigned short* weffT6 = (unsigned short*)p; p += (long)NL * NE * NE * 2;
    float*          beff6  = (float*)p;          p += (long)NL * NE * 4;
    unsigned short* w1T6   = (unsigned short*)p; p += (long)NL * NFF * NE * 2;
    unsigned short* w2T6   = (unsigned short*)p; p += (long)NL * NE * NFF * 2;
    unsigned short* lmT    = (unsigned short*)p; p += (long)NV * NE * 2;

    dim3 blk(256);

    // ---- batched weight prep ----
    transpose4b_kernel<<<dim3(NE / 32, NE / 32, 4 * NL), blk, 0, stream>>>(
        wq, wk, wv, wproj, wqkvT6, wprojT6);
    cast_kernel<<<(NL * NE * NE) / 1024, blk, 0, stream>>>(wproj, wprojC6, (long)NL * NE * NE);
    transpose_cast_b_kernel<<<dim3(NFF / 32, NE / 32, NL), blk, 0, stream>>>(w1, w1T6, NE, NFF);
    transpose_cast_b_kernel<<<dim3(NE / 32, NFF / 32, NL), blk, 0, stream>>>(w2, w2T6, NFF, NE);
    gemm_weff_kernel<<<dim3(36, 1, NL), blk, 0, stream>>>(wprojT6, wprojC6, weffT6, 6, NE, NE);
    beff_b_kernel<<<dim3(NE, NL), blk, 0, stream>>>(bproj, wprojT6, beff6);
    transpose_cast_b_kernel<<<dim3(NV / 32, NE / 32, 1), blk, 0, stream>>>(lm_w, lmT, NE, NV);

    // ---- embedding + LN1(0) ----
    embed_ln_kernel<<<NM, blk, 0, stream>>>(idx, tok, pos, ln1_g, ln1_b, x, hbuf);

    for (int l = 0; l < NL; ++l) {
        // QKV: direct bf16 output (288 blocks — no split-K needed)
        gemm_mfma<unsigned short, false, false, 1><<<dim3((NM/128)*(NQKV/128)), blk, 0, stream>>>(
            hbuf, wqkvT6 + (long)l * NQKV * NE, nullptr, qkv, NM / 128, NQKV, NE);
        vtrans_kernel<<<dim3(NT / 64, NB * NH), blk, 0, stream>>>(qkv, vt);
        fattn_kernel<<<dim3(NT / 128, NB * NH), dim3(512), 0, stream>>>(qkv, vt, att);
        gemm_mfma<float, false, false, 2><<<dim3((NM/128)*(NE/128), 2), blk, 0, stream>>>(
            att, weffT6 + (long)l * NE * NE, nullptr, parts, NM / 128, NE, NE);
        combine_ln_kernel<2><<<NM, blk, 0, stream>>>(
            parts, beff6 + (long)l * NE, x, ln2_g + (long)l * NE, ln2_b + (long)l * NE, hbuf);
        gemm_mfma<unsigned short, true, true, 1><<<dim3((NM/128)*(NFF/128)), blk, 0, stream>>>(
            hbuf, w1T6 + (long)l * NFF * NE, b1 + (long)l * NFF, hid, NM / 128, NFF, NE);
        gemm_mfma<float, false, false, 4><<<dim3((NM/128)*(NE/128), 4), blk, 0, stream>>>(
            hid, w2T6 + (long)l * NE * NFF, nullptr, parts, NM / 128, NE, NFF);
        const float* ng = (l < NL - 1) ? (ln1_g + (long)(l + 1) * NE) : lnf_g;
        const float* nb = (l < NL - 1) ? (ln1_b + (long)(l + 1) * NE) : lnf_b;
        combine_ln_kernel<4><<<NM, blk, 0, stream>>>(parts, b2 + (long)l * NE, x, ng, nb, hbuf);
    }

    // ---- LM head + fused LSE ----
    gemm256x128_lse<<<dim3((NM/256)*(NV/128)), dim3(512), 0, stream>>>(
        hbuf, lmT, lm_b, logits, pmb, psb, NM / 256, NV, NE);
    nll_combine_kernel<<<NM, blk, 0, stream>>>(logits, pmb, psb, targets, nll);
    loss_reduce_kernel<<<1, blk, 0, stream>>>(nll, loss);
}

// Round 12
// 1082.526 us; speedup vs baseline: 10.5975x; 1.0043x over previous
//
#include <hip/hip_runtime.h>
#include <math.h>

#define NL 6
#define NH 12
#define NE 768
#define NHS 64
#define NT 1024
#define NB 2
#define NV 32000
#define NM (NB * NT)   // 2048
#define NQKV (3 * NE)  // 2304
#define NFF (4 * NE)   // 3072
#define LN_EPS 1e-5f

typedef __attribute__((ext_vector_type(8))) short short8;
typedef __attribute__((ext_vector_type(4))) float f32x4;
typedef __attribute__((ext_vector_type(4))) unsigned short ushort4v;
typedef __attribute__((address_space(1))) const unsigned int as1_cuint;
typedef __attribute__((address_space(3))) unsigned int as3_uint;

__device__ __forceinline__ unsigned short f2bf(float f) {
    unsigned int u = __builtin_bit_cast(unsigned int, f);
    u += 0x7fffu + ((u >> 16) & 1u);   // RNE
    return (unsigned short)(u >> 16);
}
__device__ __forceinline__ float bf2f(unsigned short u) {
    unsigned int v = ((unsigned int)u) << 16;
    return __builtin_bit_cast(float, v);
}
__device__ __forceinline__ void gload_lds16(const void* g, void* l) {
    __builtin_amdgcn_global_load_lds((as1_cuint*)g, (as3_uint*)l, 16, 0, 0);
}

// ---------------- embedding + LN1(layer0) fused: one block per row ----------------
__global__ __launch_bounds__(256) void embed_ln_kernel(const int* __restrict__ idx,
                                                       const float* __restrict__ tok,
                                                       const float* __restrict__ pos,
                                                       const float* __restrict__ g,
                                                       const float* __restrict__ b,
                                                       float* __restrict__ x,
                                                       unsigned short* __restrict__ hbuf) {
    __shared__ float red[256];
    int row = blockIdx.x, tid = threadIdx.x;
    int t = row % NT;
    int id = idx[row];
    float v[3]; float s = 0.f;
    #pragma unroll
    for (int k = 0; k < 3; ++k) {
        int c = tid + k * 256;
        v[k] = tok[(long)id * NE + c] + pos[(long)t * NE + c];
        x[(long)row * NE + c] = v[k];
        s += v[k];
    }
    red[tid] = s; __syncthreads();
    for (int o = 128; o > 0; o >>= 1) { if (tid < o) red[tid] += red[tid + o]; __syncthreads(); }
    float mu = red[0] / NE;
    __syncthreads();
    float vr = 0.f;
    #pragma unroll
    for (int k = 0; k < 3; ++k) { float d = v[k] - mu; vr += d * d; }
    red[tid] = vr; __syncthreads();
    for (int o = 128; o > 0; o >>= 1) { if (tid < o) red[tid] += red[tid + o]; __syncthreads(); }
    float rstd = rsqrtf(red[0] / NE + LN_EPS);
    #pragma unroll
    for (int k = 0; k < 3; ++k) {
        int c = tid + k * 256;
        hbuf[(long)row * NE + c] = f2bf((v[k] - mu) * rstd * g[c] + b[c]);
    }
}

// ---------------- fused split-K combine + residual + LayerNorm ----------------
template<int S>
__global__ __launch_bounds__(256) void combine_ln_kernel(const float* __restrict__ parts,
                                                         const float* __restrict__ bias,
                                                         float* __restrict__ x,
                                                         const float* __restrict__ g,
                                                         const float* __restrict__ b,
                                                         unsigned short* __restrict__ hbuf) {
    __shared__ float red[256];
    int row = blockIdx.x, tid = threadIdx.x;
    float v[3]; float s = 0.f;
    #pragma unroll
    for (int k = 0; k < 3; ++k) {
        int c = tid + k * 256;
        long i = (long)row * NE + c;
        float a = parts[i];
        #pragma unroll
        for (int si = 1; si < S; ++si) a += parts[(long)si * NM * NE + i];
        a += bias[c] + x[i];
        x[i] = a;
        v[k] = a; s += a;
    }
    red[tid] = s; __syncthreads();
    for (int o = 128; o > 0; o >>= 1) { if (tid < o) red[tid] += red[tid + o]; __syncthreads(); }
    float mu = red[0] / NE;
    __syncthreads();
    float vr = 0.f;
    #pragma unroll
    for (int k = 0; k < 3; ++k) { float d = v[k] - mu; vr += d * d; }
    red[tid] = vr; __syncthreads();
    for (int o = 128; o > 0; o >>= 1) { if (tid < o) red[tid] += red[tid + o]; __syncthreads(); }
    float rstd = rsqrtf(red[0] / NE + LN_EPS);
    #pragma unroll
    for (int k = 0; k < 3; ++k) {
        int c = tid + k * 256;
        hbuf[(long)row * NE + c] = f2bf((v[k] - mu) * rstd * g[c] + b[c]);
    }
}

// ---------------- batched transpose of the four 768x768 weights, all layers ----------------
__global__ __launch_bounds__(256) void transpose4b_kernel(const float* __restrict__ wq,
                                                          const float* __restrict__ wk,
                                                          const float* __restrict__ wv,
                                                          const float* __restrict__ wp,
                                                          unsigned short* __restrict__ wqkvT,
                                                          unsigned short* __restrict__ wprojT) {
    __shared__ float t[32][33];
    int z = blockIdx.z, l = z >> 2, which = z & 3;
    const float* W = ((which == 0) ? wq : (which == 1) ? wk : (which == 2) ? wv : wp) + (long)l * NE * NE;
    unsigned short* WT = (which < 3) ? (wqkvT + (long)l * NQKV * NE + (long)which * NE * NE)
                                     : (wprojT + (long)l * NE * NE);
    int k0 = blockIdx.y * 32, n0 = blockIdx.x * 32;
    int c = threadIdx.x & 31, r = threadIdx.x >> 5;
    #pragma unroll
    for (int p = 0; p < 4; ++p)
        t[r + p * 8][c] = W[(long)(k0 + r + p * 8) * NE + n0 + c];
    __syncthreads();
    #pragma unroll
    for (int p = 0; p < 4; ++p)
        WT[(long)(n0 + r + p * 8) * NE + k0 + c] = f2bf(t[c][r + p * 8]);
}

// ---------------- batched tiled transpose + cast: per-layer stride K*N ----------------
__global__ __launch_bounds__(256) void transpose_cast_b_kernel(const float* __restrict__ W0,
                                                               unsigned short* __restrict__ WT0,
                                                               int K, int N) {
    __shared__ float t[32][33];
    long lofs = (long)blockIdx.z * K * N;
    const float* W = W0 + lofs;
    unsigned short* WT = WT0 + lofs;
    int k0 = blockIdx.y * 32, n0 = blockIdx.x * 32;
    int c = threadIdx.x & 31, r = threadIdx.x >> 5;
    #pragma unroll
    for (int p = 0; p < 4; ++p)
        t[r + p * 8][c] = W[(long)(k0 + r + p * 8) * N + n0 + c];
    __syncthreads();
    #pragma unroll
    for (int p = 0; p < 4; ++p)
        WT[(long)(n0 + r + p * 8) * K + k0 + c] = f2bf(t[c][r + p * 8]);
}

// ---------------- plain fp32 -> bf16 cast ----------------
__global__ __launch_bounds__(256) void cast_kernel(const float* __restrict__ W,
                                                   unsigned short* __restrict__ O, long n) {
    long i = ((long)blockIdx.x * 256 + threadIdx.x) * 4;
    if (i < n) {
        float4 v = *(const float4*)(W + i);
        ushort4v o;
        o[0] = f2bf(v.x); o[1] = f2bf(v.y); o[2] = f2bf(v.z); o[3] = f2bf(v.w);
        *(ushort4v*)(O + i) = o;
    }
}

// ---------------- batched beff ----------------
__global__ __launch_bounds__(256) void beff_b_kernel(const float* __restrict__ bproj,
                                                     const unsigned short* __restrict__ wprojT,
                                                     float* __restrict__ beff) {
    __shared__ float red[256];
    int n = blockIdx.x, l = blockIdx.y, tid = threadIdx.x;
    const unsigned short* wp = wprojT + (long)l * NE * NE + (long)n * NE;
    const float* bp = bproj + (long)l * NE;
    float acc = 0.f;
    for (int j = tid; j < NE; j += 256) acc += bp[j] * bf2f(wp[j]);
    red[tid] = acc; __syncthreads();
    for (int o = 128; o > 0; o >>= 1) { if (tid < o) red[tid] += red[tid + o]; __syncthreads(); }
    if (tid == 0) beff[(long)l * NE + n] = red[0] + bp[n];
}

// ---------------- 128x128 bf16 MFMA GEMM: 3-slot ring, depth-2 counted vmcnt ----------------
template<typename OutT, bool BIAS, bool RELU, int SPLITK>
__global__ __launch_bounds__(256) void gemm_mfma(const unsigned short* __restrict__ A,
                                                 const unsigned short* __restrict__ BT,
                                                 const float* __restrict__ bias,
                                                 OutT* __restrict__ C,
                                                 int gridM, int N, int K) {
    __shared__ unsigned short As[3][128 * 32];
    __shared__ unsigned short Bs[3][128 * 32];
    int tid = threadIdx.x;
    int lane = tid & 63, w = tid >> 6;
    int wr = w >> 1, wc = w & 1;
    int l4 = lane >> 4, l15 = lane & 15;

    int nwg = gridDim.x, orig = blockIdx.x;
    int q = nwg >> 3, r8 = nwg & 7;
    int xcd = orig & 7, ii = orig >> 3;
    int wg = (xcd < r8) ? (xcd * (q + 1) + ii) : (r8 * (q + 1) + (xcd - r8) * q + ii);
    int bm = wg % gridM, bn = wg / gridM;
    int m0 = bm * 128, n0 = bn * 128;

    int kb = K / SPLITK;
    int koff = (SPLITK > 1) ? blockIdx.y * kb : 0;
    int nkt = kb >> 5;

    f32x4 acc[4][4] = {};

    int srow = lane >> 2;
    int scol = ((lane & 3) ^ ((lane >> 3) & 3)) * 8;   // inverse-swizzled source slot
    int rsw  = (l4 ^ ((l15 >> 1) & 3)) * 8;            // swizzled read slot

    auto STAGE = [&](int slot, int kt) {   // 4 gload_lds per wave
        #pragma unroll
        for (int it = 0; it < 2; ++it) {
            int rr = w * 32 + it * 16;
            gload_lds16(&A [(long)(m0 + rr + srow) * K + koff + kt * 32 + scol], &As[slot][rr * 32]);
            gload_lds16(&BT[(long)(n0 + rr + srow) * K + koff + kt * 32 + scol], &Bs[slot][rr * 32]);
        }
    };

    STAGE(0, 0);
    if (nkt > 1) STAGE(1, 1);

    int s = 0;
    for (int t = 0; t < nkt; ++t) {
        if (t + 2 < nkt) STAGE((t + 2) % 3, t + 2);
        int ahead = nkt - 1 - t;
        if (ahead >= 2)      asm volatile("s_waitcnt vmcnt(8)" ::: "memory");
        else if (ahead == 1) asm volatile("s_waitcnt vmcnt(4)" ::: "memory");
        else                 asm volatile("s_waitcnt vmcnt(0)" ::: "memory");
        asm volatile("s_barrier" ::: "memory");        // slot s fully staged for all waves

        short8 a[4], b[4];
        #pragma unroll
        for (int f = 0; f < 4; ++f) {
            a[f] = *(const short8*)&As[s][(wr * 64 + f * 16 + l15) * 32 + rsw];
            b[f] = *(const short8*)&Bs[s][(wc * 64 + f * 16 + l15) * 32 + rsw];
        }
        asm volatile("s_waitcnt lgkmcnt(0)" ::: "memory");
        asm volatile("s_barrier" ::: "memory");        // all reads of slot s done -> restageable

        __builtin_amdgcn_s_setprio(1);
        #pragma unroll
        for (int fm = 0; fm < 4; ++fm)
            #pragma unroll
            for (int fn = 0; fn < 4; ++fn)
                acc[fm][fn] = __builtin_amdgcn_mfma_f32_16x16x32_bf16(a[fm], b[fn], acc[fm][fn], 0, 0, 0);
        __builtin_amdgcn_s_setprio(0);
        s = (s + 1) % 3;
    }

    if constexpr (SPLITK > 1) {
        float* Cp = (float*)C + (long)blockIdx.y * gridM * 128 * N;
        #pragma unroll
        for (int fm = 0; fm < 4; ++fm)
            #pragma unroll
            for (int j = 0; j < 4; ++j) {
                long row = m0 + wr * 64 + fm * 16 + l4 * 4 + j;
                #pragma unroll
                for (int fn = 0; fn < 4; ++fn)
                    Cp[row * N + n0 + wc * 64 + fn * 16 + l15] = acc[fm][fn][j];
            }
    } else {
        float bs[4];
        #pragma unroll
        for (int fn = 0; fn < 4; ++fn)
            bs[fn] = BIAS ? bias[n0 + wc * 64 + fn * 16 + l15] : 0.f;

        #pragma unroll
        for (int fm = 0; fm < 4; ++fm) {
            #pragma unroll
            for (int j = 0; j < 4; ++j) {
                long row = m0 + wr * 64 + fm * 16 + l4 * 4 + j;
                #pragma unroll
                for (int fn = 0; fn < 4; ++fn) {
                    int col = n0 + wc * 64 + fn * 16 + l15;
                    float v = acc[fm][fn][j] + bs[fn];
                    if (RELU) v = fmaxf(v, 0.f);
                    if constexpr (sizeof(OutT) == 2) C[row * N + col] = (OutT)f2bf(v);
                    else                             C[row * N + col] = v;
                }
            }
        }
    }
}

// ---------------- batched square bf16 GEMM (weff = Wp@Wp per layer), T2 swizzle ----------------
__global__ __launch_bounds__(256) void gemm_weff_kernel(const unsigned short* __restrict__ A0,
                                                        const unsigned short* __restrict__ B0,
                                                        unsigned short* __restrict__ C0,
                                                        int gridM, int N, int K) {
    __shared__ unsigned short As[2][128 * 32];
    __shared__ unsigned short Bs[2][128 * 32];
    long zofs = (long)blockIdx.z * N * K;
    const unsigned short* A = A0 + zofs;
    const unsigned short* BT = B0 + zofs;
    unsigned short* C = C0 + zofs;
    int tid = threadIdx.x;
    int lane = tid & 63, w = tid >> 6;
    int wr = w >> 1, wc = w & 1;
    int l4 = lane >> 4, l15 = lane & 15;
    int bm = blockIdx.x % gridM, bn = blockIdx.x / gridM;
    int m0 = bm * 128, n0 = bn * 128;

    f32x4 acc[4][4] = {};
    int srow = lane >> 2;
    int scol = ((lane & 3) ^ ((lane >> 3) & 3)) * 8;
    int rsw  = (l4 ^ ((l15 >> 1) & 3)) * 8;

    #pragma unroll
    for (int it = 0; it < 2; ++it) {
        int rr = w * 32 + it * 16;
        gload_lds16(&A [(long)(m0 + rr + srow) * K + scol], &As[0][rr * 32]);
        gload_lds16(&BT[(long)(n0 + rr + srow) * K + scol], &Bs[0][rr * 32]);
    }
    int cur = 0;
    for (int k0 = 0; k0 < K; k0 += 32) {
        __syncthreads();
        if (k0 + 32 < K) {
            #pragma unroll
            for (int it = 0; it < 2; ++it) {
                int rr = w * 32 + it * 16;
                gload_lds16(&A [(long)(m0 + rr + srow) * K + k0 + 32 + scol], &As[cur ^ 1][rr * 32]);
                gload_lds16(&BT[(long)(n0 + rr + srow) * K + k0 + 32 + scol], &Bs[cur ^ 1][rr * 32]);
            }
        }
        short8 a[4], b[4];
        #pragma unroll
        for (int f = 0; f < 4; ++f) {
            a[f] = *(const short8*)&As[cur][(wr * 64 + f * 16 + l15) * 32 + rsw];
            b[f] = *(const short8*)&Bs[cur][(wc * 64 + f * 16 + l15) * 32 + rsw];
        }
        #pragma unroll
        for (int fm = 0; fm < 4; ++fm)
            #pragma unroll
            for (int fn = 0; fn < 4; ++fn)
                acc[fm][fn] = __builtin_amdgcn_mfma_f32_16x16x32_bf16(a[fm], b[fn], acc[fm][fn], 0, 0, 0);
        cur ^= 1;
    }
    #pragma unroll
    for (int fm = 0; fm < 4; ++fm)
        #pragma unroll
        for (int j = 0; j < 4; ++j) {
            long row = m0 + wr * 64 + fm * 16 + l4 * 4 + j;
            #pragma unroll
            for (int fn = 0; fn < 4; ++fn)
                C[row * N + n0 + wc * 64 + fn * 16 + l15] = f2bf(acc[fm][fn][j]);
        }
}

// ---------------- LM head: 256x128 tile, 8 waves, BK=64, 2-slot dbuf, counted vmcnt ----------------
// LDS 96 KB. Rows are 128B = exact bank wrap -> chunk XOR (row&7) swizzle.
// Wave layout: 4 m-bands (64 rows) x 2 n-halves (64 cols); barriers per 64-K (halved).
__global__ __launch_bounds__(512, 2) void gemm256x128_lse(const unsigned short* __restrict__ A,
                                                          const unsigned short* __restrict__ BT,
                                                          const float* __restrict__ bias,
                                                          float* __restrict__ C,
                                                          float* __restrict__ pm, float* __restrict__ ps,
                                                          int gridM, int N, int K) {
    __shared__ unsigned short Al[2][256 * 64];   // 64 KB
    __shared__ unsigned short Bl[2][128 * 64];   // 32 KB
    int tid = threadIdx.x;
    int lane = tid & 63, w = tid >> 6;
    int wm = w >> 1, wn = w & 1;
    int l4 = lane >> 4, l15 = lane & 15;

    int nwg = gridDim.x, orig = blockIdx.x;
    int q = nwg >> 3, r8 = nwg & 7;
    int xcd = orig & 7, ii = orig >> 3;
    int wg = (xcd < r8) ? (xcd * (q + 1) + ii) : (r8 * (q + 1) + (xcd - r8) * q + ii);
    int bm = wg % gridM, bn = wg / gridM;
    int m0 = bm * 256, n0 = bn * 128;

    int nkt = K >> 6;                              // 12
    int lr = lane >> 3, lc = lane & 7;             // staging: 8 rows x 8 chunks per gload

    auto STAGE = [&](int slot, int kt) {           // 6 gload_lds per wave
        #pragma unroll
        for (int i = 0; i < 4; ++i) {
            int row = (w * 4 + i) * 8 + lr;
            gload_lds16(&A[(long)(m0 + row) * K + kt * 64 + (lc ^ (row & 7)) * 8],
                        &Al[slot][(w * 4 + i) * 8 * 64]);
        }
        #pragma unroll
        for (int i = 0; i < 2; ++i) {
            int row = (w * 2 + i) * 8 + lr;
            gload_lds16(&BT[(long)(n0 + row) * K + kt * 64 + (lc ^ (row & 7)) * 8],
                        &Bl[slot][(w * 2 + i) * 8 * 64]);
        }
    };

    f32x4 acc[4][4] = {};

    STAGE(0, 0);
    for (int t = 0; t < nkt; ++t) {
        if (t + 1 < nkt) {
            STAGE((t + 1) & 1, t + 1);
            asm volatile("s_waitcnt vmcnt(6)" ::: "memory");   // slot t's 6 loads done
        } else {
            asm volatile("s_waitcnt vmcnt(0)" ::: "memory");
        }
        asm volatile("s_barrier" ::: "memory");                // slot t staged for all waves

        int s = t & 1;
        short8 af[4][2], bf[4][2];
        #pragma unroll
        for (int f = 0; f < 4; ++f) {
            int ra = wm * 64 + f * 16 + l15;       // FIX: 64-row m-band (was wm*128, OOB)
            int rb = wn * 64 + f * 16 + l15;
            #pragma unroll
            for (int kk = 0; kk < 2; ++kk) {
                af[f][kk] = *(const short8*)&Al[s][ra * 64 + ((kk * 4 + l4) ^ (ra & 7)) * 8];
                bf[f][kk] = *(const short8*)&Bl[s][rb * 64 + ((kk * 4 + l4) ^ (rb & 7)) * 8];
            }
        }
        asm volatile("s_waitcnt lgkmcnt(0)" ::: "memory");
        asm volatile("s_barrier" ::: "memory");                // reads of slot s done -> restageable

        __builtin_amdgcn_s_setprio(1);
        #pragma unroll
        for (int kk = 0; kk < 2; ++kk)
            #pragma unroll
            for (int fm = 0; fm < 4; ++fm)
                #pragma unroll
                for (int fn = 0; fn < 4; ++fn)
                    acc[fm][fn] = __builtin_amdgcn_mfma_f32_16x16x32_bf16(af[fm][kk], bf[fn][kk], acc[fm][fn], 0, 0, 0);
        __builtin_amdgcn_s_setprio(0);
    }

    float bs[4];
    #pragma unroll
    for (int fn = 0; fn < 4; ++fn)
        bs[fn] = bias[n0 + wn * 64 + fn * 16 + l15];

    #pragma unroll
    for (int fm = 0; fm < 4; ++fm) {
        #pragma unroll
        for (int j = 0; j < 4; ++j) {
            long row = m0 + wm * 64 + fm * 16 + l4 * 4 + j;
            float v4[4];
            #pragma unroll
            for (int fn = 0; fn < 4; ++fn) {
                int col = n0 + wn * 64 + fn * 16 + l15;
                float v = acc[fm][fn][j] + bs[fn];
                __builtin_nontemporal_store(v, &C[row * N + col]);   // logits: write-once stream
                v4[fn] = v;
            }
            float mx = fmaxf(fmaxf(v4[0], v4[1]), fmaxf(v4[2], v4[3]));
            #pragma unroll
            for (int off = 1; off < 16; off <<= 1) mx = fmaxf(mx, __shfl_xor(mx, off));
            float sm = 0.f;
            #pragma unroll
            for (int fn = 0; fn < 4; ++fn) sm += __expf(v4[fn] - mx);
            #pragma unroll
            for (int off = 1; off < 16; off <<= 1) sm += __shfl_xor(sm, off);
            if (l15 == 0) {
                int pidx = bn * 2 + wn;
                pm[row * 512 + pidx] = mx;
                ps[row * 512 + pidx] = sm;
            }
        }
    }
}

// ---------------- V transpose: vt[bh][d][t] = V[b][t][h][d] ----------------
__global__ __launch_bounds__(256) void vtrans_kernel(const unsigned short* __restrict__ qkv,
                                                     unsigned short* __restrict__ vt) {
    __shared__ unsigned short t[64][72];
    int t0 = blockIdx.x * 64;
    int bh = blockIdx.y;
    int b = bh / NH, h = bh % NH;
    int tid = threadIdx.x;
    #pragma unroll
    for (int i = 0; i < 2; ++i) {
        int r = (tid >> 3) + i * 32, c8 = (tid & 7) * 8;
        short8 v = *(const short8*)(qkv + ((long)b * NT + t0 + r) * NQKV + 2 * NE + h * NHS + c8);
        *(short8*)&t[r][c8] = v;
    }
    __syncthreads();
    #pragma unroll
    for (int i = 0; i < 2; ++i) {
        int d = (tid >> 3) + i * 32, s = (tid & 7) * 8;
        short8 o;
        #pragma unroll
        for (int j = 0; j < 8; ++j) o[j] = (short)t[s + j][d];
        *(short8*)(vt + ((long)bh * NHS + d) * NT + t0 + s) = o;
    }
}

// ---------------- flash attention, QBLK=128: wave-shared tile max, deferred lsum reduce ----------------
__global__ __launch_bounds__(512) void fattn_kernel(const unsigned short* __restrict__ qkv,
                                                    const unsigned short* __restrict__ vt,
                                                    unsigned short* __restrict__ out) {
    __shared__ unsigned short Ks[2][64 * 64];     // 16 KB
    __shared__ unsigned short Vl[2][64 * 64];     // 16 KB
    __shared__ unsigned short Ps[8 * 16 * 64];    // 16 KB
    int qt = gridDim.x - 1 - blockIdx.x;          // heavy q-tiles first
    int bh = blockIdx.y;
    int b = bh / NH, h = bh % NH;
    int tid = threadIdx.x, lane = tid & 63, w = tid >> 6;   // w = 0..7
    int l4 = lane >> 4, l15 = lane & 15;
    long rowb = (long)b * NT;
    const float scale = 0.03608439182435161f;     // 768^-0.5 (reference scales by E)
    const unsigned short* vtp = vt + (long)bh * NHS * NT;

    const unsigned short* qptr = qkv + (rowb + qt * 128 + w * 16 + l15) * NQKV + h * NHS;
    short8 qa0 = *(const short8*)(qptr + l4 * 8);
    short8 qa1 = *(const short8*)(qptr + 32 + l4 * 8);

    f32x4 o[4] = {};
    float m = -INFINITY;                          // wave-shared running max (uniform across lanes)
    float lsum[4] = {};                           // per-lane partial row sums (reduced at end)

    int kr_r = tid >> 3, kr_c = (tid & 7) * 8;    // K: row 0..63, col-chunk
    int vr_d = tid >> 3, vr_s = tid & 7;          // V^T: d 0..63, t-chunk

    short8 kr, vr;
    auto LOADT = [&](int t) {
        int kbase = t * 64;
        kr = *(const short8*)(qkv + (rowb + kbase + kr_r) * NQKV + NE + h * NHS + kr_c);
        vr = *(const short8*)(vtp + (long)vr_d * NT + kbase + vr_s * 8);
    };

    int ntiles = 2 * qt + 2;
    LOADT(0);
    for (int t = 0; t < ntiles; ++t) {
        int cur = t & 1;
        *(short8*)&Ks[cur][kr_r * 64 + (kr_c ^ ((kr_r & 7) << 3))] = kr;
        *(short8*)&Vl[cur][vr_d * 64 + ((vr_s * 8) ^ ((vr_d & 7) << 3))] = vr;
        asm volatile("s_waitcnt lgkmcnt(0)" ::: "memory");
        if (t + 1 < ntiles) LOADT(t + 1);         // overlap HBM with compute
        asm volatile("s_barrier" ::: "memory");

        f32x4 s[4];
        __builtin_amdgcn_s_setprio(1);
        #pragma unroll
        for (int fn = 0; fn < 4; ++fn) {
            int key = fn * 16 + l15;
            short8 kb0 = *(const short8*)&Ks[cur][key * 64 + ((l4 * 8) ^ ((key & 7) << 3))];
            short8 kb1 = *(const short8*)&Ks[cur][key * 64 + ((32 + l4 * 8) ^ ((key & 7) << 3))];
            f32x4 z = {};
            z = __builtin_amdgcn_mfma_f32_16x16x32_bf16(qa0, kb0, z, 0, 0, 0);
            s[fn] = __builtin_amdgcn_mfma_f32_16x16x32_bf16(qa1, kb1, z, 0, 0, 0);
        }
        __builtin_amdgcn_s_setprio(0);

        if (t >= 2 * qt) {                        // only last two tiles touch the diagonal
            #pragma unroll
            for (int fn = 0; fn < 4; ++fn) {
                int key = t * 64 + fn * 16 + l15;
                #pragma unroll
                for (int j = 0; j < 4; ++j) {
                    int qrow = qt * 128 + w * 16 + l4 * 4 + j;
                    s[fn][j] = (key <= qrow) ? s[fn][j] * scale : -1e30f;
                }
            }
        } else {
            #pragma unroll
            for (int fn = 0; fn < 4; ++fn)
                #pragma unroll
                for (int j = 0; j < 4; ++j)
                    s[fn][j] *= scale;
        }

        // ---- wave-shared tile max (shared offset cancels in softmax normalization) ----
        float tmax = -INFINITY;
        #pragma unroll
        for (int fn = 0; fn < 4; ++fn)
            #pragma unroll
            for (int j = 0; j < 4; ++j)
                tmax = fmaxf(tmax, s[fn][j]);
        #pragma unroll
        for (int off = 1; off < 64; off <<= 1) tmax = fmaxf(tmax, __shfl_xor(tmax, off));

        if (tmax > m) {                            // wave-uniform rescale (skipped when max stable)
            float alpha = __expf(m - tmax);
            m = tmax;
            #pragma unroll
            for (int j = 0; j < 4; ++j) lsum[j] *= alpha;
            #pragma unroll
            for (int fn = 0; fn < 4; ++fn)
                #pragma unroll
                for (int j = 0; j < 4; ++j) o[fn][j] *= alpha;
        }

        #pragma unroll
        for (int j = 0; j < 4; ++j) {
            float psum = 0.f;
            #pragma unroll
            for (int fn = 0; fn < 4; ++fn) {
                float p = __expf(s[fn][j] - m);
                psum += p;
                int rr = l4 * 4 + j, c = fn * 16 + l15;
                Ps[w * 1024 + rr * 64 + (c ^ ((rr & 7) << 3))] = f2bf(p);
            }
            lsum[j] += psum;                       // per-lane partial; cross-lane reduce deferred
        }

        short8 pa0 = *(const short8*)&Ps[w * 1024 + l15 * 64 + ((l4 * 8) ^ ((l15 & 7) << 3))];
        short8 pa1 = *(const short8*)&Ps[w * 1024 + l15 * 64 + ((32 + l4 * 8) ^ ((l15 & 7) << 3))];
        __builtin_amdgcn_s_setprio(1);
        #pragma unroll
        for (int fn = 0; fn < 4; ++fn) {
            int d = fn * 16 + l15;
            short8 vb0 = *(const short8*)&Vl[cur][d * 64 + ((l4 * 8) ^ ((d & 7) << 3))];
            short8 vb1 = *(const short8*)&Vl[cur][d * 64 + ((32 + l4 * 8) ^ ((d & 7) << 3))];
            o[fn] = __builtin_amdgcn_mfma_f32_16x16x32_bf16(pa0, vb0, o[fn], 0, 0, 0);
            o[fn] = __builtin_amdgcn_mfma_f32_16x16x32_bf16(pa1, vb1, o[fn], 0, 0, 0);
        }
        __builtin_amdgcn_s_setprio(0);
    }

    // final cross-lane lsum reduce (16-lane groups share a row)
    #pragma unroll
    for (int j = 0; j < 4; ++j)
        #pragma unroll
        for (int off = 1; off < 16; off <<= 1)
            lsum[j] += __shfl_xor(lsum[j], off);

    #pragma unroll
    for (int j = 0; j < 4; ++j) {
        long row = rowb + qt * 128 + w * 16 + l4 * 4 + j;
        float inv = 1.0f / lsum[j];
        #pragma unroll
        for (int fn = 0; fn < 4; ++fn)
            out[row * NE + h * NHS + fn * 16 + l15] = f2bf(o[fn][j] * inv);
    }
}

// ---------------- NLL from LM-head partials ----------------
__global__ __launch_bounds__(256) void nll_combine_kernel(const float* __restrict__ logits,
                                                          const float* __restrict__ pm,
                                                          const float* __restrict__ ps,
                                                          const int* __restrict__ targets,
                                                          float* __restrict__ nll) {
    __shared__ float rm[256], rs[256];
    int row = blockIdx.x, tid = threadIdx.x;
    float m = -1e30f, s = 0.f;
    for (int i = tid; i < 500; i += 256) {
        float m2 = pm[(long)row * 512 + i], s2 = ps[(long)row * 512 + i];
        float mm = fmaxf(m, m2);
        s = s * __expf(m - mm) + s2 * __expf(m2 - mm);
        m = mm;
    }
    rm[tid] = m; rs[tid] = s; __syncthreads();
    for (int o = 128; o > 0; o >>= 1) {
        if (tid < o) {
            float m2 = rm[tid + o], s2 = rs[tid + o];
            float mm = fmaxf(rm[tid], m2);
            rs[tid] = rs[tid] * __expf(rm[tid] - mm) + s2 * __expf(m2 - mm);
            rm[tid] = mm;
        }
        __syncthreads();
    }
    if (tid == 0) {
        int tgt = targets[row];
        nll[row] = -(logits[(long)row * NV + tgt] - rm[0] - logf(rs[0]));
    }
}

__global__ void loss_reduce_kernel(const float* __restrict__ nll, float* __restrict__ out) {
    __shared__ float red[256];
    int tid = threadIdx.x;
    float s = 0.f;
    for (int i = tid; i < NM; i += 256) s += nll[i];
    red[tid] = s; __syncthreads();
    for (int o = 128; o > 0; o >>= 1) { if (tid < o) red[tid] += red[tid + o]; __syncthreads(); }
    if (tid == 0) out[0] = red[0] / NM;
}

extern "C" void kernel_launch(void* const* d_in, const int* in_sizes, int n_in,
                              void* d_out, int out_size, void* d_ws, size_t ws_size,
                              hipStream_t stream) {
    const int*   idx     = (const int*)  d_in[0];
    const int*   targets = (const int*)  d_in[1];
    const float* tok     = (const float*)d_in[2];
    const float* pos     = (const float*)d_in[3];
    const float* ln1_g   = (const float*)d_in[4];
    const float* ln1_b   = (const float*)d_in[5];
    const float* wq      = (const float*)d_in[6];
    const float* wk      = (const float*)d_in[7];
    const float* wv      = (const float*)d_in[8];
    const float* wproj   = (const float*)d_in[9];
    const float* bproj   = (const float*)d_in[10];
    const float* ln2_g   = (const float*)d_in[11];
    const float* ln2_b   = (const float*)d_in[12];
    const float* w1      = (const float*)d_in[13];
    const float* b1      = (const float*)d_in[14];
    const float* w2      = (const float*)d_in[15];
    const float* b2      = (const float*)d_in[16];
    const float* lnf_g   = (const float*)d_in[17];
    const float* lnf_b   = (const float*)d_in[18];
    const float* lm_w    = (const float*)d_in[19];
    const float* lm_b    = (const float*)d_in[20];

    float* logits = (float*)d_out;
    float* loss   = logits + (long)NM * NV;

    char* p = (char*)d_ws;
    float*          x      = (float*)p;          p += (long)NM * NE * 4;
    unsigned short* hbuf   = (unsigned short*)p; p += (long)NM * NE * 2;
    unsigned short* qkv    = (unsigned short*)p; p += (long)NM * NQKV * 2;
    unsigned short* att    = (unsigned short*)p; p += (long)NM * NE * 2;
    unsigned short* hid    = (unsigned short*)p; p += (long)NM * NFF * 2;
    unsigned short* vt     = (unsigned short*)p; p += (long)NB * NH * NHS * NT * 2;
    float*          nll    = (float*)p;          p += (long)NM * 4;
    float*          pmb    = (float*)p;          p += (long)NM * 512 * 4;
    float*          psb    = (float*)p;          p += (long)NM * 512 * 4;
    float*          parts  = (float*)p;          p += (long)2 * NM * NQKV * 4;   // covers proj S=2 / FF2 S=4
    unsigned short* wqkvT6 = (unsigned short*)p; p += (long)NL * NQKV * NE * 2;
    unsigned short* wprojT6= (unsigned short*)p; p += (long)NL * NE * NE * 2;
    unsigned short* wprojC6= (unsigned short*)p; p += (long)NL * NE * NE * 2;
    unsigned short* weffT6 = (unsigned short*)p; p += (long)NL * NE * NE * 2;
    float*          beff6  = (float*)p;          p += (long)NL * NE * 4;
    unsigned short* w1T6   = (unsigned short*)p; p += (long)NL * NFF * NE * 2;
    unsigned short* w2T6   = (unsigned short*)p; p += (long)NL * NE * NFF * 2;
    unsigned short* lmT    = (unsigned short*)p; p += (long)NV * NE * 2;

    dim3 blk(256);

    // ---- batched weight prep ----
    transpose4b_kernel<<<dim3(NE / 32, NE / 32, 4 * NL), blk, 0, stream>>>(
        wq, wk, wv, wproj, wqkvT6, wprojT6);
    cast_kernel<<<(NL * NE * NE) / 1024, blk, 0, stream>>>(wproj, wprojC6, (long)NL * NE * NE);
    transpose_cast_b_kernel<<<dim3(NFF / 32, NE / 32, NL), blk, 0, stream>>>(w1, w1T6, NE, NFF);
    transpose_cast_b_kernel<<<dim3(NE / 32, NFF / 32, NL), blk, 0, stream>>>(w2, w2T6, NFF, NE);
    gemm_weff_kernel<<<dim3(36, 1, NL), blk, 0, stream>>>(wprojT6, wprojC6, weffT6, 6, NE, NE);
    beff_b_kernel<<<dim3(NE, NL), blk, 0, stream>>>(bproj, wprojT6, beff6);
    transpose_cast_b_kernel<<<dim3(NV / 32, NE / 32, 1), blk, 0, stream>>>(lm_w, lmT, NE, NV);

    // ---- embedding + LN1(0) ----
    embed_ln_kernel<<<NM, blk, 0, stream>>>(idx, tok, pos, ln1_g, ln1_b, x, hbuf);

    for (int l = 0; l < NL; ++l) {
        gemm_mfma<unsigned short, false, false, 1><<<dim3((NM/128)*(NQKV/128)), blk, 0, stream>>>(
            hbuf, wqkvT6 + (long)l * NQKV * NE, nullptr, qkv, NM / 128, NQKV, NE);
        vtrans_kernel<<<dim3(NT / 64, NB * NH), blk, 0, stream>>>(qkv, vt);
        fattn_kernel<<<dim3(NT / 128, NB * NH), dim3(512), 0, stream>>>(qkv, vt, att);
        gemm_mfma<float, false, false, 2><<<dim3((NM/128)*(NE/128), 2), blk, 0, stream>>>(
            att, weffT6 + (long)l * NE * NE, nullptr, parts, NM / 128, NE, NE);
        combine_ln_kernel<2><<<NM, blk, 0, stream>>>(
            parts, beff6 + (long)l * NE, x, ln2_g + (long)l * NE, ln2_b + (long)l * NE, hbuf);
        gemm_mfma<unsigned short, true, true, 1><<<dim3((NM/128)*(NFF/128)), blk, 0, stream>>>(
            hbuf, w1T6 + (long)l * NFF * NE, b1 + (long)l * NFF, hid, NM / 128, NFF, NE);
        gemm_mfma<float, false, false, 4><<<dim3((NM/128)*(NE/128), 4), blk, 0, stream>>>(
            hid, w2T6 + (long)l * NE * NFF, nullptr, parts, NM / 128, NE, NFF);
        const float* ng = (l < NL - 1) ? (ln1_g + (long)(l + 1) * NE) : lnf_g;
        const float* nb = (l < NL - 1) ? (ln1_b + (long)(l + 1) * NE) : lnf_b;
        combine_ln_kernel<4><<<NM, blk, 0, stream>>>(parts, b2 + (long)l * NE, x, ng, nb, hbuf);
    }

    // ---- LM head + fused LSE ----
    gemm256x128_lse<<<dim3((NM/256)*(NV/128)), dim3(512), 0, stream>>>(
        hbuf, lmT, lm_b, logits, pmb, psb, NM / 256, NV, NE);
    nll_combine_kernel<<<NM, blk, 0, stream>>>(logits, pmb, psb, targets, nll);
    loss_reduce_kernel<<<1, blk, 0, stream>>>(nll, loss);
}

// Round 13
// 1039.973 us; speedup vs baseline: 11.0311x; 1.0409x over previous
//
#include <hip/hip_runtime.h>
#include <math.h>

#define NL 6
#define NH 12
#define NE 768
#define NHS 64
#define NT 1024
#define NB 2
#define NV 32000
#define NM (NB * NT)   // 2048
#define NQKV (3 * NE)  // 2304
#define NFF (4 * NE)   // 3072
#define LN_EPS 1e-5f

typedef __attribute__((ext_vector_type(8))) short short8;
typedef __attribute__((ext_vector_type(4))) float f32x4;
typedef __attribute__((ext_vector_type(4))) unsigned short ushort4v;
typedef __attribute__((address_space(1))) const unsigned int as1_cuint;
typedef __attribute__((address_space(3))) unsigned int as3_uint;

__device__ __forceinline__ unsigned short f2bf(float f) {
    unsigned int u = __builtin_bit_cast(unsigned int, f);
    u += 0x7fffu + ((u >> 16) & 1u);   // RNE
    return (unsigned short)(u >> 16);
}
__device__ __forceinline__ float bf2f(unsigned short u) {
    unsigned int v = ((unsigned int)u) << 16;
    return __builtin_bit_cast(float, v);
}
__device__ __forceinline__ void gload_lds16(const void* g, void* l) {
    __builtin_amdgcn_global_load_lds((as1_cuint*)g, (as3_uint*)l, 16, 0, 0);
}

// ---------------- embedding + LN1(layer0) fused: one block per row ----------------
__global__ __launch_bounds__(256) void embed_ln_kernel(const int* __restrict__ idx,
                                                       const float* __restrict__ tok,
                                                       const float* __restrict__ pos,
                                                       const float* __restrict__ g,
                                                       const float* __restrict__ b,
                                                       float* __restrict__ x,
                                                       unsigned short* __restrict__ hbuf) {
    __shared__ float red[256];
    int row = blockIdx.x, tid = threadIdx.x;
    int t = row % NT;
    int id = idx[row];
    float v[3]; float s = 0.f;
    #pragma unroll
    for (int k = 0; k < 3; ++k) {
        int c = tid + k * 256;
        v[k] = tok[(long)id * NE + c] + pos[(long)t * NE + c];
        x[(long)row * NE + c] = v[k];
        s += v[k];
    }
    red[tid] = s; __syncthreads();
    for (int o = 128; o > 0; o >>= 1) { if (tid < o) red[tid] += red[tid + o]; __syncthreads(); }
    float mu = red[0] / NE;
    __syncthreads();
    float vr = 0.f;
    #pragma unroll
    for (int k = 0; k < 3; ++k) { float d = v[k] - mu; vr += d * d; }
    red[tid] = vr; __syncthreads();
    for (int o = 128; o > 0; o >>= 1) { if (tid < o) red[tid] += red[tid + o]; __syncthreads(); }
    float rstd = rsqrtf(red[0] / NE + LN_EPS);
    #pragma unroll
    for (int k = 0; k < 3; ++k) {
        int c = tid + k * 256;
        hbuf[(long)row * NE + c] = f2bf((v[k] - mu) * rstd * g[c] + b[c]);
    }
}

// ---------------- fused split-K combine + residual + LayerNorm ----------------
template<int S>
__global__ __launch_bounds__(256) void combine_ln_kernel(const float* __restrict__ parts,
                                                         const float* __restrict__ bias,
                                                         float* __restrict__ x,
                                                         const float* __restrict__ g,
                                                         const float* __restrict__ b,
                                                         unsigned short* __restrict__ hbuf) {
    __shared__ float red[256];
    int row = blockIdx.x, tid = threadIdx.x;
    float v[3]; float s = 0.f;
    #pragma unroll
    for (int k = 0; k < 3; ++k) {
        int c = tid + k * 256;
        long i = (long)row * NE + c;
        float a = parts[i];
        #pragma unroll
        for (int si = 1; si < S; ++si) a += parts[(long)si * NM * NE + i];
        a += bias[c] + x[i];
        x[i] = a;
        v[k] = a; s += a;
    }
    red[tid] = s; __syncthreads();
    for (int o = 128; o > 0; o >>= 1) { if (tid < o) red[tid] += red[tid + o]; __syncthreads(); }
    float mu = red[0] / NE;
    __syncthreads();
    float vr = 0.f;
    #pragma unroll
    for (int k = 0; k < 3; ++k) { float d = v[k] - mu; vr += d * d; }
    red[tid] = vr; __syncthreads();
    for (int o = 128; o > 0; o >>= 1) { if (tid < o) red[tid] += red[tid + o]; __syncthreads(); }
    float rstd = rsqrtf(red[0] / NE + LN_EPS);
    #pragma unroll
    for (int k = 0; k < 3; ++k) {
        int c = tid + k * 256;
        hbuf[(long)row * NE + c] = f2bf((v[k] - mu) * rstd * g[c] + b[c]);
    }
}

// ---------------- batched transpose of the four 768x768 weights (+ straight cast of wproj) ----------------
__global__ __launch_bounds__(256) void transpose4b_kernel(const float* __restrict__ wq,
                                                          const float* __restrict__ wk,
                                                          const float* __restrict__ wv,
                                                          const float* __restrict__ wp,
                                                          unsigned short* __restrict__ wqkvT,
                                                          unsigned short* __restrict__ wprojT,
                                                          unsigned short* __restrict__ wprojC) {
    __shared__ float t[32][33];
    int z = blockIdx.z, l = z >> 2, which = z & 3;
    const float* W = ((which == 0) ? wq : (which == 1) ? wk : (which == 2) ? wv : wp) + (long)l * NE * NE;
    unsigned short* WT = (which < 3) ? (wqkvT + (long)l * NQKV * NE + (long)which * NE * NE)
                                     : (wprojT + (long)l * NE * NE);
    int k0 = blockIdx.y * 32, n0 = blockIdx.x * 32;
    int c = threadIdx.x & 31, r = threadIdx.x >> 5;
    #pragma unroll
    for (int p = 0; p < 4; ++p)
        t[r + p * 8][c] = W[(long)(k0 + r + p * 8) * NE + n0 + c];
    __syncthreads();
    #pragma unroll
    for (int p = 0; p < 4; ++p)
        WT[(long)(n0 + r + p * 8) * NE + k0 + c] = f2bf(t[c][r + p * 8]);
    if (which == 3) {   // also emit non-transposed bf16 copy (B-operand for weff GEMM)
        unsigned short* WC = wprojC + (long)l * NE * NE;
        #pragma unroll
        for (int p = 0; p < 4; ++p)
            WC[(long)(k0 + r + p * 8) * NE + n0 + c] = f2bf(t[r + p * 8][c]);
    }
}

// ---------------- batched tiled transpose + cast: per-layer stride K*N ----------------
__global__ __launch_bounds__(256) void transpose_cast_b_kernel(const float* __restrict__ W0,
                                                               unsigned short* __restrict__ WT0,
                                                               int K, int N) {
    __shared__ float t[32][33];
    long lofs = (long)blockIdx.z * K * N;
    const float* W = W0 + lofs;
    unsigned short* WT = WT0 + lofs;
    int k0 = blockIdx.y * 32, n0 = blockIdx.x * 32;
    int c = threadIdx.x & 31, r = threadIdx.x >> 5;
    #pragma unroll
    for (int p = 0; p < 4; ++p)
        t[r + p * 8][c] = W[(long)(k0 + r + p * 8) * N + n0 + c];
    __syncthreads();
    #pragma unroll
    for (int p = 0; p < 4; ++p)
        WT[(long)(n0 + r + p * 8) * K + k0 + c] = f2bf(t[c][r + p * 8]);
}

// ---------------- batched beff ----------------
__global__ __launch_bounds__(256) void beff_b_kernel(const float* __restrict__ bproj,
                                                     const unsigned short* __restrict__ wprojT,
                                                     float* __restrict__ beff) {
    __shared__ float red[256];
    int n = blockIdx.x, l = blockIdx.y, tid = threadIdx.x;
    const unsigned short* wp = wprojT + (long)l * NE * NE + (long)n * NE;
    const float* bp = bproj + (long)l * NE;
    float acc = 0.f;
    for (int j = tid; j < NE; j += 256) acc += bp[j] * bf2f(wp[j]);
    red[tid] = acc; __syncthreads();
    for (int o = 128; o > 0; o >>= 1) { if (tid < o) red[tid] += red[tid + o]; __syncthreads(); }
    if (tid == 0) beff[(long)l * NE + n] = red[0] + bp[n];
}

// ---------------- 128x128 bf16 MFMA GEMM: 3-slot ring, depth-2 counted vmcnt ----------------
template<typename OutT, bool BIAS, bool RELU, int SPLITK>
__global__ __launch_bounds__(256) void gemm_mfma(const unsigned short* __restrict__ A,
                                                 const unsigned short* __restrict__ BT,
                                                 const float* __restrict__ bias,
                                                 OutT* __restrict__ C,
                                                 int gridM, int N, int K) {
    __shared__ unsigned short As[3][128 * 32];
    __shared__ unsigned short Bs[3][128 * 32];
    int tid = threadIdx.x;
    int lane = tid & 63, w = tid >> 6;
    int wr = w >> 1, wc = w & 1;
    int l4 = lane >> 4, l15 = lane & 15;

    int nwg = gridDim.x, orig = blockIdx.x;
    int q = nwg >> 3, r8 = nwg & 7;
    int xcd = orig & 7, ii = orig >> 3;
    int wg = (xcd < r8) ? (xcd * (q + 1) + ii) : (r8 * (q + 1) + (xcd - r8) * q + ii);
    int bm = wg % gridM, bn = wg / gridM;
    int m0 = bm * 128, n0 = bn * 128;

    int kb = K / SPLITK;
    int koff = (SPLITK > 1) ? blockIdx.y * kb : 0;
    int nkt = kb >> 5;

    f32x4 acc[4][4] = {};

    int srow = lane >> 2;
    int scol = ((lane & 3) ^ ((lane >> 3) & 3)) * 8;   // inverse-swizzled source slot
    int rsw  = (l4 ^ ((l15 >> 1) & 3)) * 8;            // swizzled read slot

    auto STAGE = [&](int slot, int kt) {   // 4 gload_lds per wave
        #pragma unroll
        for (int it = 0; it < 2; ++it) {
            int rr = w * 32 + it * 16;
            gload_lds16(&A [(long)(m0 + rr + srow) * K + koff + kt * 32 + scol], &As[slot][rr * 32]);
            gload_lds16(&BT[(long)(n0 + rr + srow) * K + koff + kt * 32 + scol], &Bs[slot][rr * 32]);
        }
    };

    STAGE(0, 0);
    if (nkt > 1) STAGE(1, 1);

    int s = 0;
    for (int t = 0; t < nkt; ++t) {
        if (t + 2 < nkt) STAGE((t + 2) % 3, t + 2);
        int ahead = nkt - 1 - t;
        if (ahead >= 2)      asm volatile("s_waitcnt vmcnt(8)" ::: "memory");
        else if (ahead == 1) asm volatile("s_waitcnt vmcnt(4)" ::: "memory");
        else                 asm volatile("s_waitcnt vmcnt(0)" ::: "memory");
        asm volatile("s_barrier" ::: "memory");        // slot s fully staged for all waves

        short8 a[4], b[4];
        #pragma unroll
        for (int f = 0; f < 4; ++f) {
            a[f] = *(const short8*)&As[s][(wr * 64 + f * 16 + l15) * 32 + rsw];
            b[f] = *(const short8*)&Bs[s][(wc * 64 + f * 16 + l15) * 32 + rsw];
        }
        asm volatile("s_waitcnt lgkmcnt(0)" ::: "memory");
        asm volatile("s_barrier" ::: "memory");        // all reads of slot s done -> restageable

        __builtin_amdgcn_s_setprio(1);
        #pragma unroll
        for (int fm = 0; fm < 4; ++fm)
            #pragma unroll
            for (int fn = 0; fn < 4; ++fn)
                acc[fm][fn] = __builtin_amdgcn_mfma_f32_16x16x32_bf16(a[fm], b[fn], acc[fm][fn], 0, 0, 0);
        __builtin_amdgcn_s_setprio(0);
        s = (s + 1) % 3;
    }

    if constexpr (SPLITK > 1) {
        float* Cp = (float*)C + (long)blockIdx.y * gridM * 128 * N;
        #pragma unroll
        for (int fm = 0; fm < 4; ++fm)
            #pragma unroll
            for (int j = 0; j < 4; ++j) {
                long row = m0 + wr * 64 + fm * 16 + l4 * 4 + j;
                #pragma unroll
                for (int fn = 0; fn < 4; ++fn)
                    Cp[row * N + n0 + wc * 64 + fn * 16 + l15] = acc[fm][fn][j];
            }
    } else {
        float bs[4];
        #pragma unroll
        for (int fn = 0; fn < 4; ++fn)
            bs[fn] = BIAS ? bias[n0 + wc * 64 + fn * 16 + l15] : 0.f;

        #pragma unroll
        for (int fm = 0; fm < 4; ++fm) {
            #pragma unroll
            for (int j = 0; j < 4; ++j) {
                long row = m0 + wr * 64 + fm * 16 + l4 * 4 + j;
                #pragma unroll
                for (int fn = 0; fn < 4; ++fn) {
                    int col = n0 + wc * 64 + fn * 16 + l15;
                    float v = acc[fm][fn][j] + bs[fn];
                    if (RELU) v = fmaxf(v, 0.f);
                    if constexpr (sizeof(OutT) == 2) C[row * N + col] = (OutT)f2bf(v);
                    else                             C[row * N + col] = v;
                }
            }
        }
    }
}

// ---------------- batched square bf16 GEMM (weff = Wp@Wp per layer), T2 swizzle ----------------
__global__ __launch_bounds__(256) void gemm_weff_kernel(const unsigned short* __restrict__ A0,
                                                        const unsigned short* __restrict__ B0,
                                                        unsigned short* __restrict__ C0,
                                                        int gridM, int N, int K) {
    __shared__ unsigned short As[2][128 * 32];
    __shared__ unsigned short Bs[2][128 * 32];
    long zofs = (long)blockIdx.z * N * K;
    const unsigned short* A = A0 + zofs;
    const unsigned short* BT = B0 + zofs;
    unsigned short* C = C0 + zofs;
    int tid = threadIdx.x;
    int lane = tid & 63, w = tid >> 6;
    int wr = w >> 1, wc = w & 1;
    int l4 = lane >> 4, l15 = lane & 15;
    int bm = blockIdx.x % gridM, bn = blockIdx.x / gridM;
    int m0 = bm * 128, n0 = bn * 128;

    f32x4 acc[4][4] = {};
    int srow = lane >> 2;
    int scol = ((lane & 3) ^ ((lane >> 3) & 3)) * 8;
    int rsw  = (l4 ^ ((l15 >> 1) & 3)) * 8;

    #pragma unroll
    for (int it = 0; it < 2; ++it) {
        int rr = w * 32 + it * 16;
        gload_lds16(&A [(long)(m0 + rr + srow) * K + scol], &As[0][rr * 32]);
        gload_lds16(&BT[(long)(n0 + rr + srow) * K + scol], &Bs[0][rr * 32]);
    }
    int cur = 0;
    for (int k0 = 0; k0 < K; k0 += 32) {
        __syncthreads();
        if (k0 + 32 < K) {
            #pragma unroll
            for (int it = 0; it < 2; ++it) {
                int rr = w * 32 + it * 16;
                gload_lds16(&A [(long)(m0 + rr + srow) * K + k0 + 32 + scol], &As[cur ^ 1][rr * 32]);
                gload_lds16(&BT[(long)(n0 + rr + srow) * K + k0 + 32 + scol], &Bs[cur ^ 1][rr * 32]);
            }
        }
        short8 a[4], b[4];
        #pragma unroll
        for (int f = 0; f < 4; ++f) {
            a[f] = *(const short8*)&As[cur][(wr * 64 + f * 16 + l15) * 32 + rsw];
            b[f] = *(const short8*)&Bs[cur][(wc * 64 + f * 16 + l15) * 32 + rsw];
        }
        #pragma unroll
        for (int fm = 0; fm < 4; ++fm)
            #pragma unroll
            for (int fn = 0; fn < 4; ++fn)
                acc[fm][fn] = __builtin_amdgcn_mfma_f32_16x16x32_bf16(a[fm], b[fn], acc[fm][fn], 0, 0, 0);
        cur ^= 1;
    }
    #pragma unroll
    for (int fm = 0; fm < 4; ++fm)
        #pragma unroll
        for (int j = 0; j < 4; ++j) {
            long row = m0 + wr * 64 + fm * 16 + l4 * 4 + j;
            #pragma unroll
            for (int fn = 0; fn < 4; ++fn)
                C[row * N + n0 + wc * 64 + fn * 16 + l15] = f2bf(acc[fm][fn][j]);
        }
}

// ---------------- LM head: 256x128 tile, 8 waves, 3-slot ring BK=32, depth-2 vmcnt, nt stores ----------------
// (Round-10 proven config: 72 KB LDS, 2 blocks/CU, occupancy ~38%, ~170 us)
__global__ __launch_bounds__(512, 4) void gemm256x128_lse(const unsigned short* __restrict__ A,
                                                          const unsigned short* __restrict__ BT,
                                                          const float* __restrict__ bias,
                                                          float* __restrict__ C,
                                                          float* __restrict__ pm, float* __restrict__ ps,
                                                          int gridM, int N, int K) {
    __shared__ unsigned short Al[3][256 * 32];   // 48 KB
    __shared__ unsigned short Bl[3][128 * 32];   // 24 KB
    int tid = threadIdx.x;
    int lane = tid & 63, w = tid >> 6;
    int wm = w >> 1, wn = w & 1;
    int l4 = lane >> 4, l15 = lane & 15;

    int nwg = gridDim.x, orig = blockIdx.x;
    int q = nwg >> 3, r8 = nwg & 7;
    int xcd = orig & 7, ii = orig >> 3;
    int wg = (xcd < r8) ? (xcd * (q + 1) + ii) : (r8 * (q + 1) + (xcd - r8) * q + ii);
    int bm = wg % gridM, bn = wg / gridM;
    int m0 = bm * 256, n0 = bn * 128;

    int nkt = K >> 5;
    int srow = lane >> 2;
    int sslot = ((lane & 3) ^ ((lane >> 3) & 3)) * 8;

    auto STAGE = [&](int slot, int kt) {       // 3 gload_lds per wave
        #pragma unroll
        for (int p = 0; p < 2; ++p) {
            int r0 = p * 128 + w * 16;
            gload_lds16(&A[(long)(m0 + r0 + srow) * K + kt * 32 + sslot], &Al[slot][r0 * 32]);
        }
        int r0 = w * 16;
        gload_lds16(&BT[(long)(n0 + r0 + srow) * K + kt * 32 + sslot], &Bl[slot][r0 * 32]);
    };

    f32x4 acc[4][4] = {};
    int rsw = (l4 ^ ((l15 >> 1) & 3)) * 8;

    STAGE(0, 0);
    STAGE(1, 1);
    int s = 0;
    for (int t = 0; t < nkt; ++t) {
        if (t + 2 < nkt) STAGE((t + 2) % 3, t + 2);
        int ahead = nkt - 1 - t;
        if (ahead >= 2)      asm volatile("s_waitcnt vmcnt(6)" ::: "memory");
        else if (ahead == 1) asm volatile("s_waitcnt vmcnt(3)" ::: "memory");
        else                 asm volatile("s_waitcnt vmcnt(0)" ::: "memory");
        asm volatile("s_barrier" ::: "memory");                // slot s staged for all waves

        short8 af[4], bf[4];
        #pragma unroll
        for (int f = 0; f < 4; ++f) {
            af[f] = *(const short8*)&Al[s][(wm * 64 + f * 16 + l15) * 32 + rsw];
            bf[f] = *(const short8*)&Bl[s][(wn * 64 + f * 16 + l15) * 32 + rsw];
        }
        asm volatile("s_waitcnt lgkmcnt(0)" ::: "memory");
        asm volatile("s_barrier" ::: "memory");                // all reads of slot s done

        __builtin_amdgcn_s_setprio(1);
        #pragma unroll
        for (int fm = 0; fm < 4; ++fm)
            #pragma unroll
            for (int fn = 0; fn < 4; ++fn)
                acc[fm][fn] = __builtin_amdgcn_mfma_f32_16x16x32_bf16(af[fm], bf[fn], acc[fm][fn], 0, 0, 0);
        __builtin_amdgcn_s_setprio(0);
        s = (s + 1) % 3;
    }

    float bs[4];
    #pragma unroll
    for (int fn = 0; fn < 4; ++fn)
        bs[fn] = bias[n0 + wn * 64 + fn * 16 + l15];

    #pragma unroll
    for (int fm = 0; fm < 4; ++fm) {
        #pragma unroll
        for (int j = 0; j < 4; ++j) {
            long row = m0 + wm * 64 + fm * 16 + l4 * 4 + j;
            float v4[4];
            #pragma unroll
            for (int fn = 0; fn < 4; ++fn) {
                int col = n0 + wn * 64 + fn * 16 + l15;
                float v = acc[fm][fn][j] + bs[fn];
                __builtin_nontemporal_store(v, &C[row * N + col]);   // logits: write-once stream
                v4[fn] = v;
            }
            float mx = fmaxf(fmaxf(v4[0], v4[1]), fmaxf(v4[2], v4[3]));
            #pragma unroll
            for (int off = 1; off < 16; off <<= 1) mx = fmaxf(mx, __shfl_xor(mx, off));
            float sm = 0.f;
            #pragma unroll
            for (int fn = 0; fn < 4; ++fn) sm += __expf(v4[fn] - mx);
            #pragma unroll
            for (int off = 1; off < 16; off <<= 1) sm += __shfl_xor(sm, off);
            if (l15 == 0) {
                int pidx = bn * 2 + wn;
                pm[row * 512 + pidx] = mx;
                ps[row * 512 + pidx] = sm;
            }
        }
    }
}

// ---------------- V transpose: vt[bh][d][t] = V[b][t][h][d] ----------------
__global__ __launch_bounds__(256) void vtrans_kernel(const unsigned short* __restrict__ qkv,
                                                     unsigned short* __restrict__ vt) {
    __shared__ unsigned short t[64][72];
    int t0 = blockIdx.x * 64;
    int bh = blockIdx.y;
    int b = bh / NH, h = bh % NH;
    int tid = threadIdx.x;
    #pragma unroll
    for (int i = 0; i < 2; ++i) {
        int r = (tid >> 3) + i * 32, c8 = (tid & 7) * 8;
        short8 v = *(const short8*)(qkv + ((long)b * NT + t0 + r) * NQKV + 2 * NE + h * NHS + c8);
        *(short8*)&t[r][c8] = v;
    }
    __syncthreads();
    #pragma unroll
    for (int i = 0; i < 2; ++i) {
        int d = (tid >> 3) + i * 32, s = (tid & 7) * 8;
        short8 o;
        #pragma unroll
        for (int j = 0; j < 8; ++j) o[j] = (short)t[s + j][d];
        *(short8*)(vt + ((long)bh * NHS + d) * NT + t0 + s) = o;
    }
}

// ---------------- flash attention, QBLK=128: wave-shared tile max, deferred lsum reduce ----------------
__global__ __launch_bounds__(512) void fattn_kernel(const unsigned short* __restrict__ qkv,
                                                    const unsigned short* __restrict__ vt,
                                                    unsigned short* __restrict__ out) {
    __shared__ unsigned short Ks[2][64 * 64];     // 16 KB
    __shared__ unsigned short Vl[2][64 * 64];     // 16 KB
    __shared__ unsigned short Ps[8 * 16 * 64];    // 16 KB
    int qt = gridDim.x - 1 - blockIdx.x;          // heavy q-tiles first
    int bh = blockIdx.y;
    int b = bh / NH, h = bh % NH;
    int tid = threadIdx.x, lane = tid & 63, w = tid >> 6;   // w = 0..7
    int l4 = lane >> 4, l15 = lane & 15;
    long rowb = (long)b * NT;
    const float scale = 0.03608439182435161f;     // 768^-0.5 (reference scales by E)
    const unsigned short* vtp = vt + (long)bh * NHS * NT;

    const unsigned short* qptr = qkv + (rowb + qt * 128 + w * 16 + l15) * NQKV + h * NHS;
    short8 qa0 = *(const short8*)(qptr + l4 * 8);
    short8 qa1 = *(const short8*)(qptr + 32 + l4 * 8);

    f32x4 o[4] = {};
    float m = -INFINITY;                          // wave-shared running max (uniform across lanes)
    float lsum[4] = {};                           // per-lane partial row sums (reduced at end)

    int kr_r = tid >> 3, kr_c = (tid & 7) * 8;    // K: row 0..63, col-chunk
    int vr_d = tid >> 3, vr_s = tid & 7;          // V^T: d 0..63, t-chunk

    short8 kr, vr;
    auto LOADT = [&](int t) {
        int kbase = t * 64;
        kr = *(const short8*)(qkv + (rowb + kbase + kr_r) * NQKV + NE + h * NHS + kr_c);
        vr = *(const short8*)(vtp + (long)vr_d * NT + kbase + vr_s * 8);
    };

    int ntiles = 2 * qt + 2;
    LOADT(0);
    for (int t = 0; t < ntiles; ++t) {
        int cur = t & 1;
        *(short8*)&Ks[cur][kr_r * 64 + (kr_c ^ ((kr_r & 7) << 3))] = kr;
        *(short8*)&Vl[cur][vr_d * 64 + ((vr_s * 8) ^ ((vr_d & 7) << 3))] = vr;
        asm volatile("s_waitcnt lgkmcnt(0)" ::: "memory");
        if (t + 1 < ntiles) LOADT(t + 1);         // overlap HBM with compute
        asm volatile("s_barrier" ::: "memory");

        f32x4 s[4];
        __builtin_amdgcn_s_setprio(1);
        #pragma unroll
        for (int fn = 0; fn < 4; ++fn) {
            int key = fn * 16 + l15;
            short8 kb0 = *(const short8*)&Ks[cur][key * 64 + ((l4 * 8) ^ ((key & 7) << 3))];
            short8 kb1 = *(const short8*)&Ks[cur][key * 64 + ((32 + l4 * 8) ^ ((key & 7) << 3))];
            f32x4 z = {};
            z = __builtin_amdgcn_mfma_f32_16x16x32_bf16(qa0, kb0, z, 0, 0, 0);
            s[fn] = __builtin_amdgcn_mfma_f32_16x16x32_bf16(qa1, kb1, z, 0, 0, 0);
        }
        __builtin_amdgcn_s_setprio(0);

        if (t >= 2 * qt) {                        // only last two tiles touch the diagonal
            #pragma unroll
            for (int fn = 0; fn < 4; ++fn) {
                int key = t * 64 + fn * 16 + l15;
                #pragma unroll
                for (int j = 0; j < 4; ++j) {
                    int qrow = qt * 128 + w * 16 + l4 * 4 + j;
                    s[fn][j] = (key <= qrow) ? s[fn][j] * scale : -1e30f;
                }
            }
        } else {
            #pragma unroll
            for (int fn = 0; fn < 4; ++fn)
                #pragma unroll
                for (int j = 0; j < 4; ++j)
                    s[fn][j] *= scale;
        }

        // ---- wave-shared tile max (shared offset cancels in softmax normalization) ----
        float tmax = -INFINITY;
        #pragma unroll
        for (int fn = 0; fn < 4; ++fn)
            #pragma unroll
            for (int j = 0; j < 4; ++j)
                tmax = fmaxf(tmax, s[fn][j]);
        #pragma unroll
        for (int off = 1; off < 64; off <<= 1) tmax = fmaxf(tmax, __shfl_xor(tmax, off));

        if (tmax > m) {                            // wave-uniform rescale (skipped when max stable)
            float alpha = __expf(m - tmax);
            m = tmax;
            #pragma unroll
            for (int j = 0; j < 4; ++j) lsum[j] *= alpha;
            #pragma unroll
            for (int fn = 0; fn < 4; ++fn)
                #pragma unroll
                for (int j = 0; j < 4; ++j) o[fn][j] *= alpha;
        }

        #pragma unroll
        for (int j = 0; j < 4; ++j) {
            float psum = 0.f;
            #pragma unroll
            for (int fn = 0; fn < 4; ++fn) {
                float p = __expf(s[fn][j] - m);
                psum += p;
                int rr = l4 * 4 + j, c = fn * 16 + l15;
                Ps[w * 1024 + rr * 64 + (c ^ ((rr & 7) << 3))] = f2bf(p);
            }
            lsum[j] += psum;                       // per-lane partial; cross-lane reduce deferred
        }

        short8 pa0 = *(const short8*)&Ps[w * 1024 + l15 * 64 + ((l4 * 8) ^ ((l15 & 7) << 3))];
        short8 pa1 = *(const short8*)&Ps[w * 1024 + l15 * 64 + ((32 + l4 * 8) ^ ((l15 & 7) << 3))];
        __builtin_amdgcn_s_setprio(1);
        #pragma unroll
        for (int fn = 0; fn < 4; ++fn) {
            int d = fn * 16 + l15;
            short8 vb0 = *(const short8*)&Vl[cur][d * 64 + ((l4 * 8) ^ ((d & 7) << 3))];
            short8 vb1 = *(const short8*)&Vl[cur][d * 64 + ((32 + l4 * 8) ^ ((d & 7) << 3))];
            o[fn] = __builtin_amdgcn_mfma_f32_16x16x32_bf16(pa0, vb0, o[fn], 0, 0, 0);
            o[fn] = __builtin_amdgcn_mfma_f32_16x16x32_bf16(pa1, vb1, o[fn], 0, 0, 0);
        }
        __builtin_amdgcn_s_setprio(0);
    }

    // final cross-lane lsum reduce (16-lane groups share a row)
    #pragma unroll
    for (int j = 0; j < 4; ++j)
        #pragma unroll
        for (int off = 1; off < 16; off <<= 1)
            lsum[j] += __shfl_xor(lsum[j], off);

    #pragma unroll
    for (int j = 0; j < 4; ++j) {
        long row = rowb + qt * 128 + w * 16 + l4 * 4 + j;
        float inv = 1.0f / lsum[j];
        #pragma unroll
        for (int fn = 0; fn < 4; ++fn)
            out[row * NE + h * NHS + fn * 16 + l15] = f2bf(o[fn][j] * inv);
    }
}

// ---------------- NLL from LM-head partials ----------------
__global__ __launch_bounds__(256) void nll_combine_kernel(const float* __restrict__ logits,
                                                          const float* __restrict__ pm,
                                                          const float* __restrict__ ps,
                                                          const int* __restrict__ targets,
                                                          float* __restrict__ nll) {
    __shared__ float rm[256], rs[256];
    int row = blockIdx.x, tid = threadIdx.x;
    float m = -1e30f, s = 0.f;
    for (int i = tid; i < 500; i += 256) {
        float m2 = pm[(long)row * 512 + i], s2 = ps[(long)row * 512 + i];
        float mm = fmaxf(m, m2);
        s = s * __expf(m - mm) + s2 * __expf(m2 - mm);
        m = mm;
    }
    rm[tid] = m; rs[tid] = s; __syncthreads();
    for (int o = 128; o > 0; o >>= 1) {
        if (tid < o) {
            float m2 = rm[tid + o], s2 = rs[tid + o];
            float mm = fmaxf(rm[tid], m2);
            rs[tid] = rs[tid] * __expf(rm[tid] - mm) + s2 * __expf(m2 - mm);
            rm[tid] = mm;
        }
        __syncthreads();
    }
    if (tid == 0) {
        int tgt = targets[row];
        nll[row] = -(logits[(long)row * NV + tgt] - rm[0] - logf(rs[0]));
    }
}

__global__ void loss_reduce_kernel(const float* __restrict__ nll, float* __restrict__ out) {
    __shared__ float red[256];
    int tid = threadIdx.x;
    float s = 0.f;
    for (int i = tid; i < NM; i += 256) s += nll[i];
    red[tid] = s; __syncthreads();
    for (int o = 128; o > 0; o >>= 1) { if (tid < o) red[tid] += red[tid + o]; __syncthreads(); }
    if (tid == 0) out[0] = red[0] / NM;
}

extern "C" void kernel_launch(void* const* d_in, const int* in_sizes, int n_in,
                              void* d_out, int out_size, void* d_ws, size_t ws_size,
                              hipStream_t stream) {
    const int*   idx     = (const int*)  d_in[0];
    const int*   targets = (const int*)  d_in[1];
    const float* tok     = (const float*)d_in[2];
    const float* pos     = (const float*)d_in[3];
    const float* ln1_g   = (const float*)d_in[4];
    const float* ln1_b   = (const float*)d_in[5];
    const float* wq      = (const float*)d_in[6];
    const float* wk      = (const float*)d_in[7];
    const float* wv      = (const float*)d_in[8];
    const float* wproj   = (const float*)d_in[9];
    const float* bproj   = (const float*)d_in[10];
    const float* ln2_g   = (const float*)d_in[11];
    const float* ln2_b   = (const float*)d_in[12];
    const float* w1      = (const float*)d_in[13];
    const float* b1      = (const float*)d_in[14];
    const float* w2      = (const float*)d_in[15];
    const float* b2      = (const float*)d_in[16];
    const float* lnf_g   = (const float*)d_in[17];
    const float* lnf_b   = (const float*)d_in[18];
    const float* lm_w    = (const float*)d_in[19];
    const float* lm_b    = (const float*)d_in[20];

    float* logits = (float*)d_out;
    float* loss   = logits + (long)NM * NV;

    char* p = (char*)d_ws;
    float*          x      = (float*)p;          p += (long)NM * NE * 4;
    unsigned short* hbuf   = (unsigned short*)p; p += (long)NM * NE * 2;
    unsigned short* qkv    = (unsigned short*)p; p += (long)NM * NQKV * 2;
    unsigned short* att    = (unsigned short*)p; p += (long)NM * NE * 2;
    unsigned short* hid    = (unsigned short*)p; p += (long)NM * NFF * 2;
    unsigned short* vt     = (unsigned short*)p; p += (long)NB * NH * NHS * NT * 2;
    float*          nll    = (float*)p;          p += (long)NM * 4;
    float*          pmb    = (float*)p;          p += (long)NM * 512 * 4;
    float*          psb    = (float*)p;          p += (long)NM * 512 * 4;
    float*          parts  = (float*)p;          p += (long)2 * NM * NQKV * 4;   // covers proj S=2 / FF2 S=4
    unsigned short* wqkvT6 = (unsigned short*)p; p += (long)NL * NQKV * NE * 2;
    unsigned short* wprojT6= (unsigned short*)p; p += (long)NL * NE * NE * 2;
    unsigned short* wprojC6= (unsigned short*)p; p += (long)NL * NE * NE * 2;
    unsigned short* weffT6 = (unsigned short*)p; p += (long)NL * NE * NE * 2;
    float*          beff6  = (float*)p;          p += (long)NL * NE * 4;
    unsigned short* w1T6   = (unsigned short*)p; p += (long)NL * NFF * NE * 2;
    unsigned short* w2T6   = (unsigned short*)p; p += (long)NL * NE * NFF * 2;
    unsigned short* lmT    = (unsigned short*)p; p += (long)NV * NE * 2;

    dim3 blk(256);

    // ---- batched weight prep ----
    transpose4b_kernel<<<dim3(NE / 32, NE / 32, 4 * NL), blk, 0, stream>>>(
        wq, wk, wv, wproj, wqkvT6, wprojT6, wprojC6);
    transpose_cast_b_kernel<<<dim3(NFF / 32, NE / 32, NL), blk, 0, stream>>>(w1, w1T6, NE, NFF);
    transpose_cast_b_kernel<<<dim3(NE / 32, NFF / 32, NL), blk, 0, stream>>>(w2, w2T6, NFF, NE);
    gemm_weff_kernel<<<dim3(36, 1, NL), blk, 0, stream>>>(wprojT6, wprojC6, weffT6, 6, NE, NE);
    beff_b_kernel<<<dim3(NE, NL), blk, 0, stream>>>(bproj, wprojT6, beff6);
    transpose_cast_b_kernel<<<dim3(NV / 32, NE / 32, 1), blk, 0, stream>>>(lm_w, lmT, NE, NV);

    // ---- embedding + LN1(0) ----
    embed_ln_kernel<<<NM, blk, 0, stream>>>(idx, tok, pos, ln1_g, ln1_b, x, hbuf);

    for (int l = 0; l < NL; ++l) {
        gemm_mfma<unsigned short, false, false, 1><<<dim3((NM/128)*(NQKV/128)), blk, 0, stream>>>(
            hbuf, wqkvT6 + (long)l * NQKV * NE, nullptr, qkv, NM / 128, NQKV, NE);
        vtrans_kernel<<<dim3(NT / 64, NB * NH), blk, 0, stream>>>(qkv, vt);
        fattn_kernel<<<dim3(NT / 128, NB * NH), dim3(512), 0, stream>>>(qkv, vt, att);
        gemm_mfma<float, false, false, 2><<<dim3((NM/128)*(NE/128), 2), blk, 0, stream>>>(
            att, weffT6 + (long)l * NE * NE, nullptr, parts, NM / 128, NE, NE);
        combine_ln_kernel<2><<<NM, blk, 0, stream>>>(
            parts, beff6 + (long)l * NE, x, ln2_g + (long)l * NE, ln2_b + (long)l * NE, hbuf);
        gemm_mfma<unsigned short, true, true, 1><<<dim3((NM/128)*(NFF/128)), blk, 0, stream>>>(
            hbuf, w1T6 + (long)l * NFF * NE, b1 + (long)l * NFF, hid, NM / 128, NFF, NE);
        gemm_mfma<float, false, false, 4><<<dim3((NM/128)*(NE/128), 4), blk, 0, stream>>>(
            hid, w2T6 + (long)l * NE * NFF, nullptr, parts, NM / 128, NE, NFF);
        const float* ng = (l < NL - 1) ? (ln1_g + (long)(l + 1) * NE) : lnf_g;
        const float* nb = (l < NL - 1) ? (ln1_b + (long)(l + 1) * NE) : lnf_b;
        combine_ln_kernel<4><<<NM, blk, 0, stream>>>(parts, b2 + (long)l * NE, x, ng, nb, hbuf);
    }

    // ---- LM head + fused LSE ----
    gemm256x128_lse<<<dim3((NM/256)*(NV/128)), dim3(512), 0, stream>>>(
        hbuf, lmT, lm_b, logits, pmb, psb, NM / 256, NV, NE);
    nll_combine_kernel<<<NM, blk, 0, stream>>>(logits, pmb, psb, targets, nll);
    loss_reduce_kernel<<<1, blk, 0, stream>>>(nll, loss);
}

// Round 14
// 1006.002 us; speedup vs baseline: 11.4036x; 1.0338x over previous
//
#include <hip/hip_runtime.h>
#include <math.h>

#define NL 6
#define NH 12
#define NE 768
#define NHS 64
#define NT 1024
#define NB 2
#define NV 32000
#define NM (NB * NT)   // 2048
#define NQKV (3 * NE)  // 2304
#define NFF (4 * NE)   // 3072
#define LN_EPS 1e-5f

typedef __attribute__((ext_vector_type(8))) short short8;
typedef __attribute__((ext_vector_type(4))) float f32x4;
typedef __attribute__((ext_vector_type(4))) unsigned short ushort4v;
typedef __attribute__((address_space(1))) const unsigned int as1_cuint;
typedef __attribute__((address_space(3))) unsigned int as3_uint;

__device__ __forceinline__ unsigned short f2bf(float f) {
    unsigned int u = __builtin_bit_cast(unsigned int, f);
    u += 0x7fffu + ((u >> 16) & 1u);   // RNE
    return (unsigned short)(u >> 16);
}
__device__ __forceinline__ float bf2f(unsigned short u) {
    unsigned int v = ((unsigned int)u) << 16;
    return __builtin_bit_cast(float, v);
}
__device__ __forceinline__ void gload_lds16(const void* g, void* l) {
    __builtin_amdgcn_global_load_lds((as1_cuint*)g, (as3_uint*)l, 16, 0, 0);
}

// ---------------- embedding + LN1(layer0) fused: one block per row ----------------
__global__ __launch_bounds__(256) void embed_ln_kernel(const int* __restrict__ idx,
                                                       const float* __restrict__ tok,
                                                       const float* __restrict__ pos,
                                                       const float* __restrict__ g,
                                                       const float* __restrict__ b,
                                                       float* __restrict__ x,
                                                       unsigned short* __restrict__ hbuf) {
    __shared__ float red[256];
    int row = blockIdx.x, tid = threadIdx.x;
    int t = row % NT;
    int id = idx[row];
    float v[3]; float s = 0.f;
    #pragma unroll
    for (int k = 0; k < 3; ++k) {
        int c = tid + k * 256;
        v[k] = tok[(long)id * NE + c] + pos[(long)t * NE + c];
        x[(long)row * NE + c] = v[k];
        s += v[k];
    }
    red[tid] = s; __syncthreads();
    for (int o = 128; o > 0; o >>= 1) { if (tid < o) red[tid] += red[tid + o]; __syncthreads(); }
    float mu = red[0] / NE;
    __syncthreads();
    float vr = 0.f;
    #pragma unroll
    for (int k = 0; k < 3; ++k) { float d = v[k] - mu; vr += d * d; }
    red[tid] = vr; __syncthreads();
    for (int o = 128; o > 0; o >>= 1) { if (tid < o) red[tid] += red[tid + o]; __syncthreads(); }
    float rstd = rsqrtf(red[0] / NE + LN_EPS);
    #pragma unroll
    for (int k = 0; k < 3; ++k) {
        int c = tid + k * 256;
        hbuf[(long)row * NE + c] = f2bf((v[k] - mu) * rstd * g[c] + b[c]);
    }
}

// ---------------- fused split-K combine (bf16 parts) + residual + LayerNorm ----------------
template<int S>
__global__ __launch_bounds__(256) void combine_ln_kernel(const unsigned short* __restrict__ parts,
                                                         const float* __restrict__ bias,
                                                         float* __restrict__ x,
                                                         const float* __restrict__ g,
                                                         const float* __restrict__ b,
                                                         unsigned short* __restrict__ hbuf) {
    __shared__ float red[256];
    int row = blockIdx.x, tid = threadIdx.x;
    float v[3]; float s = 0.f;
    #pragma unroll
    for (int k = 0; k < 3; ++k) {
        int c = tid + k * 256;
        long i = (long)row * NE + c;
        float a = bf2f(parts[i]);
        #pragma unroll
        for (int si = 1; si < S; ++si) a += bf2f(parts[(long)si * NM * NE + i]);
        a += bias[c] + x[i];
        x[i] = a;
        v[k] = a; s += a;
    }
    red[tid] = s; __syncthreads();
    for (int o = 128; o > 0; o >>= 1) { if (tid < o) red[tid] += red[tid + o]; __syncthreads(); }
    float mu = red[0] / NE;
    __syncthreads();
    float vr = 0.f;
    #pragma unroll
    for (int k = 0; k < 3; ++k) { float d = v[k] - mu; vr += d * d; }
    red[tid] = vr; __syncthreads();
    for (int o = 128; o > 0; o >>= 1) { if (tid < o) red[tid] += red[tid + o]; __syncthreads(); }
    float rstd = rsqrtf(red[0] / NE + LN_EPS);
    #pragma unroll
    for (int k = 0; k < 3; ++k) {
        int c = tid + k * 256;
        hbuf[(long)row * NE + c] = f2bf((v[k] - mu) * rstd * g[c] + b[c]);
    }
}

// ---------------- batched transpose of the four 768x768 weights (+ straight cast of wproj) ----------------
__global__ __launch_bounds__(256) void transpose4b_kernel(const float* __restrict__ wq,
                                                          const float* __restrict__ wk,
                                                          const float* __restrict__ wv,
                                                          const float* __restrict__ wp,
                                                          unsigned short* __restrict__ wqkvT,
                                                          unsigned short* __restrict__ wprojT,
                                                          unsigned short* __restrict__ wprojC) {
    __shared__ float t[32][33];
    int z = blockIdx.z, l = z >> 2, which = z & 3;
    const float* W = ((which == 0) ? wq : (which == 1) ? wk : (which == 2) ? wv : wp) + (long)l * NE * NE;
    unsigned short* WT = (which < 3) ? (wqkvT + (long)l * NQKV * NE + (long)which * NE * NE)
                                     : (wprojT + (long)l * NE * NE);
    int k0 = blockIdx.y * 32, n0 = blockIdx.x * 32;
    int c = threadIdx.x & 31, r = threadIdx.x >> 5;
    #pragma unroll
    for (int p = 0; p < 4; ++p)
        t[r + p * 8][c] = W[(long)(k0 + r + p * 8) * NE + n0 + c];
    __syncthreads();
    #pragma unroll
    for (int p = 0; p < 4; ++p)
        WT[(long)(n0 + r + p * 8) * NE + k0 + c] = f2bf(t[c][r + p * 8]);
    if (which == 3) {   // also emit non-transposed bf16 copy (B-operand for weff GEMM)
        unsigned short* WC = wprojC + (long)l * NE * NE;
        #pragma unroll
        for (int p = 0; p < 4; ++p)
            WC[(long)(k0 + r + p * 8) * NE + n0 + c] = f2bf(t[r + p * 8][c]);
    }
}

// ---------------- batched tiled transpose + cast: per-layer stride K*N ----------------
__global__ __launch_bounds__(256) void transpose_cast_b_kernel(const float* __restrict__ W0,
                                                               unsigned short* __restrict__ WT0,
                                                               int K, int N) {
    __shared__ float t[32][33];
    long lofs = (long)blockIdx.z * K * N;
    const float* W = W0 + lofs;
    unsigned short* WT = WT0 + lofs;
    int k0 = blockIdx.y * 32, n0 = blockIdx.x * 32;
    int c = threadIdx.x & 31, r = threadIdx.x >> 5;
    #pragma unroll
    for (int p = 0; p < 4; ++p)
        t[r + p * 8][c] = W[(long)(k0 + r + p * 8) * N + n0 + c];
    __syncthreads();
    #pragma unroll
    for (int p = 0; p < 4; ++p)
        WT[(long)(n0 + r + p * 8) * K + k0 + c] = f2bf(t[c][r + p * 8]);
}

// ---------------- batched beff ----------------
__global__ __launch_bounds__(256) void beff_b_kernel(const float* __restrict__ bproj,
                                                     const unsigned short* __restrict__ wprojT,
                                                     float* __restrict__ beff) {
    __shared__ float red[256];
    int n = blockIdx.x, l = blockIdx.y, tid = threadIdx.x;
    const unsigned short* wp = wprojT + (long)l * NE * NE + (long)n * NE;
    const float* bp = bproj + (long)l * NE;
    float acc = 0.f;
    for (int j = tid; j < NE; j += 256) acc += bp[j] * bf2f(wp[j]);
    red[tid] = acc; __syncthreads();
    for (int o = 128; o > 0; o >>= 1) { if (tid < o) red[tid] += red[tid + o]; __syncthreads(); }
    if (tid == 0) beff[(long)l * NE + n] = red[0] + bp[n];
}

// ---------------- 128x128 bf16 MFMA GEMM: 3-slot ring, depth-2 counted vmcnt ----------------
// SPLITK>1: writes bf16 partials. VTRANS: V-columns (>=2*NE) also emitted transposed to vt.
template<typename OutT, bool BIAS, bool RELU, int SPLITK, bool VTRANS>
__global__ __launch_bounds__(256) void gemm_mfma(const unsigned short* __restrict__ A,
                                                 const unsigned short* __restrict__ BT,
                                                 const float* __restrict__ bias,
                                                 OutT* __restrict__ C,
                                                 unsigned short* __restrict__ vt,
                                                 int gridM, int N, int K) {
    __shared__ unsigned short As[3][128 * 32];
    __shared__ unsigned short Bs[3][128 * 32];
    int tid = threadIdx.x;
    int lane = tid & 63, w = tid >> 6;
    int wr = w >> 1, wc = w & 1;
    int l4 = lane >> 4, l15 = lane & 15;

    int nwg = gridDim.x, orig = blockIdx.x;
    int q = nwg >> 3, r8 = nwg & 7;
    int xcd = orig & 7, ii = orig >> 3;
    int wg = (xcd < r8) ? (xcd * (q + 1) + ii) : (r8 * (q + 1) + (xcd - r8) * q + ii);
    int bm = wg % gridM, bn = wg / gridM;
    int m0 = bm * 128, n0 = bn * 128;

    int kb = K / SPLITK;
    int koff = (SPLITK > 1) ? blockIdx.y * kb : 0;
    int nkt = kb >> 5;

    f32x4 acc[4][4] = {};

    int srow = lane >> 2;
    int scol = ((lane & 3) ^ ((lane >> 3) & 3)) * 8;   // inverse-swizzled source slot
    int rsw  = (l4 ^ ((l15 >> 1) & 3)) * 8;            // swizzled read slot

    auto STAGE = [&](int slot, int kt) {   // 4 gload_lds per wave
        #pragma unroll
        for (int it = 0; it < 2; ++it) {
            int rr = w * 32 + it * 16;
            gload_lds16(&A [(long)(m0 + rr + srow) * K + koff + kt * 32 + scol], &As[slot][rr * 32]);
            gload_lds16(&BT[(long)(n0 + rr + srow) * K + koff + kt * 32 + scol], &Bs[slot][rr * 32]);
        }
    };

    STAGE(0, 0);
    if (nkt > 1) STAGE(1, 1);

    int s = 0;
    for (int t = 0; t < nkt; ++t) {
        if (t + 2 < nkt) STAGE((t + 2) % 3, t + 2);
        int ahead = nkt - 1 - t;
        if (ahead >= 2)      asm volatile("s_waitcnt vmcnt(8)" ::: "memory");
        else if (ahead == 1) asm volatile("s_waitcnt vmcnt(4)" ::: "memory");
        else                 asm volatile("s_waitcnt vmcnt(0)" ::: "memory");
        asm volatile("s_barrier" ::: "memory");        // slot s fully staged for all waves

        short8 a[4], b[4];
        #pragma unroll
        for (int f = 0; f < 4; ++f) {
            a[f] = *(const short8*)&As[s][(wr * 64 + f * 16 + l15) * 32 + rsw];
            b[f] = *(const short8*)&Bs[s][(wc * 64 + f * 16 + l15) * 32 + rsw];
        }
        asm volatile("s_waitcnt lgkmcnt(0)" ::: "memory");
        asm volatile("s_barrier" ::: "memory");        // all reads of slot s done -> restageable

        __builtin_amdgcn_s_setprio(1);
        #pragma unroll
        for (int fm = 0; fm < 4; ++fm)
            #pragma unroll
            for (int fn = 0; fn < 4; ++fn)
                acc[fm][fn] = __builtin_amdgcn_mfma_f32_16x16x32_bf16(a[fm], b[fn], acc[fm][fn], 0, 0, 0);
        __builtin_amdgcn_s_setprio(0);
        s = (s + 1) % 3;
    }

    if constexpr (SPLITK > 1) {
        unsigned short* Cp = (unsigned short*)C + (long)blockIdx.y * gridM * 128 * N;
        #pragma unroll
        for (int fm = 0; fm < 4; ++fm)
            #pragma unroll
            for (int j = 0; j < 4; ++j) {
                long row = m0 + wr * 64 + fm * 16 + l4 * 4 + j;
                #pragma unroll
                for (int fn = 0; fn < 4; ++fn)
                    Cp[row * N + n0 + wc * 64 + fn * 16 + l15] = f2bf(acc[fm][fn][j]);
            }
    } else {
        float bs[4];
        #pragma unroll
        for (int fn = 0; fn < 4; ++fn)
            bs[fn] = BIAS ? bias[n0 + wc * 64 + fn * 16 + l15] : 0.f;

        #pragma unroll
        for (int fm = 0; fm < 4; ++fm) {
            #pragma unroll
            for (int fn = 0; fn < 4; ++fn) {
                int col = n0 + wc * 64 + fn * 16 + l15;
                long t0 = m0 + wr * 64 + fm * 16 + l4 * 4;
                ushort4v pk;
                #pragma unroll
                for (int j = 0; j < 4; ++j) {
                    long row = t0 + j;
                    float v = acc[fm][fn][j] + bs[fn];
                    if (RELU) v = fmaxf(v, 0.f);
                    if constexpr (sizeof(OutT) == 2) { unsigned short h = f2bf(v); C[row * N + col] = (OutT)h; pk[j] = h; }
                    else                             C[row * N + col] = v;
                }
                if constexpr (VTRANS) {
                    if (col >= 2 * NE) {    // V region: emit vt[bh][d][t] transposed
                        int d = col - 2 * NE;               // h*64 + dd
                        int b = (int)(t0 >> 10);            // whole 128-row band is one batch
                        long vofs = ((long)(b * NH) * NHS + d) * NT + (t0 & 1023);
                        *(ushort4v*)&vt[vofs] = pk;
                    }
                }
            }
        }
    }
}

// ---------------- batched square bf16 GEMM (weff = Wp@Wp per layer), T2 swizzle ----------------
__global__ __launch_bounds__(256) void gemm_weff_kernel(const unsigned short* __restrict__ A0,
                                                        const unsigned short* __restrict__ B0,
                                                        unsigned short* __restrict__ C0,
                                                        int gridM, int N, int K) {
    __shared__ unsigned short As[2][128 * 32];
    __shared__ unsigned short Bs[2][128 * 32];
    long zofs = (long)blockIdx.z * N * K;
    const unsigned short* A = A0 + zofs;
    const unsigned short* BT = B0 + zofs;
    unsigned short* C = C0 + zofs;
    int tid = threadIdx.x;
    int lane = tid & 63, w = tid >> 6;
    int wr = w >> 1, wc = w & 1;
    int l4 = lane >> 4, l15 = lane & 15;
    int bm = blockIdx.x % gridM, bn = blockIdx.x / gridM;
    int m0 = bm * 128, n0 = bn * 128;

    f32x4 acc[4][4] = {};
    int srow = lane >> 2;
    int scol = ((lane & 3) ^ ((lane >> 3) & 3)) * 8;
    int rsw  = (l4 ^ ((l15 >> 1) & 3)) * 8;

    #pragma unroll
    for (int it = 0; it < 2; ++it) {
        int rr = w * 32 + it * 16;
        gload_lds16(&A [(long)(m0 + rr + srow) * K + scol], &As[0][rr * 32]);
        gload_lds16(&BT[(long)(n0 + rr + srow) * K + scol], &Bs[0][rr * 32]);
    }
    int cur = 0;
    for (int k0 = 0; k0 < K; k0 += 32) {
        __syncthreads();
        if (k0 + 32 < K) {
            #pragma unroll
            for (int it = 0; it < 2; ++it) {
                int rr = w * 32 + it * 16;
                gload_lds16(&A [(long)(m0 + rr + srow) * K + k0 + 32 + scol], &As[cur ^ 1][rr * 32]);
                gload_lds16(&BT[(long)(n0 + rr + srow) * K + k0 + 32 + scol], &Bs[cur ^ 1][rr * 32]);
            }
        }
        short8 a[4], b[4];
        #pragma unroll
        for (int f = 0; f < 4; ++f) {
            a[f] = *(const short8*)&As[cur][(wr * 64 + f * 16 + l15) * 32 + rsw];
            b[f] = *(const short8*)&Bs[cur][(wc * 64 + f * 16 + l15) * 32 + rsw];
        }
        #pragma unroll
        for (int fm = 0; fm < 4; ++fm)
            #pragma unroll
            for (int fn = 0; fn < 4; ++fn)
                acc[fm][fn] = __builtin_amdgcn_mfma_f32_16x16x32_bf16(a[fm], b[fn], acc[fm][fn], 0, 0, 0);
        cur ^= 1;
    }
    #pragma unroll
    for (int fm = 0; fm < 4; ++fm)
        #pragma unroll
        for (int j = 0; j < 4; ++j) {
            long row = m0 + wr * 64 + fm * 16 + l4 * 4 + j;
            #pragma unroll
            for (int fn = 0; fn < 4; ++fn)
                C[row * N + n0 + wc * 64 + fn * 16 + l15] = f2bf(acc[fm][fn][j]);
        }
}

// ---------------- LM head: 256x128 tile, 8 waves, 3-slot ring BK=32, depth-2 vmcnt, nt stores ----------------
__global__ __launch_bounds__(512, 4) void gemm256x128_lse(const unsigned short* __restrict__ A,
                                                          const unsigned short* __restrict__ BT,
                                                          const float* __restrict__ bias,
                                                          float* __restrict__ C,
                                                          float* __restrict__ pm, float* __restrict__ ps,
                                                          int gridM, int N, int K) {
    __shared__ unsigned short Al[3][256 * 32];   // 48 KB
    __shared__ unsigned short Bl[3][128 * 32];   // 24 KB
    int tid = threadIdx.x;
    int lane = tid & 63, w = tid >> 6;
    int wm = w >> 1, wn = w & 1;
    int l4 = lane >> 4, l15 = lane & 15;

    int nwg = gridDim.x, orig = blockIdx.x;
    int q = nwg >> 3, r8 = nwg & 7;
    int xcd = orig & 7, ii = orig >> 3;
    int wg = (xcd < r8) ? (xcd * (q + 1) + ii) : (r8 * (q + 1) + (xcd - r8) * q + ii);
    int bm = wg % gridM, bn = wg / gridM;
    int m0 = bm * 256, n0 = bn * 128;

    int nkt = K >> 5;
    int srow = lane >> 2;
    int sslot = ((lane & 3) ^ ((lane >> 3) & 3)) * 8;

    auto STAGE = [&](int slot, int kt) {       // 3 gload_lds per wave
        #pragma unroll
        for (int p = 0; p < 2; ++p) {
            int r0 = p * 128 + w * 16;
            gload_lds16(&A[(long)(m0 + r0 + srow) * K + kt * 32 + sslot], &Al[slot][r0 * 32]);
        }
        int r0 = w * 16;
        gload_lds16(&BT[(long)(n0 + r0 + srow) * K + kt * 32 + sslot], &Bl[slot][r0 * 32]);
    };

    f32x4 acc[4][4] = {};
    int rsw = (l4 ^ ((l15 >> 1) & 3)) * 8;

    STAGE(0, 0);
    STAGE(1, 1);
    int s = 0;
    for (int t = 0; t < nkt; ++t) {
        if (t + 2 < nkt) STAGE((t + 2) % 3, t + 2);
        int ahead = nkt - 1 - t;
        if (ahead >= 2)      asm volatile("s_waitcnt vmcnt(6)" ::: "memory");
        else if (ahead == 1) asm volatile("s_waitcnt vmcnt(3)" ::: "memory");
        else                 asm volatile("s_waitcnt vmcnt(0)" ::: "memory");
        asm volatile("s_barrier" ::: "memory");                // slot s staged for all waves

        short8 af[4], bf[4];
        #pragma unroll
        for (int f = 0; f < 4; ++f) {
            af[f] = *(const short8*)&Al[s][(wm * 64 + f * 16 + l15) * 32 + rsw];
            bf[f] = *(const short8*)&Bl[s][(wn * 64 + f * 16 + l15) * 32 + rsw];
        }
        asm volatile("s_waitcnt lgkmcnt(0)" ::: "memory");
        asm volatile("s_barrier" ::: "memory");                // all reads of slot s done

        __builtin_amdgcn_s_setprio(1);
        #pragma unroll
        for (int fm = 0; fm < 4; ++fm)
            #pragma unroll
            for (int fn = 0; fn < 4; ++fn)
                acc[fm][fn] = __builtin_amdgcn_mfma_f32_16x16x32_bf16(af[fm], bf[fn], acc[fm][fn], 0, 0, 0);
        __builtin_amdgcn_s_setprio(0);
        s = (s + 1) % 3;
    }

    float bs[4];
    #pragma unroll
    for (int fn = 0; fn < 4; ++fn)
        bs[fn] = bias[n0 + wn * 64 + fn * 16 + l15];

    #pragma unroll
    for (int fm = 0; fm < 4; ++fm) {
        #pragma unroll
        for (int j = 0; j < 4; ++j) {
            long row = m0 + wm * 64 + fm * 16 + l4 * 4 + j;
            float v4[4];
            #pragma unroll
            for (int fn = 0; fn < 4; ++fn) {
                int col = n0 + wn * 64 + fn * 16 + l15;
                float v = acc[fm][fn][j] + bs[fn];
                __builtin_nontemporal_store(v, &C[row * N + col]);   // logits: write-once stream
                v4[fn] = v;
            }
            float mx = fmaxf(fmaxf(v4[0], v4[1]), fmaxf(v4[2], v4[3]));
            #pragma unroll
            for (int off = 1; off < 16; off <<= 1) mx = fmaxf(mx, __shfl_xor(mx, off));
            float sm = 0.f;
            #pragma unroll
            for (int fn = 0; fn < 4; ++fn) sm += __expf(v4[fn] - mx);
            #pragma unroll
            for (int off = 1; off < 16; off <<= 1) sm += __shfl_xor(sm, off);
            if (l15 == 0) {
                int pidx = bn * 2 + wn;
                pm[row * 512 + pidx] = mx;
                ps[row * 512 + pidx] = sm;
            }
        }
    }
}

// ---------------- flash attention, QBLK=128: wave-shared tile max, deferred lsum reduce ----------------
__global__ __launch_bounds__(512) void fattn_kernel(const unsigned short* __restrict__ qkv,
                                                    const unsigned short* __restrict__ vt,
                                                    unsigned short* __restrict__ out) {
    __shared__ unsigned short Ks[2][64 * 64];     // 16 KB
    __shared__ unsigned short Vl[2][64 * 64];     // 16 KB
    __shared__ unsigned short Ps[8 * 16 * 64];    // 16 KB
    int qt = gridDim.x - 1 - blockIdx.x;          // heavy q-tiles first
    int bh = blockIdx.y;
    int b = bh / NH, h = bh % NH;
    int tid = threadIdx.x, lane = tid & 63, w = tid >> 6;   // w = 0..7
    int l4 = lane >> 4, l15 = lane & 15;
    long rowb = (long)b * NT;
    const float scale = 0.03608439182435161f;     // 768^-0.5 (reference scales by E)
    const unsigned short* vtp = vt + (long)bh * NHS * NT;

    const unsigned short* qptr = qkv + (rowb + qt * 128 + w * 16 + l15) * NQKV + h * NHS;
    short8 qa0 = *(const short8*)(qptr + l4 * 8);
    short8 qa1 = *(const short8*)(qptr + 32 + l4 * 8);

    f32x4 o[4] = {};
    float m = -INFINITY;                          // wave-shared running max
    float lsum[4] = {};                           // per-lane partials (reduced at end)

    int kr_r = tid >> 3, kr_c = (tid & 7) * 8;
    int vr_d = tid >> 3, vr_s = tid & 7;

    short8 kr, vr;
    auto LOADT = [&](int t) {
        int kbase = t * 64;
        kr = *(const short8*)(qkv + (rowb + kbase + kr_r) * NQKV + NE + h * NHS + kr_c);
        vr = *(const short8*)(vtp + (long)vr_d * NT + kbase + vr_s * 8);
    };

    int ntiles = 2 * qt + 2;
    LOADT(0);
    for (int t = 0; t < ntiles; ++t) {
        int cur = t & 1;
        *(short8*)&Ks[cur][kr_r * 64 + (kr_c ^ ((kr_r & 7) << 3))] = kr;
        *(short8*)&Vl[cur][vr_d * 64 + ((vr_s * 8) ^ ((vr_d & 7) << 3))] = vr;
        asm volatile("s_waitcnt lgkmcnt(0)" ::: "memory");
        if (t + 1 < ntiles) LOADT(t + 1);
        asm volatile("s_barrier" ::: "memory");

        f32x4 s[4];
        __builtin_amdgcn_s_setprio(1);
        #pragma unroll
        for (int fn = 0; fn < 4; ++fn) {
            int key = fn * 16 + l15;
            short8 kb0 = *(const short8*)&Ks[cur][key * 64 + ((l4 * 8) ^ ((key & 7) << 3))];
            short8 kb1 = *(const short8*)&Ks[cur][key * 64 + ((32 + l4 * 8) ^ ((key & 7) << 3))];
            f32x4 z = {};
            z = __builtin_amdgcn_mfma_f32_16x16x32_bf16(qa0, kb0, z, 0, 0, 0);
            s[fn] = __builtin_amdgcn_mfma_f32_16x16x32_bf16(qa1, kb1, z, 0, 0, 0);
        }
        __builtin_amdgcn_s_setprio(0);

        if (t >= 2 * qt) {
            #pragma unroll
            for (int fn = 0; fn < 4; ++fn) {
                int key = t * 64 + fn * 16 + l15;
                #pragma unroll
                for (int j = 0; j < 4; ++j) {
                    int qrow = qt * 128 + w * 16 + l4 * 4 + j;
                    s[fn][j] = (key <= qrow) ? s[fn][j] * scale : -1e30f;
                }
            }
        } else {
            #pragma unroll
            for (int fn = 0; fn < 4; ++fn)
                #pragma unroll
                for (int j = 0; j < 4; ++j)
                    s[fn][j] *= scale;
        }

        float tmax = -INFINITY;
        #pragma unroll
        for (int fn = 0; fn < 4; ++fn)
            #pragma unroll
            for (int j = 0; j < 4; ++j)
                tmax = fmaxf(tmax, s[fn][j]);
        #pragma unroll
        for (int off = 1; off < 64; off <<= 1) tmax = fmaxf(tmax, __shfl_xor(tmax, off));

        if (tmax > m) {
            float alpha = __expf(m - tmax);
            m = tmax;
            #pragma unroll
            for (int j = 0; j < 4; ++j) lsum[j] *= alpha;
            #pragma unroll
            for (int fn = 0; fn < 4; ++fn)
                #pragma unroll
                for (int j = 0; j < 4; ++j) o[fn][j] *= alpha;
        }

        #pragma unroll
        for (int j = 0; j < 4; ++j) {
            float psum = 0.f;
            #pragma unroll
            for (int fn = 0; fn < 4; ++fn) {
                float p = __expf(s[fn][j] - m);
                psum += p;
                int rr = l4 * 4 + j, c = fn * 16 + l15;
                Ps[w * 1024 + rr * 64 + (c ^ ((rr & 7) << 3))] = f2bf(p);
            }
            lsum[j] += psum;
        }

        short8 pa0 = *(const short8*)&Ps[w * 1024 + l15 * 64 + ((l4 * 8) ^ ((l15 & 7) << 3))];
        short8 pa1 = *(const short8*)&Ps[w * 1024 + l15 * 64 + ((32 + l4 * 8) ^ ((l15 & 7) << 3))];
        __builtin_amdgcn_s_setprio(1);
        #pragma unroll
        for (int fn = 0; fn < 4; ++fn) {
            int d = fn * 16 + l15;
            short8 vb0 = *(const short8*)&Vl[cur][d * 64 + ((l4 * 8) ^ ((d & 7) << 3))];
            short8 vb1 = *(const short8*)&Vl[cur][d * 64 + ((32 + l4 * 8) ^ ((d & 7) << 3))];
            o[fn] = __builtin_amdgcn_mfma_f32_16x16x32_bf16(pa0, vb0, o[fn], 0, 0, 0);
            o[fn] = __builtin_amdgcn_mfma_f32_16x16x32_bf16(pa1, vb1, o[fn], 0, 0, 0);
        }
        __builtin_amdgcn_s_setprio(0);
    }

    #pragma unroll
    for (int j = 0; j < 4; ++j)
        #pragma unroll
        for (int off = 1; off < 16; off <<= 1)
            lsum[j] += __shfl_xor(lsum[j], off);

    #pragma unroll
    for (int j = 0; j < 4; ++j) {
        long row = rowb + qt * 128 + w * 16 + l4 * 4 + j;
        float inv = 1.0f / lsum[j];
        #pragma unroll
        for (int fn = 0; fn < 4; ++fn)
            out[row * NE + h * NHS + fn * 16 + l15] = f2bf(o[fn][j] * inv);
    }
}

// ---------------- NLL from LM-head partials ----------------
__global__ __launch_bounds__(256) void nll_combine_kernel(const float* __restrict__ logits,
                                                          const float* __restrict__ pm,
                                                          const float* __restrict__ ps,
                                                          const int* __restrict__ targets,
                                                          float* __restrict__ nll) {
    __shared__ float rm[256], rs[256];
    int row = blockIdx.x, tid = threadIdx.x;
    float m = -1e30f, s = 0.f;
    for (int i = tid; i < 500; i += 256) {
        float m2 = pm[(long)row * 512 + i], s2 = ps[(long)row * 512 + i];
        float mm = fmaxf(m, m2);
        s = s * __expf(m - mm) + s2 * __expf(m2 - mm);
        m = mm;
    }
    rm[tid] = m; rs[tid] = s; __syncthreads();
    for (int o = 128; o > 0; o >>= 1) {
        if (tid < o) {
            float m2 = rm[tid + o], s2 = rs[tid + o];
            float mm = fmaxf(rm[tid], m2);
            rs[tid] = rs[tid] * __expf(rm[tid] - mm) + s2 * __expf(m2 - mm);
            rm[tid] = mm;
        }
        __syncthreads();
    }
    if (tid == 0) {
        int tgt = targets[row];
        nll[row] = -(logits[(long)row * NV + tgt] - rm[0] - logf(rs[0]));
    }
}

__global__ void loss_reduce_kernel(const float* __restrict__ nll, float* __restrict__ out) {
    __shared__ float red[256];
    int tid = threadIdx.x;
    float s = 0.f;
    for (int i = tid; i < NM; i += 256) s += nll[i];
    red[tid] = s; __syncthreads();
    for (int o = 128; o > 0; o >>= 1) { if (tid < o) red[tid] += red[tid + o]; __syncthreads(); }
    if (tid == 0) out[0] = red[0] / NM;
}

extern "C" void kernel_launch(void* const* d_in, const int* in_sizes, int n_in,
                              void* d_out, int out_size, void* d_ws, size_t ws_size,
                              hipStream_t stream) {
    const int*   idx     = (const int*)  d_in[0];
    const int*   targets = (const int*)  d_in[1];
    const float* tok     = (const float*)d_in[2];
    const float* pos     = (const float*)d_in[3];
    const float* ln1_g   = (const float*)d_in[4];
    const float* ln1_b   = (const float*)d_in[5];
    const float* wq      = (const float*)d_in[6];
    const float* wk      = (const float*)d_in[7];
    const float* wv      = (const float*)d_in[8];
    const float* wproj   = (const float*)d_in[9];
    const float* bproj   = (const float*)d_in[10];
    const float* ln2_g   = (const float*)d_in[11];
    const float* ln2_b   = (const float*)d_in[12];
    const float* w1      = (const float*)d_in[13];
    const float* b1      = (const float*)d_in[14];
    const float* w2      = (const float*)d_in[15];
    const float* b2      = (const float*)d_in[16];
    const float* lnf_g   = (const float*)d_in[17];
    const float* lnf_b   = (const float*)d_in[18];
    const float* lm_w    = (const float*)d_in[19];
    const float* lm_b    = (const float*)d_in[20];

    float* logits = (float*)d_out;
    float* loss   = logits + (long)NM * NV;

    char* p = (char*)d_ws;
    float*          x      = (float*)p;          p += (long)NM * NE * 4;
    unsigned short* hbuf   = (unsigned short*)p; p += (long)NM * NE * 2;
    unsigned short* qkv    = (unsigned short*)p; p += (long)NM * NQKV * 2;
    unsigned short* att    = (unsigned short*)p; p += (long)NM * NE * 2;
    unsigned short* hid    = (unsigned short*)p; p += (long)NM * NFF * 2;
    unsigned short* vt     = (unsigned short*)p; p += (long)NB * NH * NHS * NT * 2;
    float*          nll    = (float*)p;          p += (long)NM * 4;
    float*          pmb    = (float*)p;          p += (long)NM * 512 * 4;
    float*          psb    = (float*)p;          p += (long)NM * 512 * 4;
    unsigned short* parts  = (unsigned short*)p; p += (long)4 * NM * NE * 2;   // bf16 split-K partials
    unsigned short* wqkvT6 = (unsigned short*)p; p += (long)NL * NQKV * NE * 2;
    unsigned short* wprojT6= (unsigned short*)p; p += (long)NL * NE * NE * 2;
    unsigned short* wprojC6= (unsigned short*)p; p += (long)NL * NE * NE * 2;
    unsigned short* weffT6 = (unsigned short*)p; p += (long)NL * NE * NE * 2;
    float*          beff6  = (float*)p;          p += (long)NL * NE * 4;
    unsigned short* w1T6   = (unsigned short*)p; p += (long)NL * NFF * NE * 2;
    unsigned short* w2T6   = (unsigned short*)p; p += (long)NL * NE * NFF * 2;
    unsigned short* lmT    = (unsigned short*)p; p += (long)NV * NE * 2;

    dim3 blk(256);

    // ---- batched weight prep ----
    transpose4b_kernel<<<dim3(NE / 32, NE / 32, 4 * NL), blk, 0, stream>>>(
        wq, wk, wv, wproj, wqkvT6, wprojT6, wprojC6);
    transpose_cast_b_kernel<<<dim3(NFF / 32, NE / 32, NL), blk, 0, stream>>>(w1, w1T6, NE, NFF);
    transpose_cast_b_kernel<<<dim3(NE / 32, NFF / 32, NL), blk, 0, stream>>>(w2, w2T6, NFF, NE);
    gemm_weff_kernel<<<dim3(36, 1, NL), blk, 0, stream>>>(wprojT6, wprojC6, weffT6, 6, NE, NE);
    beff_b_kernel<<<dim3(NE, NL), blk, 0, stream>>>(bproj, wprojT6, beff6);
    transpose_cast_b_kernel<<<dim3(NV / 32, NE / 32, 1), blk, 0, stream>>>(lm_w, lmT, NE, NV);

    // ---- embedding + LN1(0) ----
    embed_ln_kernel<<<NM, blk, 0, stream>>>(idx, tok, pos, ln1_g, ln1_b, x, hbuf);

    for (int l = 0; l < NL; ++l) {
        // QKV: direct bf16 output + fused V-transpose epilogue
        gemm_mfma<unsigned short, false, false, 1, true><<<dim3((NM/128)*(NQKV/128)), blk, 0, stream>>>(
            hbuf, wqkvT6 + (long)l * NQKV * NE, nullptr, qkv, vt, NM / 128, NQKV, NE);
        fattn_kernel<<<dim3(NT / 128, NB * NH), dim3(512), 0, stream>>>(qkv, vt, att);
        gemm_mfma<unsigned short, false, false, 2, false><<<dim3((NM/128)*(NE/128), 2), blk, 0, stream>>>(
            att, weffT6 + (long)l * NE * NE, nullptr, parts, nullptr, NM / 128, NE, NE);
        combine_ln_kernel<2><<<NM, blk, 0, stream>>>(
            parts, beff6 + (long)l * NE, x, ln2_g + (long)l * NE, ln2_b + (long)l * NE, hbuf);
        gemm_mfma<unsigned short, true, true, 1, false><<<dim3((NM/128)*(NFF/128)), blk, 0, stream>>>(
            hbuf, w1T6 + (long)l * NFF * NE, b1 + (long)l * NFF, hid, nullptr, NM / 128, NFF, NE);
        gemm_mfma<unsigned short, false, false, 4, false><<<dim3((NM/128)*(NE/128), 4), blk, 0, stream>>>(
            hid, w2T6 + (long)l * NE * NFF, nullptr, parts, nullptr, NM / 128, NE, NFF);
        const float* ng = (l < NL - 1) ? (ln1_g + (long)(l + 1) * NE) : lnf_g;
        const float* nb = (l < NL - 1) ? (ln1_b + (long)(l + 1) * NE) : lnf_b;
        combine_ln_kernel<4><<<NM, blk, 0, stream>>>(parts, b2 + (long)l * NE, x, ng, nb, hbuf);
    }

    // ---- LM head + fused LSE ----
    gemm256x128_lse<<<dim3((NM/256)*(NV/128)), dim3(512), 0, stream>>>(
        hbuf, lmT, lm_b, logits, pmb, psb, NM / 256, NV, NE);
    nll_combine_kernel<<<NM, blk, 0, stream>>>(logits, pmb, psb, targets, nll);
    loss_reduce_kernel<<<1, blk, 0, stream>>>(nll, loss);
}